// Round 10
// baseline (534.186 us; speedup 1.0000x reference)
//
#include <hip/hip_runtime.h>
#include <math.h>

typedef unsigned int u32;
typedef unsigned short ushort_t;
typedef __attribute__((ext_vector_type(8))) short short8;
typedef __attribute__((ext_vector_type(4))) float f32x4;

__device__ __forceinline__ ushort_t f2bf(float x) {
  u32 u = __float_as_uint(x);
  u32 r = (u + 0x7fffu + ((u >> 16) & 1u)) >> 16;
  return (ushort_t)r;
}
__device__ __forceinline__ float bf2f(u32 s) {
  return __uint_as_float(s << 16);
}
__device__ __forceinline__ void ld4bf(const ushort_t* p, float* o) {
  uint2 u = *(const uint2*)p;
  o[0] = bf2f(u.x & 0xffffu); o[1] = bf2f(u.x >> 16);
  o[2] = bf2f(u.y & 0xffffu); o[3] = bf2f(u.y >> 16);
}

// ---------------- block reduction helpers (256 threads = 4 waves) ----------
__device__ __forceinline__ float block_sum256(float v, float* red) {
  #pragma unroll
  for (int o = 32; o > 0; o >>= 1) v += __shfl_down(v, o, 64);
  __syncthreads();
  if ((threadIdx.x & 63) == 0) red[threadIdx.x >> 6] = v;
  __syncthreads();
  return red[0] + red[1] + red[2] + red[3];
}

// =====================================================================
// Fused attention layer 1 (flash-style, max-free softmax).
// Per block: one head (blockIdx.y), 64 q-rows (blockIdx.x*64).
// Loops 64 KV-tiles of 64 nodes: S=QK^T (MFMA, direct-global frags),
// exp2 in-register, P via per-wave-private LDS (no barriers), O += P.V.
// End: row-normalize O by accumulated row-sums, scatter-store f32.
// qk: [4096,512] node-major (q cols h*64, k cols 256+h*64, zero-padded 50->64)
// v:  [512,4096] feature-major (rows h*128+f, f>=50 zero)
// o1p:[512,4096] f32 feature-major, normalized attention output.
// =====================================================================
__global__ __launch_bounds__(256) void fused_attn1(
    const ushort_t* __restrict__ qk, const ushort_t* __restrict__ v,
    float* __restrict__ o1p, float scale)
{
  __shared__ ushort_t Pl[64][72];            // 144B row stride (bank-spread)
  const int t = threadIdx.x;
  const int lane = t & 63;
  const int wv = t >> 6;                     // wave owns q rows wv*16..+15
  const int h = blockIdx.y;
  const int m0 = blockIdx.x * 64;
  const int lr = lane & 15;
  const int hk = lane >> 4;                  // 8-elem k-chunk 0..3

  // A-frags for S (constant over KV loop): q rows m0+wv*16+lr
  short8 aq0, aq1;
  {
    const ushort_t* qrow = qk + (size_t)(m0 + wv * 16 + lr) * 512 + h * 64;
    aq0 = *(const short8*)(qrow + hk * 8);
    aq1 = *(const short8*)(qrow + 32 + hk * 8);
  }

  f32x4 oAcc[4];
  #pragma unroll
  for (int i = 0; i < 4; ++i) oAcc[i] = (f32x4){0.f, 0.f, 0.f, 0.f};
  float racc[4] = {0.f, 0.f, 0.f, 0.f};

  const size_t kbase = (size_t)256 + h * 64;

  for (int kt = 0; kt < 64; ++kt) {
    const int n0 = kt * 64;
    // ---- S-tile [16q x 64n] per wave
    f32x4 sA[4];
    #pragma unroll
    for (int nf = 0; nf < 4; ++nf) {
      const ushort_t* krow = qk + (size_t)(n0 + nf * 16 + lr) * 512 + kbase;
      short8 b0 = *(const short8*)(krow + hk * 8);
      short8 b1 = *(const short8*)(krow + 32 + hk * 8);
      f32x4 sa = (f32x4){0.f, 0.f, 0.f, 0.f};
      sa = __builtin_amdgcn_mfma_f32_16x16x32_bf16(aq0, b0, sa, 0, 0, 0);
      sa = __builtin_amdgcn_mfma_f32_16x16x32_bf16(aq1, b1, sa, 0, 0, 0);
      sA[nf] = sa;
    }
    // ---- exp2 + rowsum + P->LDS (per-wave-private rows, no barrier)
    #pragma unroll
    for (int nf = 0; nf < 4; ++nf) {
      #pragma unroll
      for (int r = 0; r < 4; ++r) {
        float e = exp2f(sA[nf][r] * scale);
        racc[r] += e;
        Pl[wv * 16 + hk * 4 + r][nf * 16 + lr] = f2bf(e);
      }
    }
    // ---- PV: O[16q x 64f] += P[16q x 64n] . V[64n x 64f]
    short8 ap0 = *(const short8*)&Pl[wv * 16 + lr][hk * 8];
    short8 ap1 = *(const short8*)&Pl[wv * 16 + lr][32 + hk * 8];
    #pragma unroll
    for (int ff = 0; ff < 4; ++ff) {
      const ushort_t* vrow = v + (size_t)(h * 128 + ff * 16 + lr) * 4096 + n0;
      short8 b0 = *(const short8*)(vrow + hk * 8);
      short8 b1 = *(const short8*)(vrow + 32 + hk * 8);
      oAcc[ff] = __builtin_amdgcn_mfma_f32_16x16x32_bf16(ap0, b0, oAcc[ff], 0, 0, 0);
      oAcc[ff] = __builtin_amdgcn_mfma_f32_16x16x32_bf16(ap1, b1, oAcc[ff], 0, 0, 0);
    }
  }

  // ---- full row-sums: reduce across the 16 col-lanes
  #pragma unroll
  for (int r = 0; r < 4; ++r) {
    racc[r] += __shfl_xor(racc[r], 1);
    racc[r] += __shfl_xor(racc[r], 2);
    racc[r] += __shfl_xor(racc[r], 4);
    racc[r] += __shfl_xor(racc[r], 8);
  }
  // ---- normalize + store (f32, feature-major scatter)
  #pragma unroll
  for (int ff = 0; ff < 4; ++ff) {
    const size_t fbase = (size_t)(h * 128 + ff * 16 + lr) * 4096;
    #pragma unroll
    for (int r = 0; r < 4; ++r) {
      const int q = m0 + wv * 16 + hk * 4 + r;
      o1p[fbase + q] = oAcc[ff][r] / racc[r];
    }
  }
}

// =====================================================================
// 256x256-tile, 8-phase, counted-vmcnt MFMA GEMM. LONG-K only (R7 lesson).
// =====================================================================
#define RD_A(bb, mm, cc) (*(const short8*)(lsAc + (bb)*32768 + arow + (mm)*2048 + (cc)))
#define RD_B(bb, nn, cc) (*(const short8*)(lsBc + (bb)*32768 + brow + (nn)*2048 + (cc)))

#define MM8(nn, bv) { \
  acc[0][nn] = __builtin_amdgcn_mfma_f32_16x16x32_bf16(a0, bv, acc[0][nn], 0,0,0); \
  acc[1][nn] = __builtin_amdgcn_mfma_f32_16x16x32_bf16(a1, bv, acc[1][nn], 0,0,0); \
  acc[2][nn] = __builtin_amdgcn_mfma_f32_16x16x32_bf16(a2, bv, acc[2][nn], 0,0,0); \
  acc[3][nn] = __builtin_amdgcn_mfma_f32_16x16x32_bf16(a3, bv, acc[3][nn], 0,0,0); \
  acc[4][nn] = __builtin_amdgcn_mfma_f32_16x16x32_bf16(a4, bv, acc[4][nn], 0,0,0); \
  acc[5][nn] = __builtin_amdgcn_mfma_f32_16x16x32_bf16(a5, bv, acc[5][nn], 0,0,0); \
  acc[6][nn] = __builtin_amdgcn_mfma_f32_16x16x32_bf16(a6, bv, acc[6][nn], 0,0,0); \
  acc[7][nn] = __builtin_amdgcn_mfma_f32_16x16x32_bf16(a7, bv, acc[7][nn], 0,0,0); }

#define STG(BASE, LD, LS, bb, hf, tt) { \
  _Pragma("unroll") \
  for (int ii = 0; ii < 2; ++ii) { \
    const int s_ = t + ii * 512; \
    const int r_ = s_ >> 3; \
    const int lc_ = (s_ & 7) ^ (r_ & 7); \
    __builtin_amdgcn_global_load_lds( \
      (const __attribute__((address_space(1))) u32*)((BASE) + (size_t)((hf) * 128 + r_) * (LD) + (size_t)(tt) * 64 + lc_ * 8), \
      (__attribute__((address_space(3))) u32*)(&(LS)[bb][(hf) * 8192 + s_ * 8]), 16, 0, 0); \
  } }

#define BAR() __builtin_amdgcn_s_barrier()
#define PRIO(x) __builtin_amdgcn_s_setprio(x)

#define GRP(bf, tS1, tS2) { \
  a0=RD_A(bf,0,c0); a1=RD_A(bf,1,c0); a2=RD_A(bf,2,c0); a3=RD_A(bf,3,c0); \
  a4=RD_A(bf,4,c0); a5=RD_A(bf,5,c0); a6=RD_A(bf,6,c0); a7=RD_A(bf,7,c0); \
  b0=RD_B(bf,0,c0); b1=RD_B(bf,1,c0); \
  STG(Ab, lda, lsA, 1-(bf), 1, tS1); STG(Bb, ldb, lsB, 1-(bf), 0, tS1); \
  BAR(); PRIO(1); MM8(0, b0); MM8(1, b1); PRIO(0); BAR(); \
  b2=RD_B(bf,2,c0); b3=RD_B(bf,3,c0); \
  STG(Bb, ldb, lsB, 1-(bf), 1, tS1); \
  BAR(); PRIO(1); MM8(2, b2); MM8(3, b3); PRIO(0); BAR(); \
  a0=RD_A(bf,0,c1); a1=RD_A(bf,1,c1); a2=RD_A(bf,2,c1); a3=RD_A(bf,3,c1); \
  a4=RD_A(bf,4,c1); a5=RD_A(bf,5,c1); a6=RD_A(bf,6,c1); a7=RD_A(bf,7,c1); \
  b0=RD_B(bf,0,c1); b1=RD_B(bf,1,c1); \
  BAR(); PRIO(1); MM8(0, b0); MM8(1, b1); PRIO(0); BAR(); \
  b2=RD_B(bf,2,c1); b3=RD_B(bf,3,c1); \
  STG(Ab, lda, lsA, (bf), 0, tS2); \
  BAR(); PRIO(1); MM8(2, b2); MM8(3, b3); PRIO(0); \
  asm volatile("s_waitcnt vmcnt(2)" ::: "memory"); \
  BAR(); }

template<int CMODE, bool RELU, bool EXPSUM>
__global__ __launch_bounds__(512, 2) void mfma256_8ph(
    const ushort_t* __restrict__ A, const ushort_t* __restrict__ B,
    void* __restrict__ Cv, int lda, int ldb, int ldc,
    int K, int zsplit, size_t zA, size_t zB, size_t zC,
    int bShift, size_t bHead, int Mvalid, float scale,
    float* __restrict__ Rs)
{
  __shared__ ushort_t lsA[2][16384];
  __shared__ ushort_t lsB[2][16384];
  const int t = threadIdx.x;
  const int gx = gridDim.x;
  const int nwg = gx * gridDim.y;
  const int bid = blockIdx.y * gx + blockIdx.x;
  const int qq = nwg >> 3, rr_ = nwg & 7;
  const int xcd = bid & 7, idx = bid >> 3;
  const int swz = (xcd < rr_ ? xcd * (qq + 1) : rr_ * (qq + 1) + (xcd - rr_) * qq) + idx;
  const int m0 = (swz / gx) * 256;
  const int n0 = (swz % gx) * 256;
  const int z = blockIdx.z;
  int Kc = K, kOff = 0;
  size_t aZ = 0, bZ = 0, cZ = 0;
  if (zsplit > 1) { Kc = K / zsplit; kOff = z * Kc; cZ = (size_t)z * zC; }
  else { aZ = (size_t)z * zA; bZ = (size_t)z * zB; cZ = (size_t)z * zC; }
  const ushort_t* Ab = A + aZ + (size_t)m0 * lda + kOff;
  const ushort_t* Bb = B + bZ + (size_t)n0 * ldb + kOff
                     + (bShift >= 0 ? (size_t)(m0 >> bShift) * bHead : 0);
  const int NT = Kc / 64;

  f32x4 acc[8][4];
  #pragma unroll
  for (int i = 0; i < 8; ++i)
    #pragma unroll
    for (int j = 0; j < 4; ++j) acc[i][j] = (f32x4){0.f, 0.f, 0.f, 0.f};

  const int lane = t & 63;
  const int wv = t >> 6;
  const int wr = (wv >> 2) * 128;
  const int wc = (wv & 3) * 64;
  const int lr = lane & 15;
  const int kc = lane >> 4;
  const int sw = lane & 7;
  const int c0 = (kc ^ sw) * 16;
  const int c1 = c0 ^ 64;
  const int arow = (wr + lr) * 128;
  const int brow = (wc + lr) * 128;
  const char* lsAc = (const char*)lsA;
  const char* lsBc = (const char*)lsB;

  short8 a0, a1, a2, a3, a4, a5, a6, a7, b0, b1, b2, b3;

  STG(Ab, lda, lsA, 0, 0, 0); STG(Ab, lda, lsA, 0, 1, 0);
  STG(Bb, ldb, lsB, 0, 0, 0); STG(Bb, ldb, lsB, 0, 1, 0);
  STG(Ab, lda, lsA, 1, 0, 1);
  asm volatile("s_waitcnt vmcnt(2)" ::: "memory");
  BAR();

  const int NITER = NT >> 1;
  for (int it = 0; it < NITER; ++it) {
    const int tb = 2 * it;
    const int s1 = tb + 1;
    const int s2 = (tb + 2 < NT) ? tb + 2 : 0;
    const int s3 = (tb + 3 < NT) ? tb + 3 : 0;
    GRP(0, s1, s2)
    GRP(1, s2, s3)
  }

  const int row4 = (lane >> 4) * 4;
  const int coln = lane & 15;
  float* Cf = (float*)Cv + cZ;
  ushort_t* Ch = (ushort_t*)Cv + cZ;
  float* rs = EXPSUM ? (Rs + (size_t)z * 4096) : nullptr;
  #pragma unroll
  for (int m = 0; m < 8; ++m) {
    #pragma unroll
    for (int r = 0; r < 4; ++r) {
      const int gm = m0 + wr + m * 16 + row4 + r;
      const bool ok = gm < Mvalid;
      float rowpart = 0.f;
      #pragma unroll
      for (int n = 0; n < 4; ++n) {
        const int gn = n0 + wc + n * 16 + coln;
        float v = acc[m][n][r] * scale;
        if (EXPSUM) { v = exp2f(v); rowpart += v; }
        if (RELU) v = fmaxf(v, 0.f);
        if (ok) {
          if (CMODE == 0)      Cf[(size_t)gm * ldc + gn] = v;
          else if (CMODE == 1) Ch[(size_t)gm * ldc + gn] = f2bf(v);
          else                 atomicAdd(&Cf[(size_t)gm * ldc + gn], v);
        }
      }
      if (EXPSUM) {
        rowpart += __shfl_xor(rowpart, 1);
        rowpart += __shfl_xor(rowpart, 2);
        rowpart += __shfl_xor(rowpart, 4);
        rowpart += __shfl_xor(rowpart, 8);
        if (ok && (lane & 15) == 0) atomicAdd(&rs[gm], rowpart);
      }
    }
  }
}

#undef GRP
#undef STG
#undef MM8
#undef RD_A
#undef RD_B

// ================= 128x128-tile MFMA GEMM, 256 threads (SHORT-K) ===========
template<int CMODE, bool RELU, bool EXPSUM>
__global__ __launch_bounds__(256) void mfma_bt(
    const ushort_t* __restrict__ A, const ushort_t* __restrict__ B,
    void* __restrict__ Cv, int lda, int ldb, int ldc,
    int K, int Ksplit, size_t zA, size_t zB, size_t zC,
    int bShift, size_t bHead, int mMask, int Mvalid, float scale,
    float* __restrict__ Rs)
{
  __shared__ ushort_t lsA[2][128 * 32];
  __shared__ ushort_t lsB[2][128 * 32];
  const int t  = threadIdx.x;
  const int m0 = blockIdx.y * 128;
  const int n0 = blockIdx.x * 128;
  const int z = blockIdx.z;
  int Kc = K, kOff = 0;
  size_t aZ = 0, bZ = 0, cZ = 0;
  if (Ksplit > 1) { Kc = K / Ksplit; kOff = z * Kc; cZ = (size_t)z * zC; }
  else { aZ = (size_t)z * zA; bZ = (size_t)z * zB; cZ = (size_t)z * zC; }
  const int NT = Kc / 32;
  const ushort_t* Ab = A + aZ + (size_t)m0 * lda + kOff;
  const ushort_t* Bb = B + bZ + (size_t)n0 * ldb + kOff
                     + (bShift >= 0 ? (size_t)(m0 >> bShift) * bHead : 0);
  const int cs = t & 3;

  f32x4 acc[4][4];
  #pragma unroll
  for (int i = 0; i < 4; ++i)
    #pragma unroll
    for (int j = 0; j < 4; ++j) acc[i][j] = (f32x4){0.f, 0.f, 0.f, 0.f};

  const int lane = t & 63;
  const int wv = t >> 6;
  const int wr = (wv >> 1) * 64;
  const int wc = (wv & 1) * 64;
  const int lr = lane & 15;
  const int kc = lane >> 4;

  int roffA[4], roffB[4];
  #pragma unroll
  for (int m = 0; m < 4; ++m) {
    int ra = wr + m * 16 + lr;
    roffA[m] = ra * 64 + ((kc ^ (ra & 3)) * 16);
    int rb = wc + m * 16 + lr;
    roffB[m] = rb * 64 + ((kc ^ (rb & 3)) * 16);
  }

  auto stage = [&](int buf, int kt) {
    const ushort_t* As = Ab + kt * 32;
    const ushort_t* Bs = Bb + kt * 32;
    #pragma unroll
    for (int i = 0; i < 2; ++i) {
      int s = t + i * 256;
      int r = s >> 2;
      int c = cs ^ (r & 3);
      __builtin_amdgcn_global_load_lds(
          (const __attribute__((address_space(1))) u32*)(As + (size_t)r * lda + c * 8),
          (__attribute__((address_space(3))) u32*)(&lsA[buf][s * 8]), 16, 0, 0);
    }
    #pragma unroll
    for (int i = 0; i < 2; ++i) {
      int s = t + i * 256;
      int r = s >> 2;
      int c = cs ^ (r & 3);
      __builtin_amdgcn_global_load_lds(
          (const __attribute__((address_space(1))) u32*)(Bs + (size_t)r * ldb + c * 8),
          (__attribute__((address_space(3))) u32*)(&lsB[buf][s * 8]), 16, 0, 0);
    }
  };

  stage(0, 0);
  __syncthreads();
  int cur = 0;
  for (int kt = 0; kt < NT; ++kt) {
    if (kt + 1 < NT) stage(cur ^ 1, kt + 1);
    short8 af[4], bfr[4];
    const char* baseA = (const char*)&lsA[cur][0];
    const char* baseB = (const char*)&lsB[cur][0];
    #pragma unroll
    for (int m = 0; m < 4; ++m) af[m]  = *(const short8*)(baseA + roffA[m]);
    #pragma unroll
    for (int n = 0; n < 4; ++n) bfr[n] = *(const short8*)(baseB + roffB[n]);
    #pragma unroll
    for (int m = 0; m < 4; ++m)
      #pragma unroll
      for (int n = 0; n < 4; ++n)
        acc[m][n] = __builtin_amdgcn_mfma_f32_16x16x32_bf16(af[m], bfr[n], acc[m][n], 0, 0, 0);
    __syncthreads();
    cur ^= 1;
  }

  const int row4 = (lane >> 4) * 4;
  const int coln = lane & 15;
  float* Cf = (float*)Cv + cZ;
  ushort_t* Ch = (ushort_t*)Cv + cZ;
  float* rs = EXPSUM ? (Rs + (size_t)z * 4096) : nullptr;
  #pragma unroll
  for (int m = 0; m < 4; ++m) {
    #pragma unroll
    for (int r = 0; r < 4; ++r) {
      const int gm = m0 + wr + m * 16 + row4 + r;
      const bool ok = (mMask >= 0) ? ((gm & mMask) < Mvalid) : (gm < Mvalid);
      float rowpart = 0.f;
      #pragma unroll
      for (int n = 0; n < 4; ++n) {
        const int gn = n0 + wc + n * 16 + coln;
        float v = acc[m][n][r] * scale;
        if (EXPSUM) { v = exp2f(v); rowpart += v; }
        if (RELU) v = fmaxf(v, 0.f);
        if (ok) {
          if (CMODE == 0)      Cf[(size_t)gm * ldc + gn] = v;
          else if (CMODE == 1) Ch[(size_t)gm * ldc + gn] = f2bf(v);
          else                 atomicAdd(&Cf[(size_t)gm * ldc + gn], v);
        }
      }
      if (EXPSUM) {
        rowpart += __shfl_xor(rowpart, 1);
        rowpart += __shfl_xor(rowpart, 2);
        rowpart += __shfl_xor(rowpart, 4);
        rowpart += __shfl_xor(rowpart, 8);
        if (ok && (lane & 15) == 0) atomicAdd(&rs[gm], rowpart);
      }
    }
  }
}

// ---------------- weights: dst[Mp,Kp] bf16 = W^T (+ bias slot at k==Kv) ----
__global__ __launch_bounds__(256) void wt_conv(
    const float* __restrict__ W, const float* __restrict__ bias,
    ushort_t* __restrict__ dst, int Mtot, int ldw, int Kv, int Kp,
    int PADH, int VALH)
{
  const int m = blockIdx.x;
  const int h = m / PADH, c0 = m % PADH;
  const int fout = h * VALH + c0;
  const bool valid = (c0 < VALH) && (fout < Mtot);
  for (int k = threadIdx.x; k < Kp; k += blockDim.x) {
    float v = 0.f;
    if (valid) {
      if (k < Kv) v = W[(size_t)k * ldw + fout];
      else if (k == Kv) v = bias[fout];
    }
    dst[(size_t)m * Kp + k] = f2bf(v);
  }
}

// ---------------- wt_trans: dst[4][256][512] bf16 (padded W~^T per head) ---
__global__ __launch_bounds__(256) void wt_trans(
    const float* __restrict__ W, const float* __restrict__ bias,
    ushort_t* __restrict__ dst)
{
  const int rid = blockIdx.x;          // 0..1023
  const int h = rid >> 8, a = rid & 255;
  for (int f = threadIdx.x; f < 512; f += 256) {
    float v = 0.f;
    if (a < 200)       v = W[(size_t)a * 2048 + h * 512 + f];
    else if (a == 200) v = bias[h * 512 + f];
    dst[(size_t)rid * 512 + f] = f2bf(v);
  }
}

// ---------------- transpose fp32 [Kv,4096] -> bf16 [4096,Kp], bias slot ----
__global__ __launch_bounds__(256) void trans_pad(
    const float* __restrict__ src, ushort_t* __restrict__ dst, int Kv, int Kp)
{
  __shared__ float tl[64][65];
  const int t = threadIdx.x;
  const int f0 = blockIdx.x * 64;
  const int i0 = blockIdx.y * 64;
  const int c = t & 63, rbase = t >> 6;
  #pragma unroll
  for (int it = 0; it < 16; ++it) {
    int r = rbase + it * 4;
    int f = f0 + r;
    tl[r][c] = (f < Kv) ? src[(size_t)f * 4096 + i0 + c] : 0.f;
  }
  __syncthreads();
  #pragma unroll
  for (int it = 0; it < 16; ++it) {
    int r = rbase + it * 4;
    int f = f0 + c;
    if (f < Kp) {
      float v = (f < Kv) ? tl[c][r] : ((f == Kv) ? 1.f : 0.f);
      dst[(size_t)(i0 + r) * Kp + f] = f2bf(v);
    }
  }
}

// ---------------- GraphNorm layer 1: x = skip + attn (pre-normalized) ------
__global__ __launch_bounds__(256) void graph_norm_attn1(
    const float* __restrict__ skip, const float* __restrict__ attn,
    float* __restrict__ out,
    const float* __restrict__ w, const float* __restrict__ b,
    const float* __restrict__ ms)
{
  __shared__ float red[4];
  const int t = threadIdx.x;
  const int row = blockIdx.x;            // 0..199
  const int pr = (row / 50) * 128 + row % 50;
  const float* sk = skip + (size_t)pr * 4096;
  const float* at = attn + (size_t)pr * 4096;
  float v[16];
  float s = 0.f;
  #pragma unroll
  for (int e = 0; e < 4; ++e) {
    const int idx = t * 4 + 1024 * e;
    float4 a = *(const float4*)&sk[idx];
    float4 o = *(const float4*)&at[idx];
    v[e*4+0] = a.x + o.x; v[e*4+1] = a.y + o.y;
    v[e*4+2] = a.z + o.z; v[e*4+3] = a.w + o.w;
    s += v[e*4+0] + v[e*4+1] + v[e*4+2] + v[e*4+3];
  }
  const float mean = block_sum256(s, red) * (1.f / 4096.f);
  const float sub = mean * ms[row];
  float s2 = 0.f;
  #pragma unroll
  for (int e = 0; e < 16; ++e) { v[e] -= sub; s2 += v[e] * v[e]; }
  const float var = block_sum256(s2, red) * (1.f / 4096.f);
  const float scl = rsqrtf(var + 1e-5f) * w[row];
  const float bb = b[row];
  float* y = out + (size_t)row * 4096;
  #pragma unroll
  for (int e = 0; e < 4; ++e) {
    float o0[4];
    #pragma unroll
    for (int q = 0; q < 4; ++q) o0[q] = v[e * 4 + q] * scl + bb;
    *(float4*)&y[t * 4 + 1024 * e] = *(float4*)&o0[0];
  }
}

// ---------------- GraphNorm layer 2: x = skip + (p0+p1)/r, gn, L2, bf16 ----
__global__ __launch_bounds__(256) void graph_norm_attn2(
    const ushort_t* __restrict__ skip, const ushort_t* __restrict__ p2,
    const float* __restrict__ r2, ushort_t* __restrict__ out,
    const float* __restrict__ w, const float* __restrict__ b,
    const float* __restrict__ ms)
{
  __shared__ float red[4];
  const int t = threadIdx.x;
  const int row = blockIdx.x;            // 0..2047
  const ushort_t* sk = skip + (size_t)row * 4096;
  const ushort_t* pa = p2 + (size_t)row * 4096;
  const ushort_t* pb = p2 + (size_t)2048 * 4096 + (size_t)row * 4096;
  const float* rr = r2 + (size_t)(row >> 9) * 4096;
  float v[16];
  float s = 0.f;
  #pragma unroll
  for (int e = 0; e < 4; ++e) {
    const int idx = t * 4 + 1024 * e;
    float a[4], oa[4], ob[4];
    ld4bf(&sk[idx], a); ld4bf(&pa[idx], oa); ld4bf(&pb[idx], ob);
    float4 rv = *(const float4*)&rr[idx];
    v[e*4+0] = a[0] + (oa[0] + ob[0]) / rv.x;
    v[e*4+1] = a[1] + (oa[1] + ob[1]) / rv.y;
    v[e*4+2] = a[2] + (oa[2] + ob[2]) / rv.z;
    v[e*4+3] = a[3] + (oa[3] + ob[3]) / rv.w;
    s += v[e*4+0] + v[e*4+1] + v[e*4+2] + v[e*4+3];
  }
  const float mean = block_sum256(s, red) * (1.f / 4096.f);
  const float sub = mean * ms[row];
  float s2 = 0.f;
  #pragma unroll
  for (int e = 0; e < 16; ++e) { v[e] -= sub; s2 += v[e] * v[e]; }
  const float var = block_sum256(s2, red) * (1.f / 4096.f);
  const float scl = rsqrtf(var + 1e-5f) * w[row];
  const float bb = b[row];
  #pragma unroll
  for (int e = 0; e < 16; ++e) v[e] = v[e] * scl + bb;
  float s3 = 0.f;
  #pragma unroll
  for (int e = 0; e < 16; ++e) s3 += v[e] * v[e];
  const float osc = rsqrtf(block_sum256(s3, red));
  ushort_t* y = out + (size_t)row * 4096;
  #pragma unroll
  for (int e = 0; e < 4; ++e) {
    ushort_t o0[4];
    #pragma unroll
    for (int q = 0; q < 4; ++q) o0[q] = f2bf(v[e * 4 + q] * osc);
    *(ushort2*)&y[t * 4 + 1024 * e] = *(ushort2*)&o0[0];
    *(ushort2*)&y[t * 4 + 1024 * e + 2] = *(ushort2*)&o0[2];
  }
}

// ---------------- out = relu(g0+g1+g2+g3), float4-wide ---------------------
__global__ __launch_bounds__(256) void add4_relu(
    const float* __restrict__ g, float* __restrict__ out)
{
  const size_t i = (size_t)blockIdx.x * 256 + threadIdx.x;
  const size_t ss = (size_t)2048 * 2048 / 4;
  float4 a = ((const float4*)g)[i];
  float4 b = ((const float4*)g)[i + ss];
  float4 c = ((const float4*)g)[i + 2 * ss];
  float4 d = ((const float4*)g)[i + 3 * ss];
  float4 o;
  o.x = fmaxf(a.x + b.x + c.x + d.x, 0.f);
  o.y = fmaxf(a.y + b.y + c.y + d.y, 0.f);
  o.z = fmaxf(a.z + b.z + c.z + d.z, 0.f);
  o.w = fmaxf(a.w + b.w + c.w + d.w, 0.f);
  ((float4*)out)[i] = o;
}

extern "C" void kernel_launch(void* const* d_in, const int* in_sizes, int n_in,
                              void* d_out, int out_size, void* d_ws, size_t ws_size,
                              hipStream_t stream)
{
  (void)in_sizes; (void)n_in; (void)out_size; (void)ws_size;
  const float* lr_x = (const float*)d_in[0];
  const float* Wq1 = (const float*)d_in[1];  const float* bq1 = (const float*)d_in[2];
  const float* Wk1 = (const float*)d_in[3];  const float* bk1 = (const float*)d_in[4];
  const float* Wv1 = (const float*)d_in[5];  const float* bv1 = (const float*)d_in[6];
  const float* Ws1 = (const float*)d_in[7];  const float* bs1 = (const float*)d_in[8];
  const float* gn1w = (const float*)d_in[9]; const float* gn1b = (const float*)d_in[10];
  const float* gn1ms = (const float*)d_in[11];
  const float* Wq2 = (const float*)d_in[12]; const float* bq2 = (const float*)d_in[13];
  const float* Wk2 = (const float*)d_in[14]; const float* bk2 = (const float*)d_in[15];
  const float* Wv2 = (const float*)d_in[16]; const float* bv2 = (const float*)d_in[17];
  const float* Ws2 = (const float*)d_in[18]; const float* bs2 = (const float*)d_in[19];
  const float* gn2w = (const float*)d_in[20]; const float* gn2b = (const float*)d_in[21];
  const float* gn2ms = (const float*)d_in[22];

  // ---- workspace carve (~251 MB total, < 256 MiB cap) ----
  char* p = (char*)d_ws;
  auto alloc = [&](size_t bytes) { char* r = p; p += (bytes + 255) & ~(size_t)255; return r; };
  const size_t PSTR = (size_t)4096 * 4096;
  ushort_t* Pall = (ushort_t*)alloc(PSTR * 4 * 2);              // attn-2 P; Gram partials alias
  ushort_t* xb   = (ushort_t*)alloc((size_t)4096 * 544 * 2);
  ushort_t* qk1b = (ushort_t*)alloc((size_t)4096 * 512 * 2);
  ushort_t* v1b  = (ushort_t*)alloc((size_t)512 * 4096 * 2);
  char*     u0   = alloc((size_t)16 * 1024 * 1024);             // s1p+o1p, later h2b
  float*    s1p  = (float*)u0;                                  // [512,4096] f32 skip
  float*    o1p  = (float*)(u0 + (size_t)8 * 1024 * 1024);      // [512,4096] f32 attn (normalized)
  float*    h1nT = (float*)   alloc((size_t)200 * 4096 * 4);
  ushort_t* h1nb = (ushort_t*)alloc((size_t)4096 * 256 * 2);
  ushort_t* Wqk1 = (ushort_t*)alloc((size_t)512 * 544 * 2);
  ushort_t* Wv1b = (ushort_t*)alloc((size_t)512 * 544 * 2);
  ushort_t* Ws1p = (ushort_t*)alloc((size_t)512 * 544 * 2);
  ushort_t* Wcat = (ushort_t*)alloc((size_t)4096 * 256 * 2);    // [v2 | s2] weights
  ushort_t* Qt   = (ushort_t*)alloc((size_t)4 * 256 * 512 * 2); // per-head W~q^T [256,512]
  ushort_t* Kt   = (ushort_t*)alloc((size_t)4 * 256 * 512 * 2); // per-head W~k^T [256,512]
  ushort_t* Mtall= (ushort_t*)alloc((size_t)4 * 256 * 256 * 2); // per-head M^T [256,256]
  ushort_t* Tall = (ushort_t*)alloc((size_t)4 * 4096 * 256 * 2);// per-head T=XM [4096,256]
  ushort_t* vs2b = (ushort_t*)alloc((size_t)4096 * 4096 * 2);   // rows 0..2047=v2T, 2048..4095=skip2
  ushort_t* p2   = (ushort_t*)alloc((size_t)2 * 2048 * 4096 * 2);// PV-2 partials bf16
  float*    r2   = (float*)   alloc((size_t)4 * 4096 * 4);
  // aliases (regions dead by the time the alias is written):
  ushort_t* h2b  = (ushort_t*)u0;  // gn2 output: s1p/o1p dead after gn1
  float*    g4   = (float*)Pall;   // Gram partials: Pall dead after PV-2

  const dim3 b256(256, 1, 1);
  const dim3 b512(512, 1, 1);
  const float LOG2E = 1.4426950408889634f;
  const float sc1e = 0.14142135623730951f * LOG2E;  // 1/sqrt(50) * log2e
  const float sc2e = 0.04419417382415922f * LOG2E;  // 1/sqrt(512) * log2e

  hipMemsetAsync(r2, 0, (size_t)4 * 4096 * 4, stream);

  // ---- weight conversions
  wt_conv<<<dim3(256),  b256, 0, stream>>>(Wq1, bq1, Wqk1,             200, 200, 512, 544, 64, 50);
  wt_conv<<<dim3(256),  b256, 0, stream>>>(Wk1, bk1, Wqk1 + 256 * 544, 200, 200, 512, 544, 64, 50);
  wt_conv<<<dim3(512),  b256, 0, stream>>>(Wv1, bv1, Wv1b,             200, 200, 512, 544, 128, 50);
  wt_conv<<<dim3(512),  b256, 0, stream>>>(Ws1, bs1, Ws1p,             200, 200, 512, 544, 128, 50);
  wt_conv<<<dim3(2048), b256, 0, stream>>>(Wv2, bv2, Wcat,              2048, 2048, 200, 256, 2048, 2048);
  wt_conv<<<dim3(2048), b256, 0, stream>>>(Ws2, bs2, Wcat + 2048 * 256, 2048, 2048, 200, 256, 2048, 2048);
  wt_trans<<<dim3(1024), b256, 0, stream>>>(Wq2, bq2, Qt);
  wt_trans<<<dim3(1024), b256, 0, stream>>>(Wk2, bk2, Kt);
  trans_pad<<<dim3(9, 64), b256, 0, stream>>>(lr_x, xb, 512, 544);

  // ---- layer-1 projections (128^2 kernel)
  mfma_bt<1, false, false><<<dim3(4, 32), b256, 0, stream>>>(
      xb, Wqk1, qk1b, 544, 544, 512, 544, 1, 0, 0, 0, -1, 0, -1, 4096, 1.f, nullptr);
  mfma_bt<1, false, false><<<dim3(32, 4), b256, 0, stream>>>(
      Wv1b, xb, v1b, 544, 544, 4096, 544, 1, 0, 0, 0, -1, 0, -1, 512, 1.f, nullptr);
  mfma_bt<0, false, false><<<dim3(32, 4), b256, 0, stream>>>(
      Ws1p, xb, s1p, 544, 544, 4096, 544, 1, 0, 0, 0, -1, 0, 127, 50, 1.f, nullptr);

  // ---- attention 1: FUSED flash-style (no P materialization)
  fused_attn1<<<dim3(64, 4), b256, 0, stream>>>(qk1b, v1b, o1p, sc1e);
  graph_norm_attn1<<<dim3(200), b256, 0, stream>>>(s1p, o1p, h1nT, gn1w, gn1b, gn1ms);
  trans_pad<<<dim3(4, 64), b256, 0, stream>>>(h1nT, h1nb, 200, 256);

  // ---- layer-2 V+skip projection (K=256, 128^2 kernel)
  mfma_bt<1, false, false><<<dim3(32, 32), b256, 0, stream>>>(
      Wcat, h1nb, vs2b, 256, 256, 4096, 256, 1, 0, 0, 0, -1, 0, -1, 4096, 1.f, nullptr);

  // ---- attention 2 scores via low-rank factorization:
  mfma_bt<1, false, false><<<dim3(2, 2, 4), b256, 0, stream>>>(
      Kt, Qt, Mtall, 512, 512, 256, 512, 1,
      (size_t)256 * 512, (size_t)256 * 512, (size_t)256 * 256, -1, 0, -1, 256, 1.f, nullptr);
  mfma_bt<1, false, false><<<dim3(2, 32, 4), b256, 0, stream>>>(
      h1nb, Mtall, Tall, 256, 256, 256, 256, 1,
      0, (size_t)256 * 256, (size_t)4096 * 256, -1, 0, -1, 4096, 1.f, nullptr);
  mfma_bt<1, false, true><<<dim3(32, 32, 4), b256, 0, stream>>>(
      Tall, h1nb, Pall, 256, 256, 4096, 256, 1,
      (size_t)4096 * 256, 0, PSTR, -1, 0, -1, 4096, sc2e, r2);

  // ---- PV-2: LONG K (Kc=2048) -> 8-phase kernel; bf16 partials
  mfma256_8ph<1, false, false><<<dim3(16, 8, 2), b512, 0, stream>>>(
      vs2b, Pall, p2, 4096, 4096, 4096, 4096, 2,
      0, 0, (size_t)2048 * 4096, 9, PSTR, 2048, 1.f, nullptr);
  graph_norm_attn2<<<dim3(2048), b256, 0, stream>>>(
      vs2b + (size_t)2048 * 4096, p2, r2, h2b, gn2w, gn2b, gn2ms);

  // ---- out = relu(h2n . h2n^T): LONG K (Kc=1024) -> 8-phase; partials+reduce
  mfma256_8ph<0, false, false><<<dim3(8, 8, 4), b512, 0, stream>>>(
      h2b, h2b, g4, 4096, 4096, 2048, 4096, 4,
      0, 0, (size_t)2048 * 2048, -1, 0, 2048, 1.f, nullptr);
  add4_relu<<<dim3(4096), b256, 0, stream>>>(g4, (float*)d_out);
}

// Round 11
// 499.953 us; speedup vs baseline: 1.0685x; 1.0685x over previous
//
#include <hip/hip_runtime.h>
#include <math.h>

typedef unsigned int u32;
typedef unsigned short ushort_t;
typedef __attribute__((ext_vector_type(8))) short short8;
typedef __attribute__((ext_vector_type(4))) float f32x4;

__device__ __forceinline__ ushort_t f2bf(float x) {
  u32 u = __float_as_uint(x);
  u32 r = (u + 0x7fffu + ((u >> 16) & 1u)) >> 16;
  return (ushort_t)r;
}
__device__ __forceinline__ float bf2f(u32 s) {
  return __uint_as_float(s << 16);
}
__device__ __forceinline__ void ld4bf(const ushort_t* p, float* o) {
  uint2 u = *(const uint2*)p;
  o[0] = bf2f(u.x & 0xffffu); o[1] = bf2f(u.x >> 16);
  o[2] = bf2f(u.y & 0xffffu); o[3] = bf2f(u.y >> 16);
}

// ---------------- block reduction helpers (256 threads = 4 waves) ----------
__device__ __forceinline__ float block_sum256(float v, float* red) {
  #pragma unroll
  for (int o = 32; o > 0; o >>= 1) v += __shfl_down(v, o, 64);
  __syncthreads();
  if ((threadIdx.x & 63) == 0) red[threadIdx.x >> 6] = v;
  __syncthreads();
  return red[0] + red[1] + red[2] + red[3];
}

// =====================================================================
// Fused attention layer 1 (flash-style, max-free softmax), KV-SPLIT x4.
// Grid (64, 4, 4): blockIdx.x = q-tile (64 rows), .y = head, .z = KV chunk
// (16 of 64 KV-tiles). 1024 blocks -> 4 waves/SIMD (R10 was 1: latency-bound).
// Outputs PARTIALS (plain stores, no atomics):
//   oP [z][512][4096] f32 (unnormalized PV partial)
//   r1p[z][4][4096]   f32 (expS row-sum partial)
// gn1 combines: x = skip + (sum_z oP) / (sum_z r1p).
// =====================================================================
__global__ __launch_bounds__(256) void fused_attn1(
    const ushort_t* __restrict__ qk, const ushort_t* __restrict__ v,
    float* __restrict__ oP, float* __restrict__ r1p, float scale)
{
  __shared__ ushort_t Pl[64][72];            // 144B row stride
  const int t = threadIdx.x;
  const int lane = t & 63;
  const int wv = t >> 6;                     // wave owns q rows wv*16..+15
  const int h = blockIdx.y;
  const int m0 = blockIdx.x * 64;
  const int z = blockIdx.z;
  const int lr = lane & 15;
  const int hk = lane >> 4;                  // 8-elem k-chunk 0..3

  short8 aq0, aq1;
  {
    const ushort_t* qrow = qk + (size_t)(m0 + wv * 16 + lr) * 512 + h * 64;
    aq0 = *(const short8*)(qrow + hk * 8);
    aq1 = *(const short8*)(qrow + 32 + hk * 8);
  }

  f32x4 oAcc[4];
  #pragma unroll
  for (int i = 0; i < 4; ++i) oAcc[i] = (f32x4){0.f, 0.f, 0.f, 0.f};
  float racc[4] = {0.f, 0.f, 0.f, 0.f};

  const size_t kbase = (size_t)256 + h * 64;

  for (int kt = z * 16; kt < z * 16 + 16; ++kt) {
    const int n0 = kt * 64;
    // ---- S-tile [16q x 64n] per wave
    f32x4 sA[4];
    #pragma unroll
    for (int nf = 0; nf < 4; ++nf) {
      const ushort_t* krow = qk + (size_t)(n0 + nf * 16 + lr) * 512 + kbase;
      short8 b0 = *(const short8*)(krow + hk * 8);
      short8 b1 = *(const short8*)(krow + 32 + hk * 8);
      f32x4 sa = (f32x4){0.f, 0.f, 0.f, 0.f};
      sa = __builtin_amdgcn_mfma_f32_16x16x32_bf16(aq0, b0, sa, 0, 0, 0);
      sa = __builtin_amdgcn_mfma_f32_16x16x32_bf16(aq1, b1, sa, 0, 0, 0);
      sA[nf] = sa;
    }
    // ---- exp2 + rowsum + P->LDS (per-wave-private rows, no barrier)
    #pragma unroll
    for (int nf = 0; nf < 4; ++nf) {
      #pragma unroll
      for (int r = 0; r < 4; ++r) {
        float e = exp2f(sA[nf][r] * scale);
        racc[r] += e;
        Pl[wv * 16 + hk * 4 + r][nf * 16 + lr] = f2bf(e);
      }
    }
    // ---- PV: O[16q x 64f] += P[16q x 64n] . V[64n x 64f]
    short8 ap0 = *(const short8*)&Pl[wv * 16 + lr][hk * 8];
    short8 ap1 = *(const short8*)&Pl[wv * 16 + lr][32 + hk * 8];
    #pragma unroll
    for (int ff = 0; ff < 4; ++ff) {
      const ushort_t* vrow = v + (size_t)(h * 128 + ff * 16 + lr) * 4096 + n0;
      short8 b0 = *(const short8*)(vrow + hk * 8);
      short8 b1 = *(const short8*)(vrow + 32 + hk * 8);
      oAcc[ff] = __builtin_amdgcn_mfma_f32_16x16x32_bf16(ap0, b0, oAcc[ff], 0, 0, 0);
      oAcc[ff] = __builtin_amdgcn_mfma_f32_16x16x32_bf16(ap1, b1, oAcc[ff], 0, 0, 0);
    }
  }

  // ---- partial row-sums: reduce across the 16 col-lanes (lr bits)
  #pragma unroll
  for (int r = 0; r < 4; ++r) {
    racc[r] += __shfl_xor(racc[r], 1);
    racc[r] += __shfl_xor(racc[r], 2);
    racc[r] += __shfl_xor(racc[r], 4);
    racc[r] += __shfl_xor(racc[r], 8);
  }
  if (lr == 0) {
    float* rp = r1p + ((size_t)z * 4 + h) * 4096;
    #pragma unroll
    for (int r = 0; r < 4; ++r) rp[m0 + wv * 16 + hk * 4 + r] = racc[r];
  }
  // ---- store O partial (plain f32, feature-major scatter)
  float* ob = oP + (size_t)z * 512 * 4096;
  #pragma unroll
  for (int ff = 0; ff < 4; ++ff) {
    const size_t fbase = (size_t)(h * 128 + ff * 16 + lr) * 4096;
    #pragma unroll
    for (int r = 0; r < 4; ++r) {
      const int q = m0 + wv * 16 + hk * 4 + r;
      ob[fbase + q] = oAcc[ff][r];
    }
  }
}

// =====================================================================
// 256x256-tile, 8-phase, counted-vmcnt MFMA GEMM. LONG-K only (R7 lesson).
// =====================================================================
#define RD_A(bb, mm, cc) (*(const short8*)(lsAc + (bb)*32768 + arow + (mm)*2048 + (cc)))
#define RD_B(bb, nn, cc) (*(const short8*)(lsBc + (bb)*32768 + brow + (nn)*2048 + (cc)))

#define MM8(nn, bv) { \
  acc[0][nn] = __builtin_amdgcn_mfma_f32_16x16x32_bf16(a0, bv, acc[0][nn], 0,0,0); \
  acc[1][nn] = __builtin_amdgcn_mfma_f32_16x16x32_bf16(a1, bv, acc[1][nn], 0,0,0); \
  acc[2][nn] = __builtin_amdgcn_mfma_f32_16x16x32_bf16(a2, bv, acc[2][nn], 0,0,0); \
  acc[3][nn] = __builtin_amdgcn_mfma_f32_16x16x32_bf16(a3, bv, acc[3][nn], 0,0,0); \
  acc[4][nn] = __builtin_amdgcn_mfma_f32_16x16x32_bf16(a4, bv, acc[4][nn], 0,0,0); \
  acc[5][nn] = __builtin_amdgcn_mfma_f32_16x16x32_bf16(a5, bv, acc[5][nn], 0,0,0); \
  acc[6][nn] = __builtin_amdgcn_mfma_f32_16x16x32_bf16(a6, bv, acc[6][nn], 0,0,0); \
  acc[7][nn] = __builtin_amdgcn_mfma_f32_16x16x32_bf16(a7, bv, acc[7][nn], 0,0,0); }

#define STG(BASE, LD, LS, bb, hf, tt) { \
  _Pragma("unroll") \
  for (int ii = 0; ii < 2; ++ii) { \
    const int s_ = t + ii * 512; \
    const int r_ = s_ >> 3; \
    const int lc_ = (s_ & 7) ^ (r_ & 7); \
    __builtin_amdgcn_global_load_lds( \
      (const __attribute__((address_space(1))) u32*)((BASE) + (size_t)((hf) * 128 + r_) * (LD) + (size_t)(tt) * 64 + lc_ * 8), \
      (__attribute__((address_space(3))) u32*)(&(LS)[bb][(hf) * 8192 + s_ * 8]), 16, 0, 0); \
  } }

#define BAR() __builtin_amdgcn_s_barrier()
#define PRIO(x) __builtin_amdgcn_s_setprio(x)

#define GRP(bf, tS1, tS2) { \
  a0=RD_A(bf,0,c0); a1=RD_A(bf,1,c0); a2=RD_A(bf,2,c0); a3=RD_A(bf,3,c0); \
  a4=RD_A(bf,4,c0); a5=RD_A(bf,5,c0); a6=RD_A(bf,6,c0); a7=RD_A(bf,7,c0); \
  b0=RD_B(bf,0,c0); b1=RD_B(bf,1,c0); \
  STG(Ab, lda, lsA, 1-(bf), 1, tS1); STG(Bb, ldb, lsB, 1-(bf), 0, tS1); \
  BAR(); PRIO(1); MM8(0, b0); MM8(1, b1); PRIO(0); BAR(); \
  b2=RD_B(bf,2,c0); b3=RD_B(bf,3,c0); \
  STG(Bb, ldb, lsB, 1-(bf), 1, tS1); \
  BAR(); PRIO(1); MM8(2, b2); MM8(3, b3); PRIO(0); BAR(); \
  a0=RD_A(bf,0,c1); a1=RD_A(bf,1,c1); a2=RD_A(bf,2,c1); a3=RD_A(bf,3,c1); \
  a4=RD_A(bf,4,c1); a5=RD_A(bf,5,c1); a6=RD_A(bf,6,c1); a7=RD_A(bf,7,c1); \
  b0=RD_B(bf,0,c1); b1=RD_B(bf,1,c1); \
  BAR(); PRIO(1); MM8(0, b0); MM8(1, b1); PRIO(0); BAR(); \
  b2=RD_B(bf,2,c1); b3=RD_B(bf,3,c1); \
  STG(Ab, lda, lsA, (bf), 0, tS2); \
  BAR(); PRIO(1); MM8(2, b2); MM8(3, b3); PRIO(0); \
  asm volatile("s_waitcnt vmcnt(2)" ::: "memory"); \
  BAR(); }

template<int CMODE, bool RELU, bool EXPSUM>
__global__ __launch_bounds__(512, 2) void mfma256_8ph(
    const ushort_t* __restrict__ A, const ushort_t* __restrict__ B,
    void* __restrict__ Cv, int lda, int ldb, int ldc,
    int K, int zsplit, size_t zA, size_t zB, size_t zC,
    int bShift, size_t bHead, int Mvalid, float scale,
    float* __restrict__ Rs)
{
  __shared__ ushort_t lsA[2][16384];
  __shared__ ushort_t lsB[2][16384];
  const int t = threadIdx.x;
  const int gx = gridDim.x;
  const int nwg = gx * gridDim.y;
  const int bid = blockIdx.y * gx + blockIdx.x;
  const int qq = nwg >> 3, rr_ = nwg & 7;
  const int xcd = bid & 7, idx = bid >> 3;
  const int swz = (xcd < rr_ ? xcd * (qq + 1) : rr_ * (qq + 1) + (xcd - rr_) * qq) + idx;
  const int m0 = (swz / gx) * 256;
  const int n0 = (swz % gx) * 256;
  const int z = blockIdx.z;
  int Kc = K, kOff = 0;
  size_t aZ = 0, bZ = 0, cZ = 0;
  if (zsplit > 1) { Kc = K / zsplit; kOff = z * Kc; cZ = (size_t)z * zC; }
  else { aZ = (size_t)z * zA; bZ = (size_t)z * zB; cZ = (size_t)z * zC; }
  const ushort_t* Ab = A + aZ + (size_t)m0 * lda + kOff;
  const ushort_t* Bb = B + bZ + (size_t)n0 * ldb + kOff
                     + (bShift >= 0 ? (size_t)(m0 >> bShift) * bHead : 0);
  const int NT = Kc / 64;

  f32x4 acc[8][4];
  #pragma unroll
  for (int i = 0; i < 8; ++i)
    #pragma unroll
    for (int j = 0; j < 4; ++j) acc[i][j] = (f32x4){0.f, 0.f, 0.f, 0.f};

  const int lane = t & 63;
  const int wv = t >> 6;
  const int wr = (wv >> 2) * 128;
  const int wc = (wv & 3) * 64;
  const int lr = lane & 15;
  const int kc = lane >> 4;
  const int sw = lane & 7;
  const int c0 = (kc ^ sw) * 16;
  const int c1 = c0 ^ 64;
  const int arow = (wr + lr) * 128;
  const int brow = (wc + lr) * 128;
  const char* lsAc = (const char*)lsA;
  const char* lsBc = (const char*)lsB;

  short8 a0, a1, a2, a3, a4, a5, a6, a7, b0, b1, b2, b3;

  STG(Ab, lda, lsA, 0, 0, 0); STG(Ab, lda, lsA, 0, 1, 0);
  STG(Bb, ldb, lsB, 0, 0, 0); STG(Bb, ldb, lsB, 0, 1, 0);
  STG(Ab, lda, lsA, 1, 0, 1);
  asm volatile("s_waitcnt vmcnt(2)" ::: "memory");
  BAR();

  const int NITER = NT >> 1;
  for (int it = 0; it < NITER; ++it) {
    const int tb = 2 * it;
    const int s1 = tb + 1;
    const int s2 = (tb + 2 < NT) ? tb + 2 : 0;
    const int s3 = (tb + 3 < NT) ? tb + 3 : 0;
    GRP(0, s1, s2)
    GRP(1, s2, s3)
  }

  const int row4 = (lane >> 4) * 4;
  const int coln = lane & 15;
  float* Cf = (float*)Cv + cZ;
  ushort_t* Ch = (ushort_t*)Cv + cZ;
  float* rs = EXPSUM ? (Rs + (size_t)z * 4096) : nullptr;
  #pragma unroll
  for (int m = 0; m < 8; ++m) {
    #pragma unroll
    for (int r = 0; r < 4; ++r) {
      const int gm = m0 + wr + m * 16 + row4 + r;
      const bool ok = gm < Mvalid;
      float rowpart = 0.f;
      #pragma unroll
      for (int n = 0; n < 4; ++n) {
        const int gn = n0 + wc + n * 16 + coln;
        float v = acc[m][n][r] * scale;
        if (EXPSUM) { v = exp2f(v); rowpart += v; }
        if (RELU) v = fmaxf(v, 0.f);
        if (ok) {
          if (CMODE == 0)      Cf[(size_t)gm * ldc + gn] = v;
          else if (CMODE == 1) Ch[(size_t)gm * ldc + gn] = f2bf(v);
          else                 atomicAdd(&Cf[(size_t)gm * ldc + gn], v);
        }
      }
      if (EXPSUM) {
        rowpart += __shfl_xor(rowpart, 1);
        rowpart += __shfl_xor(rowpart, 2);
        rowpart += __shfl_xor(rowpart, 4);
        rowpart += __shfl_xor(rowpart, 8);
        if (ok && (lane & 15) == 0) atomicAdd(&rs[gm], rowpart);
      }
    }
  }
}

#undef GRP
#undef STG
#undef MM8
#undef RD_A
#undef RD_B

// ================= 128x128-tile MFMA GEMM, 256 threads (SHORT-K) ===========
template<int CMODE, bool RELU, bool EXPSUM>
__global__ __launch_bounds__(256) void mfma_bt(
    const ushort_t* __restrict__ A, const ushort_t* __restrict__ B,
    void* __restrict__ Cv, int lda, int ldb, int ldc,
    int K, int Ksplit, size_t zA, size_t zB, size_t zC,
    int bShift, size_t bHead, int mMask, int Mvalid, float scale,
    float* __restrict__ Rs)
{
  __shared__ ushort_t lsA[2][128 * 32];
  __shared__ ushort_t lsB[2][128 * 32];
  const int t  = threadIdx.x;
  const int m0 = blockIdx.y * 128;
  const int n0 = blockIdx.x * 128;
  const int z = blockIdx.z;
  int Kc = K, kOff = 0;
  size_t aZ = 0, bZ = 0, cZ = 0;
  if (Ksplit > 1) { Kc = K / Ksplit; kOff = z * Kc; cZ = (size_t)z * zC; }
  else { aZ = (size_t)z * zA; bZ = (size_t)z * zB; cZ = (size_t)z * zC; }
  const int NT = Kc / 32;
  const ushort_t* Ab = A + aZ + (size_t)m0 * lda + kOff;
  const ushort_t* Bb = B + bZ + (size_t)n0 * ldb + kOff
                     + (bShift >= 0 ? (size_t)(m0 >> bShift) * bHead : 0);
  const int cs = t & 3;

  f32x4 acc[4][4];
  #pragma unroll
  for (int i = 0; i < 4; ++i)
    #pragma unroll
    for (int j = 0; j < 4; ++j) acc[i][j] = (f32x4){0.f, 0.f, 0.f, 0.f};

  const int lane = t & 63;
  const int wv = t >> 6;
  const int wr = (wv >> 1) * 64;
  const int wc = (wv & 1) * 64;
  const int lr = lane & 15;
  const int kc = lane >> 4;

  int roffA[4], roffB[4];
  #pragma unroll
  for (int m = 0; m < 4; ++m) {
    int ra = wr + m * 16 + lr;
    roffA[m] = ra * 64 + ((kc ^ (ra & 3)) * 16);
    int rb = wc + m * 16 + lr;
    roffB[m] = rb * 64 + ((kc ^ (rb & 3)) * 16);
  }

  auto stage = [&](int buf, int kt) {
    const ushort_t* As = Ab + kt * 32;
    const ushort_t* Bs = Bb + kt * 32;
    #pragma unroll
    for (int i = 0; i < 2; ++i) {
      int s = t + i * 256;
      int r = s >> 2;
      int c = cs ^ (r & 3);
      __builtin_amdgcn_global_load_lds(
          (const __attribute__((address_space(1))) u32*)(As + (size_t)r * lda + c * 8),
          (__attribute__((address_space(3))) u32*)(&lsA[buf][s * 8]), 16, 0, 0);
    }
    #pragma unroll
    for (int i = 0; i < 2; ++i) {
      int s = t + i * 256;
      int r = s >> 2;
      int c = cs ^ (r & 3);
      __builtin_amdgcn_global_load_lds(
          (const __attribute__((address_space(1))) u32*)(Bs + (size_t)r * ldb + c * 8),
          (__attribute__((address_space(3))) u32*)(&lsB[buf][s * 8]), 16, 0, 0);
    }
  };

  stage(0, 0);
  __syncthreads();
  int cur = 0;
  for (int kt = 0; kt < NT; ++kt) {
    if (kt + 1 < NT) stage(cur ^ 1, kt + 1);
    short8 af[4], bfr[4];
    const char* baseA = (const char*)&lsA[cur][0];
    const char* baseB = (const char*)&lsB[cur][0];
    #pragma unroll
    for (int m = 0; m < 4; ++m) af[m]  = *(const short8*)(baseA + roffA[m]);
    #pragma unroll
    for (int n = 0; n < 4; ++n) bfr[n] = *(const short8*)(baseB + roffB[n]);
    #pragma unroll
    for (int m = 0; m < 4; ++m)
      #pragma unroll
      for (int n = 0; n < 4; ++n)
        acc[m][n] = __builtin_amdgcn_mfma_f32_16x16x32_bf16(af[m], bfr[n], acc[m][n], 0, 0, 0);
    __syncthreads();
    cur ^= 1;
  }

  const int row4 = (lane >> 4) * 4;
  const int coln = lane & 15;
  float* Cf = (float*)Cv + cZ;
  ushort_t* Ch = (ushort_t*)Cv + cZ;
  float* rs = EXPSUM ? (Rs + (size_t)z * 4096) : nullptr;
  #pragma unroll
  for (int m = 0; m < 4; ++m) {
    #pragma unroll
    for (int r = 0; r < 4; ++r) {
      const int gm = m0 + wr + m * 16 + row4 + r;
      const bool ok = (mMask >= 0) ? ((gm & mMask) < Mvalid) : (gm < Mvalid);
      float rowpart = 0.f;
      #pragma unroll
      for (int n = 0; n < 4; ++n) {
        const int gn = n0 + wc + n * 16 + coln;
        float v = acc[m][n][r] * scale;
        if (EXPSUM) { v = exp2f(v); rowpart += v; }
        if (RELU) v = fmaxf(v, 0.f);
        if (ok) {
          if (CMODE == 0)      Cf[(size_t)gm * ldc + gn] = v;
          else if (CMODE == 1) Ch[(size_t)gm * ldc + gn] = f2bf(v);
          else                 atomicAdd(&Cf[(size_t)gm * ldc + gn], v);
        }
      }
      if (EXPSUM) {
        rowpart += __shfl_xor(rowpart, 1);
        rowpart += __shfl_xor(rowpart, 2);
        rowpart += __shfl_xor(rowpart, 4);
        rowpart += __shfl_xor(rowpart, 8);
        if (ok && (lane & 15) == 0) atomicAdd(&rs[gm], rowpart);
      }
    }
  }
}

// ---------------- weights: dst[Mp,Kp] bf16 = W^T (+ bias slot at k==Kv) ----
__global__ __launch_bounds__(256) void wt_conv(
    const float* __restrict__ W, const float* __restrict__ bias,
    ushort_t* __restrict__ dst, int Mtot, int ldw, int Kv, int Kp,
    int PADH, int VALH)
{
  const int m = blockIdx.x;
  const int h = m / PADH, c0 = m % PADH;
  const int fout = h * VALH + c0;
  const bool valid = (c0 < VALH) && (fout < Mtot);
  for (int k = threadIdx.x; k < Kp; k += blockDim.x) {
    float v = 0.f;
    if (valid) {
      if (k < Kv) v = W[(size_t)k * ldw + fout];
      else if (k == Kv) v = bias[fout];
    }
    dst[(size_t)m * Kp + k] = f2bf(v);
  }
}

// ---------------- wt_trans: dst[4][256][512] bf16 (padded W~^T per head) ---
__global__ __launch_bounds__(256) void wt_trans(
    const float* __restrict__ W, const float* __restrict__ bias,
    ushort_t* __restrict__ dst)
{
  const int rid = blockIdx.x;          // 0..1023
  const int h = rid >> 8, a = rid & 255;
  for (int f = threadIdx.x; f < 512; f += 256) {
    float v = 0.f;
    if (a < 200)       v = W[(size_t)a * 2048 + h * 512 + f];
    else if (a == 200) v = bias[h * 512 + f];
    dst[(size_t)rid * 512 + f] = f2bf(v);
  }
}

// ---------------- transpose fp32 [Kv,4096] -> bf16 [4096,Kp], bias slot ----
__global__ __launch_bounds__(256) void trans_pad(
    const float* __restrict__ src, ushort_t* __restrict__ dst, int Kv, int Kp)
{
  __shared__ float tl[64][65];
  const int t = threadIdx.x;
  const int f0 = blockIdx.x * 64;
  const int i0 = blockIdx.y * 64;
  const int c = t & 63, rbase = t >> 6;
  #pragma unroll
  for (int it = 0; it < 16; ++it) {
    int r = rbase + it * 4;
    int f = f0 + r;
    tl[r][c] = (f < Kv) ? src[(size_t)f * 4096 + i0 + c] : 0.f;
  }
  __syncthreads();
  #pragma unroll
  for (int it = 0; it < 16; ++it) {
    int r = rbase + it * 4;
    int f = f0 + c;
    if (f < Kp) {
      float v = (f < Kv) ? tl[c][r] : ((f == Kv) ? 1.f : 0.f);
      dst[(size_t)(i0 + r) * Kp + f] = f2bf(v);
    }
  }
}

// ---------------- GraphNorm layer 1: x = skip + (sum_z oP)/(sum_z r) -------
__global__ __launch_bounds__(256) void graph_norm_attn1(
    const float* __restrict__ skip, const float* __restrict__ oP,
    const float* __restrict__ r1p, float* __restrict__ out,
    const float* __restrict__ w, const float* __restrict__ b,
    const float* __restrict__ ms)
{
  __shared__ float red[4];
  const int t = threadIdx.x;
  const int row = blockIdx.x;            // 0..199
  const int h = row / 50;
  const int pr = h * 128 + row % 50;
  const float* sk = skip + (size_t)pr * 4096;
  const size_t OSTR = (size_t)512 * 4096;
  float v[16];
  float s = 0.f;
  #pragma unroll
  for (int e = 0; e < 4; ++e) {
    const int idx = t * 4 + 1024 * e;
    float4 a = *(const float4*)&sk[idx];
    float4 o0 = *(const float4*)&oP[(size_t)pr * 4096 + idx];
    float4 o1 = *(const float4*)&oP[OSTR + (size_t)pr * 4096 + idx];
    float4 o2 = *(const float4*)&oP[2 * OSTR + (size_t)pr * 4096 + idx];
    float4 o3 = *(const float4*)&oP[3 * OSTR + (size_t)pr * 4096 + idx];
    float4 r0 = *(const float4*)&r1p[(size_t)h * 4096 + idx];
    float4 r1 = *(const float4*)&r1p[(size_t)(4 + h) * 4096 + idx];
    float4 r2 = *(const float4*)&r1p[(size_t)(8 + h) * 4096 + idx];
    float4 r3 = *(const float4*)&r1p[(size_t)(12 + h) * 4096 + idx];
    v[e*4+0] = a.x + (o0.x + o1.x + o2.x + o3.x) / (r0.x + r1.x + r2.x + r3.x);
    v[e*4+1] = a.y + (o0.y + o1.y + o2.y + o3.y) / (r0.y + r1.y + r2.y + r3.y);
    v[e*4+2] = a.z + (o0.z + o1.z + o2.z + o3.z) / (r0.z + r1.z + r2.z + r3.z);
    v[e*4+3] = a.w + (o0.w + o1.w + o2.w + o3.w) / (r0.w + r1.w + r2.w + r3.w);
    s += v[e*4+0] + v[e*4+1] + v[e*4+2] + v[e*4+3];
  }
  const float mean = block_sum256(s, red) * (1.f / 4096.f);
  const float sub = mean * ms[row];
  float s2 = 0.f;
  #pragma unroll
  for (int e = 0; e < 16; ++e) { v[e] -= sub; s2 += v[e] * v[e]; }
  const float var = block_sum256(s2, red) * (1.f / 4096.f);
  const float scl = rsqrtf(var + 1e-5f) * w[row];
  const float bb = b[row];
  float* y = out + (size_t)row * 4096;
  #pragma unroll
  for (int e = 0; e < 4; ++e) {
    float o0[4];
    #pragma unroll
    for (int q = 0; q < 4; ++q) o0[q] = v[e * 4 + q] * scl + bb;
    *(float4*)&y[t * 4 + 1024 * e] = *(float4*)&o0[0];
  }
}

// ---------------- GraphNorm layer 2: x = skip + (p0+p1)/r, gn, L2, bf16 ----
__global__ __launch_bounds__(256) void graph_norm_attn2(
    const ushort_t* __restrict__ skip, const ushort_t* __restrict__ p2,
    const float* __restrict__ r2, ushort_t* __restrict__ out,
    const float* __restrict__ w, const float* __restrict__ b,
    const float* __restrict__ ms)
{
  __shared__ float red[4];
  const int t = threadIdx.x;
  const int row = blockIdx.x;            // 0..2047
  const ushort_t* sk = skip + (size_t)row * 4096;
  const ushort_t* pa = p2 + (size_t)row * 4096;
  const ushort_t* pb = p2 + (size_t)2048 * 4096 + (size_t)row * 4096;
  const float* rr = r2 + (size_t)(row >> 9) * 4096;
  float v[16];
  float s = 0.f;
  #pragma unroll
  for (int e = 0; e < 4; ++e) {
    const int idx = t * 4 + 1024 * e;
    float a[4], oa[4], ob[4];
    ld4bf(&sk[idx], a); ld4bf(&pa[idx], oa); ld4bf(&pb[idx], ob);
    float4 rv = *(const float4*)&rr[idx];
    v[e*4+0] = a[0] + (oa[0] + ob[0]) / rv.x;
    v[e*4+1] = a[1] + (oa[1] + ob[1]) / rv.y;
    v[e*4+2] = a[2] + (oa[2] + ob[2]) / rv.z;
    v[e*4+3] = a[3] + (oa[3] + ob[3]) / rv.w;
    s += v[e*4+0] + v[e*4+1] + v[e*4+2] + v[e*4+3];
  }
  const float mean = block_sum256(s, red) * (1.f / 4096.f);
  const float sub = mean * ms[row];
  float s2 = 0.f;
  #pragma unroll
  for (int e = 0; e < 16; ++e) { v[e] -= sub; s2 += v[e] * v[e]; }
  const float var = block_sum256(s2, red) * (1.f / 4096.f);
  const float scl = rsqrtf(var + 1e-5f) * w[row];
  const float bb = b[row];
  #pragma unroll
  for (int e = 0; e < 16; ++e) v[e] = v[e] * scl + bb;
  float s3 = 0.f;
  #pragma unroll
  for (int e = 0; e < 16; ++e) s3 += v[e] * v[e];
  const float osc = rsqrtf(block_sum256(s3, red));
  ushort_t* y = out + (size_t)row * 4096;
  #pragma unroll
  for (int e = 0; e < 4; ++e) {
    ushort_t o0[4];
    #pragma unroll
    for (int q = 0; q < 4; ++q) o0[q] = f2bf(v[e * 4 + q] * osc);
    *(ushort2*)&y[t * 4 + 1024 * e] = *(ushort2*)&o0[0];
    *(ushort2*)&y[t * 4 + 1024 * e + 2] = *(ushort2*)&o0[2];
  }
}

// ---------------- out = relu(g0+g1+g2+g3), float4-wide ---------------------
__global__ __launch_bounds__(256) void add4_relu(
    const float* __restrict__ g, float* __restrict__ out)
{
  const size_t i = (size_t)blockIdx.x * 256 + threadIdx.x;
  const size_t ss = (size_t)2048 * 2048 / 4;
  float4 a = ((const float4*)g)[i];
  float4 b = ((const float4*)g)[i + ss];
  float4 c = ((const float4*)g)[i + 2 * ss];
  float4 d = ((const float4*)g)[i + 3 * ss];
  float4 o;
  o.x = fmaxf(a.x + b.x + c.x + d.x, 0.f);
  o.y = fmaxf(a.y + b.y + c.y + d.y, 0.f);
  o.z = fmaxf(a.z + b.z + c.z + d.z, 0.f);
  o.w = fmaxf(a.w + b.w + c.w + d.w, 0.f);
  ((float4*)out)[i] = o;
}

extern "C" void kernel_launch(void* const* d_in, const int* in_sizes, int n_in,
                              void* d_out, int out_size, void* d_ws, size_t ws_size,
                              hipStream_t stream)
{
  (void)in_sizes; (void)n_in; (void)out_size; (void)ws_size;
  const float* lr_x = (const float*)d_in[0];
  const float* Wq1 = (const float*)d_in[1];  const float* bq1 = (const float*)d_in[2];
  const float* Wk1 = (const float*)d_in[3];  const float* bk1 = (const float*)d_in[4];
  const float* Wv1 = (const float*)d_in[5];  const float* bv1 = (const float*)d_in[6];
  const float* Ws1 = (const float*)d_in[7];  const float* bs1 = (const float*)d_in[8];
  const float* gn1w = (const float*)d_in[9]; const float* gn1b = (const float*)d_in[10];
  const float* gn1ms = (const float*)d_in[11];
  const float* Wq2 = (const float*)d_in[12]; const float* bq2 = (const float*)d_in[13];
  const float* Wk2 = (const float*)d_in[14]; const float* bk2 = (const float*)d_in[15];
  const float* Wv2 = (const float*)d_in[16]; const float* bv2 = (const float*)d_in[17];
  const float* Ws2 = (const float*)d_in[18]; const float* bs2 = (const float*)d_in[19];
  const float* gn2w = (const float*)d_in[20]; const float* gn2b = (const float*)d_in[21];
  const float* gn2ms = (const float*)d_in[22];

  // ---- workspace carve (~251 MB total, < 256 MiB cap) ----
  char* p = (char*)d_ws;
  auto alloc = [&](size_t bytes) { char* r = p; p += (bytes + 255) & ~(size_t)255; return r; };
  const size_t PSTR = (size_t)4096 * 4096;
  ushort_t* Pall = (ushort_t*)alloc(PSTR * 4 * 2);              // attn-2 P; Gram partials alias
  ushort_t* xb   = (ushort_t*)alloc((size_t)4096 * 544 * 2);
  ushort_t* qk1b = (ushort_t*)alloc((size_t)4096 * 512 * 2);
  ushort_t* v1b  = (ushort_t*)alloc((size_t)512 * 4096 * 2);
  char*     u0   = alloc((size_t)16 * 1024 * 1024);             // s1p, later h2b
  float*    s1p  = (float*)u0;                                  // [512,4096] f32 skip
  float*    h1nT = (float*)   alloc((size_t)200 * 4096 * 4);
  ushort_t* h1nb = (ushort_t*)alloc((size_t)4096 * 256 * 2);
  ushort_t* Wqk1 = (ushort_t*)alloc((size_t)512 * 544 * 2);
  ushort_t* Wv1b = (ushort_t*)alloc((size_t)512 * 544 * 2);
  ushort_t* Ws1p = (ushort_t*)alloc((size_t)512 * 544 * 2);
  ushort_t* Wcat = (ushort_t*)alloc((size_t)4096 * 256 * 2);    // [v2 | s2] weights
  ushort_t* Qt   = (ushort_t*)alloc((size_t)4 * 256 * 512 * 2); // per-head W~q^T [256,512]
  ushort_t* Kt   = (ushort_t*)alloc((size_t)4 * 256 * 512 * 2); // per-head W~k^T [256,512]
  ushort_t* Mtall= (ushort_t*)alloc((size_t)4 * 256 * 256 * 2); // per-head M^T [256,256]
  ushort_t* Tall = (ushort_t*)alloc((size_t)4 * 4096 * 256 * 2);// per-head T=XM [4096,256]
  ushort_t* vs2b = (ushort_t*)alloc((size_t)4096 * 4096 * 2);   // rows 0..2047=v2T, 2048..4095=skip2
  ushort_t* p2   = (ushort_t*)alloc((size_t)2 * 2048 * 4096 * 2);// PV-2 partials bf16
  float*    r1p  = (float*)   alloc((size_t)16 * 4096 * 4);     // attn-1 rowsum partials [z][h][4096]
  float*    r2   = (float*)   alloc((size_t)4 * 4096 * 4);
  // aliases (regions dead by the time the alias is written):
  float*    oP   = (float*)p2;     // attn-1 O partials 4x[512,4096] f32 = 32MB; p2 written later
  ushort_t* h2b  = (ushort_t*)u0;  // gn2 output: s1p dead after gn1
  float*    g4   = (float*)Pall;   // Gram partials: Pall dead after PV-2

  const dim3 b256(256, 1, 1);
  const dim3 b512(512, 1, 1);
  const float LOG2E = 1.4426950408889634f;
  const float sc1e = 0.14142135623730951f * LOG2E;  // 1/sqrt(50) * log2e
  const float sc2e = 0.04419417382415922f * LOG2E;  // 1/sqrt(512) * log2e

  hipMemsetAsync(r2, 0, (size_t)4 * 4096 * 4, stream);

  // ---- weight conversions
  wt_conv<<<dim3(256),  b256, 0, stream>>>(Wq1, bq1, Wqk1,             200, 200, 512, 544, 64, 50);
  wt_conv<<<dim3(256),  b256, 0, stream>>>(Wk1, bk1, Wqk1 + 256 * 544, 200, 200, 512, 544, 64, 50);
  wt_conv<<<dim3(512),  b256, 0, stream>>>(Wv1, bv1, Wv1b,             200, 200, 512, 544, 128, 50);
  wt_conv<<<dim3(512),  b256, 0, stream>>>(Ws1, bs1, Ws1p,             200, 200, 512, 544, 128, 50);
  wt_conv<<<dim3(2048), b256, 0, stream>>>(Wv2, bv2, Wcat,              2048, 2048, 200, 256, 2048, 2048);
  wt_conv<<<dim3(2048), b256, 0, stream>>>(Ws2, bs2, Wcat + 2048 * 256, 2048, 2048, 200, 256, 2048, 2048);
  wt_trans<<<dim3(1024), b256, 0, stream>>>(Wq2, bq2, Qt);
  wt_trans<<<dim3(1024), b256, 0, stream>>>(Wk2, bk2, Kt);
  trans_pad<<<dim3(9, 64), b256, 0, stream>>>(lr_x, xb, 512, 544);

  // ---- layer-1 projections (128^2 kernel)
  mfma_bt<1, false, false><<<dim3(4, 32), b256, 0, stream>>>(
      xb, Wqk1, qk1b, 544, 544, 512, 544, 1, 0, 0, 0, -1, 0, -1, 4096, 1.f, nullptr);
  mfma_bt<1, false, false><<<dim3(32, 4), b256, 0, stream>>>(
      Wv1b, xb, v1b, 544, 544, 4096, 544, 1, 0, 0, 0, -1, 0, -1, 512, 1.f, nullptr);
  mfma_bt<0, false, false><<<dim3(32, 4), b256, 0, stream>>>(
      Ws1p, xb, s1p, 544, 544, 4096, 544, 1, 0, 0, 0, -1, 0, 127, 50, 1.f, nullptr);

  // ---- attention 1: FUSED flash-style, KV-split x4 (partials, no atomics)
  fused_attn1<<<dim3(64, 4, 4), b256, 0, stream>>>(qk1b, v1b, oP, r1p, sc1e);
  graph_norm_attn1<<<dim3(200), b256, 0, stream>>>(s1p, oP, r1p, h1nT, gn1w, gn1b, gn1ms);
  trans_pad<<<dim3(4, 64), b256, 0, stream>>>(h1nT, h1nb, 200, 256);

  // ---- layer-2 V+skip projection (K=256, 128^2 kernel)
  mfma_bt<1, false, false><<<dim3(32, 32), b256, 0, stream>>>(
      Wcat, h1nb, vs2b, 256, 256, 4096, 256, 1, 0, 0, 0, -1, 0, -1, 4096, 1.f, nullptr);

  // ---- attention 2 scores via low-rank factorization:
  mfma_bt<1, false, false><<<dim3(2, 2, 4), b256, 0, stream>>>(
      Kt, Qt, Mtall, 512, 512, 256, 512, 1,
      (size_t)256 * 512, (size_t)256 * 512, (size_t)256 * 256, -1, 0, -1, 256, 1.f, nullptr);
  mfma_bt<1, false, false><<<dim3(2, 32, 4), b256, 0, stream>>>(
      h1nb, Mtall, Tall, 256, 256, 256, 256, 1,
      0, (size_t)256 * 256, (size_t)4096 * 256, -1, 0, -1, 4096, 1.f, nullptr);
  mfma_bt<1, false, true><<<dim3(32, 32, 4), b256, 0, stream>>>(
      Tall, h1nb, Pall, 256, 256, 4096, 256, 1,
      (size_t)4096 * 256, 0, PSTR, -1, 0, -1, 4096, sc2e, r2);

  // ---- PV-2: LONG K (Kc=2048) -> 8-phase kernel; bf16 partials
  mfma256_8ph<1, false, false><<<dim3(16, 8, 2), b512, 0, stream>>>(
      vs2b, Pall, p2, 4096, 4096, 4096, 4096, 2,
      0, 0, (size_t)2048 * 4096, 9, PSTR, 2048, 1.f, nullptr);
  graph_norm_attn2<<<dim3(2048), b256, 0, stream>>>(
      vs2b + (size_t)2048 * 4096, p2, r2, h2b, gn2w, gn2b, gn2ms);

  // ---- out = relu(h2n . h2n^T): LONG K (Kc=1024) -> 8-phase; partials+reduce
  mfma256_8ph<0, false, false><<<dim3(8, 8, 4), b512, 0, stream>>>(
      h2b, h2b, g4, 4096, 4096, 2048, 4096, 4,
      0, 0, (size_t)2048 * 2048, -1, 0, 2048, 1.f, nullptr);
  add4_relu<<<dim3(4096), b256, 0, stream>>>(g4, (float*)d_out);
}

// Round 12
// 422.520 us; speedup vs baseline: 1.2643x; 1.1833x over previous
//
#include <hip/hip_runtime.h>
#include <math.h>

typedef unsigned int u32;
typedef unsigned short ushort_t;
typedef __attribute__((ext_vector_type(8))) short short8;
typedef __attribute__((ext_vector_type(4))) float f32x4;

__device__ __forceinline__ ushort_t f2bf(float x) {
  u32 u = __float_as_uint(x);
  u32 r = (u + 0x7fffu + ((u >> 16) & 1u)) >> 16;
  return (ushort_t)r;
}
__device__ __forceinline__ float bf2f(u32 s) {
  return __uint_as_float(s << 16);
}
__device__ __forceinline__ void ld4bf(const ushort_t* p, float* o) {
  uint2 u = *(const uint2*)p;
  o[0] = bf2f(u.x & 0xffffu); o[1] = bf2f(u.x >> 16);
  o[2] = bf2f(u.y & 0xffffu); o[3] = bf2f(u.y >> 16);
}

// ---------------- block reduction helpers (256 threads = 4 waves) ----------
__device__ __forceinline__ float block_sum256(float v, float* red) {
  #pragma unroll
  for (int o = 32; o > 0; o >>= 1) v += __shfl_down(v, o, 64);
  __syncthreads();
  if ((threadIdx.x & 63) == 0) red[threadIdx.x >> 6] = v;
  __syncthreads();
  return red[0] + red[1] + red[2] + red[3];
}

// =====================================================================
// Fused attention layer 1, v3: LDS-staged double-buffered K/V tiles.
// Block = 512 thr (8 waves, q-tile 128 rows). Grid (32, 4heads, 4kvchunks).
// Per KV-tile(64 nodes): stage K/V once per block (global_load_lds, XOR
// swizzle both-sides), dbuf prefetch of kt+1 before compute of kt (m97
// 2-phase), one __syncthreads per tile. S=QK^T MFMA (frags from LDS),
// exp2 in-reg, P via per-wave-private LDS rows, O += P.V (frags from LDS).
// Outputs partials: oP[z][512][4096] f32, r1p[z][4][4096] f32.
// =====================================================================
__global__ __launch_bounds__(512) void fused_attn1(
    const ushort_t* __restrict__ qk, const ushort_t* __restrict__ v,
    float* __restrict__ oP, float* __restrict__ r1p, float scale)
{
  __shared__ ushort_t Kl[2][4096];     // 2 x 8 KB (64 rows x 128 B)
  __shared__ ushort_t Vl[2][4096];     // 2 x 8 KB
  __shared__ ushort_t Pl[128][80];     // 20 KB (row stride 160 B)
  const int t = threadIdx.x;
  const int lane = t & 63;
  const int wv = t >> 6;               // 0..7, wave owns q rows wv*16..+15
  const int h = blockIdx.y;
  const int m0 = blockIdx.x * 128;
  const int z = blockIdx.z;
  const int lr = lane & 15;
  const int hk = lane >> 4;            // 8-elem k-chunk 0..3

  // Q A-frags (constant over KV loop): rows m0+wv*16+lr, head cols
  short8 aq0, aq1;
  {
    const ushort_t* qrow = qk + (size_t)(m0 + wv * 16 + lr) * 512 + h * 64;
    aq0 = *(const short8*)(qrow + hk * 8);
    aq1 = *(const short8*)(qrow + 32 + hk * 8);
  }

  f32x4 oAcc[4];
  #pragma unroll
  for (int i = 0; i < 4; ++i) oAcc[i] = (f32x4){0.f, 0.f, 0.f, 0.f};
  float racc[4] = {0.f, 0.f, 0.f, 0.f};

  const size_t kbase = (size_t)256 + h * 64;
  const int rS = t >> 3;               // staging row 0..63
  const int cS = t & 7;                // staging chunk slot
  const int lcS = cS ^ (rS & 7);       // inverse-swizzled source chunk

  for (int i0 = 0; i0 < 1; ++i0) {}    // (no-op, keeps structure clear)

  // prologue: stage tile 0 of this z-chunk
  {
    const int n0 = z * 16 * 64;
    __builtin_amdgcn_global_load_lds(
        (const __attribute__((address_space(1))) u32*)(qk + (size_t)(n0 + rS) * 512 + kbase + lcS * 8),
        (__attribute__((address_space(3))) u32*)(&Kl[0][t * 8]), 16, 0, 0);
    __builtin_amdgcn_global_load_lds(
        (const __attribute__((address_space(1))) u32*)(v + (size_t)(h * 128 + rS) * 4096 + n0 + lcS * 8),
        (__attribute__((address_space(3))) u32*)(&Vl[0][t * 8]), 16, 0, 0);
  }
  __syncthreads();

  int cur = 0;
  for (int it = 0; it < 16; ++it) {
    // prefetch next tile into buf^1 (async; drains at the end-of-iter barrier)
    if (it + 1 < 16) {
      const int n1 = (z * 16 + it + 1) * 64;
      __builtin_amdgcn_global_load_lds(
          (const __attribute__((address_space(1))) u32*)(qk + (size_t)(n1 + rS) * 512 + kbase + lcS * 8),
          (__attribute__((address_space(3))) u32*)(&Kl[cur ^ 1][t * 8]), 16, 0, 0);
      __builtin_amdgcn_global_load_lds(
          (const __attribute__((address_space(1))) u32*)(v + (size_t)(h * 128 + rS) * 4096 + n1 + lcS * 8),
          (__attribute__((address_space(3))) u32*)(&Vl[cur ^ 1][t * 8]), 16, 0, 0);
    }
    // ---- S-tile [16q x 64n] per wave (K frags from LDS, swizzled)
    f32x4 sA[4];
    #pragma unroll
    for (int nf = 0; nf < 4; ++nf) {
      const int rl = nf * 16 + lr;
      const char* kb = (const char*)&Kl[cur][0] + rl * 128;
      short8 b0 = *(const short8*)(kb + ((hk ^ (rl & 7)) * 16));
      short8 b1 = *(const short8*)(kb + (((4 + hk) ^ (rl & 7)) * 16));
      f32x4 sa = (f32x4){0.f, 0.f, 0.f, 0.f};
      sa = __builtin_amdgcn_mfma_f32_16x16x32_bf16(aq0, b0, sa, 0, 0, 0);
      sa = __builtin_amdgcn_mfma_f32_16x16x32_bf16(aq1, b1, sa, 0, 0, 0);
      sA[nf] = sa;
    }
    // ---- exp2 + rowsum + P->LDS (per-wave-private rows, no barrier)
    #pragma unroll
    for (int nf = 0; nf < 4; ++nf) {
      #pragma unroll
      for (int r = 0; r < 4; ++r) {
        float e = exp2f(sA[nf][r] * scale);
        racc[r] += e;
        Pl[wv * 16 + hk * 4 + r][nf * 16 + lr] = f2bf(e);
      }
    }
    // ---- PV: O[16q x 64f] += P[16q x 64n] . V[64f x 64n]^T
    short8 ap0 = *(const short8*)&Pl[wv * 16 + lr][hk * 8];
    short8 ap1 = *(const short8*)&Pl[wv * 16 + lr][32 + hk * 8];
    #pragma unroll
    for (int ff = 0; ff < 4; ++ff) {
      const int rl = ff * 16 + lr;
      const char* vb = (const char*)&Vl[cur][0] + rl * 128;
      short8 b0 = *(const short8*)(vb + ((hk ^ (rl & 7)) * 16));
      short8 b1 = *(const short8*)(vb + (((4 + hk) ^ (rl & 7)) * 16));
      oAcc[ff] = __builtin_amdgcn_mfma_f32_16x16x32_bf16(ap0, b0, oAcc[ff], 0, 0, 0);
      oAcc[ff] = __builtin_amdgcn_mfma_f32_16x16x32_bf16(ap1, b1, oAcc[ff], 0, 0, 0);
    }
    __syncthreads();      // drains prefetch (vmcnt) + guards buffer flip
    cur ^= 1;
  }

  // ---- partial row-sums: reduce across the 16 col-lanes
  #pragma unroll
  for (int r = 0; r < 4; ++r) {
    racc[r] += __shfl_xor(racc[r], 1);
    racc[r] += __shfl_xor(racc[r], 2);
    racc[r] += __shfl_xor(racc[r], 4);
    racc[r] += __shfl_xor(racc[r], 8);
  }
  if (lr == 0) {
    float* rp = r1p + ((size_t)z * 4 + h) * 4096;
    #pragma unroll
    for (int r = 0; r < 4; ++r) rp[m0 + wv * 16 + hk * 4 + r] = racc[r];
  }
  // ---- store O partial (plain f32, feature-major scatter)
  float* ob = oP + (size_t)z * 512 * 4096;
  #pragma unroll
  for (int ff = 0; ff < 4; ++ff) {
    const size_t fbase = (size_t)(h * 128 + ff * 16 + lr) * 4096;
    #pragma unroll
    for (int r = 0; r < 4; ++r) {
      const int q = m0 + wv * 16 + hk * 4 + r;
      ob[fbase + q] = oAcc[ff][r];
    }
  }
}

// =====================================================================
// 256x256-tile, 8-phase, counted-vmcnt MFMA GEMM. LONG-K only (R7 lesson).
// =====================================================================
#define RD_A(bb, mm, cc) (*(const short8*)(lsAc + (bb)*32768 + arow + (mm)*2048 + (cc)))
#define RD_B(bb, nn, cc) (*(const short8*)(lsBc + (bb)*32768 + brow + (nn)*2048 + (cc)))

#define MM8(nn, bv) { \
  acc[0][nn] = __builtin_amdgcn_mfma_f32_16x16x32_bf16(a0, bv, acc[0][nn], 0,0,0); \
  acc[1][nn] = __builtin_amdgcn_mfma_f32_16x16x32_bf16(a1, bv, acc[1][nn], 0,0,0); \
  acc[2][nn] = __builtin_amdgcn_mfma_f32_16x16x32_bf16(a2, bv, acc[2][nn], 0,0,0); \
  acc[3][nn] = __builtin_amdgcn_mfma_f32_16x16x32_bf16(a3, bv, acc[3][nn], 0,0,0); \
  acc[4][nn] = __builtin_amdgcn_mfma_f32_16x16x32_bf16(a4, bv, acc[4][nn], 0,0,0); \
  acc[5][nn] = __builtin_amdgcn_mfma_f32_16x16x32_bf16(a5, bv, acc[5][nn], 0,0,0); \
  acc[6][nn] = __builtin_amdgcn_mfma_f32_16x16x32_bf16(a6, bv, acc[6][nn], 0,0,0); \
  acc[7][nn] = __builtin_amdgcn_mfma_f32_16x16x32_bf16(a7, bv, acc[7][nn], 0,0,0); }

#define STG(BASE, LD, LS, bb, hf, tt) { \
  _Pragma("unroll") \
  for (int ii = 0; ii < 2; ++ii) { \
    const int s_ = t + ii * 512; \
    const int r_ = s_ >> 3; \
    const int lc_ = (s_ & 7) ^ (r_ & 7); \
    __builtin_amdgcn_global_load_lds( \
      (const __attribute__((address_space(1))) u32*)((BASE) + (size_t)((hf) * 128 + r_) * (LD) + (size_t)(tt) * 64 + lc_ * 8), \
      (__attribute__((address_space(3))) u32*)(&(LS)[bb][(hf) * 8192 + s_ * 8]), 16, 0, 0); \
  } }

#define BAR() __builtin_amdgcn_s_barrier()
#define PRIO(x) __builtin_amdgcn_s_setprio(x)

#define GRP(bf, tS1, tS2) { \
  a0=RD_A(bf,0,c0); a1=RD_A(bf,1,c0); a2=RD_A(bf,2,c0); a3=RD_A(bf,3,c0); \
  a4=RD_A(bf,4,c0); a5=RD_A(bf,5,c0); a6=RD_A(bf,6,c0); a7=RD_A(bf,7,c0); \
  b0=RD_B(bf,0,c0); b1=RD_B(bf,1,c0); \
  STG(Ab, lda, lsA, 1-(bf), 1, tS1); STG(Bb, ldb, lsB, 1-(bf), 0, tS1); \
  BAR(); PRIO(1); MM8(0, b0); MM8(1, b1); PRIO(0); BAR(); \
  b2=RD_B(bf,2,c0); b3=RD_B(bf,3,c0); \
  STG(Bb, ldb, lsB, 1-(bf), 1, tS1); \
  BAR(); PRIO(1); MM8(2, b2); MM8(3, b3); PRIO(0); BAR(); \
  a0=RD_A(bf,0,c1); a1=RD_A(bf,1,c1); a2=RD_A(bf,2,c1); a3=RD_A(bf,3,c1); \
  a4=RD_A(bf,4,c1); a5=RD_A(bf,5,c1); a6=RD_A(bf,6,c1); a7=RD_A(bf,7,c1); \
  b0=RD_B(bf,0,c1); b1=RD_B(bf,1,c1); \
  BAR(); PRIO(1); MM8(0, b0); MM8(1, b1); PRIO(0); BAR(); \
  b2=RD_B(bf,2,c1); b3=RD_B(bf,3,c1); \
  STG(Ab, lda, lsA, (bf), 0, tS2); \
  BAR(); PRIO(1); MM8(2, b2); MM8(3, b3); PRIO(0); \
  asm volatile("s_waitcnt vmcnt(2)" ::: "memory"); \
  BAR(); }

template<int CMODE, bool RELU, bool EXPSUM>
__global__ __launch_bounds__(512, 2) void mfma256_8ph(
    const ushort_t* __restrict__ A, const ushort_t* __restrict__ B,
    void* __restrict__ Cv, int lda, int ldb, int ldc,
    int K, int zsplit, size_t zA, size_t zB, size_t zC,
    int bShift, size_t bHead, int Mvalid, float scale,
    float* __restrict__ Rs)
{
  __shared__ ushort_t lsA[2][16384];
  __shared__ ushort_t lsB[2][16384];
  const int t = threadIdx.x;
  const int gx = gridDim.x;
  const int nwg = gx * gridDim.y;
  const int bid = blockIdx.y * gx + blockIdx.x;
  const int qq = nwg >> 3, rr_ = nwg & 7;
  const int xcd = bid & 7, idx = bid >> 3;
  const int swz = (xcd < rr_ ? xcd * (qq + 1) : rr_ * (qq + 1) + (xcd - rr_) * qq) + idx;
  const int m0 = (swz / gx) * 256;
  const int n0 = (swz % gx) * 256;
  const int z = blockIdx.z;
  int Kc = K, kOff = 0;
  size_t aZ = 0, bZ = 0, cZ = 0;
  if (zsplit > 1) { Kc = K / zsplit; kOff = z * Kc; cZ = (size_t)z * zC; }
  else { aZ = (size_t)z * zA; bZ = (size_t)z * zB; cZ = (size_t)z * zC; }
  const ushort_t* Ab = A + aZ + (size_t)m0 * lda + kOff;
  const ushort_t* Bb = B + bZ + (size_t)n0 * ldb + kOff
                     + (bShift >= 0 ? (size_t)(m0 >> bShift) * bHead : 0);
  const int NT = Kc / 64;

  f32x4 acc[8][4];
  #pragma unroll
  for (int i = 0; i < 8; ++i)
    #pragma unroll
    for (int j = 0; j < 4; ++j) acc[i][j] = (f32x4){0.f, 0.f, 0.f, 0.f};

  const int lane = t & 63;
  const int wv = t >> 6;
  const int wr = (wv >> 2) * 128;
  const int wc = (wv & 3) * 64;
  const int lr = lane & 15;
  const int kc = lane >> 4;
  const int sw = lane & 7;
  const int c0 = (kc ^ sw) * 16;
  const int c1 = c0 ^ 64;
  const int arow = (wr + lr) * 128;
  const int brow = (wc + lr) * 128;
  const char* lsAc = (const char*)lsA;
  const char* lsBc = (const char*)lsB;

  short8 a0, a1, a2, a3, a4, a5, a6, a7, b0, b1, b2, b3;

  STG(Ab, lda, lsA, 0, 0, 0); STG(Ab, lda, lsA, 0, 1, 0);
  STG(Bb, ldb, lsB, 0, 0, 0); STG(Bb, ldb, lsB, 0, 1, 0);
  STG(Ab, lda, lsA, 1, 0, 1);
  asm volatile("s_waitcnt vmcnt(2)" ::: "memory");
  BAR();

  const int NITER = NT >> 1;
  for (int it = 0; it < NITER; ++it) {
    const int tb = 2 * it;
    const int s1 = tb + 1;
    const int s2 = (tb + 2 < NT) ? tb + 2 : 0;
    const int s3 = (tb + 3 < NT) ? tb + 3 : 0;
    GRP(0, s1, s2)
    GRP(1, s2, s3)
  }

  const int row4 = (lane >> 4) * 4;
  const int coln = lane & 15;
  float* Cf = (float*)Cv + cZ;
  ushort_t* Ch = (ushort_t*)Cv + cZ;
  float* rs = EXPSUM ? (Rs + (size_t)z * 4096) : nullptr;
  #pragma unroll
  for (int m = 0; m < 8; ++m) {
    #pragma unroll
    for (int r = 0; r < 4; ++r) {
      const int gm = m0 + wr + m * 16 + row4 + r;
      const bool ok = gm < Mvalid;
      float rowpart = 0.f;
      #pragma unroll
      for (int n = 0; n < 4; ++n) {
        const int gn = n0 + wc + n * 16 + coln;
        float v = acc[m][n][r] * scale;
        if (EXPSUM) { v = exp2f(v); rowpart += v; }
        if (RELU) v = fmaxf(v, 0.f);
        if (ok) {
          if (CMODE == 0)      Cf[(size_t)gm * ldc + gn] = v;
          else if (CMODE == 1) Ch[(size_t)gm * ldc + gn] = f2bf(v);
          else                 atomicAdd(&Cf[(size_t)gm * ldc + gn], v);
        }
      }
      if (EXPSUM) {
        rowpart += __shfl_xor(rowpart, 1);
        rowpart += __shfl_xor(rowpart, 2);
        rowpart += __shfl_xor(rowpart, 4);
        rowpart += __shfl_xor(rowpart, 8);
        if (ok && (lane & 15) == 0) atomicAdd(&rs[gm], rowpart);
      }
    }
  }
}

#undef GRP
#undef STG
#undef MM8
#undef RD_A
#undef RD_B

// ================= 128x128-tile MFMA GEMM, 256 threads (SHORT-K) ===========
template<int CMODE, bool RELU, bool EXPSUM>
__global__ __launch_bounds__(256) void mfma_bt(
    const ushort_t* __restrict__ A, const ushort_t* __restrict__ B,
    void* __restrict__ Cv, int lda, int ldb, int ldc,
    int K, int Ksplit, size_t zA, size_t zB, size_t zC,
    int bShift, size_t bHead, int mMask, int Mvalid, float scale,
    float* __restrict__ Rs)
{
  __shared__ ushort_t lsA[2][128 * 32];
  __shared__ ushort_t lsB[2][128 * 32];
  const int t  = threadIdx.x;
  const int m0 = blockIdx.y * 128;
  const int n0 = blockIdx.x * 128;
  const int z = blockIdx.z;
  int Kc = K, kOff = 0;
  size_t aZ = 0, bZ = 0, cZ = 0;
  if (Ksplit > 1) { Kc = K / Ksplit; kOff = z * Kc; cZ = (size_t)z * zC; }
  else { aZ = (size_t)z * zA; bZ = (size_t)z * zB; cZ = (size_t)z * zC; }
  const int NT = Kc / 32;
  const ushort_t* Ab = A + aZ + (size_t)m0 * lda + kOff;
  const ushort_t* Bb = B + bZ + (size_t)n0 * ldb + kOff
                     + (bShift >= 0 ? (size_t)(m0 >> bShift) * bHead : 0);
  const int cs = t & 3;

  f32x4 acc[4][4];
  #pragma unroll
  for (int i = 0; i < 4; ++i)
    #pragma unroll
    for (int j = 0; j < 4; ++j) acc[i][j] = (f32x4){0.f, 0.f, 0.f, 0.f};

  const int lane = t & 63;
  const int wv = t >> 6;
  const int wr = (wv >> 1) * 64;
  const int wc = (wv & 1) * 64;
  const int lr = lane & 15;
  const int kc = lane >> 4;

  int roffA[4], roffB[4];
  #pragma unroll
  for (int m = 0; m < 4; ++m) {
    int ra = wr + m * 16 + lr;
    roffA[m] = ra * 64 + ((kc ^ (ra & 3)) * 16);
    int rb = wc + m * 16 + lr;
    roffB[m] = rb * 64 + ((kc ^ (rb & 3)) * 16);
  }

  auto stage = [&](int buf, int kt) {
    const ushort_t* As = Ab + kt * 32;
    const ushort_t* Bs = Bb + kt * 32;
    #pragma unroll
    for (int i = 0; i < 2; ++i) {
      int s = t + i * 256;
      int r = s >> 2;
      int c = cs ^ (r & 3);
      __builtin_amdgcn_global_load_lds(
          (const __attribute__((address_space(1))) u32*)(As + (size_t)r * lda + c * 8),
          (__attribute__((address_space(3))) u32*)(&lsA[buf][s * 8]), 16, 0, 0);
    }
    #pragma unroll
    for (int i = 0; i < 2; ++i) {
      int s = t + i * 256;
      int r = s >> 2;
      int c = cs ^ (r & 3);
      __builtin_amdgcn_global_load_lds(
          (const __attribute__((address_space(1))) u32*)(Bs + (size_t)r * ldb + c * 8),
          (__attribute__((address_space(3))) u32*)(&lsB[buf][s * 8]), 16, 0, 0);
    }
  };

  stage(0, 0);
  __syncthreads();
  int cur = 0;
  for (int kt = 0; kt < NT; ++kt) {
    if (kt + 1 < NT) stage(cur ^ 1, kt + 1);
    short8 af[4], bfr[4];
    const char* baseA = (const char*)&lsA[cur][0];
    const char* baseB = (const char*)&lsB[cur][0];
    #pragma unroll
    for (int m = 0; m < 4; ++m) af[m]  = *(const short8*)(baseA + roffA[m]);
    #pragma unroll
    for (int n = 0; n < 4; ++n) bfr[n] = *(const short8*)(baseB + roffB[n]);
    #pragma unroll
    for (int m = 0; m < 4; ++m)
      #pragma unroll
      for (int n = 0; n < 4; ++n)
        acc[m][n] = __builtin_amdgcn_mfma_f32_16x16x32_bf16(af[m], bfr[n], acc[m][n], 0, 0, 0);
    __syncthreads();
    cur ^= 1;
  }

  const int row4 = (lane >> 4) * 4;
  const int coln = lane & 15;
  float* Cf = (float*)Cv + cZ;
  ushort_t* Ch = (ushort_t*)Cv + cZ;
  float* rs = EXPSUM ? (Rs + (size_t)z * 4096) : nullptr;
  #pragma unroll
  for (int m = 0; m < 4; ++m) {
    #pragma unroll
    for (int r = 0; r < 4; ++r) {
      const int gm = m0 + wr + m * 16 + row4 + r;
      const bool ok = (mMask >= 0) ? ((gm & mMask) < Mvalid) : (gm < Mvalid);
      float rowpart = 0.f;
      #pragma unroll
      for (int n = 0; n < 4; ++n) {
        const int gn = n0 + wc + n * 16 + coln;
        float v = acc[m][n][r] * scale;
        if (EXPSUM) { v = exp2f(v); rowpart += v; }
        if (RELU) v = fmaxf(v, 0.f);
        if (ok) {
          if (CMODE == 0)      Cf[(size_t)gm * ldc + gn] = v;
          else if (CMODE == 1) Ch[(size_t)gm * ldc + gn] = f2bf(v);
          else                 atomicAdd(&Cf[(size_t)gm * ldc + gn], v);
        }
      }
      if (EXPSUM) {
        rowpart += __shfl_xor(rowpart, 1);
        rowpart += __shfl_xor(rowpart, 2);
        rowpart += __shfl_xor(rowpart, 4);
        rowpart += __shfl_xor(rowpart, 8);
        if (ok && (lane & 15) == 0) atomicAdd(&rs[gm], rowpart);
      }
    }
  }
}

// ---------------- weights: dst[Mp,Kp] bf16 = W^T (+ bias slot at k==Kv) ----
__global__ __launch_bounds__(256) void wt_conv(
    const float* __restrict__ W, const float* __restrict__ bias,
    ushort_t* __restrict__ dst, int Mtot, int ldw, int Kv, int Kp,
    int PADH, int VALH)
{
  const int m = blockIdx.x;
  const int h = m / PADH, c0 = m % PADH;
  const int fout = h * VALH + c0;
  const bool valid = (c0 < VALH) && (fout < Mtot);
  for (int k = threadIdx.x; k < Kp; k += blockDim.x) {
    float v = 0.f;
    if (valid) {
      if (k < Kv) v = W[(size_t)k * ldw + fout];
      else if (k == Kv) v = bias[fout];
    }
    dst[(size_t)m * Kp + k] = f2bf(v);
  }
}

// ---------------- wt_trans: dst[4][256][512] bf16 (padded W~^T per head) ---
__global__ __launch_bounds__(256) void wt_trans(
    const float* __restrict__ W, const float* __restrict__ bias,
    ushort_t* __restrict__ dst)
{
  const int rid = blockIdx.x;          // 0..1023
  const int h = rid >> 8, a = rid & 255;
  for (int f = threadIdx.x; f < 512; f += 256) {
    float v = 0.f;
    if (a < 200)       v = W[(size_t)a * 2048 + h * 512 + f];
    else if (a == 200) v = bias[h * 512 + f];
    dst[(size_t)rid * 512 + f] = f2bf(v);
  }
}

// ---------------- transpose fp32 [Kv,4096] -> bf16 [4096,Kp], bias slot ----
__global__ __launch_bounds__(256) void trans_pad(
    const float* __restrict__ src, ushort_t* __restrict__ dst, int Kv, int Kp)
{
  __shared__ float tl[64][65];
  const int t = threadIdx.x;
  const int f0 = blockIdx.x * 64;
  const int i0 = blockIdx.y * 64;
  const int c = t & 63, rbase = t >> 6;
  #pragma unroll
  for (int it = 0; it < 16; ++it) {
    int r = rbase + it * 4;
    int f = f0 + r;
    tl[r][c] = (f < Kv) ? src[(size_t)f * 4096 + i0 + c] : 0.f;
  }
  __syncthreads();
  #pragma unroll
  for (int it = 0; it < 16; ++it) {
    int r = rbase + it * 4;
    int f = f0 + c;
    if (f < Kp) {
      float v = (f < Kv) ? tl[c][r] : ((f == Kv) ? 1.f : 0.f);
      dst[(size_t)(i0 + r) * Kp + f] = f2bf(v);
    }
  }
}

// ---------------- GraphNorm layer 1: x = skip + (sum_z oP)/(sum_z r) -------
__global__ __launch_bounds__(256) void graph_norm_attn1(
    const float* __restrict__ skip, const float* __restrict__ oP,
    const float* __restrict__ r1p, float* __restrict__ out,
    const float* __restrict__ w, const float* __restrict__ b,
    const float* __restrict__ ms)
{
  __shared__ float red[4];
  const int t = threadIdx.x;
  const int row = blockIdx.x;            // 0..199
  const int h = row / 50;
  const int pr = h * 128 + row % 50;
  const float* sk = skip + (size_t)pr * 4096;
  const size_t OSTR = (size_t)512 * 4096;
  float v[16];
  float s = 0.f;
  #pragma unroll
  for (int e = 0; e < 4; ++e) {
    const int idx = t * 4 + 1024 * e;
    float4 a = *(const float4*)&sk[idx];
    float4 o0 = *(const float4*)&oP[(size_t)pr * 4096 + idx];
    float4 o1 = *(const float4*)&oP[OSTR + (size_t)pr * 4096 + idx];
    float4 o2 = *(const float4*)&oP[2 * OSTR + (size_t)pr * 4096 + idx];
    float4 o3 = *(const float4*)&oP[3 * OSTR + (size_t)pr * 4096 + idx];
    float4 r0 = *(const float4*)&r1p[(size_t)h * 4096 + idx];
    float4 r1 = *(const float4*)&r1p[(size_t)(4 + h) * 4096 + idx];
    float4 r2 = *(const float4*)&r1p[(size_t)(8 + h) * 4096 + idx];
    float4 r3 = *(const float4*)&r1p[(size_t)(12 + h) * 4096 + idx];
    v[e*4+0] = a.x + (o0.x + o1.x + o2.x + o3.x) / (r0.x + r1.x + r2.x + r3.x);
    v[e*4+1] = a.y + (o0.y + o1.y + o2.y + o3.y) / (r0.y + r1.y + r2.y + r3.y);
    v[e*4+2] = a.z + (o0.z + o1.z + o2.z + o3.z) / (r0.z + r1.z + r2.z + r3.z);
    v[e*4+3] = a.w + (o0.w + o1.w + o2.w + o3.w) / (r0.w + r1.w + r2.w + r3.w);
    s += v[e*4+0] + v[e*4+1] + v[e*4+2] + v[e*4+3];
  }
  const float mean = block_sum256(s, red) * (1.f / 4096.f);
  const float sub = mean * ms[row];
  float s2 = 0.f;
  #pragma unroll
  for (int e = 0; e < 16; ++e) { v[e] -= sub; s2 += v[e] * v[e]; }
  const float var = block_sum256(s2, red) * (1.f / 4096.f);
  const float scl = rsqrtf(var + 1e-5f) * w[row];
  const float bb = b[row];
  float* y = out + (size_t)row * 4096;
  #pragma unroll
  for (int e = 0; e < 4; ++e) {
    float o0[4];
    #pragma unroll
    for (int q = 0; q < 4; ++q) o0[q] = v[e * 4 + q] * scl + bb;
    *(float4*)&y[t * 4 + 1024 * e] = *(float4*)&o0[0];
  }
}

// ---------------- GraphNorm layer 2: x = skip + (p0+p1)/r, gn, L2, bf16 ----
__global__ __launch_bounds__(256) void graph_norm_attn2(
    const ushort_t* __restrict__ skip, const ushort_t* __restrict__ p2,
    const float* __restrict__ r2, ushort_t* __restrict__ out,
    const float* __restrict__ w, const float* __restrict__ b,
    const float* __restrict__ ms)
{
  __shared__ float red[4];
  const int t = threadIdx.x;
  const int row = blockIdx.x;            // 0..2047
  const ushort_t* sk = skip + (size_t)row * 4096;
  const ushort_t* pa = p2 + (size_t)row * 4096;
  const ushort_t* pb = p2 + (size_t)2048 * 4096 + (size_t)row * 4096;
  const float* rr = r2 + (size_t)(row >> 9) * 4096;
  float v[16];
  float s = 0.f;
  #pragma unroll
  for (int e = 0; e < 4; ++e) {
    const int idx = t * 4 + 1024 * e;
    float a[4], oa[4], ob[4];
    ld4bf(&sk[idx], a); ld4bf(&pa[idx], oa); ld4bf(&pb[idx], ob);
    float4 rv = *(const float4*)&rr[idx];
    v[e*4+0] = a[0] + (oa[0] + ob[0]) / rv.x;
    v[e*4+1] = a[1] + (oa[1] + ob[1]) / rv.y;
    v[e*4+2] = a[2] + (oa[2] + ob[2]) / rv.z;
    v[e*4+3] = a[3] + (oa[3] + ob[3]) / rv.w;
    s += v[e*4+0] + v[e*4+1] + v[e*4+2] + v[e*4+3];
  }
  const float mean = block_sum256(s, red) * (1.f / 4096.f);
  const float sub = mean * ms[row];
  float s2 = 0.f;
  #pragma unroll
  for (int e = 0; e < 16; ++e) { v[e] -= sub; s2 += v[e] * v[e]; }
  const float var = block_sum256(s2, red) * (1.f / 4096.f);
  const float scl = rsqrtf(var + 1e-5f) * w[row];
  const float bb = b[row];
  #pragma unroll
  for (int e = 0; e < 16; ++e) v[e] = v[e] * scl + bb;
  float s3 = 0.f;
  #pragma unroll
  for (int e = 0; e < 16; ++e) s3 += v[e] * v[e];
  const float osc = rsqrtf(block_sum256(s3, red));
  ushort_t* y = out + (size_t)row * 4096;
  #pragma unroll
  for (int e = 0; e < 4; ++e) {
    ushort_t o0[4];
    #pragma unroll
    for (int q = 0; q < 4; ++q) o0[q] = f2bf(v[e * 4 + q] * osc);
    *(ushort2*)&y[t * 4 + 1024 * e] = *(ushort2*)&o0[0];
    *(ushort2*)&y[t * 4 + 1024 * e + 2] = *(ushort2*)&o0[2];
  }
}

// ---------------- out = relu(g0+g1+g2+g3), float4-wide ---------------------
__global__ __launch_bounds__(256) void add4_relu(
    const float* __restrict__ g, float* __restrict__ out)
{
  const size_t i = (size_t)blockIdx.x * 256 + threadIdx.x;
  const size_t ss = (size_t)2048 * 2048 / 4;
  float4 a = ((const float4*)g)[i];
  float4 b = ((const float4*)g)[i + ss];
  float4 c = ((const float4*)g)[i + 2 * ss];
  float4 d = ((const float4*)g)[i + 3 * ss];
  float4 o;
  o.x = fmaxf(a.x + b.x + c.x + d.x, 0.f);
  o.y = fmaxf(a.y + b.y + c.y + d.y, 0.f);
  o.z = fmaxf(a.z + b.z + c.z + d.z, 0.f);
  o.w = fmaxf(a.w + b.w + c.w + d.w, 0.f);
  ((float4*)out)[i] = o;
}

extern "C" void kernel_launch(void* const* d_in, const int* in_sizes, int n_in,
                              void* d_out, int out_size, void* d_ws, size_t ws_size,
                              hipStream_t stream)
{
  (void)in_sizes; (void)n_in; (void)out_size; (void)ws_size;
  const float* lr_x = (const float*)d_in[0];
  const float* Wq1 = (const float*)d_in[1];  const float* bq1 = (const float*)d_in[2];
  const float* Wk1 = (const float*)d_in[3];  const float* bk1 = (const float*)d_in[4];
  const float* Wv1 = (const float*)d_in[5];  const float* bv1 = (const float*)d_in[6];
  const float* Ws1 = (const float*)d_in[7];  const float* bs1 = (const float*)d_in[8];
  const float* gn1w = (const float*)d_in[9]; const float* gn1b = (const float*)d_in[10];
  const float* gn1ms = (const float*)d_in[11];
  const float* Wq2 = (const float*)d_in[12]; const float* bq2 = (const float*)d_in[13];
  const float* Wk2 = (const float*)d_in[14]; const float* bk2 = (const float*)d_in[15];
  const float* Wv2 = (const float*)d_in[16]; const float* bv2 = (const float*)d_in[17];
  const float* Ws2 = (const float*)d_in[18]; const float* bs2 = (const float*)d_in[19];
  const float* gn2w = (const float*)d_in[20]; const float* gn2b = (const float*)d_in[21];
  const float* gn2ms = (const float*)d_in[22];

  // ---- workspace carve (~251 MB total, < 256 MiB cap) ----
  char* p = (char*)d_ws;
  auto alloc = [&](size_t bytes) { char* r = p; p += (bytes + 255) & ~(size_t)255; return r; };
  const size_t PSTR = (size_t)4096 * 4096;
  ushort_t* Pall = (ushort_t*)alloc(PSTR * 4 * 2);              // attn-2 P; Gram partials alias
  ushort_t* xb   = (ushort_t*)alloc((size_t)4096 * 544 * 2);
  ushort_t* qk1b = (ushort_t*)alloc((size_t)4096 * 512 * 2);
  ushort_t* v1b  = (ushort_t*)alloc((size_t)512 * 4096 * 2);
  char*     u0   = alloc((size_t)16 * 1024 * 1024);             // s1p, later h2b
  float*    s1p  = (float*)u0;                                  // [512,4096] f32 skip
  float*    h1nT = (float*)   alloc((size_t)200 * 4096 * 4);
  ushort_t* h1nb = (ushort_t*)alloc((size_t)4096 * 256 * 2);
  ushort_t* Wqk1 = (ushort_t*)alloc((size_t)512 * 544 * 2);
  ushort_t* Wv1b = (ushort_t*)alloc((size_t)512 * 544 * 2);
  ushort_t* Ws1p = (ushort_t*)alloc((size_t)512 * 544 * 2);
  ushort_t* Wcat = (ushort_t*)alloc((size_t)4096 * 256 * 2);    // [v2 | s2] weights
  ushort_t* Qt   = (ushort_t*)alloc((size_t)4 * 256 * 512 * 2); // per-head W~q^T [256,512]
  ushort_t* Kt   = (ushort_t*)alloc((size_t)4 * 256 * 512 * 2); // per-head W~k^T [256,512]
  ushort_t* Mtall= (ushort_t*)alloc((size_t)4 * 256 * 256 * 2); // per-head M^T [256,256]
  ushort_t* Tall = (ushort_t*)alloc((size_t)4 * 4096 * 256 * 2);// per-head T=XM [4096,256]
  ushort_t* vs2b = (ushort_t*)alloc((size_t)4096 * 4096 * 2);   // rows 0..2047=v2T, 2048..4095=skip2
  ushort_t* p2   = (ushort_t*)alloc((size_t)2 * 2048 * 4096 * 2);// PV-2 partials bf16
  float*    r1p  = (float*)   alloc((size_t)16 * 4096 * 4);     // attn-1 rowsum partials [z][h][4096]
  float*    r2   = (float*)   alloc((size_t)4 * 4096 * 4);
  // aliases (regions dead by the time the alias is written):
  float*    oP   = (float*)p2;     // attn-1 O partials 4x[512,4096] f32 = 32MB; p2 written later
  ushort_t* h2b  = (ushort_t*)u0;  // gn2 output: s1p dead after gn1
  float*    g4   = (float*)Pall;   // Gram partials: Pall dead after PV-2

  const dim3 b256(256, 1, 1);
  const dim3 b512(512, 1, 1);
  const float LOG2E = 1.4426950408889634f;
  const float sc1e = 0.14142135623730951f * LOG2E;  // 1/sqrt(50) * log2e
  const float sc2e = 0.04419417382415922f * LOG2E;  // 1/sqrt(512) * log2e

  hipMemsetAsync(r2, 0, (size_t)4 * 4096 * 4, stream);

  // ---- weight conversions
  wt_conv<<<dim3(256),  b256, 0, stream>>>(Wq1, bq1, Wqk1,             200, 200, 512, 544, 64, 50);
  wt_conv<<<dim3(256),  b256, 0, stream>>>(Wk1, bk1, Wqk1 + 256 * 544, 200, 200, 512, 544, 64, 50);
  wt_conv<<<dim3(512),  b256, 0, stream>>>(Wv1, bv1, Wv1b,             200, 200, 512, 544, 128, 50);
  wt_conv<<<dim3(512),  b256, 0, stream>>>(Ws1, bs1, Ws1p,             200, 200, 512, 544, 128, 50);
  wt_conv<<<dim3(2048), b256, 0, stream>>>(Wv2, bv2, Wcat,              2048, 2048, 200, 256, 2048, 2048);
  wt_conv<<<dim3(2048), b256, 0, stream>>>(Ws2, bs2, Wcat + 2048 * 256, 2048, 2048, 200, 256, 2048, 2048);
  wt_trans<<<dim3(1024), b256, 0, stream>>>(Wq2, bq2, Qt);
  wt_trans<<<dim3(1024), b256, 0, stream>>>(Wk2, bk2, Kt);
  trans_pad<<<dim3(9, 64), b256, 0, stream>>>(lr_x, xb, 512, 544);

  // ---- layer-1 projections (128^2 kernel)
  mfma_bt<1, false, false><<<dim3(4, 32), b256, 0, stream>>>(
      xb, Wqk1, qk1b, 544, 544, 512, 544, 1, 0, 0, 0, -1, 0, -1, 4096, 1.f, nullptr);
  mfma_bt<1, false, false><<<dim3(32, 4), b256, 0, stream>>>(
      Wv1b, xb, v1b, 544, 544, 4096, 544, 1, 0, 0, 0, -1, 0, -1, 512, 1.f, nullptr);
  mfma_bt<0, false, false><<<dim3(32, 4), b256, 0, stream>>>(
      Ws1p, xb, s1p, 544, 544, 4096, 544, 1, 0, 0, 0, -1, 0, 127, 50, 1.f, nullptr);

  // ---- attention 1: FUSED, LDS-staged dbuf K/V, KV-split x4 (partials)
  fused_attn1<<<dim3(32, 4, 4), b512, 0, stream>>>(qk1b, v1b, oP, r1p, sc1e);
  graph_norm_attn1<<<dim3(200), b256, 0, stream>>>(s1p, oP, r1p, h1nT, gn1w, gn1b, gn1ms);
  trans_pad<<<dim3(4, 64), b256, 0, stream>>>(h1nT, h1nb, 200, 256);

  // ---- layer-2 V+skip projection (K=256, 128^2 kernel)
  mfma_bt<1, false, false><<<dim3(32, 32), b256, 0, stream>>>(
      Wcat, h1nb, vs2b, 256, 256, 4096, 256, 1, 0, 0, 0, -1, 0, -1, 4096, 1.f, nullptr);

  // ---- attention 2 scores via low-rank factorization:
  mfma_bt<1, false, false><<<dim3(2, 2, 4), b256, 0, stream>>>(
      Kt, Qt, Mtall, 512, 512, 256, 512, 1,
      (size_t)256 * 512, (size_t)256 * 512, (size_t)256 * 256, -1, 0, -1, 256, 1.f, nullptr);
  mfma_bt<1, false, false><<<dim3(2, 32, 4), b256, 0, stream>>>(
      h1nb, Mtall, Tall, 256, 256, 256, 256, 1,
      0, (size_t)256 * 256, (size_t)4096 * 256, -1, 0, -1, 4096, 1.f, nullptr);
  mfma_bt<1, false, true><<<dim3(32, 32, 4), b256, 0, stream>>>(
      Tall, h1nb, Pall, 256, 256, 4096, 256, 1,
      (size_t)4096 * 256, 0, PSTR, -1, 0, -1, 4096, sc2e, r2);

  // ---- PV-2: LONG K (Kc=2048) -> 8-phase kernel; bf16 partials
  mfma256_8ph<1, false, false><<<dim3(16, 8, 2), b512, 0, stream>>>(
      vs2b, Pall, p2, 4096, 4096, 4096, 4096, 2,
      0, 0, (size_t)2048 * 4096, 9, PSTR, 2048, 1.f, nullptr);
  graph_norm_attn2<<<dim3(2048), b256, 0, stream>>>(
      vs2b + (size_t)2048 * 4096, p2, r2, h2b, gn2w, gn2b, gn2ms);

  // ---- out = relu(h2n . h2n^T): LONG K (Kc=1024) -> 8-phase; partials+reduce
  mfma256_8ph<0, false, false><<<dim3(8, 8, 4), b512, 0, stream>>>(
      h2b, h2b, g4, 4096, 4096, 2048, 4096, 4,
      0, 0, (size_t)2048 * 2048, -1, 0, 2048, 1.f, nullptr);
  add4_relu<<<dim3(4096), b256, 0, stream>>>(g4, (float*)d_out);
}

// Round 13
// 410.144 us; speedup vs baseline: 1.3024x; 1.0302x over previous
//
#include <hip/hip_runtime.h>
#include <math.h>

typedef unsigned int u32;
typedef unsigned short ushort_t;
typedef __attribute__((ext_vector_type(8))) short short8;
typedef __attribute__((ext_vector_type(4))) float f32x4;

__device__ __forceinline__ ushort_t f2bf(float x) {
  u32 u = __float_as_uint(x);
  u32 r = (u + 0x7fffu + ((u >> 16) & 1u)) >> 16;
  return (ushort_t)r;
}
__device__ __forceinline__ float bf2f(u32 s) {
  return __uint_as_float(s << 16);
}
__device__ __forceinline__ void ld4bf(const ushort_t* p, float* o) {
  uint2 u = *(const uint2*)p;
  o[0] = bf2f(u.x & 0xffffu); o[1] = bf2f(u.x >> 16);
  o[2] = bf2f(u.y & 0xffffu); o[3] = bf2f(u.y >> 16);
}

// ---------------- block reduction helpers (256 threads = 4 waves) ----------
__device__ __forceinline__ float block_sum256(float v, float* red) {
  #pragma unroll
  for (int o = 32; o > 0; o >>= 1) v += __shfl_down(v, o, 64);
  __syncthreads();
  if ((threadIdx.x & 63) == 0) red[threadIdx.x >> 6] = v;
  __syncthreads();
  return red[0] + red[1] + red[2] + red[3];
}

// =====================================================================
// Fused attention layer 1, v3: LDS-staged double-buffered K/V tiles.
// (unchanged from R12 — proven)
// =====================================================================
__global__ __launch_bounds__(512) void fused_attn1(
    const ushort_t* __restrict__ qk, const ushort_t* __restrict__ v,
    float* __restrict__ oP, float* __restrict__ r1p, float scale)
{
  __shared__ ushort_t Kl[2][4096];
  __shared__ ushort_t Vl[2][4096];
  __shared__ ushort_t Pl[128][80];
  const int t = threadIdx.x;
  const int lane = t & 63;
  const int wv = t >> 6;
  const int h = blockIdx.y;
  const int m0 = blockIdx.x * 128;
  const int z = blockIdx.z;
  const int lr = lane & 15;
  const int hk = lane >> 4;

  short8 aq0, aq1;
  {
    const ushort_t* qrow = qk + (size_t)(m0 + wv * 16 + lr) * 512 + h * 64;
    aq0 = *(const short8*)(qrow + hk * 8);
    aq1 = *(const short8*)(qrow + 32 + hk * 8);
  }

  f32x4 oAcc[4];
  #pragma unroll
  for (int i = 0; i < 4; ++i) oAcc[i] = (f32x4){0.f, 0.f, 0.f, 0.f};
  float racc[4] = {0.f, 0.f, 0.f, 0.f};

  const size_t kbase = (size_t)256 + h * 64;
  const int rS = t >> 3;
  const int cS = t & 7;
  const int lcS = cS ^ (rS & 7);

  {
    const int n0 = z * 16 * 64;
    __builtin_amdgcn_global_load_lds(
        (const __attribute__((address_space(1))) u32*)(qk + (size_t)(n0 + rS) * 512 + kbase + lcS * 8),
        (__attribute__((address_space(3))) u32*)(&Kl[0][t * 8]), 16, 0, 0);
    __builtin_amdgcn_global_load_lds(
        (const __attribute__((address_space(1))) u32*)(v + (size_t)(h * 128 + rS) * 4096 + n0 + lcS * 8),
        (__attribute__((address_space(3))) u32*)(&Vl[0][t * 8]), 16, 0, 0);
  }
  __syncthreads();

  int cur = 0;
  for (int it = 0; it < 16; ++it) {
    if (it + 1 < 16) {
      const int n1 = (z * 16 + it + 1) * 64;
      __builtin_amdgcn_global_load_lds(
          (const __attribute__((address_space(1))) u32*)(qk + (size_t)(n1 + rS) * 512 + kbase + lcS * 8),
          (__attribute__((address_space(3))) u32*)(&Kl[cur ^ 1][t * 8]), 16, 0, 0);
      __builtin_amdgcn_global_load_lds(
          (const __attribute__((address_space(1))) u32*)(v + (size_t)(h * 128 + rS) * 4096 + n1 + lcS * 8),
          (__attribute__((address_space(3))) u32*)(&Vl[cur ^ 1][t * 8]), 16, 0, 0);
    }
    f32x4 sA[4];
    #pragma unroll
    for (int nf = 0; nf < 4; ++nf) {
      const int rl = nf * 16 + lr;
      const char* kb = (const char*)&Kl[cur][0] + rl * 128;
      short8 b0 = *(const short8*)(kb + ((hk ^ (rl & 7)) * 16));
      short8 b1 = *(const short8*)(kb + (((4 + hk) ^ (rl & 7)) * 16));
      f32x4 sa = (f32x4){0.f, 0.f, 0.f, 0.f};
      sa = __builtin_amdgcn_mfma_f32_16x16x32_bf16(aq0, b0, sa, 0, 0, 0);
      sa = __builtin_amdgcn_mfma_f32_16x16x32_bf16(aq1, b1, sa, 0, 0, 0);
      sA[nf] = sa;
    }
    #pragma unroll
    for (int nf = 0; nf < 4; ++nf) {
      #pragma unroll
      for (int r = 0; r < 4; ++r) {
        float e = exp2f(sA[nf][r] * scale);
        racc[r] += e;
        Pl[wv * 16 + hk * 4 + r][nf * 16 + lr] = f2bf(e);
      }
    }
    short8 ap0 = *(const short8*)&Pl[wv * 16 + lr][hk * 8];
    short8 ap1 = *(const short8*)&Pl[wv * 16 + lr][32 + hk * 8];
    #pragma unroll
    for (int ff = 0; ff < 4; ++ff) {
      const int rl = ff * 16 + lr;
      const char* vb = (const char*)&Vl[cur][0] + rl * 128;
      short8 b0 = *(const short8*)(vb + ((hk ^ (rl & 7)) * 16));
      short8 b1 = *(const short8*)(vb + (((4 + hk) ^ (rl & 7)) * 16));
      oAcc[ff] = __builtin_amdgcn_mfma_f32_16x16x32_bf16(ap0, b0, oAcc[ff], 0, 0, 0);
      oAcc[ff] = __builtin_amdgcn_mfma_f32_16x16x32_bf16(ap1, b1, oAcc[ff], 0, 0, 0);
    }
    __syncthreads();
    cur ^= 1;
  }

  #pragma unroll
  for (int r = 0; r < 4; ++r) {
    racc[r] += __shfl_xor(racc[r], 1);
    racc[r] += __shfl_xor(racc[r], 2);
    racc[r] += __shfl_xor(racc[r], 4);
    racc[r] += __shfl_xor(racc[r], 8);
  }
  if (lr == 0) {
    float* rp = r1p + ((size_t)z * 4 + h) * 4096;
    #pragma unroll
    for (int r = 0; r < 4; ++r) rp[m0 + wv * 16 + hk * 4 + r] = racc[r];
  }
  float* ob = oP + (size_t)z * 512 * 4096;
  #pragma unroll
  for (int ff = 0; ff < 4; ++ff) {
    const size_t fbase = (size_t)(h * 128 + ff * 16 + lr) * 4096;
    #pragma unroll
    for (int r = 0; r < 4; ++r) {
      const int q = m0 + wv * 16 + hk * 4 + r;
      ob[fbase + q] = oAcc[ff][r];
    }
  }
}

// =====================================================================
// 256x256-tile, 8-phase, counted-vmcnt MFMA GEMM. LONG-K only (R7 lesson).
// =====================================================================
#define RD_A(bb, mm, cc) (*(const short8*)(lsAc + (bb)*32768 + arow + (mm)*2048 + (cc)))
#define RD_B(bb, nn, cc) (*(const short8*)(lsBc + (bb)*32768 + brow + (nn)*2048 + (cc)))

#define MM8(nn, bv) { \
  acc[0][nn] = __builtin_amdgcn_mfma_f32_16x16x32_bf16(a0, bv, acc[0][nn], 0,0,0); \
  acc[1][nn] = __builtin_amdgcn_mfma_f32_16x16x32_bf16(a1, bv, acc[1][nn], 0,0,0); \
  acc[2][nn] = __builtin_amdgcn_mfma_f32_16x16x32_bf16(a2, bv, acc[2][nn], 0,0,0); \
  acc[3][nn] = __builtin_amdgcn_mfma_f32_16x16x32_bf16(a3, bv, acc[3][nn], 0,0,0); \
  acc[4][nn] = __builtin_amdgcn_mfma_f32_16x16x32_bf16(a4, bv, acc[4][nn], 0,0,0); \
  acc[5][nn] = __builtin_amdgcn_mfma_f32_16x16x32_bf16(a5, bv, acc[5][nn], 0,0,0); \
  acc[6][nn] = __builtin_amdgcn_mfma_f32_16x16x32_bf16(a6, bv, acc[6][nn], 0,0,0); \
  acc[7][nn] = __builtin_amdgcn_mfma_f32_16x16x32_bf16(a7, bv, acc[7][nn], 0,0,0); }

#define STG(BASE, LD, LS, bb, hf, tt) { \
  _Pragma("unroll") \
  for (int ii = 0; ii < 2; ++ii) { \
    const int s_ = t + ii * 512; \
    const int r_ = s_ >> 3; \
    const int lc_ = (s_ & 7) ^ (r_ & 7); \
    __builtin_amdgcn_global_load_lds( \
      (const __attribute__((address_space(1))) u32*)((BASE) + (size_t)((hf) * 128 + r_) * (LD) + (size_t)(tt) * 64 + lc_ * 8), \
      (__attribute__((address_space(3))) u32*)(&(LS)[bb][(hf) * 8192 + s_ * 8]), 16, 0, 0); \
  } }

#define BAR() __builtin_amdgcn_s_barrier()
#define PRIO(x) __builtin_amdgcn_s_setprio(x)

#define GRP(bf, tS1, tS2) { \
  a0=RD_A(bf,0,c0); a1=RD_A(bf,1,c0); a2=RD_A(bf,2,c0); a3=RD_A(bf,3,c0); \
  a4=RD_A(bf,4,c0); a5=RD_A(bf,5,c0); a6=RD_A(bf,6,c0); a7=RD_A(bf,7,c0); \
  b0=RD_B(bf,0,c0); b1=RD_B(bf,1,c0); \
  STG(Ab, lda, lsA, 1-(bf), 1, tS1); STG(Bb, ldb, lsB, 1-(bf), 0, tS1); \
  BAR(); PRIO(1); MM8(0, b0); MM8(1, b1); PRIO(0); BAR(); \
  b2=RD_B(bf,2,c0); b3=RD_B(bf,3,c0); \
  STG(Bb, ldb, lsB, 1-(bf), 1, tS1); \
  BAR(); PRIO(1); MM8(2, b2); MM8(3, b3); PRIO(0); BAR(); \
  a0=RD_A(bf,0,c1); a1=RD_A(bf,1,c1); a2=RD_A(bf,2,c1); a3=RD_A(bf,3,c1); \
  a4=RD_A(bf,4,c1); a5=RD_A(bf,5,c1); a6=RD_A(bf,6,c1); a7=RD_A(bf,7,c1); \
  b0=RD_B(bf,0,c1); b1=RD_B(bf,1,c1); \
  BAR(); PRIO(1); MM8(0, b0); MM8(1, b1); PRIO(0); BAR(); \
  b2=RD_B(bf,2,c1); b3=RD_B(bf,3,c1); \
  STG(Ab, lda, lsA, (bf), 0, tS2); \
  BAR(); PRIO(1); MM8(2, b2); MM8(3, b3); PRIO(0); \
  asm volatile("s_waitcnt vmcnt(2)" ::: "memory"); \
  BAR(); }

template<int CMODE, bool RELU>
__global__ __launch_bounds__(512, 2) void mfma256_8ph(
    const ushort_t* __restrict__ A, const ushort_t* __restrict__ B,
    void* __restrict__ Cv, int lda, int ldb, int ldc,
    int K, int zsplit, size_t zA, size_t zB, size_t zC,
    int bShift, size_t bHead, int Mvalid, float scale)
{
  __shared__ ushort_t lsA[2][16384];
  __shared__ ushort_t lsB[2][16384];
  const int t = threadIdx.x;
  const int gx = gridDim.x;
  const int nwg = gx * gridDim.y;
  const int bid = blockIdx.y * gx + blockIdx.x;
  const int qq = nwg >> 3, rr_ = nwg & 7;
  const int xcd = bid & 7, idx = bid >> 3;
  const int swz = (xcd < rr_ ? xcd * (qq + 1) : rr_ * (qq + 1) + (xcd - rr_) * qq) + idx;
  const int m0 = (swz / gx) * 256;
  const int n0 = (swz % gx) * 256;
  const int z = blockIdx.z;
  int Kc = K, kOff = 0;
  size_t aZ = 0, bZ = 0, cZ = 0;
  if (zsplit > 1) { Kc = K / zsplit; kOff = z * Kc; cZ = (size_t)z * zC; }
  else { aZ = (size_t)z * zA; bZ = (size_t)z * zB; cZ = (size_t)z * zC; }
  const ushort_t* Ab = A + aZ + (size_t)m0 * lda + kOff;
  const ushort_t* Bb = B + bZ + (size_t)n0 * ldb + kOff
                     + (bShift >= 0 ? (size_t)(m0 >> bShift) * bHead : 0);
  const int NT = Kc / 64;

  f32x4 acc[8][4];
  #pragma unroll
  for (int i = 0; i < 8; ++i)
    #pragma unroll
    for (int j = 0; j < 4; ++j) acc[i][j] = (f32x4){0.f, 0.f, 0.f, 0.f};

  const int lane = t & 63;
  const int wv = t >> 6;
  const int wr = (wv >> 2) * 128;
  const int wc = (wv & 3) * 64;
  const int lr = lane & 15;
  const int kc = lane >> 4;
  const int sw = lane & 7;
  const int c0 = (kc ^ sw) * 16;
  const int c1 = c0 ^ 64;
  const int arow = (wr + lr) * 128;
  const int brow = (wc + lr) * 128;
  const char* lsAc = (const char*)lsA;
  const char* lsBc = (const char*)lsB;

  short8 a0, a1, a2, a3, a4, a5, a6, a7, b0, b1, b2, b3;

  STG(Ab, lda, lsA, 0, 0, 0); STG(Ab, lda, lsA, 0, 1, 0);
  STG(Bb, ldb, lsB, 0, 0, 0); STG(Bb, ldb, lsB, 0, 1, 0);
  STG(Ab, lda, lsA, 1, 0, 1);
  asm volatile("s_waitcnt vmcnt(2)" ::: "memory");
  BAR();

  const int NITER = NT >> 1;
  for (int it = 0; it < NITER; ++it) {
    const int tb = 2 * it;
    const int s1 = tb + 1;
    const int s2 = (tb + 2 < NT) ? tb + 2 : 0;
    const int s3 = (tb + 3 < NT) ? tb + 3 : 0;
    GRP(0, s1, s2)
    GRP(1, s2, s3)
  }

  const int row4 = (lane >> 4) * 4;
  const int coln = lane & 15;
  float* Cf = (float*)Cv + cZ;
  ushort_t* Ch = (ushort_t*)Cv + cZ;
  #pragma unroll
  for (int m = 0; m < 8; ++m) {
    #pragma unroll
    for (int r = 0; r < 4; ++r) {
      const int gm = m0 + wr + m * 16 + row4 + r;
      const bool ok = gm < Mvalid;
      #pragma unroll
      for (int n = 0; n < 4; ++n) {
        const int gn = n0 + wc + n * 16 + coln;
        float v = acc[m][n][r] * scale;
        if (RELU) v = fmaxf(v, 0.f);
        if (ok) {
          if (CMODE == 0)      Cf[(size_t)gm * ldc + gn] = v;
          else if (CMODE == 1) Ch[(size_t)gm * ldc + gn] = f2bf(v);
          else                 atomicAdd(&Cf[(size_t)gm * ldc + gn], v);
        }
      }
    }
  }
}

#undef GRP
#undef STG
#undef MM8
#undef RD_A
#undef RD_B

// ================= 128x128-tile MFMA GEMM, 256 threads (SHORT-K) ===========
// EXPSUM: v = exp2(v*scale); per-(block, wc-band) row-sum partials are
// PLAIN-STORED to Rs[(blockIdx.x*2 + band)*gridDim.z + z][4096] (R12 lesson:
// the old per-row atomicAdd had ~64-way address contention).
template<int CMODE, bool RELU, bool EXPSUM>
__global__ __launch_bounds__(256) void mfma_bt(
    const ushort_t* __restrict__ A, const ushort_t* __restrict__ B,
    void* __restrict__ Cv, int lda, int ldb, int ldc,
    int K, int Ksplit, size_t zA, size_t zB, size_t zC,
    int bShift, size_t bHead, int mMask, int Mvalid, float scale,
    float* __restrict__ Rs)
{
  __shared__ ushort_t lsA[2][128 * 32];
  __shared__ ushort_t lsB[2][128 * 32];
  const int t  = threadIdx.x;
  const int m0 = blockIdx.y * 128;
  const int n0 = blockIdx.x * 128;
  const int z = blockIdx.z;
  int Kc = K, kOff = 0;
  size_t aZ = 0, bZ = 0, cZ = 0;
  if (Ksplit > 1) { Kc = K / Ksplit; kOff = z * Kc; cZ = (size_t)z * zC; }
  else { aZ = (size_t)z * zA; bZ = (size_t)z * zB; cZ = (size_t)z * zC; }
  const int NT = Kc / 32;
  const ushort_t* Ab = A + aZ + (size_t)m0 * lda + kOff;
  const ushort_t* Bb = B + bZ + (size_t)n0 * ldb + kOff
                     + (bShift >= 0 ? (size_t)(m0 >> bShift) * bHead : 0);
  const int cs = t & 3;

  f32x4 acc[4][4];
  #pragma unroll
  for (int i = 0; i < 4; ++i)
    #pragma unroll
    for (int j = 0; j < 4; ++j) acc[i][j] = (f32x4){0.f, 0.f, 0.f, 0.f};

  const int lane = t & 63;
  const int wv = t >> 6;
  const int wr = (wv >> 1) * 64;
  const int wc = (wv & 1) * 64;
  const int lr = lane & 15;
  const int kc = lane >> 4;

  int roffA[4], roffB[4];
  #pragma unroll
  for (int m = 0; m < 4; ++m) {
    int ra = wr + m * 16 + lr;
    roffA[m] = ra * 64 + ((kc ^ (ra & 3)) * 16);
    int rb = wc + m * 16 + lr;
    roffB[m] = rb * 64 + ((kc ^ (rb & 3)) * 16);
  }

  auto stage = [&](int buf, int kt) {
    const ushort_t* As = Ab + kt * 32;
    const ushort_t* Bs = Bb + kt * 32;
    #pragma unroll
    for (int i = 0; i < 2; ++i) {
      int s = t + i * 256;
      int r = s >> 2;
      int c = cs ^ (r & 3);
      __builtin_amdgcn_global_load_lds(
          (const __attribute__((address_space(1))) u32*)(As + (size_t)r * lda + c * 8),
          (__attribute__((address_space(3))) u32*)(&lsA[buf][s * 8]), 16, 0, 0);
    }
    #pragma unroll
    for (int i = 0; i < 2; ++i) {
      int s = t + i * 256;
      int r = s >> 2;
      int c = cs ^ (r & 3);
      __builtin_amdgcn_global_load_lds(
          (const __attribute__((address_space(1))) u32*)(Bs + (size_t)r * ldb + c * 8),
          (__attribute__((address_space(3))) u32*)(&lsB[buf][s * 8]), 16, 0, 0);
    }
  };

  stage(0, 0);
  __syncthreads();
  int cur = 0;
  for (int kt = 0; kt < NT; ++kt) {
    if (kt + 1 < NT) stage(cur ^ 1, kt + 1);
    short8 af[4], bfr[4];
    const char* baseA = (const char*)&lsA[cur][0];
    const char* baseB = (const char*)&lsB[cur][0];
    #pragma unroll
    for (int m = 0; m < 4; ++m) af[m]  = *(const short8*)(baseA + roffA[m]);
    #pragma unroll
    for (int n = 0; n < 4; ++n) bfr[n] = *(const short8*)(baseB + roffB[n]);
    #pragma unroll
    for (int m = 0; m < 4; ++m)
      #pragma unroll
      for (int n = 0; n < 4; ++n)
        acc[m][n] = __builtin_amdgcn_mfma_f32_16x16x32_bf16(af[m], bfr[n], acc[m][n], 0, 0, 0);
    __syncthreads();
    cur ^= 1;
  }

  const int row4 = (lane >> 4) * 4;
  const int coln = lane & 15;
  float* Cf = (float*)Cv + cZ;
  ushort_t* Ch = (ushort_t*)Cv + cZ;
  float* rs = nullptr;
  if (EXPSUM) {
    const int slot = blockIdx.x * 2 + (wc >> 6);
    rs = Rs + ((size_t)slot * gridDim.z + z) * 4096;
  }
  #pragma unroll
  for (int m = 0; m < 4; ++m) {
    #pragma unroll
    for (int r = 0; r < 4; ++r) {
      const int gm = m0 + wr + m * 16 + row4 + r;
      const bool ok = (mMask >= 0) ? ((gm & mMask) < Mvalid) : (gm < Mvalid);
      float rowpart = 0.f;
      #pragma unroll
      for (int n = 0; n < 4; ++n) {
        const int gn = n0 + wc + n * 16 + coln;
        float v = acc[m][n][r] * scale;
        if (EXPSUM) { v = exp2f(v); rowpart += v; }
        if (RELU) v = fmaxf(v, 0.f);
        if (ok) {
          if (CMODE == 0)      Cf[(size_t)gm * ldc + gn] = v;
          else if (CMODE == 1) Ch[(size_t)gm * ldc + gn] = f2bf(v);
          else                 atomicAdd(&Cf[(size_t)gm * ldc + gn], v);
        }
      }
      if (EXPSUM) {
        rowpart += __shfl_xor(rowpart, 1);
        rowpart += __shfl_xor(rowpart, 2);
        rowpart += __shfl_xor(rowpart, 4);
        rowpart += __shfl_xor(rowpart, 8);
        if (ok && lr == 0) rs[gm] = rowpart;   // plain store, no contention
      }
    }
  }
}

// ---------------- reduce r2p[64][4][4096] -> r2[4][4096] -------------------
__global__ __launch_bounds__(256) void reduce_r2(
    const float* __restrict__ r2p, float* __restrict__ r2)
{
  const int i = blockIdx.x * 256 + threadIdx.x;   // 0..16383 = h*4096+q
  float s = 0.f;
  #pragma unroll 8
  for (int sl = 0; sl < 64; ++sl) s += r2p[(size_t)sl * 16384 + i];
  r2[i] = s;
}

// ---------------- weights: dst[Mp,Kp] bf16 = W^T (+ bias slot at k==Kv) ----
__global__ __launch_bounds__(256) void wt_conv(
    const float* __restrict__ W, const float* __restrict__ bias,
    ushort_t* __restrict__ dst, int Mtot, int ldw, int Kv, int Kp,
    int PADH, int VALH)
{
  const int m = blockIdx.x;
  const int h = m / PADH, c0 = m % PADH;
  const int fout = h * VALH + c0;
  const bool valid = (c0 < VALH) && (fout < Mtot);
  for (int k = threadIdx.x; k < Kp; k += blockDim.x) {
    float v = 0.f;
    if (valid) {
      if (k < Kv) v = W[(size_t)k * ldw + fout];
      else if (k == Kv) v = bias[fout];
    }
    dst[(size_t)m * Kp + k] = f2bf(v);
  }
}

// ---------------- wt_trans: dst[4][256][512] bf16 (padded W~^T per head) ---
__global__ __launch_bounds__(256) void wt_trans(
    const float* __restrict__ W, const float* __restrict__ bias,
    ushort_t* __restrict__ dst)
{
  const int rid = blockIdx.x;          // 0..1023
  const int h = rid >> 8, a = rid & 255;
  for (int f = threadIdx.x; f < 512; f += 256) {
    float v = 0.f;
    if (a < 200)       v = W[(size_t)a * 2048 + h * 512 + f];
    else if (a == 200) v = bias[h * 512 + f];
    dst[(size_t)rid * 512 + f] = f2bf(v);
  }
}

// ---------------- transpose fp32 [Kv,4096] -> bf16 [4096,Kp], bias slot ----
__global__ __launch_bounds__(256) void trans_pad(
    const float* __restrict__ src, ushort_t* __restrict__ dst, int Kv, int Kp)
{
  __shared__ float tl[64][65];
  const int t = threadIdx.x;
  const int f0 = blockIdx.x * 64;
  const int i0 = blockIdx.y * 64;
  const int c = t & 63, rbase = t >> 6;
  #pragma unroll
  for (int it = 0; it < 16; ++it) {
    int r = rbase + it * 4;
    int f = f0 + r;
    tl[r][c] = (f < Kv) ? src[(size_t)f * 4096 + i0 + c] : 0.f;
  }
  __syncthreads();
  #pragma unroll
  for (int it = 0; it < 16; ++it) {
    int r = rbase + it * 4;
    int f = f0 + c;
    if (f < Kp) {
      float v = (f < Kv) ? tl[c][r] : ((f == Kv) ? 1.f : 0.f);
      dst[(size_t)(i0 + r) * Kp + f] = f2bf(v);
    }
  }
}

// ---------------- GraphNorm layer 1: x = skip + (sum_z oP)/(sum_z r) -------
__global__ __launch_bounds__(256) void graph_norm_attn1(
    const float* __restrict__ skip, const float* __restrict__ oP,
    const float* __restrict__ r1p, float* __restrict__ out,
    const float* __restrict__ w, const float* __restrict__ b,
    const float* __restrict__ ms)
{
  __shared__ float red[4];
  const int t = threadIdx.x;
  const int row = blockIdx.x;            // 0..199
  const int h = row / 50;
  const int pr = h * 128 + row % 50;
  const float* sk = skip + (size_t)pr * 4096;
  const size_t OSTR = (size_t)512 * 4096;
  float v[16];
  float s = 0.f;
  #pragma unroll
  for (int e = 0; e < 4; ++e) {
    const int idx = t * 4 + 1024 * e;
    float4 a = *(const float4*)&sk[idx];
    float4 o0 = *(const float4*)&oP[(size_t)pr * 4096 + idx];
    float4 o1 = *(const float4*)&oP[OSTR + (size_t)pr * 4096 + idx];
    float4 o2 = *(const float4*)&oP[2 * OSTR + (size_t)pr * 4096 + idx];
    float4 o3 = *(const float4*)&oP[3 * OSTR + (size_t)pr * 4096 + idx];
    float4 r0 = *(const float4*)&r1p[(size_t)h * 4096 + idx];
    float4 r1 = *(const float4*)&r1p[(size_t)(4 + h) * 4096 + idx];
    float4 r2 = *(const float4*)&r1p[(size_t)(8 + h) * 4096 + idx];
    float4 r3 = *(const float4*)&r1p[(size_t)(12 + h) * 4096 + idx];
    v[e*4+0] = a.x + (o0.x + o1.x + o2.x + o3.x) / (r0.x + r1.x + r2.x + r3.x);
    v[e*4+1] = a.y + (o0.y + o1.y + o2.y + o3.y) / (r0.y + r1.y + r2.y + r3.y);
    v[e*4+2] = a.z + (o0.z + o1.z + o2.z + o3.z) / (r0.z + r1.z + r2.z + r3.z);
    v[e*4+3] = a.w + (o0.w + o1.w + o2.w + o3.w) / (r0.w + r1.w + r2.w + r3.w);
    s += v[e*4+0] + v[e*4+1] + v[e*4+2] + v[e*4+3];
  }
  const float mean = block_sum256(s, red) * (1.f / 4096.f);
  const float sub = mean * ms[row];
  float s2 = 0.f;
  #pragma unroll
  for (int e = 0; e < 16; ++e) { v[e] -= sub; s2 += v[e] * v[e]; }
  const float var = block_sum256(s2, red) * (1.f / 4096.f);
  const float scl = rsqrtf(var + 1e-5f) * w[row];
  const float bb = b[row];
  float* y = out + (size_t)row * 4096;
  #pragma unroll
  for (int e = 0; e < 4; ++e) {
    float o0[4];
    #pragma unroll
    for (int q = 0; q < 4; ++q) o0[q] = v[e * 4 + q] * scl + bb;
    *(float4*)&y[t * 4 + 1024 * e] = *(float4*)&o0[0];
  }
}

// ---------------- GraphNorm layer 2: x = skip + (p0+p1)/r, gn, L2, bf16 ----
__global__ __launch_bounds__(256) void graph_norm_attn2(
    const ushort_t* __restrict__ skip, const ushort_t* __restrict__ p2,
    const float* __restrict__ r2, ushort_t* __restrict__ out,
    const float* __restrict__ w, const float* __restrict__ b,
    const float* __restrict__ ms)
{
  __shared__ float red[4];
  const int t = threadIdx.x;
  const int row = blockIdx.x;            // 0..2047
  const ushort_t* sk = skip + (size_t)row * 4096;
  const ushort_t* pa = p2 + (size_t)row * 4096;
  const ushort_t* pb = p2 + (size_t)2048 * 4096 + (size_t)row * 4096;
  const float* rr = r2 + (size_t)(row >> 9) * 4096;
  float v[16];
  float s = 0.f;
  #pragma unroll
  for (int e = 0; e < 4; ++e) {
    const int idx = t * 4 + 1024 * e;
    float a[4], oa[4], ob[4];
    ld4bf(&sk[idx], a); ld4bf(&pa[idx], oa); ld4bf(&pb[idx], ob);
    float4 rv = *(const float4*)&rr[idx];
    v[e*4+0] = a[0] + (oa[0] + ob[0]) / rv.x;
    v[e*4+1] = a[1] + (oa[1] + ob[1]) / rv.y;
    v[e*4+2] = a[2] + (oa[2] + ob[2]) / rv.z;
    v[e*4+3] = a[3] + (oa[3] + ob[3]) / rv.w;
    s += v[e*4+0] + v[e*4+1] + v[e*4+2] + v[e*4+3];
  }
  const float mean = block_sum256(s, red) * (1.f / 4096.f);
  const float sub = mean * ms[row];
  float s2 = 0.f;
  #pragma unroll
  for (int e = 0; e < 16; ++e) { v[e] -= sub; s2 += v[e] * v[e]; }
  const float var = block_sum256(s2, red) * (1.f / 4096.f);
  const float scl = rsqrtf(var + 1e-5f) * w[row];
  const float bb = b[row];
  #pragma unroll
  for (int e = 0; e < 16; ++e) v[e] = v[e] * scl + bb;
  float s3 = 0.f;
  #pragma unroll
  for (int e = 0; e < 16; ++e) s3 += v[e] * v[e];
  const float osc = rsqrtf(block_sum256(s3, red));
  ushort_t* y = out + (size_t)row * 4096;
  #pragma unroll
  for (int e = 0; e < 4; ++e) {
    ushort_t o0[4];
    #pragma unroll
    for (int q = 0; q < 4; ++q) o0[q] = f2bf(v[e * 4 + q] * osc);
    *(ushort2*)&y[t * 4 + 1024 * e] = *(ushort2*)&o0[0];
    *(ushort2*)&y[t * 4 + 1024 * e + 2] = *(ushort2*)&o0[2];
  }
}

// ---------------- out = relu(sum of 4 bf16 partial planes) -----------------
__global__ __launch_bounds__(256) void add4_relu_bf16(
    const ushort_t* __restrict__ g, float* __restrict__ out)
{
  const size_t i = (size_t)blockIdx.x * 256 + threadIdx.x;   // x4 elems
  const size_t ss = (size_t)2048 * 2048;
  float a[4], b[4], c[4], d[4];
  ld4bf(&g[i * 4], a);
  ld4bf(&g[ss + i * 4], b);
  ld4bf(&g[2 * ss + i * 4], c);
  ld4bf(&g[3 * ss + i * 4], d);
  float4 o;
  o.x = fmaxf(a[0] + b[0] + c[0] + d[0], 0.f);
  o.y = fmaxf(a[1] + b[1] + c[1] + d[1], 0.f);
  o.z = fmaxf(a[2] + b[2] + c[2] + d[2], 0.f);
  o.w = fmaxf(a[3] + b[3] + c[3] + d[3], 0.f);
  ((float4*)out)[i] = o;
}

extern "C" void kernel_launch(void* const* d_in, const int* in_sizes, int n_in,
                              void* d_out, int out_size, void* d_ws, size_t ws_size,
                              hipStream_t stream)
{
  (void)in_sizes; (void)n_in; (void)out_size; (void)ws_size;
  const float* lr_x = (const float*)d_in[0];
  const float* Wq1 = (const float*)d_in[1];  const float* bq1 = (const float*)d_in[2];
  const float* Wk1 = (const float*)d_in[3];  const float* bk1 = (const float*)d_in[4];
  const float* Wv1 = (const float*)d_in[5];  const float* bv1 = (const float*)d_in[6];
  const float* Ws1 = (const float*)d_in[7];  const float* bs1 = (const float*)d_in[8];
  const float* gn1w = (const float*)d_in[9]; const float* gn1b = (const float*)d_in[10];
  const float* gn1ms = (const float*)d_in[11];
  const float* Wq2 = (const float*)d_in[12]; const float* bq2 = (const float*)d_in[13];
  const float* Wk2 = (const float*)d_in[14]; const float* bk2 = (const float*)d_in[15];
  const float* Wv2 = (const float*)d_in[16]; const float* bv2 = (const float*)d_in[17];
  const float* Ws2 = (const float*)d_in[18]; const float* bs2 = (const float*)d_in[19];
  const float* gn2w = (const float*)d_in[20]; const float* gn2b = (const float*)d_in[21];
  const float* gn2ms = (const float*)d_in[22];

  // ---- workspace carve (~257 MB total; <= R4-proven 267 MB) ----
  char* p = (char*)d_ws;
  auto alloc = [&](size_t bytes) { char* r = p; p += (bytes + 255) & ~(size_t)255; return r; };
  const size_t PSTR = (size_t)4096 * 4096;
  ushort_t* Pall = (ushort_t*)alloc(PSTR * 4 * 2);              // attn-2 P; Gram partials alias
  ushort_t* xb   = (ushort_t*)alloc((size_t)4096 * 544 * 2);
  ushort_t* qk1b = (ushort_t*)alloc((size_t)4096 * 512 * 2);
  ushort_t* v1b  = (ushort_t*)alloc((size_t)512 * 4096 * 2);
  char*     u0   = alloc((size_t)16 * 1024 * 1024);             // s1p, later h2b
  float*    s1p  = (float*)u0;                                  // [512,4096] f32 skip
  float*    h1nT = (float*)   alloc((size_t)200 * 4096 * 4);
  ushort_t* h1nb = (ushort_t*)alloc((size_t)4096 * 256 * 2);
  ushort_t* Wqk1 = (ushort_t*)alloc((size_t)512 * 544 * 2);
  ushort_t* Wv1b = (ushort_t*)alloc((size_t)512 * 544 * 2);
  ushort_t* Ws1p = (ushort_t*)alloc((size_t)512 * 544 * 2);
  ushort_t* Wcat = (ushort_t*)alloc((size_t)4096 * 256 * 2);    // [v2 | s2] weights
  ushort_t* Qt   = (ushort_t*)alloc((size_t)4 * 256 * 512 * 2);
  ushort_t* Kt   = (ushort_t*)alloc((size_t)4 * 256 * 512 * 2);
  ushort_t* Mtall= (ushort_t*)alloc((size_t)4 * 256 * 256 * 2);
  ushort_t* Tall = (ushort_t*)alloc((size_t)4 * 4096 * 256 * 2);
  ushort_t* vs2b = (ushort_t*)alloc((size_t)4096 * 4096 * 2);   // rows 0..2047=v2T, 2048..4095=skip2
  ushort_t* p2   = (ushort_t*)alloc((size_t)2 * 2048 * 4096 * 2);// PV-2 partials bf16
  float*    r1p  = (float*)   alloc((size_t)16 * 4096 * 4);
  float*    r2p  = (float*)   alloc((size_t)64 * 4 * 4096 * 4); // scores-2 rowsum partials
  float*    r2   = (float*)   alloc((size_t)4 * 4096 * 4);
  // aliases:
  float*    oP   = (float*)p2;     // attn-1 O partials (p2 written later)
  ushort_t* h2b  = (ushort_t*)u0;  // gn2 output (s1p dead after gn1)
  ushort_t* g4   = (ushort_t*)Pall;// Gram bf16 partials (Pall dead after PV-2)

  const dim3 b256(256, 1, 1);
  const dim3 b512(512, 1, 1);
  const float LOG2E = 1.4426950408889634f;
  const float sc1e = 0.14142135623730951f * LOG2E;
  const float sc2e = 0.04419417382415922f * LOG2E;

  // ---- weight conversions
  wt_conv<<<dim3(256),  b256, 0, stream>>>(Wq1, bq1, Wqk1,             200, 200, 512, 544, 64, 50);
  wt_conv<<<dim3(256),  b256, 0, stream>>>(Wk1, bk1, Wqk1 + 256 * 544, 200, 200, 512, 544, 64, 50);
  wt_conv<<<dim3(512),  b256, 0, stream>>>(Wv1, bv1, Wv1b,             200, 200, 512, 544, 128, 50);
  wt_conv<<<dim3(512),  b256, 0, stream>>>(Ws1, bs1, Ws1p,             200, 200, 512, 544, 128, 50);
  wt_conv<<<dim3(2048), b256, 0, stream>>>(Wv2, bv2, Wcat,              2048, 2048, 200, 256, 2048, 2048);
  wt_conv<<<dim3(2048), b256, 0, stream>>>(Ws2, bs2, Wcat + 2048 * 256, 2048, 2048, 200, 256, 2048, 2048);
  wt_trans<<<dim3(1024), b256, 0, stream>>>(Wq2, bq2, Qt);
  wt_trans<<<dim3(1024), b256, 0, stream>>>(Wk2, bk2, Kt);
  trans_pad<<<dim3(9, 64), b256, 0, stream>>>(lr_x, xb, 512, 544);

  // ---- layer-1 projections (128^2 kernel)
  mfma_bt<1, false, false><<<dim3(4, 32), b256, 0, stream>>>(
      xb, Wqk1, qk1b, 544, 544, 512, 544, 1, 0, 0, 0, -1, 0, -1, 4096, 1.f, nullptr);
  mfma_bt<1, false, false><<<dim3(32, 4), b256, 0, stream>>>(
      Wv1b, xb, v1b, 544, 544, 4096, 544, 1, 0, 0, 0, -1, 0, -1, 512, 1.f, nullptr);
  mfma_bt<0, false, false><<<dim3(32, 4), b256, 0, stream>>>(
      Ws1p, xb, s1p, 544, 544, 4096, 544, 1, 0, 0, 0, -1, 0, 127, 50, 1.f, nullptr);

  // ---- attention 1: FUSED, LDS-staged dbuf K/V, KV-split x4 (partials)
  fused_attn1<<<dim3(32, 4, 4), b512, 0, stream>>>(qk1b, v1b, oP, r1p, sc1e);
  graph_norm_attn1<<<dim3(200), b256, 0, stream>>>(s1p, oP, r1p, h1nT, gn1w, gn1b, gn1ms);
  trans_pad<<<dim3(4, 64), b256, 0, stream>>>(h1nT, h1nb, 200, 256);

  // ---- layer-2 V+skip projection (K=256, 128^2 kernel)
  mfma_bt<1, false, false><<<dim3(32, 32), b256, 0, stream>>>(
      Wcat, h1nb, vs2b, 256, 256, 4096, 256, 1, 0, 0, 0, -1, 0, -1, 4096, 1.f, nullptr);

  // ---- attention 2 scores via low-rank factorization:
  mfma_bt<1, false, false><<<dim3(2, 2, 4), b256, 0, stream>>>(
      Kt, Qt, Mtall, 512, 512, 256, 512, 1,
      (size_t)256 * 512, (size_t)256 * 512, (size_t)256 * 256, -1, 0, -1, 256, 1.f, nullptr);
  mfma_bt<1, false, false><<<dim3(2, 32, 4), b256, 0, stream>>>(
      h1nb, Mtall, Tall, 256, 256, 256, 256, 1,
      0, (size_t)256 * 256, (size_t)4096 * 256, -1, 0, -1, 4096, 1.f, nullptr);
  mfma_bt<1, false, true><<<dim3(32, 32, 4), b256, 0, stream>>>(
      Tall, h1nb, Pall, 256, 256, 4096, 256, 1,
      (size_t)4096 * 256, 0, PSTR, -1, 0, -1, 4096, sc2e, r2p);
  reduce_r2<<<dim3(64), b256, 0, stream>>>(r2p, r2);

  // ---- PV-2: LONG K (Kc=2048) -> 8-phase kernel; bf16 partials
  mfma256_8ph<1, false><<<dim3(16, 8, 2), b512, 0, stream>>>(
      vs2b, Pall, p2, 4096, 4096, 4096, 4096, 2,
      0, 0, (size_t)2048 * 4096, 9, PSTR, 2048, 1.f);
  graph_norm_attn2<<<dim3(2048), b256, 0, stream>>>(
      vs2b + (size_t)2048 * 4096, p2, r2, h2b, gn2w, gn2b, gn2ms);

  // ---- out = relu(h2n . h2n^T): K-split bf16 partials (alias Pall) + reduce
  mfma256_8ph<1, false><<<dim3(8, 8, 4), b512, 0, stream>>>(
      h2b, h2b, g4, 4096, 4096, 2048, 4096, 4,
      0, 0, (size_t)2048 * 2048, -1, 0, 2048, 1.f);
  add4_relu_bf16<<<dim3(4096), b256, 0, stream>>>(g4, (float*)d_out);
}

// Round 14
// 362.877 us; speedup vs baseline: 1.4721x; 1.1303x over previous
//
#include <hip/hip_runtime.h>
#include <math.h>

typedef unsigned int u32;
typedef unsigned short ushort_t;
typedef __attribute__((ext_vector_type(8))) short short8;
typedef __attribute__((ext_vector_type(4))) float f32x4;

__device__ __forceinline__ ushort_t f2bf(float x) {
  u32 u = __float_as_uint(x);
  u32 r = (u + 0x7fffu + ((u >> 16) & 1u)) >> 16;
  return (ushort_t)r;
}
__device__ __forceinline__ float bf2f(u32 s) {
  return __uint_as_float(s << 16);
}
__device__ __forceinline__ void ld4bf(const ushort_t* p, float* o) {
  uint2 u = *(const uint2*)p;
  o[0] = bf2f(u.x & 0xffffu); o[1] = bf2f(u.x >> 16);
  o[2] = bf2f(u.y & 0xffffu); o[3] = bf2f(u.y >> 16);
}

// ---------------- block reduction helper (256 threads = 4 waves) -----------
__device__ __forceinline__ float block_sum256(float v, float* red) {
  #pragma unroll
  for (int o = 32; o > 0; o >>= 1) v += __shfl_down(v, o, 64);
  __syncthreads();
  if ((threadIdx.x & 63) == 0) red[threadIdx.x >> 6] = v;
  __syncthreads();
  return red[0] + red[1] + red[2] + red[3];
}

// =====================================================================
// Fused attention layer 1 (R12-proven): LDS-staged dbuf K/V, KV-split x4.
// =====================================================================
__global__ __launch_bounds__(512) void fused_attn1(
    const ushort_t* __restrict__ qk, const ushort_t* __restrict__ v,
    float* __restrict__ oP, float* __restrict__ r1p, float scale)
{
  __shared__ ushort_t Kl[2][4096];
  __shared__ ushort_t Vl[2][4096];
  __shared__ ushort_t Pl[128][80];
  const int t = threadIdx.x;
  const int lane = t & 63;
  const int wv = t >> 6;
  const int h = blockIdx.y;
  const int m0 = blockIdx.x * 128;
  const int z = blockIdx.z;
  const int lr = lane & 15;
  const int hk = lane >> 4;

  short8 aq0, aq1;
  {
    const ushort_t* qrow = qk + (size_t)(m0 + wv * 16 + lr) * 512 + h * 64;
    aq0 = *(const short8*)(qrow + hk * 8);
    aq1 = *(const short8*)(qrow + 32 + hk * 8);
  }

  f32x4 oAcc[4];
  #pragma unroll
  for (int i = 0; i < 4; ++i) oAcc[i] = (f32x4){0.f, 0.f, 0.f, 0.f};
  float racc[4] = {0.f, 0.f, 0.f, 0.f};

  const size_t kbase = (size_t)256 + h * 64;
  const int rS = t >> 3;
  const int cS = t & 7;
  const int lcS = cS ^ (rS & 7);

  {
    const int n0 = z * 16 * 64;
    __builtin_amdgcn_global_load_lds(
        (const __attribute__((address_space(1))) u32*)(qk + (size_t)(n0 + rS) * 512 + kbase + lcS * 8),
        (__attribute__((address_space(3))) u32*)(&Kl[0][t * 8]), 16, 0, 0);
    __builtin_amdgcn_global_load_lds(
        (const __attribute__((address_space(1))) u32*)(v + (size_t)(h * 128 + rS) * 4096 + n0 + lcS * 8),
        (__attribute__((address_space(3))) u32*)(&Vl[0][t * 8]), 16, 0, 0);
  }
  __syncthreads();

  int cur = 0;
  for (int it = 0; it < 16; ++it) {
    if (it + 1 < 16) {
      const int n1 = (z * 16 + it + 1) * 64;
      __builtin_amdgcn_global_load_lds(
          (const __attribute__((address_space(1))) u32*)(qk + (size_t)(n1 + rS) * 512 + kbase + lcS * 8),
          (__attribute__((address_space(3))) u32*)(&Kl[cur ^ 1][t * 8]), 16, 0, 0);
      __builtin_amdgcn_global_load_lds(
          (const __attribute__((address_space(1))) u32*)(v + (size_t)(h * 128 + rS) * 4096 + n1 + lcS * 8),
          (__attribute__((address_space(3))) u32*)(&Vl[cur ^ 1][t * 8]), 16, 0, 0);
    }
    f32x4 sA[4];
    #pragma unroll
    for (int nf = 0; nf < 4; ++nf) {
      const int rl = nf * 16 + lr;
      const char* kb = (const char*)&Kl[cur][0] + rl * 128;
      short8 b0 = *(const short8*)(kb + ((hk ^ (rl & 7)) * 16));
      short8 b1 = *(const short8*)(kb + (((4 + hk) ^ (rl & 7)) * 16));
      f32x4 sa = (f32x4){0.f, 0.f, 0.f, 0.f};
      sa = __builtin_amdgcn_mfma_f32_16x16x32_bf16(aq0, b0, sa, 0, 0, 0);
      sa = __builtin_amdgcn_mfma_f32_16x16x32_bf16(aq1, b1, sa, 0, 0, 0);
      sA[nf] = sa;
    }
    #pragma unroll
    for (int nf = 0; nf < 4; ++nf) {
      #pragma unroll
      for (int r = 0; r < 4; ++r) {
        float e = exp2f(sA[nf][r] * scale);
        racc[r] += e;
        Pl[wv * 16 + hk * 4 + r][nf * 16 + lr] = f2bf(e);
      }
    }
    short8 ap0 = *(const short8*)&Pl[wv * 16 + lr][hk * 8];
    short8 ap1 = *(const short8*)&Pl[wv * 16 + lr][32 + hk * 8];
    #pragma unroll
    for (int ff = 0; ff < 4; ++ff) {
      const int rl = ff * 16 + lr;
      const char* vb = (const char*)&Vl[cur][0] + rl * 128;
      short8 b0 = *(const short8*)(vb + ((hk ^ (rl & 7)) * 16));
      short8 b1 = *(const short8*)(vb + (((4 + hk) ^ (rl & 7)) * 16));
      oAcc[ff] = __builtin_amdgcn_mfma_f32_16x16x32_bf16(ap0, b0, oAcc[ff], 0, 0, 0);
      oAcc[ff] = __builtin_amdgcn_mfma_f32_16x16x32_bf16(ap1, b1, oAcc[ff], 0, 0, 0);
    }
    __syncthreads();
    cur ^= 1;
  }

  #pragma unroll
  for (int r = 0; r < 4; ++r) {
    racc[r] += __shfl_xor(racc[r], 1);
    racc[r] += __shfl_xor(racc[r], 2);
    racc[r] += __shfl_xor(racc[r], 4);
    racc[r] += __shfl_xor(racc[r], 8);
  }
  if (lr == 0) {
    float* rp = r1p + ((size_t)z * 4 + h) * 4096;
    #pragma unroll
    for (int r = 0; r < 4; ++r) rp[m0 + wv * 16 + hk * 4 + r] = racc[r];
  }
  float* ob = oP + (size_t)z * 512 * 4096;
  #pragma unroll
  for (int ff = 0; ff < 4; ++ff) {
    const size_t fbase = (size_t)(h * 128 + ff * 16 + lr) * 4096;
    #pragma unroll
    for (int r = 0; r < 4; ++r) {
      const int q = m0 + wv * 16 + hk * 4 + r;
      ob[fbase + q] = oAcc[ff][r];
    }
  }
}

// =====================================================================
// Fused attention layer 2: never materializes P.
// Grid (32 qtiles, 4 heads, 2 z); 512 thr (8 waves, 16 q-rows each).
// Per KV-tile (64 nodes): stage X[64,256] + Xt[256,64] (dbuf, XOR swz);
// S^T[node,q] = mfma(X-frag, T-frag) over K=256 (T regs serve as B);
// exp2 in-reg -> per-wave-private P rows; U^T[a,q] += mfma(Xt-frag, P-frag).
// X col 200 == 1 => U^T[200,q] = rowsum; bias rides through O = U.Wv.
// Output: Up[z][h][256][4096] f32 partials (coalesced).
// =====================================================================
__global__ __launch_bounds__(512) void fused_attn2(
    const ushort_t* __restrict__ Tm, const ushort_t* __restrict__ X,
    const ushort_t* __restrict__ Xt, float* __restrict__ Up, float scale)
{
  __shared__ ushort_t Xl[2][16384];     // [64 n][256 a] swizzled, 32 KB ea
  __shared__ ushort_t Xtl[2][16384];    // [256 a][64 n] swizzled, 32 KB ea
  __shared__ ushort_t Pl[128][68];      // [q][node], stride 136 B
  const int t = threadIdx.x;
  const int lane = t & 63;
  const int wv = t >> 6;
  const int h = blockIdx.y;
  const int m0 = blockIdx.x * 128;
  const int z = blockIdx.z;
  const int lr = lane & 15;
  const int hk = lane >> 4;

  // T fragments (B-operand layout: lane lr = q-row, hk = k-chunk), K=256
  short8 tq[8];
  {
    const ushort_t* trow = Tm + ((size_t)h * 4096 + m0 + wv * 16 + lr) * 256;
    #pragma unroll
    for (int s = 0; s < 8; ++s) tq[s] = *(const short8*)(trow + s * 32 + hk * 8);
  }

  f32x4 uAcc[16];
  #pragma unroll
  for (int i = 0; i < 16; ++i) uAcc[i] = (f32x4){0.f, 0.f, 0.f, 0.f};

  auto stage = [&](int buf, int n0) {
    #pragma unroll
    for (int i = 0; i < 4; ++i) {          // X tile: 64 rows x 32 chunks
      const int st = t + i * 512;
      const int row = st >> 5, ph = st & 31;
      const int lc = (ph & 24) | ((ph & 7) ^ (row & 7));
      __builtin_amdgcn_global_load_lds(
          (const __attribute__((address_space(1))) u32*)(X + (size_t)(n0 + row) * 256 + lc * 8),
          (__attribute__((address_space(3))) u32*)(&Xl[buf][st * 8]), 16, 0, 0);
    }
    #pragma unroll
    for (int i = 0; i < 4; ++i) {          // Xt tile: 256 rows x 8 chunks
      const int st = t + i * 512;
      const int row = st >> 3, ph = st & 7;
      const int lc = ph ^ (row & 7);
      __builtin_amdgcn_global_load_lds(
          (const __attribute__((address_space(1))) u32*)(Xt + (size_t)row * 4096 + n0 + lc * 8),
          (__attribute__((address_space(3))) u32*)(&Xtl[buf][st * 8]), 16, 0, 0);
    }
  };

  stage(0, z * 2048);
  __syncthreads();

  int cur = 0;
  for (int it = 0; it < 32; ++it) {
    if (it + 1 < 32) stage(cur ^ 1, z * 2048 + (it + 1) * 64);
    // ---- S^T: C[node, q], A = X-tile frags, B = tq regs
    const char* xb = (const char*)&Xl[cur][0];
    #pragma unroll
    for (int nf = 0; nf < 4; ++nf) {
      const int row = nf * 16 + lr;
      const char* rb = xb + row * 512;
      f32x4 sa = (f32x4){0.f, 0.f, 0.f, 0.f};
      #pragma unroll
      for (int s = 0; s < 8; ++s) {
        const int c = s * 4 + hk;
        const int ph = (c & 24) | ((c & 7) ^ (row & 7));
        short8 xf = *(const short8*)(rb + ph * 16);
        sa = __builtin_amdgcn_mfma_f32_16x16x32_bf16(xf, tq[s], sa, 0, 0, 0);
      }
      #pragma unroll
      for (int r = 0; r < 4; ++r)
        Pl[wv * 16 + lr][nf * 16 + hk * 4 + r] = f2bf(exp2f(sa[r] * scale));
    }
    // ---- U^T: C[a, q] += Xt . P  (A = Xt frags, B = own P rows)
    short8 ap0 = *(const short8*)((const char*)&Pl[wv * 16 + lr][0] + hk * 16);
    short8 ap1 = *(const short8*)((const char*)&Pl[wv * 16 + lr][0] + (4 + hk) * 16);
    const char* xtb = (const char*)&Xtl[cur][0];
    #pragma unroll
    for (int ff = 0; ff < 16; ++ff) {
      const int row = ff * 16 + lr;
      const char* rb2 = xtb + row * 128;
      short8 x0 = *(const short8*)(rb2 + ((hk ^ (row & 7)) * 16));
      short8 x1 = *(const short8*)(rb2 + (((4 + hk) ^ (row & 7)) * 16));
      uAcc[ff] = __builtin_amdgcn_mfma_f32_16x16x32_bf16(x0, ap0, uAcc[ff], 0, 0, 0);
      uAcc[ff] = __builtin_amdgcn_mfma_f32_16x16x32_bf16(x1, ap1, uAcc[ff], 0, 0, 0);
    }
    __syncthreads();
    cur ^= 1;
  }

  // ---- store U^T partials [z][h][a][4096], coalesced over q
  float* ub = Up + ((size_t)(z * 4 + h) * 256) * 4096;
  #pragma unroll
  for (int ff = 0; ff < 16; ++ff) {
    #pragma unroll
    for (int r = 0; r < 4; ++r) {
      const int a = ff * 16 + hk * 4 + r;
      ub[(size_t)a * 4096 + m0 + wv * 16 + lr] = uAcc[ff][r];
    }
  }
}

// ---------------- combine_u: Usum[h][q][256] = bf16(U0+U1) (transpose),
// r2[h][q] = (U0+U1)[a==200]. Grid (64 qtiles, 4 atiles, 4 heads). ---------
__global__ __launch_bounds__(256) void combine_u(
    const float* __restrict__ Up, ushort_t* __restrict__ Usum,
    float* __restrict__ r2)
{
  __shared__ float tl[64][65];
  const int t = threadIdx.x;
  const int qt = blockIdx.x;
  const int at = blockIdx.y;
  const int h  = blockIdx.z;
  const int c = t & 63;
  const int rb = t >> 6;
  #pragma unroll
  for (int i = 0; i < 16; ++i) {
    const int r = rb + i * 4;               // a-local
    const int a = at * 64 + r;
    const int q = qt * 64 + c;
    const size_t i0 = ((size_t)h * 256 + a) * 4096 + q;
    float val = Up[i0] + Up[(size_t)4 * 256 * 4096 + i0];
    tl[r][c] = val;
    if (a == 200) r2[(size_t)h * 4096 + q] = val;
  }
  __syncthreads();
  #pragma unroll
  for (int i = 0; i < 16; ++i) {
    const int r = rb + i * 4;               // q-local
    const int q = qt * 64 + r;
    const int a = at * 64 + c;
    Usum[((size_t)h * 4096 + q) * 256 + a] = f2bf(tl[c][r]);
  }
}

// =====================================================================
// 256x256-tile, 8-phase MFMA GEMM (LONG-K only). Used for the Gram.
// =====================================================================
#define RD_A(bb, mm, cc) (*(const short8*)(lsAc + (bb)*32768 + arow + (mm)*2048 + (cc)))
#define RD_B(bb, nn, cc) (*(const short8*)(lsBc + (bb)*32768 + brow + (nn)*2048 + (cc)))

#define MM8(nn, bv) { \
  acc[0][nn] = __builtin_amdgcn_mfma_f32_16x16x32_bf16(a0, bv, acc[0][nn], 0,0,0); \
  acc[1][nn] = __builtin_amdgcn_mfma_f32_16x16x32_bf16(a1, bv, acc[1][nn], 0,0,0); \
  acc[2][nn] = __builtin_amdgcn_mfma_f32_16x16x32_bf16(a2, bv, acc[2][nn], 0,0,0); \
  acc[3][nn] = __builtin_amdgcn_mfma_f32_16x16x32_bf16(a3, bv, acc[3][nn], 0,0,0); \
  acc[4][nn] = __builtin_amdgcn_mfma_f32_16x16x32_bf16(a4, bv, acc[4][nn], 0,0,0); \
  acc[5][nn] = __builtin_amdgcn_mfma_f32_16x16x32_bf16(a5, bv, acc[5][nn], 0,0,0); \
  acc[6][nn] = __builtin_amdgcn_mfma_f32_16x16x32_bf16(a6, bv, acc[6][nn], 0,0,0); \
  acc[7][nn] = __builtin_amdgcn_mfma_f32_16x16x32_bf16(a7, bv, acc[7][nn], 0,0,0); }

#define STG(BASE, LD, LS, bb, hf, tt) { \
  _Pragma("unroll") \
  for (int ii = 0; ii < 2; ++ii) { \
    const int s_ = t + ii * 512; \
    const int r_ = s_ >> 3; \
    const int lc_ = (s_ & 7) ^ (r_ & 7); \
    __builtin_amdgcn_global_load_lds( \
      (const __attribute__((address_space(1))) u32*)((BASE) + (size_t)((hf) * 128 + r_) * (LD) + (size_t)(tt) * 64 + lc_ * 8), \
      (__attribute__((address_space(3))) u32*)(&(LS)[bb][(hf) * 8192 + s_ * 8]), 16, 0, 0); \
  } }

#define BAR() __builtin_amdgcn_s_barrier()
#define PRIO(x) __builtin_amdgcn_s_setprio(x)

#define GRP(bf, tS1, tS2) { \
  a0=RD_A(bf,0,c0); a1=RD_A(bf,1,c0); a2=RD_A(bf,2,c0); a3=RD_A(bf,3,c0); \
  a4=RD_A(bf,4,c0); a5=RD_A(bf,5,c0); a6=RD_A(bf,6,c0); a7=RD_A(bf,7,c0); \
  b0=RD_B(bf,0,c0); b1=RD_B(bf,1,c0); \
  STG(Ab, lda, lsA, 1-(bf), 1, tS1); STG(Bb, ldb, lsB, 1-(bf), 0, tS1); \
  BAR(); PRIO(1); MM8(0, b0); MM8(1, b1); PRIO(0); BAR(); \
  b2=RD_B(bf,2,c0); b3=RD_B(bf,3,c0); \
  STG(Bb, ldb, lsB, 1-(bf), 1, tS1); \
  BAR(); PRIO(1); MM8(2, b2); MM8(3, b3); PRIO(0); BAR(); \
  a0=RD_A(bf,0,c1); a1=RD_A(bf,1,c1); a2=RD_A(bf,2,c1); a3=RD_A(bf,3,c1); \
  a4=RD_A(bf,4,c1); a5=RD_A(bf,5,c1); a6=RD_A(bf,6,c1); a7=RD_A(bf,7,c1); \
  b0=RD_B(bf,0,c1); b1=RD_B(bf,1,c1); \
  BAR(); PRIO(1); MM8(0, b0); MM8(1, b1); PRIO(0); BAR(); \
  b2=RD_B(bf,2,c1); b3=RD_B(bf,3,c1); \
  STG(Ab, lda, lsA, (bf), 0, tS2); \
  BAR(); PRIO(1); MM8(2, b2); MM8(3, b3); PRIO(0); \
  asm volatile("s_waitcnt vmcnt(2)" ::: "memory"); \
  BAR(); }

template<int CMODE, bool RELU>
__global__ __launch_bounds__(512, 2) void mfma256_8ph(
    const ushort_t* __restrict__ A, const ushort_t* __restrict__ B,
    void* __restrict__ Cv, int lda, int ldb, int ldc,
    int K, int zsplit, size_t zA, size_t zB, size_t zC,
    int bShift, size_t bHead, int Mvalid, float scale)
{
  __shared__ ushort_t lsA[2][16384];
  __shared__ ushort_t lsB[2][16384];
  const int t = threadIdx.x;
  const int gx = gridDim.x;
  const int nwg = gx * gridDim.y;
  const int bid = blockIdx.y * gx + blockIdx.x;
  const int qq = nwg >> 3, rr_ = nwg & 7;
  const int xcd = bid & 7, idx = bid >> 3;
  const int swz = (xcd < rr_ ? xcd * (qq + 1) : rr_ * (qq + 1) + (xcd - rr_) * qq) + idx;
  const int m0 = (swz / gx) * 256;
  const int n0 = (swz % gx) * 256;
  const int z = blockIdx.z;
  int Kc = K, kOff = 0;
  size_t aZ = 0, bZ = 0, cZ = 0;
  if (zsplit > 1) { Kc = K / zsplit; kOff = z * Kc; cZ = (size_t)z * zC; }
  else { aZ = (size_t)z * zA; bZ = (size_t)z * zB; cZ = (size_t)z * zC; }
  const ushort_t* Ab = A + aZ + (size_t)m0 * lda + kOff;
  const ushort_t* Bb = B + bZ + (size_t)n0 * ldb + kOff
                     + (bShift >= 0 ? (size_t)(m0 >> bShift) * bHead : 0);
  const int NT = Kc / 64;

  f32x4 acc[8][4];
  #pragma unroll
  for (int i = 0; i < 8; ++i)
    #pragma unroll
    for (int j = 0; j < 4; ++j) acc[i][j] = (f32x4){0.f, 0.f, 0.f, 0.f};

  const int lane = t & 63;
  const int wv = t >> 6;
  const int wr = (wv >> 2) * 128;
  const int wc = (wv & 3) * 64;
  const int lr = lane & 15;
  const int kc = lane >> 4;
  const int sw = lane & 7;
  const int c0 = (kc ^ sw) * 16;
  const int c1 = c0 ^ 64;
  const int arow = (wr + lr) * 128;
  const int brow = (wc + lr) * 128;
  const char* lsAc = (const char*)lsA;
  const char* lsBc = (const char*)lsB;

  short8 a0, a1, a2, a3, a4, a5, a6, a7, b0, b1, b2, b3;

  STG(Ab, lda, lsA, 0, 0, 0); STG(Ab, lda, lsA, 0, 1, 0);
  STG(Bb, ldb, lsB, 0, 0, 0); STG(Bb, ldb, lsB, 0, 1, 0);
  STG(Ab, lda, lsA, 1, 0, 1);
  asm volatile("s_waitcnt vmcnt(2)" ::: "memory");
  BAR();

  const int NITER = NT >> 1;
  for (int it = 0; it < NITER; ++it) {
    const int tb = 2 * it;
    const int s1 = tb + 1;
    const int s2 = (tb + 2 < NT) ? tb + 2 : 0;
    const int s3 = (tb + 3 < NT) ? tb + 3 : 0;
    GRP(0, s1, s2)
    GRP(1, s2, s3)
  }

  const int row4 = (lane >> 4) * 4;
  const int coln = lane & 15;
  float* Cf = (float*)Cv + cZ;
  ushort_t* Ch = (ushort_t*)Cv + cZ;
  #pragma unroll
  for (int m = 0; m < 8; ++m) {
    #pragma unroll
    for (int r = 0; r < 4; ++r) {
      const int gm = m0 + wr + m * 16 + row4 + r;
      const bool ok = gm < Mvalid;
      #pragma unroll
      for (int n = 0; n < 4; ++n) {
        const int gn = n0 + wc + n * 16 + coln;
        float v = acc[m][n][r] * scale;
        if (RELU) v = fmaxf(v, 0.f);
        if (ok) {
          if (CMODE == 0)      Cf[(size_t)gm * ldc + gn] = v;
          else if (CMODE == 1) Ch[(size_t)gm * ldc + gn] = f2bf(v);
          else                 atomicAdd(&Cf[(size_t)gm * ldc + gn], v);
        }
      }
    }
  }
}

#undef GRP
#undef STG
#undef MM8
#undef RD_A
#undef RD_B

// ================= 128x128-tile MFMA GEMM, 256 threads (SHORT-K) ===========
template<int CMODE, bool RELU>
__global__ __launch_bounds__(256) void mfma_bt(
    const ushort_t* __restrict__ A, const ushort_t* __restrict__ B,
    void* __restrict__ Cv, int lda, int ldb, int ldc,
    int K, int Ksplit, size_t zA, size_t zB, size_t zC,
    int bShift, size_t bHead, int mMask, int Mvalid, float scale)
{
  __shared__ ushort_t lsA[2][128 * 32];
  __shared__ ushort_t lsB[2][128 * 32];
  const int t  = threadIdx.x;
  const int m0 = blockIdx.y * 128;
  const int n0 = blockIdx.x * 128;
  const int z = blockIdx.z;
  int Kc = K, kOff = 0;
  size_t aZ = 0, bZ = 0, cZ = 0;
  if (Ksplit > 1) { Kc = K / Ksplit; kOff = z * Kc; cZ = (size_t)z * zC; }
  else { aZ = (size_t)z * zA; bZ = (size_t)z * zB; cZ = (size_t)z * zC; }
  const int NT = Kc / 32;
  const ushort_t* Ab = A + aZ + (size_t)m0 * lda + kOff;
  const ushort_t* Bb = B + bZ + (size_t)n0 * ldb + kOff
                     + (bShift >= 0 ? (size_t)(m0 >> bShift) * bHead : 0);
  const int cs = t & 3;

  f32x4 acc[4][4];
  #pragma unroll
  for (int i = 0; i < 4; ++i)
    #pragma unroll
    for (int j = 0; j < 4; ++j) acc[i][j] = (f32x4){0.f, 0.f, 0.f, 0.f};

  const int lane = t & 63;
  const int wv = t >> 6;
  const int wr = (wv >> 1) * 64;
  const int wc = (wv & 1) * 64;
  const int lr = lane & 15;
  const int kc = lane >> 4;

  int roffA[4], roffB[4];
  #pragma unroll
  for (int m = 0; m < 4; ++m) {
    int ra = wr + m * 16 + lr;
    roffA[m] = ra * 64 + ((kc ^ (ra & 3)) * 16);
    int rb = wc + m * 16 + lr;
    roffB[m] = rb * 64 + ((kc ^ (rb & 3)) * 16);
  }

  auto stage = [&](int buf, int kt) {
    const ushort_t* As = Ab + kt * 32;
    const ushort_t* Bs = Bb + kt * 32;
    #pragma unroll
    for (int i = 0; i < 2; ++i) {
      int s = t + i * 256;
      int r = s >> 2;
      int c = cs ^ (r & 3);
      __builtin_amdgcn_global_load_lds(
          (const __attribute__((address_space(1))) u32*)(As + (size_t)r * lda + c * 8),
          (__attribute__((address_space(3))) u32*)(&lsA[buf][s * 8]), 16, 0, 0);
    }
    #pragma unroll
    for (int i = 0; i < 2; ++i) {
      int s = t + i * 256;
      int r = s >> 2;
      int c = cs ^ (r & 3);
      __builtin_amdgcn_global_load_lds(
          (const __attribute__((address_space(1))) u32*)(Bs + (size_t)r * ldb + c * 8),
          (__attribute__((address_space(3))) u32*)(&lsB[buf][s * 8]), 16, 0, 0);
    }
  };

  stage(0, 0);
  __syncthreads();
  int cur = 0;
  for (int kt = 0; kt < NT; ++kt) {
    if (kt + 1 < NT) stage(cur ^ 1, kt + 1);
    short8 af[4], bfr[4];
    const char* baseA = (const char*)&lsA[cur][0];
    const char* baseB = (const char*)&lsB[cur][0];
    #pragma unroll
    for (int m = 0; m < 4; ++m) af[m]  = *(const short8*)(baseA + roffA[m]);
    #pragma unroll
    for (int n = 0; n < 4; ++n) bfr[n] = *(const short8*)(baseB + roffB[n]);
    #pragma unroll
    for (int m = 0; m < 4; ++m)
      #pragma unroll
      for (int n = 0; n < 4; ++n)
        acc[m][n] = __builtin_amdgcn_mfma_f32_16x16x32_bf16(af[m], bfr[n], acc[m][n], 0, 0, 0);
    __syncthreads();
    cur ^= 1;
  }

  const int row4 = (lane >> 4) * 4;
  const int coln = lane & 15;
  float* Cf = (float*)Cv + cZ;
  ushort_t* Ch = (ushort_t*)Cv + cZ;
  #pragma unroll
  for (int m = 0; m < 4; ++m) {
    #pragma unroll
    for (int r = 0; r < 4; ++r) {
      const int gm = m0 + wr + m * 16 + row4 + r;
      const bool ok = (mMask >= 0) ? ((gm & mMask) < Mvalid) : (gm < Mvalid);
      #pragma unroll
      for (int n = 0; n < 4; ++n) {
        const int gn = n0 + wc + n * 16 + coln;
        float v = acc[m][n][r] * scale;
        if (RELU) v = fmaxf(v, 0.f);
        if (ok) {
          if (CMODE == 0)      Cf[(size_t)gm * ldc + gn] = v;
          else if (CMODE == 1) Ch[(size_t)gm * ldc + gn] = f2bf(v);
          else                 atomicAdd(&Cf[(size_t)gm * ldc + gn], v);
        }
      }
    }
  }
}

// ---------------- weights: dst[Mp,Kp] bf16 = W^T (+ bias slot at k==Kv) ----
__global__ __launch_bounds__(256) void wt_conv(
    const float* __restrict__ W, const float* __restrict__ bias,
    ushort_t* __restrict__ dst, int Mtot, int ldw, int Kv, int Kp,
    int PADH, int VALH)
{
  const int m = blockIdx.x;
  const int h = m / PADH, c0 = m % PADH;
  const int fout = h * VALH + c0;
  const bool valid = (c0 < VALH) && (fout < Mtot);
  for (int k = threadIdx.x; k < Kp; k += blockDim.x) {
    float v = 0.f;
    if (valid) {
      if (k < Kv) v = W[(size_t)k * ldw + fout];
      else if (k == Kv) v = bias[fout];
    }
    dst[(size_t)m * Kp + k] = f2bf(v);
  }
}

// ---------------- wt_trans: dst[4][256][512] bf16 (padded W~^T per head) ---
__global__ __launch_bounds__(256) void wt_trans(
    const float* __restrict__ W, const float* __restrict__ bias,
    ushort_t* __restrict__ dst)
{
  const int rid = blockIdx.x;
  const int h = rid >> 8, a = rid & 255;
  for (int f = threadIdx.x; f < 512; f += 256) {
    float v = 0.f;
    if (a < 200)       v = W[(size_t)a * 2048 + h * 512 + f];
    else if (a == 200) v = bias[h * 512 + f];
    dst[(size_t)rid * 512 + f] = f2bf(v);
  }
}

// ---------------- xt_conv: Xt[256][4096] bf16 from h1nT (a-major) ----------
__global__ __launch_bounds__(256) void xt_conv(
    const float* __restrict__ h1nT, ushort_t* __restrict__ Xt)
{
  const int a = blockIdx.x;             // 0..255
  for (int q = threadIdx.x; q < 4096; q += 256) {
    float v = (a < 200) ? h1nT[(size_t)a * 4096 + q] : ((a == 200) ? 1.f : 0.f);
    Xt[(size_t)a * 4096 + q] = f2bf(v);
  }
}

// ---------------- transpose fp32 [Kv,4096] -> bf16 [4096,Kp], bias slot ----
__global__ __launch_bounds__(256) void trans_pad(
    const float* __restrict__ src, ushort_t* __restrict__ dst, int Kv, int Kp)
{
  __shared__ float tl[64][65];
  const int t = threadIdx.x;
  const int f0 = blockIdx.x * 64;
  const int i0 = blockIdx.y * 64;
  const int c = t & 63, rbase = t >> 6;
  #pragma unroll
  for (int it = 0; it < 16; ++it) {
    int r = rbase + it * 4;
    int f = f0 + r;
    tl[r][c] = (f < Kv) ? src[(size_t)f * 4096 + i0 + c] : 0.f;
  }
  __syncthreads();
  #pragma unroll
  for (int it = 0; it < 16; ++it) {
    int r = rbase + it * 4;
    int f = f0 + c;
    if (f < Kp) {
      float v = (f < Kv) ? tl[c][r] : ((f == Kv) ? 1.f : 0.f);
      dst[(size_t)(i0 + r) * Kp + f] = f2bf(v);
    }
  }
}

// ---------------- GraphNorm layer 1: x = skip + (sum_z oP)/(sum_z r) -------
__global__ __launch_bounds__(256) void graph_norm_attn1(
    const float* __restrict__ skip, const float* __restrict__ oP,
    const float* __restrict__ r1p, float* __restrict__ out,
    const float* __restrict__ w, const float* __restrict__ b,
    const float* __restrict__ ms)
{
  __shared__ float red[4];
  const int t = threadIdx.x;
  const int row = blockIdx.x;
  const int h = row / 50;
  const int pr = h * 128 + row % 50;
  const float* sk = skip + (size_t)pr * 4096;
  const size_t OSTR = (size_t)512 * 4096;
  float v[16];
  float s = 0.f;
  #pragma unroll
  for (int e = 0; e < 4; ++e) {
    const int idx = t * 4 + 1024 * e;
    float4 a = *(const float4*)&sk[idx];
    float4 o0 = *(const float4*)&oP[(size_t)pr * 4096 + idx];
    float4 o1 = *(const float4*)&oP[OSTR + (size_t)pr * 4096 + idx];
    float4 o2 = *(const float4*)&oP[2 * OSTR + (size_t)pr * 4096 + idx];
    float4 o3 = *(const float4*)&oP[3 * OSTR + (size_t)pr * 4096 + idx];
    float4 r0 = *(const float4*)&r1p[(size_t)h * 4096 + idx];
    float4 r1 = *(const float4*)&r1p[(size_t)(4 + h) * 4096 + idx];
    float4 r2 = *(const float4*)&r1p[(size_t)(8 + h) * 4096 + idx];
    float4 r3 = *(const float4*)&r1p[(size_t)(12 + h) * 4096 + idx];
    v[e*4+0] = a.x + (o0.x + o1.x + o2.x + o3.x) / (r0.x + r1.x + r2.x + r3.x);
    v[e*4+1] = a.y + (o0.y + o1.y + o2.y + o3.y) / (r0.y + r1.y + r2.y + r3.y);
    v[e*4+2] = a.z + (o0.z + o1.z + o2.z + o3.z) / (r0.z + r1.z + r2.z + r3.z);
    v[e*4+3] = a.w + (o0.w + o1.w + o2.w + o3.w) / (r0.w + r1.w + r2.w + r3.w);
    s += v[e*4+0] + v[e*4+1] + v[e*4+2] + v[e*4+3];
  }
  const float mean = block_sum256(s, red) * (1.f / 4096.f);
  const float sub = mean * ms[row];
  float s2 = 0.f;
  #pragma unroll
  for (int e = 0; e < 16; ++e) { v[e] -= sub; s2 += v[e] * v[e]; }
  const float var = block_sum256(s2, red) * (1.f / 4096.f);
  const float scl = rsqrtf(var + 1e-5f) * w[row];
  const float bb = b[row];
  float* y = out + (size_t)row * 4096;
  #pragma unroll
  for (int e = 0; e < 4; ++e) {
    float o0[4];
    #pragma unroll
    for (int q = 0; q < 4; ++q) o0[q] = v[e * 4 + q] * scl + bb;
    *(float4*)&y[t * 4 + 1024 * e] = *(float4*)&o0[0];
  }
}

// ---------------- GraphNorm layer 2 (single O plane): x = skip + O/r -------
__global__ __launch_bounds__(256) void graph_norm_attn2(
    const ushort_t* __restrict__ skip, const ushort_t* __restrict__ O,
    const float* __restrict__ r2, ushort_t* __restrict__ out,
    const float* __restrict__ w, const float* __restrict__ b,
    const float* __restrict__ ms)
{
  __shared__ float red[4];
  const int t = threadIdx.x;
  const int row = blockIdx.x;
  const ushort_t* sk = skip + (size_t)row * 4096;
  const ushort_t* pa = O + (size_t)row * 4096;
  const float* rr = r2 + (size_t)(row >> 9) * 4096;
  float v[16];
  float s = 0.f;
  #pragma unroll
  for (int e = 0; e < 4; ++e) {
    const int idx = t * 4 + 1024 * e;
    float a[4], oa[4];
    ld4bf(&sk[idx], a); ld4bf(&pa[idx], oa);
    float4 rv = *(const float4*)&rr[idx];
    v[e*4+0] = a[0] + oa[0] / rv.x;
    v[e*4+1] = a[1] + oa[1] / rv.y;
    v[e*4+2] = a[2] + oa[2] / rv.z;
    v[e*4+3] = a[3] + oa[3] / rv.w;
    s += v[e*4+0] + v[e*4+1] + v[e*4+2] + v[e*4+3];
  }
  const float mean = block_sum256(s, red) * (1.f / 4096.f);
  const float sub = mean * ms[row];
  float s2 = 0.f;
  #pragma unroll
  for (int e = 0; e < 16; ++e) { v[e] -= sub; s2 += v[e] * v[e]; }
  const float var = block_sum256(s2, red) * (1.f / 4096.f);
  const float scl = rsqrtf(var + 1e-5f) * w[row];
  const float bb = b[row];
  #pragma unroll
  for (int e = 0; e < 16; ++e) v[e] = v[e] * scl + bb;
  float s3 = 0.f;
  #pragma unroll
  for (int e = 0; e < 16; ++e) s3 += v[e] * v[e];
  const float osc = rsqrtf(block_sum256(s3, red));
  ushort_t* y = out + (size_t)row * 4096;
  #pragma unroll
  for (int e = 0; e < 4; ++e) {
    ushort_t o0[4];
    #pragma unroll
    for (int q = 0; q < 4; ++q) o0[q] = f2bf(v[e * 4 + q] * osc);
    *(ushort2*)&y[t * 4 + 1024 * e] = *(ushort2*)&o0[0];
    *(ushort2*)&y[t * 4 + 1024 * e + 2] = *(ushort2*)&o0[2];
  }
}

// ---------------- out = relu(sum of 4 bf16 partial planes) -----------------
__global__ __launch_bounds__(256) void add4_relu_bf16(
    const ushort_t* __restrict__ g, float* __restrict__ out)
{
  const size_t i = (size_t)blockIdx.x * 256 + threadIdx.x;
  const size_t ss = (size_t)2048 * 2048;
  float a[4], b[4], c[4], d[4];
  ld4bf(&g[i * 4], a);
  ld4bf(&g[ss + i * 4], b);
  ld4bf(&g[2 * ss + i * 4], c);
  ld4bf(&g[3 * ss + i * 4], d);
  float4 o;
  o.x = fmaxf(a[0] + b[0] + c[0] + d[0], 0.f);
  o.y = fmaxf(a[1] + b[1] + c[1] + d[1], 0.f);
  o.z = fmaxf(a[2] + b[2] + c[2] + d[2], 0.f);
  o.w = fmaxf(a[3] + b[3] + c[3] + d[3], 0.f);
  ((float4*)out)[i] = o;
}

extern "C" void kernel_launch(void* const* d_in, const int* in_sizes, int n_in,
                              void* d_out, int out_size, void* d_ws, size_t ws_size,
                              hipStream_t stream)
{
  (void)in_sizes; (void)n_in; (void)out_size; (void)ws_size;
  const float* lr_x = (const float*)d_in[0];
  const float* Wq1 = (const float*)d_in[1];  const float* bq1 = (const float*)d_in[2];
  const float* Wk1 = (const float*)d_in[3];  const float* bk1 = (const float*)d_in[4];
  const float* Wv1 = (const float*)d_in[5];  const float* bv1 = (const float*)d_in[6];
  const float* Ws1 = (const float*)d_in[7];  const float* bs1 = (const float*)d_in[8];
  const float* gn1w = (const float*)d_in[9]; const float* gn1b = (const float*)d_in[10];
  const float* gn1ms = (const float*)d_in[11];
  const float* Wq2 = (const float*)d_in[12]; const float* bq2 = (const float*)d_in[13];
  const float* Wk2 = (const float*)d_in[14]; const float* bk2 = (const float*)d_in[15];
  const float* Wv2 = (const float*)d_in[16]; const float* bv2 = (const float*)d_in[17];
  const float* Ws2 = (const float*)d_in[18]; const float* bs2 = (const float*)d_in[19];
  const float* gn2w = (const float*)d_in[20]; const float* gn2b = (const float*)d_in[21];
  const float* gn2ms = (const float*)d_in[22];

  // ---- workspace (~146 MB total) ----
  char* p = (char*)d_ws;
  auto alloc = [&](size_t bytes) { char* r = p; p += (bytes + 255) & ~(size_t)255; return r; };
  char*     scrA = alloc((size_t)32 * 1024 * 1024);  // oP -> Up -> Gram partials
  ushort_t* xb   = (ushort_t*)alloc((size_t)4096 * 544 * 2);
  ushort_t* qk1b = (ushort_t*)alloc((size_t)4096 * 512 * 2);
  ushort_t* v1b  = (ushort_t*)alloc((size_t)512 * 4096 * 2);
  char*     u0   = alloc((size_t)16 * 1024 * 1024);  // s1p, later h2b
  float*    s1p  = (float*)u0;
  float*    h1nT = (float*)   alloc((size_t)200 * 4096 * 4);
  ushort_t* h1nb = (ushort_t*)alloc((size_t)4096 * 256 * 2);
  ushort_t* Wqk1 = (ushort_t*)alloc((size_t)512 * 544 * 2);
  ushort_t* Wv1b = (ushort_t*)alloc((size_t)512 * 544 * 2);
  ushort_t* Ws1p = (ushort_t*)alloc((size_t)512 * 544 * 2);
  ushort_t* Wcat = (ushort_t*)alloc((size_t)4096 * 256 * 2);
  ushort_t* Qt   = (ushort_t*)alloc((size_t)4 * 256 * 512 * 2);
  ushort_t* Kt   = (ushort_t*)alloc((size_t)4 * 256 * 512 * 2);
  ushort_t* Mtall= (ushort_t*)alloc((size_t)4 * 256 * 256 * 2);
  ushort_t* Tall = (ushort_t*)alloc((size_t)4 * 4096 * 256 * 2);
  ushort_t* Xtb  = (ushort_t*)alloc((size_t)256 * 4096 * 2);
  ushort_t* vs2b = (ushort_t*)alloc((size_t)4096 * 4096 * 2);
  ushort_t* Usum = (ushort_t*)alloc((size_t)4 * 4096 * 256 * 2);
  ushort_t* Opl  = (ushort_t*)alloc((size_t)2048 * 4096 * 2);
  float*    r1p  = (float*)   alloc((size_t)16 * 4096 * 4);
  float*    r2   = (float*)   alloc((size_t)4 * 4096 * 4);
  // phase aliases of scrA:
  float*    oP   = (float*)scrA;      // attn-1 partials (dead after gn1)
  float*    Up   = (float*)scrA;      // attn-2 U^T partials (dead after combine)
  ushort_t* g4   = (ushort_t*)scrA;   // Gram bf16 partials
  ushort_t* h2b  = (ushort_t*)u0;     // gn2 output (s1p dead after gn1)

  const dim3 b256(256, 1, 1);
  const dim3 b512(512, 1, 1);
  const float LOG2E = 1.4426950408889634f;
  const float sc1e = 0.14142135623730951f * LOG2E;
  const float sc2e = 0.04419417382415922f * LOG2E;

  // ---- weight conversions
  wt_conv<<<dim3(256),  b256, 0, stream>>>(Wq1, bq1, Wqk1,             200, 200, 512, 544, 64, 50);
  wt_conv<<<dim3(256),  b256, 0, stream>>>(Wk1, bk1, Wqk1 + 256 * 544, 200, 200, 512, 544, 64, 50);
  wt_conv<<<dim3(512),  b256, 0, stream>>>(Wv1, bv1, Wv1b,             200, 200, 512, 544, 128, 50);
  wt_conv<<<dim3(512),  b256, 0, stream>>>(Ws1, bs1, Ws1p,             200, 200, 512, 544, 128, 50);
  wt_conv<<<dim3(2048), b256, 0, stream>>>(Wv2, bv2, Wcat,              2048, 2048, 200, 256, 2048, 2048);
  wt_conv<<<dim3(2048), b256, 0, stream>>>(Ws2, bs2, Wcat + 2048 * 256, 2048, 2048, 200, 256, 2048, 2048);
  wt_trans<<<dim3(1024), b256, 0, stream>>>(Wq2, bq2, Qt);
  wt_trans<<<dim3(1024), b256, 0, stream>>>(Wk2, bk2, Kt);
  trans_pad<<<dim3(9, 64), b256, 0, stream>>>(lr_x, xb, 512, 544);

  // ---- layer-1 projections
  mfma_bt<1, false><<<dim3(4, 32), b256, 0, stream>>>(
      xb, Wqk1, qk1b, 544, 544, 512, 544, 1, 0, 0, 0, -1, 0, -1, 4096, 1.f);
  mfma_bt<1, false><<<dim3(32, 4), b256, 0, stream>>>(
      Wv1b, xb, v1b, 544, 544, 4096, 544, 1, 0, 0, 0, -1, 0, -1, 512, 1.f);
  mfma_bt<0, false><<<dim3(32, 4), b256, 0, stream>>>(
      Ws1p, xb, s1p, 544, 544, 4096, 544, 1, 0, 0, 0, -1, 0, 127, 50, 1.f);

  // ---- attention 1 (fused) + gn1
  fused_attn1<<<dim3(32, 4, 4), b512, 0, stream>>>(qk1b, v1b, oP, r1p, sc1e);
  graph_norm_attn1<<<dim3(200), b256, 0, stream>>>(s1p, oP, r1p, h1nT, gn1w, gn1b, gn1ms);
  trans_pad<<<dim3(4, 64), b256, 0, stream>>>(h1nT, h1nb, 200, 256);
  xt_conv<<<dim3(256), b256, 0, stream>>>(h1nT, Xtb);

  // ---- layer-2 V+skip projection
  mfma_bt<1, false><<<dim3(32, 32), b256, 0, stream>>>(
      Wcat, h1nb, vs2b, 256, 256, 4096, 256, 1, 0, 0, 0, -1, 0, -1, 4096, 1.f);

  // ---- attention 2: low-rank T, then fused flash (no P, no V)
  mfma_bt<1, false><<<dim3(2, 2, 4), b256, 0, stream>>>(
      Kt, Qt, Mtall, 512, 512, 256, 512, 1,
      (size_t)256 * 512, (size_t)256 * 512, (size_t)256 * 256, -1, 0, -1, 256, 1.f);
  mfma_bt<1, false><<<dim3(2, 32, 4), b256, 0, stream>>>(
      h1nb, Mtall, Tall, 256, 256, 256, 256, 1,
      0, (size_t)256 * 256, (size_t)4096 * 256, -1, 0, -1, 4096, 1.f);
  fused_attn2<<<dim3(32, 4, 2), b512, 0, stream>>>(Tall, h1nb, Xtb, Up, sc2e);
  combine_u<<<dim3(64, 4, 4), b256, 0, stream>>>(Up, Usum, r2);
  // O = Wv . U  (bias rides via a==200 column)
  mfma_bt<1, false><<<dim3(32, 16), b256, 0, stream>>>(
      Wcat, Usum, Opl, 256, 256, 4096, 256, 1,
      0, 0, 0, 9, (size_t)4096 * 256, -1, 2048, 1.f);
  graph_norm_attn2<<<dim3(2048), b256, 0, stream>>>(
      vs2b + (size_t)2048 * 4096, Opl, r2, h2b, gn2w, gn2b, gn2ms);

  // ---- out = relu(h2n . h2n^T): K-split bf16 partials + reduce
  mfma256_8ph<1, false><<<dim3(8, 8, 4), b512, 0, stream>>>(
      h2b, h2b, g4, 4096, 4096, 2048, 4096, 4,
      0, 0, (size_t)2048 * 2048, -1, 0, 2048, 1.f);
  add4_relu_bf16<<<dim3(4096), b256, 0, stream>>>(g4, (float*)d_out);
}

// Round 15
// 350.496 us; speedup vs baseline: 1.5241x; 1.0353x over previous
//
#include <hip/hip_runtime.h>
#include <math.h>

typedef unsigned int u32;
typedef unsigned short ushort_t;
typedef __attribute__((ext_vector_type(8))) short short8;
typedef __attribute__((ext_vector_type(4))) float f32x4;

__device__ __forceinline__ ushort_t f2bf(float x) {
  u32 u = __float_as_uint(x);
  u32 r = (u + 0x7fffu + ((u >> 16) & 1u)) >> 16;
  return (ushort_t)r;
}
__device__ __forceinline__ float bf2f(u32 s) {
  return __uint_as_float(s << 16);
}
__device__ __forceinline__ void ld4bf(const ushort_t* p, float* o) {
  uint2 u = *(const uint2*)p;
  o[0] = bf2f(u.x & 0xffffu); o[1] = bf2f(u.x >> 16);
  o[2] = bf2f(u.y & 0xffffu); o[3] = bf2f(u.y >> 16);
}

// ---------------- block reduction helper (256 threads = 4 waves) -----------
__device__ __forceinline__ float block_sum256(float v, float* red) {
  #pragma unroll
  for (int o = 32; o > 0; o >>= 1) v += __shfl_down(v, o, 64);
  __syncthreads();
  if ((threadIdx.x & 63) == 0) red[threadIdx.x >> 6] = v;
  __syncthreads();
  return red[0] + red[1] + red[2] + red[3];
}

// =====================================================================
// Fused attention layer 1 (R12-proven): LDS-staged dbuf K/V, KV-split x4.
// =====================================================================
__global__ __launch_bounds__(512) void fused_attn1(
    const ushort_t* __restrict__ qk, const ushort_t* __restrict__ v,
    float* __restrict__ oP, float* __restrict__ r1p, float scale)
{
  __shared__ ushort_t Kl[2][4096];
  __shared__ ushort_t Vl[2][4096];
  __shared__ ushort_t Pl[128][80];
  const int t = threadIdx.x;
  const int lane = t & 63;
  const int wv = t >> 6;
  const int h = blockIdx.y;
  const int m0 = blockIdx.x * 128;
  const int z = blockIdx.z;
  const int lr = lane & 15;
  const int hk = lane >> 4;

  short8 aq0, aq1;
  {
    const ushort_t* qrow = qk + (size_t)(m0 + wv * 16 + lr) * 512 + h * 64;
    aq0 = *(const short8*)(qrow + hk * 8);
    aq1 = *(const short8*)(qrow + 32 + hk * 8);
  }

  f32x4 oAcc[4];
  #pragma unroll
  for (int i = 0; i < 4; ++i) oAcc[i] = (f32x4){0.f, 0.f, 0.f, 0.f};
  float racc[4] = {0.f, 0.f, 0.f, 0.f};

  const size_t kbase = (size_t)256 + h * 64;
  const int rS = t >> 3;
  const int cS = t & 7;
  const int lcS = cS ^ (rS & 7);

  {
    const int n0 = z * 16 * 64;
    __builtin_amdgcn_global_load_lds(
        (const __attribute__((address_space(1))) u32*)(qk + (size_t)(n0 + rS) * 512 + kbase + lcS * 8),
        (__attribute__((address_space(3))) u32*)(&Kl[0][t * 8]), 16, 0, 0);
    __builtin_amdgcn_global_load_lds(
        (const __attribute__((address_space(1))) u32*)(v + (size_t)(h * 128 + rS) * 4096 + n0 + lcS * 8),
        (__attribute__((address_space(3))) u32*)(&Vl[0][t * 8]), 16, 0, 0);
  }
  __syncthreads();

  int cur = 0;
  for (int it = 0; it < 16; ++it) {
    if (it + 1 < 16) {
      const int n1 = (z * 16 + it + 1) * 64;
      __builtin_amdgcn_global_load_lds(
          (const __attribute__((address_space(1))) u32*)(qk + (size_t)(n1 + rS) * 512 + kbase + lcS * 8),
          (__attribute__((address_space(3))) u32*)(&Kl[cur ^ 1][t * 8]), 16, 0, 0);
      __builtin_amdgcn_global_load_lds(
          (const __attribute__((address_space(1))) u32*)(v + (size_t)(h * 128 + rS) * 4096 + n1 + lcS * 8),
          (__attribute__((address_space(3))) u32*)(&Vl[cur ^ 1][t * 8]), 16, 0, 0);
    }
    f32x4 sA[4];
    #pragma unroll
    for (int nf = 0; nf < 4; ++nf) {
      const int rl = nf * 16 + lr;
      const char* kb = (const char*)&Kl[cur][0] + rl * 128;
      short8 b0 = *(const short8*)(kb + ((hk ^ (rl & 7)) * 16));
      short8 b1 = *(const short8*)(kb + (((4 + hk) ^ (rl & 7)) * 16));
      f32x4 sa = (f32x4){0.f, 0.f, 0.f, 0.f};
      sa = __builtin_amdgcn_mfma_f32_16x16x32_bf16(aq0, b0, sa, 0, 0, 0);
      sa = __builtin_amdgcn_mfma_f32_16x16x32_bf16(aq1, b1, sa, 0, 0, 0);
      sA[nf] = sa;
    }
    #pragma unroll
    for (int nf = 0; nf < 4; ++nf) {
      #pragma unroll
      for (int r = 0; r < 4; ++r) {
        float e = exp2f(sA[nf][r] * scale);
        racc[r] += e;
        Pl[wv * 16 + hk * 4 + r][nf * 16 + lr] = f2bf(e);
      }
    }
    short8 ap0 = *(const short8*)&Pl[wv * 16 + lr][hk * 8];
    short8 ap1 = *(const short8*)&Pl[wv * 16 + lr][32 + hk * 8];
    #pragma unroll
    for (int ff = 0; ff < 4; ++ff) {
      const int rl = ff * 16 + lr;
      const char* vb = (const char*)&Vl[cur][0] + rl * 128;
      short8 b0 = *(const short8*)(vb + ((hk ^ (rl & 7)) * 16));
      short8 b1 = *(const short8*)(vb + (((4 + hk) ^ (rl & 7)) * 16));
      oAcc[ff] = __builtin_amdgcn_mfma_f32_16x16x32_bf16(ap0, b0, oAcc[ff], 0, 0, 0);
      oAcc[ff] = __builtin_amdgcn_mfma_f32_16x16x32_bf16(ap1, b1, oAcc[ff], 0, 0, 0);
    }
    __syncthreads();
    cur ^= 1;
  }

  #pragma unroll
  for (int r = 0; r < 4; ++r) {
    racc[r] += __shfl_xor(racc[r], 1);
    racc[r] += __shfl_xor(racc[r], 2);
    racc[r] += __shfl_xor(racc[r], 4);
    racc[r] += __shfl_xor(racc[r], 8);
  }
  if (lr == 0) {
    float* rp = r1p + ((size_t)z * 4 + h) * 4096;
    #pragma unroll
    for (int r = 0; r < 4; ++r) rp[m0 + wv * 16 + hk * 4 + r] = racc[r];
  }
  float* ob = oP + (size_t)z * 512 * 4096;
  #pragma unroll
  for (int ff = 0; ff < 4; ++ff) {
    const size_t fbase = (size_t)(h * 128 + ff * 16 + lr) * 4096;
    #pragma unroll
    for (int r = 0; r < 4; ++r) {
      const int q = m0 + wv * 16 + hk * 4 + r;
      ob[fbase + q] = oAcc[ff][r];
    }
  }
}

// =====================================================================
// Fused attention layer 2 v2: 2 q-blocks per wave (R14 post-mortem:
// LDS-read-bound with 8x redundant A-frag reads; each read now feeds 2
// MFMAs). Grid (16 qtiles of 256, 4 heads, 4 z of 16 KV-tiles), 512 thr.
// LDS: X[64x256] single-buf (restaged mid-iter), Xt dbuf, P[256][66].
// Output: Up[z][h][256][4096] bf16 partials; X col 200==1 => U[200]=rowsum.
// =====================================================================
__global__ __launch_bounds__(512, 2) void fused_attn2(
    const ushort_t* __restrict__ Tm, const ushort_t* __restrict__ X,
    const ushort_t* __restrict__ Xt, ushort_t* __restrict__ Up, float scale)
{
  __shared__ ushort_t Xl[16384];        // [64 n][256 a] swizzled, 32 KB
  __shared__ ushort_t Xtl[2][16384];    // [256 a][64 n] swizzled, 32 KB ea
  __shared__ ushort_t Pl[256][66];      // [q][node], stride 132 B
  const int t = threadIdx.x;
  const int lane = t & 63;
  const int wv = t >> 6;
  const int h = blockIdx.y;
  const int m0 = blockIdx.x * 256;
  const int z = blockIdx.z;
  const int lr = lane & 15;
  const int hk = lane >> 4;

  // T fragments for 2 q-blocks (B-operand layout: lane lr = q-row)
  short8 tq[2][8];
  #pragma unroll
  for (int qb = 0; qb < 2; ++qb) {
    const ushort_t* trow = Tm + ((size_t)h * 4096 + m0 + wv * 32 + qb * 16 + lr) * 256;
    #pragma unroll
    for (int s = 0; s < 8; ++s) tq[qb][s] = *(const short8*)(trow + s * 32 + hk * 8);
  }

  f32x4 uAcc[16][2];
  #pragma unroll
  for (int i = 0; i < 16; ++i) {
    uAcc[i][0] = (f32x4){0.f, 0.f, 0.f, 0.f};
    uAcc[i][1] = (f32x4){0.f, 0.f, 0.f, 0.f};
  }

  auto stageX = [&](int n0) {
    #pragma unroll
    for (int i = 0; i < 4; ++i) {          // X tile: 64 rows x 32 chunks
      const int st = t + i * 512;
      const int row = st >> 5, ph = st & 31;
      const int lc = (ph & 24) | ((ph & 7) ^ (row & 7));
      __builtin_amdgcn_global_load_lds(
          (const __attribute__((address_space(1))) u32*)(X + (size_t)(n0 + row) * 256 + lc * 8),
          (__attribute__((address_space(3))) u32*)(&Xl[st * 8]), 16, 0, 0);
    }
  };
  auto stageXt = [&](int buf, int n0) {
    #pragma unroll
    for (int i = 0; i < 4; ++i) {          // Xt tile: 256 rows x 8 chunks
      const int st = t + i * 512;
      const int row = st >> 3, ph = st & 7;
      const int lc = ph ^ (row & 7);
      __builtin_amdgcn_global_load_lds(
          (const __attribute__((address_space(1))) u32*)(Xt + (size_t)row * 4096 + n0 + lc * 8),
          (__attribute__((address_space(3))) u32*)(&Xtl[buf][st * 8]), 16, 0, 0);
    }
  };

  const int base = z * 16;
  stageX(base * 64);
  stageXt(0, base * 64);
  __syncthreads();

  int cur = 0;
  for (int it = 0; it < 16; ++it) {
    if (it + 1 < 16) stageXt(cur ^ 1, (base + it + 1) * 64);
    // ---- S^T phase: C[node, q] x 2 q-blocks; A = X frags, B = tq regs
    const char* xb = (const char*)&Xl[0];
    #pragma unroll
    for (int nf = 0; nf < 4; ++nf) {
      const int row = nf * 16 + lr;
      const char* rb = xb + row * 512;
      f32x4 sa0 = (f32x4){0.f, 0.f, 0.f, 0.f};
      f32x4 sa1 = (f32x4){0.f, 0.f, 0.f, 0.f};
      #pragma unroll
      for (int s = 0; s < 8; ++s) {
        const int c = s * 4 + hk;
        const int ph = (c & 24) | ((c & 7) ^ (row & 7));
        short8 xf = *(const short8*)(rb + ph * 16);
        sa0 = __builtin_amdgcn_mfma_f32_16x16x32_bf16(xf, tq[0][s], sa0, 0, 0, 0);
        sa1 = __builtin_amdgcn_mfma_f32_16x16x32_bf16(xf, tq[1][s], sa1, 0, 0, 0);
      }
      #pragma unroll
      for (int r = 0; r < 4; ++r) {
        Pl[wv * 32 + lr][nf * 16 + hk * 4 + r]      = f2bf(exp2f(sa0[r] * scale));
        Pl[wv * 32 + 16 + lr][nf * 16 + hk * 4 + r] = f2bf(exp2f(sa1[r] * scale));
      }
    }
    __syncthreads();                       // all waves done reading Xl
    if (it + 1 < 16) stageX((base + it + 1) * 64);
    // ---- U phase: C[a, q] += Xt . P  (each Xt read feeds 2 q-blocks)
    short8 p00 = *(const short8*)((const char*)&Pl[wv * 32 + lr][0] + hk * 16);
    short8 p01 = *(const short8*)((const char*)&Pl[wv * 32 + lr][0] + (4 + hk) * 16);
    short8 p10 = *(const short8*)((const char*)&Pl[wv * 32 + 16 + lr][0] + hk * 16);
    short8 p11 = *(const short8*)((const char*)&Pl[wv * 32 + 16 + lr][0] + (4 + hk) * 16);
    const char* xtb = (const char*)&Xtl[cur][0];
    #pragma unroll
    for (int ff = 0; ff < 16; ++ff) {
      const int row = ff * 16 + lr;
      const char* rb2 = xtb + row * 128;
      short8 x0 = *(const short8*)(rb2 + ((hk ^ (row & 7)) * 16));
      short8 x1 = *(const short8*)(rb2 + (((4 + hk) ^ (row & 7)) * 16));
      uAcc[ff][0] = __builtin_amdgcn_mfma_f32_16x16x32_bf16(x0, p00, uAcc[ff][0], 0, 0, 0);
      uAcc[ff][0] = __builtin_amdgcn_mfma_f32_16x16x32_bf16(x1, p01, uAcc[ff][0], 0, 0, 0);
      uAcc[ff][1] = __builtin_amdgcn_mfma_f32_16x16x32_bf16(x0, p10, uAcc[ff][1], 0, 0, 0);
      uAcc[ff][1] = __builtin_amdgcn_mfma_f32_16x16x32_bf16(x1, p11, uAcc[ff][1], 0, 0, 0);
    }
    __syncthreads();                       // drains stages; guards flips
    cur ^= 1;
  }

  // ---- store U^T partials [z][h][a][4096] bf16, coalesced over q
  ushort_t* ub = Up + (size_t)(z * 4 + h) * 256 * 4096;
  #pragma unroll
  for (int ff = 0; ff < 16; ++ff) {
    #pragma unroll
    for (int qb = 0; qb < 2; ++qb) {
      #pragma unroll
      for (int r = 0; r < 4; ++r) {
        const int a = ff * 16 + hk * 4 + r;
        ub[(size_t)a * 4096 + m0 + wv * 32 + qb * 16 + lr] = f2bf(uAcc[ff][qb][r]);
      }
    }
  }
}

// ---------------- combine_u: Usum[h][q][256] = bf16(sum_z Uz) (transpose),
// r2[h][q] = sum_z Uz[a==200]. Grid (64 qtiles, 4 atiles, 4 heads). --------
__global__ __launch_bounds__(256) void combine_u(
    const ushort_t* __restrict__ Up, ushort_t* __restrict__ Usum,
    float* __restrict__ r2)
{
  __shared__ float tl[64][65];
  const int t = threadIdx.x;
  const int qt = blockIdx.x;
  const int at = blockIdx.y;
  const int h  = blockIdx.z;
  const int c = t & 63;
  const int rb = t >> 6;
  const size_t PLN = (size_t)4 * 256 * 4096;
  #pragma unroll
  for (int i = 0; i < 16; ++i) {
    const int r = rb + i * 4;               // a-local
    const int a = at * 64 + r;
    const int q = qt * 64 + c;
    const size_t i0 = ((size_t)h * 256 + a) * 4096 + q;
    float val = bf2f(Up[i0]) + bf2f(Up[PLN + i0])
              + bf2f(Up[2 * PLN + i0]) + bf2f(Up[3 * PLN + i0]);
    tl[r][c] = val;
    if (a == 200) r2[(size_t)h * 4096 + q] = val;
  }
  __syncthreads();
  #pragma unroll
  for (int i = 0; i < 16; ++i) {
    const int r = rb + i * 4;               // q-local
    const int q = qt * 64 + r;
    const int a = at * 64 + c;
    Usum[((size_t)h * 4096 + q) * 256 + a] = f2bf(tl[c][r]);
  }
}

// =====================================================================
// 256x256-tile, 8-phase MFMA GEMM (LONG-K only). Used for the Gram.
// =====================================================================
#define RD_A(bb, mm, cc) (*(const short8*)(lsAc + (bb)*32768 + arow + (mm)*2048 + (cc)))
#define RD_B(bb, nn, cc) (*(const short8*)(lsBc + (bb)*32768 + brow + (nn)*2048 + (cc)))

#define MM8(nn, bv) { \
  acc[0][nn] = __builtin_amdgcn_mfma_f32_16x16x32_bf16(a0, bv, acc[0][nn], 0,0,0); \
  acc[1][nn] = __builtin_amdgcn_mfma_f32_16x16x32_bf16(a1, bv, acc[1][nn], 0,0,0); \
  acc[2][nn] = __builtin_amdgcn_mfma_f32_16x16x32_bf16(a2, bv, acc[2][nn], 0,0,0); \
  acc[3][nn] = __builtin_amdgcn_mfma_f32_16x16x32_bf16(a3, bv, acc[3][nn], 0,0,0); \
  acc[4][nn] = __builtin_amdgcn_mfma_f32_16x16x32_bf16(a4, bv, acc[4][nn], 0,0,0); \
  acc[5][nn] = __builtin_amdgcn_mfma_f32_16x16x32_bf16(a5, bv, acc[5][nn], 0,0,0); \
  acc[6][nn] = __builtin_amdgcn_mfma_f32_16x16x32_bf16(a6, bv, acc[6][nn], 0,0,0); \
  acc[7][nn] = __builtin_amdgcn_mfma_f32_16x16x32_bf16(a7, bv, acc[7][nn], 0,0,0); }

#define STG(BASE, LD, LS, bb, hf, tt) { \
  _Pragma("unroll") \
  for (int ii = 0; ii < 2; ++ii) { \
    const int s_ = t + ii * 512; \
    const int r_ = s_ >> 3; \
    const int lc_ = (s_ & 7) ^ (r_ & 7); \
    __builtin_amdgcn_global_load_lds( \
      (const __attribute__((address_space(1))) u32*)((BASE) + (size_t)((hf) * 128 + r_) * (LD) + (size_t)(tt) * 64 + lc_ * 8), \
      (__attribute__((address_space(3))) u32*)(&(LS)[bb][(hf) * 8192 + s_ * 8]), 16, 0, 0); \
  } }

#define BAR() __builtin_amdgcn_s_barrier()
#define PRIO(x) __builtin_amdgcn_s_setprio(x)

#define GRP(bf, tS1, tS2) { \
  a0=RD_A(bf,0,c0); a1=RD_A(bf,1,c0); a2=RD_A(bf,2,c0); a3=RD_A(bf,3,c0); \
  a4=RD_A(bf,4,c0); a5=RD_A(bf,5,c0); a6=RD_A(bf,6,c0); a7=RD_A(bf,7,c0); \
  b0=RD_B(bf,0,c0); b1=RD_B(bf,1,c0); \
  STG(Ab, lda, lsA, 1-(bf), 1, tS1); STG(Bb, ldb, lsB, 1-(bf), 0, tS1); \
  BAR(); PRIO(1); MM8(0, b0); MM8(1, b1); PRIO(0); BAR(); \
  b2=RD_B(bf,2,c0); b3=RD_B(bf,3,c0); \
  STG(Bb, ldb, lsB, 1-(bf), 1, tS1); \
  BAR(); PRIO(1); MM8(2, b2); MM8(3, b3); PRIO(0); BAR(); \
  a0=RD_A(bf,0,c1); a1=RD_A(bf,1,c1); a2=RD_A(bf,2,c1); a3=RD_A(bf,3,c1); \
  a4=RD_A(bf,4,c1); a5=RD_A(bf,5,c1); a6=RD_A(bf,6,c1); a7=RD_A(bf,7,c1); \
  b0=RD_B(bf,0,c1); b1=RD_B(bf,1,c1); \
  BAR(); PRIO(1); MM8(0, b0); MM8(1, b1); PRIO(0); BAR(); \
  b2=RD_B(bf,2,c1); b3=RD_B(bf,3,c1); \
  STG(Ab, lda, lsA, (bf), 0, tS2); \
  BAR(); PRIO(1); MM8(2, b2); MM8(3, b3); PRIO(0); \
  asm volatile("s_waitcnt vmcnt(2)" ::: "memory"); \
  BAR(); }

template<int CMODE, bool RELU>
__global__ __launch_bounds__(512, 2) void mfma256_8ph(
    const ushort_t* __restrict__ A, const ushort_t* __restrict__ B,
    void* __restrict__ Cv, int lda, int ldb, int ldc,
    int K, int zsplit, size_t zA, size_t zB, size_t zC,
    int bShift, size_t bHead, int Mvalid, float scale)
{
  __shared__ ushort_t lsA[2][16384];
  __shared__ ushort_t lsB[2][16384];
  const int t = threadIdx.x;
  const int gx = gridDim.x;
  const int nwg = gx * gridDim.y;
  const int bid = blockIdx.y * gx + blockIdx.x;
  const int qq = nwg >> 3, rr_ = nwg & 7;
  const int xcd = bid & 7, idx = bid >> 3;
  const int swz = (xcd < rr_ ? xcd * (qq + 1) : rr_ * (qq + 1) + (xcd - rr_) * qq) + idx;
  const int m0 = (swz / gx) * 256;
  const int n0 = (swz % gx) * 256;
  const int z = blockIdx.z;
  int Kc = K, kOff = 0;
  size_t aZ = 0, bZ = 0, cZ = 0;
  if (zsplit > 1) { Kc = K / zsplit; kOff = z * Kc; cZ = (size_t)z * zC; }
  else { aZ = (size_t)z * zA; bZ = (size_t)z * zB; cZ = (size_t)z * zC; }
  const ushort_t* Ab = A + aZ + (size_t)m0 * lda + kOff;
  const ushort_t* Bb = B + bZ + (size_t)n0 * ldb + kOff
                     + (bShift >= 0 ? (size_t)(m0 >> bShift) * bHead : 0);
  const int NT = Kc / 64;

  f32x4 acc[8][4];
  #pragma unroll
  for (int i = 0; i < 8; ++i)
    #pragma unroll
    for (int j = 0; j < 4; ++j) acc[i][j] = (f32x4){0.f, 0.f, 0.f, 0.f};

  const int lane = t & 63;
  const int wv = t >> 6;
  const int wr = (wv >> 2) * 128;
  const int wc = (wv & 3) * 64;
  const int lr = lane & 15;
  const int kc = lane >> 4;
  const int sw = lane & 7;
  const int c0 = (kc ^ sw) * 16;
  const int c1 = c0 ^ 64;
  const int arow = (wr + lr) * 128;
  const int brow = (wc + lr) * 128;
  const char* lsAc = (const char*)lsA;
  const char* lsBc = (const char*)lsB;

  short8 a0, a1, a2, a3, a4, a5, a6, a7, b0, b1, b2, b3;

  STG(Ab, lda, lsA, 0, 0, 0); STG(Ab, lda, lsA, 0, 1, 0);
  STG(Bb, ldb, lsB, 0, 0, 0); STG(Bb, ldb, lsB, 0, 1, 0);
  STG(Ab, lda, lsA, 1, 0, 1);
  asm volatile("s_waitcnt vmcnt(2)" ::: "memory");
  BAR();

  const int NITER = NT >> 1;
  for (int it = 0; it < NITER; ++it) {
    const int tb = 2 * it;
    const int s1 = tb + 1;
    const int s2 = (tb + 2 < NT) ? tb + 2 : 0;
    const int s3 = (tb + 3 < NT) ? tb + 3 : 0;
    GRP(0, s1, s2)
    GRP(1, s2, s3)
  }

  const int row4 = (lane >> 4) * 4;
  const int coln = lane & 15;
  float* Cf = (float*)Cv + cZ;
  ushort_t* Ch = (ushort_t*)Cv + cZ;
  #pragma unroll
  for (int m = 0; m < 8; ++m) {
    #pragma unroll
    for (int r = 0; r < 4; ++r) {
      const int gm = m0 + wr + m * 16 + row4 + r;
      const bool ok = gm < Mvalid;
      #pragma unroll
      for (int n = 0; n < 4; ++n) {
        const int gn = n0 + wc + n * 16 + coln;
        float v = acc[m][n][r] * scale;
        if (RELU) v = fmaxf(v, 0.f);
        if (ok) {
          if (CMODE == 0)      Cf[(size_t)gm * ldc + gn] = v;
          else if (CMODE == 1) Ch[(size_t)gm * ldc + gn] = f2bf(v);
          else                 atomicAdd(&Cf[(size_t)gm * ldc + gn], v);
        }
      }
    }
  }
}

#undef GRP
#undef STG
#undef MM8
#undef RD_A
#undef RD_B

// ================= 128x128-tile MFMA GEMM, 256 threads (SHORT-K) ===========
template<int CMODE, bool RELU>
__global__ __launch_bounds__(256) void mfma_bt(
    const ushort_t* __restrict__ A, const ushort_t* __restrict__ B,
    void* __restrict__ Cv, int lda, int ldb, int ldc,
    int K, int Ksplit, size_t zA, size_t zB, size_t zC,
    int bShift, size_t bHead, int mMask, int Mvalid, float scale)
{
  __shared__ ushort_t lsA[2][128 * 32];
  __shared__ ushort_t lsB[2][128 * 32];
  const int t  = threadIdx.x;
  const int m0 = blockIdx.y * 128;
  const int n0 = blockIdx.x * 128;
  const int z = blockIdx.z;
  int Kc = K, kOff = 0;
  size_t aZ = 0, bZ = 0, cZ = 0;
  if (Ksplit > 1) { Kc = K / Ksplit; kOff = z * Kc; cZ = (size_t)z * zC; }
  else { aZ = (size_t)z * zA; bZ = (size_t)z * zB; cZ = (size_t)z * zC; }
  const int NT = Kc / 32;
  const ushort_t* Ab = A + aZ + (size_t)m0 * lda + kOff;
  const ushort_t* Bb = B + bZ + (size_t)n0 * ldb + kOff
                     + (bShift >= 0 ? (size_t)(m0 >> bShift) * bHead : 0);
  const int cs = t & 3;

  f32x4 acc[4][4];
  #pragma unroll
  for (int i = 0; i < 4; ++i)
    #pragma unroll
    for (int j = 0; j < 4; ++j) acc[i][j] = (f32x4){0.f, 0.f, 0.f, 0.f};

  const int lane = t & 63;
  const int wv = t >> 6;
  const int wr = (wv >> 1) * 64;
  const int wc = (wv & 1) * 64;
  const int lr = lane & 15;
  const int kc = lane >> 4;

  int roffA[4], roffB[4];
  #pragma unroll
  for (int m = 0; m < 4; ++m) {
    int ra = wr + m * 16 + lr;
    roffA[m] = ra * 64 + ((kc ^ (ra & 3)) * 16);
    int rb = wc + m * 16 + lr;
    roffB[m] = rb * 64 + ((kc ^ (rb & 3)) * 16);
  }

  auto stage = [&](int buf, int kt) {
    const ushort_t* As = Ab + kt * 32;
    const ushort_t* Bs = Bb + kt * 32;
    #pragma unroll
    for (int i = 0; i < 2; ++i) {
      int s = t + i * 256;
      int r = s >> 2;
      int c = cs ^ (r & 3);
      __builtin_amdgcn_global_load_lds(
          (const __attribute__((address_space(1))) u32*)(As + (size_t)r * lda + c * 8),
          (__attribute__((address_space(3))) u32*)(&lsA[buf][s * 8]), 16, 0, 0);
    }
    #pragma unroll
    for (int i = 0; i < 2; ++i) {
      int s = t + i * 256;
      int r = s >> 2;
      int c = cs ^ (r & 3);
      __builtin_amdgcn_global_load_lds(
          (const __attribute__((address_space(1))) u32*)(Bs + (size_t)r * ldb + c * 8),
          (__attribute__((address_space(3))) u32*)(&lsB[buf][s * 8]), 16, 0, 0);
    }
  };

  stage(0, 0);
  __syncthreads();
  int cur = 0;
  for (int kt = 0; kt < NT; ++kt) {
    if (kt + 1 < NT) stage(cur ^ 1, kt + 1);
    short8 af[4], bfr[4];
    const char* baseA = (const char*)&lsA[cur][0];
    const char* baseB = (const char*)&lsB[cur][0];
    #pragma unroll
    for (int m = 0; m < 4; ++m) af[m]  = *(const short8*)(baseA + roffA[m]);
    #pragma unroll
    for (int n = 0; n < 4; ++n) bfr[n] = *(const short8*)(baseB + roffB[n]);
    #pragma unroll
    for (int m = 0; m < 4; ++m)
      #pragma unroll
      for (int n = 0; n < 4; ++n)
        acc[m][n] = __builtin_amdgcn_mfma_f32_16x16x32_bf16(af[m], bfr[n], acc[m][n], 0, 0, 0);
    __syncthreads();
    cur ^= 1;
  }

  const int row4 = (lane >> 4) * 4;
  const int coln = lane & 15;
  float* Cf = (float*)Cv + cZ;
  ushort_t* Ch = (ushort_t*)Cv + cZ;
  #pragma unroll
  for (int m = 0; m < 4; ++m) {
    #pragma unroll
    for (int r = 0; r < 4; ++r) {
      const int gm = m0 + wr + m * 16 + row4 + r;
      const bool ok = (mMask >= 0) ? ((gm & mMask) < Mvalid) : (gm < Mvalid);
      #pragma unroll
      for (int n = 0; n < 4; ++n) {
        const int gn = n0 + wc + n * 16 + coln;
        float v = acc[m][n][r] * scale;
        if (RELU) v = fmaxf(v, 0.f);
        if (ok) {
          if (CMODE == 0)      Cf[(size_t)gm * ldc + gn] = v;
          else if (CMODE == 1) Ch[(size_t)gm * ldc + gn] = f2bf(v);
          else                 atomicAdd(&Cf[(size_t)gm * ldc + gn], v);
        }
      }
    }
  }
}

// ---------------- weights: dst[Mp,Kp] bf16 = W^T (+ bias slot at k==Kv) ----
__global__ __launch_bounds__(256) void wt_conv(
    const float* __restrict__ W, const float* __restrict__ bias,
    ushort_t* __restrict__ dst, int Mtot, int ldw, int Kv, int Kp,
    int PADH, int VALH)
{
  const int m = blockIdx.x;
  const int h = m / PADH, c0 = m % PADH;
  const int fout = h * VALH + c0;
  const bool valid = (c0 < VALH) && (fout < Mtot);
  for (int k = threadIdx.x; k < Kp; k += blockDim.x) {
    float v = 0.f;
    if (valid) {
      if (k < Kv) v = W[(size_t)k * ldw + fout];
      else if (k == Kv) v = bias[fout];
    }
    dst[(size_t)m * Kp + k] = f2bf(v);
  }
}

// ---------------- wt_trans: dst[4][256][512] bf16 (padded W~^T per head) ---
__global__ __launch_bounds__(256) void wt_trans(
    const float* __restrict__ W, const float* __restrict__ bias,
    ushort_t* __restrict__ dst)
{
  const int rid = blockIdx.x;
  const int h = rid >> 8, a = rid & 255;
  for (int f = threadIdx.x; f < 512; f += 256) {
    float v = 0.f;
    if (a < 200)       v = W[(size_t)a * 2048 + h * 512 + f];
    else if (a == 200) v = bias[h * 512 + f];
    dst[(size_t)rid * 512 + f] = f2bf(v);
  }
}

// ---------------- xt_conv: Xt[256][4096] bf16 from h1nT (a-major) ----------
__global__ __launch_bounds__(256) void xt_conv(
    const float* __restrict__ h1nT, ushort_t* __restrict__ Xt)
{
  const int a = blockIdx.x;
  for (int q = threadIdx.x; q < 4096; q += 256) {
    float v = (a < 200) ? h1nT[(size_t)a * 4096 + q] : ((a == 200) ? 1.f : 0.f);
    Xt[(size_t)a * 4096 + q] = f2bf(v);
  }
}

// ---------------- transpose fp32 [Kv,4096] -> bf16 [4096,Kp], bias slot ----
__global__ __launch_bounds__(256) void trans_pad(
    const float* __restrict__ src, ushort_t* __restrict__ dst, int Kv, int Kp)
{
  __shared__ float tl[64][65];
  const int t = threadIdx.x;
  const int f0 = blockIdx.x * 64;
  const int i0 = blockIdx.y * 64;
  const int c = t & 63, rbase = t >> 6;
  #pragma unroll
  for (int it = 0; it < 16; ++it) {
    int r = rbase + it * 4;
    int f = f0 + r;
    tl[r][c] = (f < Kv) ? src[(size_t)f * 4096 + i0 + c] : 0.f;
  }
  __syncthreads();
  #pragma unroll
  for (int it = 0; it < 16; ++it) {
    int r = rbase + it * 4;
    int f = f0 + c;
    if (f < Kp) {
      float v = (f < Kv) ? tl[c][r] : ((f == Kv) ? 1.f : 0.f);
      dst[(size_t)(i0 + r) * Kp + f] = f2bf(v);
    }
  }
}

// ---------------- GraphNorm layer 1: x = skip + (sum_z oP)/(sum_z r) -------
__global__ __launch_bounds__(256) void graph_norm_attn1(
    const float* __restrict__ skip, const float* __restrict__ oP,
    const float* __restrict__ r1p, float* __restrict__ out,
    const float* __restrict__ w, const float* __restrict__ b,
    const float* __restrict__ ms)
{
  __shared__ float red[4];
  const int t = threadIdx.x;
  const int row = blockIdx.x;
  const int h = row / 50;
  const int pr = h * 128 + row % 50;
  const float* sk = skip + (size_t)pr * 4096;
  const size_t OSTR = (size_t)512 * 4096;
  float v[16];
  float s = 0.f;
  #pragma unroll
  for (int e = 0; e < 4; ++e) {
    const int idx = t * 4 + 1024 * e;
    float4 a = *(const float4*)&sk[idx];
    float4 o0 = *(const float4*)&oP[(size_t)pr * 4096 + idx];
    float4 o1 = *(const float4*)&oP[OSTR + (size_t)pr * 4096 + idx];
    float4 o2 = *(const float4*)&oP[2 * OSTR + (size_t)pr * 4096 + idx];
    float4 o3 = *(const float4*)&oP[3 * OSTR + (size_t)pr * 4096 + idx];
    float4 r0 = *(const float4*)&r1p[(size_t)h * 4096 + idx];
    float4 r1 = *(const float4*)&r1p[(size_t)(4 + h) * 4096 + idx];
    float4 r2 = *(const float4*)&r1p[(size_t)(8 + h) * 4096 + idx];
    float4 r3 = *(const float4*)&r1p[(size_t)(12 + h) * 4096 + idx];
    v[e*4+0] = a.x + (o0.x + o1.x + o2.x + o3.x) / (r0.x + r1.x + r2.x + r3.x);
    v[e*4+1] = a.y + (o0.y + o1.y + o2.y + o3.y) / (r0.y + r1.y + r2.y + r3.y);
    v[e*4+2] = a.z + (o0.z + o1.z + o2.z + o3.z) / (r0.z + r1.z + r2.z + r3.z);
    v[e*4+3] = a.w + (o0.w + o1.w + o2.w + o3.w) / (r0.w + r1.w + r2.w + r3.w);
    s += v[e*4+0] + v[e*4+1] + v[e*4+2] + v[e*4+3];
  }
  const float mean = block_sum256(s, red) * (1.f / 4096.f);
  const float sub = mean * ms[row];
  float s2 = 0.f;
  #pragma unroll
  for (int e = 0; e < 16; ++e) { v[e] -= sub; s2 += v[e] * v[e]; }
  const float var = block_sum256(s2, red) * (1.f / 4096.f);
  const float scl = rsqrtf(var + 1e-5f) * w[row];
  const float bb = b[row];
  float* y = out + (size_t)row * 4096;
  #pragma unroll
  for (int e = 0; e < 4; ++e) {
    float o0[4];
    #pragma unroll
    for (int q = 0; q < 4; ++q) o0[q] = v[e * 4 + q] * scl + bb;
    *(float4*)&y[t * 4 + 1024 * e] = *(float4*)&o0[0];
  }
}

// ---------------- GraphNorm layer 2 (single O plane): x = skip + O/r -------
__global__ __launch_bounds__(256) void graph_norm_attn2(
    const ushort_t* __restrict__ skip, const ushort_t* __restrict__ O,
    const float* __restrict__ r2, ushort_t* __restrict__ out,
    const float* __restrict__ w, const float* __restrict__ b,
    const float* __restrict__ ms)
{
  __shared__ float red[4];
  const int t = threadIdx.x;
  const int row = blockIdx.x;
  const ushort_t* sk = skip + (size_t)row * 4096;
  const ushort_t* pa = O + (size_t)row * 4096;
  const float* rr = r2 + (size_t)(row >> 9) * 4096;
  float v[16];
  float s = 0.f;
  #pragma unroll
  for (int e = 0; e < 4; ++e) {
    const int idx = t * 4 + 1024 * e;
    float a[4], oa[4];
    ld4bf(&sk[idx], a); ld4bf(&pa[idx], oa);
    float4 rv = *(const float4*)&rr[idx];
    v[e*4+0] = a[0] + oa[0] / rv.x;
    v[e*4+1] = a[1] + oa[1] / rv.y;
    v[e*4+2] = a[2] + oa[2] / rv.z;
    v[e*4+3] = a[3] + oa[3] / rv.w;
    s += v[e*4+0] + v[e*4+1] + v[e*4+2] + v[e*4+3];
  }
  const float mean = block_sum256(s, red) * (1.f / 4096.f);
  const float sub = mean * ms[row];
  float s2 = 0.f;
  #pragma unroll
  for (int e = 0; e < 16; ++e) { v[e] -= sub; s2 += v[e] * v[e]; }
  const float var = block_sum256(s2, red) * (1.f / 4096.f);
  const float scl = rsqrtf(var + 1e-5f) * w[row];
  const float bb = b[row];
  #pragma unroll
  for (int e = 0; e < 16; ++e) v[e] = v[e] * scl + bb;
  float s3 = 0.f;
  #pragma unroll
  for (int e = 0; e < 16; ++e) s3 += v[e] * v[e];
  const float osc = rsqrtf(block_sum256(s3, red));
  ushort_t* y = out + (size_t)row * 4096;
  #pragma unroll
  for (int e = 0; e < 4; ++e) {
    ushort_t o0[4];
    #pragma unroll
    for (int q = 0; q < 4; ++q) o0[q] = f2bf(v[e * 4 + q] * osc);
    *(ushort2*)&y[t * 4 + 1024 * e] = *(ushort2*)&o0[0];
    *(ushort2*)&y[t * 4 + 1024 * e + 2] = *(ushort2*)&o0[2];
  }
}

// ---------------- out = relu(sum of 4 bf16 partial planes) -----------------
__global__ __launch_bounds__(256) void add4_relu_bf16(
    const ushort_t* __restrict__ g, float* __restrict__ out)
{
  const size_t i = (size_t)blockIdx.x * 256 + threadIdx.x;
  const size_t ss = (size_t)2048 * 2048;
  float a[4], b[4], c[4], d[4];
  ld4bf(&g[i * 4], a);
  ld4bf(&g[ss + i * 4], b);
  ld4bf(&g[2 * ss + i * 4], c);
  ld4bf(&g[3 * ss + i * 4], d);
  float4 o;
  o.x = fmaxf(a[0] + b[0] + c[0] + d[0], 0.f);
  o.y = fmaxf(a[1] + b[1] + c[1] + d[1], 0.f);
  o.z = fmaxf(a[2] + b[2] + c[2] + d[2], 0.f);
  o.w = fmaxf(a[3] + b[3] + c[3] + d[3], 0.f);
  ((float4*)out)[i] = o;
}

extern "C" void kernel_launch(void* const* d_in, const int* in_sizes, int n_in,
                              void* d_out, int out_size, void* d_ws, size_t ws_size,
                              hipStream_t stream)
{
  (void)in_sizes; (void)n_in; (void)out_size; (void)ws_size;
  const float* lr_x = (const float*)d_in[0];
  const float* Wq1 = (const float*)d_in[1];  const float* bq1 = (const float*)d_in[2];
  const float* Wk1 = (const float*)d_in[3];  const float* bk1 = (const float*)d_in[4];
  const float* Wv1 = (const float*)d_in[5];  const float* bv1 = (const float*)d_in[6];
  const float* Ws1 = (const float*)d_in[7];  const float* bs1 = (const float*)d_in[8];
  const float* gn1w = (const float*)d_in[9]; const float* gn1b = (const float*)d_in[10];
  const float* gn1ms = (const float*)d_in[11];
  const float* Wq2 = (const float*)d_in[12]; const float* bq2 = (const float*)d_in[13];
  const float* Wk2 = (const float*)d_in[14]; const float* bk2 = (const float*)d_in[15];
  const float* Wv2 = (const float*)d_in[16]; const float* bv2 = (const float*)d_in[17];
  const float* Ws2 = (const float*)d_in[18]; const float* bs2 = (const float*)d_in[19];
  const float* gn2w = (const float*)d_in[20]; const float* gn2b = (const float*)d_in[21];
  const float* gn2ms = (const float*)d_in[22];

  // ---- workspace (~146 MB total) ----
  char* p = (char*)d_ws;
  auto alloc = [&](size_t bytes) { char* r = p; p += (bytes + 255) & ~(size_t)255; return r; };
  char*     scrA = alloc((size_t)32 * 1024 * 1024);  // oP -> Up -> Gram partials
  ushort_t* xb   = (ushort_t*)alloc((size_t)4096 * 544 * 2);
  ushort_t* qk1b = (ushort_t*)alloc((size_t)4096 * 512 * 2);
  ushort_t* v1b  = (ushort_t*)alloc((size_t)512 * 4096 * 2);
  char*     u0   = alloc((size_t)16 * 1024 * 1024);  // s1p, later h2b
  float*    s1p  = (float*)u0;
  float*    h1nT = (float*)   alloc((size_t)200 * 4096 * 4);
  ushort_t* h1nb = (ushort_t*)alloc((size_t)4096 * 256 * 2);
  ushort_t* Wqk1 = (ushort_t*)alloc((size_t)512 * 544 * 2);
  ushort_t* Wv1b = (ushort_t*)alloc((size_t)512 * 544 * 2);
  ushort_t* Ws1p = (ushort_t*)alloc((size_t)512 * 544 * 2);
  ushort_t* Wcat = (ushort_t*)alloc((size_t)4096 * 256 * 2);
  ushort_t* Qt   = (ushort_t*)alloc((size_t)4 * 256 * 512 * 2);
  ushort_t* Kt   = (ushort_t*)alloc((size_t)4 * 256 * 512 * 2);
  ushort_t* Mtall= (ushort_t*)alloc((size_t)4 * 256 * 256 * 2);
  ushort_t* Tall = (ushort_t*)alloc((size_t)4 * 4096 * 256 * 2);
  ushort_t* Xtb  = (ushort_t*)alloc((size_t)256 * 4096 * 2);
  ushort_t* vs2b = (ushort_t*)alloc((size_t)4096 * 4096 * 2);
  ushort_t* Usum = (ushort_t*)alloc((size_t)4 * 4096 * 256 * 2);
  ushort_t* Opl  = (ushort_t*)alloc((size_t)2048 * 4096 * 2);
  float*    r1p  = (float*)   alloc((size_t)16 * 4096 * 4);
  float*    r2   = (float*)   alloc((size_t)4 * 4096 * 4);
  // phase aliases of scrA:
  float*    oP   = (float*)scrA;      // attn-1 partials (dead after gn1)
  ushort_t* UpH  = (ushort_t*)scrA;   // attn-2 U^T bf16 partials (dead after combine)
  ushort_t* g4   = (ushort_t*)scrA;   // Gram bf16 partials
  ushort_t* h2b  = (ushort_t*)u0;     // gn2 output (s1p dead after gn1)

  const dim3 b256(256, 1, 1);
  const dim3 b512(512, 1, 1);
  const float LOG2E = 1.4426950408889634f;
  const float sc1e = 0.14142135623730951f * LOG2E;
  const float sc2e = 0.04419417382415922f * LOG2E;

  // ---- weight conversions
  wt_conv<<<dim3(256),  b256, 0, stream>>>(Wq1, bq1, Wqk1,             200, 200, 512, 544, 64, 50);
  wt_conv<<<dim3(256),  b256, 0, stream>>>(Wk1, bk1, Wqk1 + 256 * 544, 200, 200, 512, 544, 64, 50);
  wt_conv<<<dim3(512),  b256, 0, stream>>>(Wv1, bv1, Wv1b,             200, 200, 512, 544, 128, 50);
  wt_conv<<<dim3(512),  b256, 0, stream>>>(Ws1, bs1, Ws1p,             200, 200, 512, 544, 128, 50);
  wt_conv<<<dim3(2048), b256, 0, stream>>>(Wv2, bv2, Wcat,              2048, 2048, 200, 256, 2048, 2048);
  wt_conv<<<dim3(2048), b256, 0, stream>>>(Ws2, bs2, Wcat + 2048 * 256, 2048, 2048, 200, 256, 2048, 2048);
  wt_trans<<<dim3(1024), b256, 0, stream>>>(Wq2, bq2, Qt);
  wt_trans<<<dim3(1024), b256, 0, stream>>>(Wk2, bk2, Kt);
  trans_pad<<<dim3(9, 64), b256, 0, stream>>>(lr_x, xb, 512, 544);

  // ---- layer-1 projections
  mfma_bt<1, false><<<dim3(4, 32), b256, 0, stream>>>(
      xb, Wqk1, qk1b, 544, 544, 512, 544, 1, 0, 0, 0, -1, 0, -1, 4096, 1.f);
  mfma_bt<1, false><<<dim3(32, 4), b256, 0, stream>>>(
      Wv1b, xb, v1b, 544, 544, 4096, 544, 1, 0, 0, 0, -1, 0, -1, 512, 1.f);
  mfma_bt<0, false><<<dim3(32, 4), b256, 0, stream>>>(
      Ws1p, xb, s1p, 544, 544, 4096, 544, 1, 0, 0, 0, -1, 0, 127, 50, 1.f);

  // ---- attention 1 (fused) + gn1
  fused_attn1<<<dim3(32, 4, 4), b512, 0, stream>>>(qk1b, v1b, oP, r1p, sc1e);
  graph_norm_attn1<<<dim3(200), b256, 0, stream>>>(s1p, oP, r1p, h1nT, gn1w, gn1b, gn1ms);
  trans_pad<<<dim3(4, 64), b256, 0, stream>>>(h1nT, h1nb, 200, 256);
  xt_conv<<<dim3(256), b256, 0, stream>>>(h1nT, Xtb);

  // ---- layer-2 V+skip projection
  mfma_bt<1, false><<<dim3(32, 32), b256, 0, stream>>>(
      Wcat, h1nb, vs2b, 256, 256, 4096, 256, 1, 0, 0, 0, -1, 0, -1, 4096, 1.f);

  // ---- attention 2: low-rank T, then fused flash (no P, no V)
  mfma_bt<1, false><<<dim3(2, 2, 4), b256, 0, stream>>>(
      Kt, Qt, Mtall, 512, 512, 256, 512, 1,
      (size_t)256 * 512, (size_t)256 * 512, (size_t)256 * 256, -1, 0, -1, 256, 1.f);
  mfma_bt<1, false><<<dim3(2, 32, 4), b256, 0, stream>>>(
      h1nb, Mtall, Tall, 256, 256, 256, 256, 1,
      0, (size_t)256 * 256, (size_t)4096 * 256, -1, 0, -1, 4096, 1.f);
  fused_attn2<<<dim3(16, 4, 4), b512, 0, stream>>>(Tall, h1nb, Xtb, UpH, sc2e);
  combine_u<<<dim3(64, 4, 4), b256, 0, stream>>>(UpH, Usum, r2);
  // O = Wv . U  (bias rides via a==200 column)
  mfma_bt<1, false><<<dim3(32, 16), b256, 0, stream>>>(
      Wcat, Usum, Opl, 256, 256, 4096, 256, 1,
      0, 0, 0, 9, (size_t)4096 * 256, -1, 2048, 1.f);
  graph_norm_attn2<<<dim3(2048), b256, 0, stream>>>(
      vs2b + (size_t)2048 * 4096, Opl, r2, h2b, gn2w, gn2b, gn2ms);

  // ---- out = relu(h2n . h2n^T): K-split bf16 partials + reduce
  mfma256_8ph<1, false><<<dim3(8, 8, 4), b512, 0, stream>>>(
      h2b, h2b, g4, 4096, 4096, 2048, 4096, 4,
      0, 0, (size_t)2048 * 2048, -1, 0, 2048, 1.f);
  add4_relu_bf16<<<dim3(4096), b256, 0, stream>>>(g4, (float*)d_out);
}

// Round 16
// 328.148 us; speedup vs baseline: 1.6279x; 1.0681x over previous
//
#include <hip/hip_runtime.h>
#include <math.h>

typedef unsigned int u32;
typedef unsigned short ushort_t;
typedef __attribute__((ext_vector_type(8))) short short8;
typedef __attribute__((ext_vector_type(4))) float f32x4;

__device__ __forceinline__ ushort_t f2bf(float x) {
  u32 u = __float_as_uint(x);
  u32 r = (u + 0x7fffu + ((u >> 16) & 1u)) >> 16;
  return (ushort_t)r;
}
__device__ __forceinline__ float bf2f(u32 s) {
  return __uint_as_float(s << 16);
}
__device__ __forceinline__ void ld4bf(const ushort_t* p, float* o) {
  uint2 u = *(const uint2*)p;
  o[0] = bf2f(u.x & 0xffffu); o[1] = bf2f(u.x >> 16);
  o[2] = bf2f(u.y & 0xffffu); o[3] = bf2f(u.y >> 16);
}

// ---------------- block reduction helper (256 threads = 4 waves) -----------
__device__ __forceinline__ float block_sum256(float v, float* red) {
  #pragma unroll
  for (int o = 32; o > 0; o >>= 1) v += __shfl_down(v, o, 64);
  __syncthreads();
  if ((threadIdx.x & 63) == 0) red[threadIdx.x >> 6] = v;
  __syncthreads();
  return red[0] + red[1] + red[2] + red[3];
}

// =====================================================================
// Fused attention layer 1 (R12-proven): LDS-staged dbuf K/V, KV-split x4.
// =====================================================================
__global__ __launch_bounds__(512) void fused_attn1(
    const ushort_t* __restrict__ qk, const ushort_t* __restrict__ v,
    float* __restrict__ oP, float* __restrict__ r1p, float scale)
{
  __shared__ ushort_t Kl[2][4096];
  __shared__ ushort_t Vl[2][4096];
  __shared__ ushort_t Pl[128][80];
  const int t = threadIdx.x;
  const int lane = t & 63;
  const int wv = t >> 6;
  const int h = blockIdx.y;
  const int m0 = blockIdx.x * 128;
  const int z = blockIdx.z;
  const int lr = lane & 15;
  const int hk = lane >> 4;

  short8 aq0, aq1;
  {
    const ushort_t* qrow = qk + (size_t)(m0 + wv * 16 + lr) * 512 + h * 64;
    aq0 = *(const short8*)(qrow + hk * 8);
    aq1 = *(const short8*)(qrow + 32 + hk * 8);
  }

  f32x4 oAcc[4];
  #pragma unroll
  for (int i = 0; i < 4; ++i) oAcc[i] = (f32x4){0.f, 0.f, 0.f, 0.f};
  float racc[4] = {0.f, 0.f, 0.f, 0.f};

  const size_t kbase = (size_t)256 + h * 64;
  const int rS = t >> 3;
  const int cS = t & 7;
  const int lcS = cS ^ (rS & 7);

  {
    const int n0 = z * 16 * 64;
    __builtin_amdgcn_global_load_lds(
        (const __attribute__((address_space(1))) u32*)(qk + (size_t)(n0 + rS) * 512 + kbase + lcS * 8),
        (__attribute__((address_space(3))) u32*)(&Kl[0][t * 8]), 16, 0, 0);
    __builtin_amdgcn_global_load_lds(
        (const __attribute__((address_space(1))) u32*)(v + (size_t)(h * 128 + rS) * 4096 + n0 + lcS * 8),
        (__attribute__((address_space(3))) u32*)(&Vl[0][t * 8]), 16, 0, 0);
  }
  __syncthreads();

  int cur = 0;
  for (int it = 0; it < 16; ++it) {
    if (it + 1 < 16) {
      const int n1 = (z * 16 + it + 1) * 64;
      __builtin_amdgcn_global_load_lds(
          (const __attribute__((address_space(1))) u32*)(qk + (size_t)(n1 + rS) * 512 + kbase + lcS * 8),
          (__attribute__((address_space(3))) u32*)(&Kl[cur ^ 1][t * 8]), 16, 0, 0);
      __builtin_amdgcn_global_load_lds(
          (const __attribute__((address_space(1))) u32*)(v + (size_t)(h * 128 + rS) * 4096 + n1 + lcS * 8),
          (__attribute__((address_space(3))) u32*)(&Vl[cur ^ 1][t * 8]), 16, 0, 0);
    }
    f32x4 sA[4];
    #pragma unroll
    for (int nf = 0; nf < 4; ++nf) {
      const int rl = nf * 16 + lr;
      const char* kb = (const char*)&Kl[cur][0] + rl * 128;
      short8 b0 = *(const short8*)(kb + ((hk ^ (rl & 7)) * 16));
      short8 b1 = *(const short8*)(kb + (((4 + hk) ^ (rl & 7)) * 16));
      f32x4 sa = (f32x4){0.f, 0.f, 0.f, 0.f};
      sa = __builtin_amdgcn_mfma_f32_16x16x32_bf16(aq0, b0, sa, 0, 0, 0);
      sa = __builtin_amdgcn_mfma_f32_16x16x32_bf16(aq1, b1, sa, 0, 0, 0);
      sA[nf] = sa;
    }
    #pragma unroll
    for (int nf = 0; nf < 4; ++nf) {
      #pragma unroll
      for (int r = 0; r < 4; ++r) {
        float e = exp2f(sA[nf][r] * scale);
        racc[r] += e;
        Pl[wv * 16 + hk * 4 + r][nf * 16 + lr] = f2bf(e);
      }
    }
    short8 ap0 = *(const short8*)&Pl[wv * 16 + lr][hk * 8];
    short8 ap1 = *(const short8*)&Pl[wv * 16 + lr][32 + hk * 8];
    #pragma unroll
    for (int ff = 0; ff < 4; ++ff) {
      const int rl = ff * 16 + lr;
      const char* vb = (const char*)&Vl[cur][0] + rl * 128;
      short8 b0 = *(const short8*)(vb + ((hk ^ (rl & 7)) * 16));
      short8 b1 = *(const short8*)(vb + (((4 + hk) ^ (rl & 7)) * 16));
      oAcc[ff] = __builtin_amdgcn_mfma_f32_16x16x32_bf16(ap0, b0, oAcc[ff], 0, 0, 0);
      oAcc[ff] = __builtin_amdgcn_mfma_f32_16x16x32_bf16(ap1, b1, oAcc[ff], 0, 0, 0);
    }
    __syncthreads();
    cur ^= 1;
  }

  #pragma unroll
  for (int r = 0; r < 4; ++r) {
    racc[r] += __shfl_xor(racc[r], 1);
    racc[r] += __shfl_xor(racc[r], 2);
    racc[r] += __shfl_xor(racc[r], 4);
    racc[r] += __shfl_xor(racc[r], 8);
  }
  if (lr == 0) {
    float* rp = r1p + ((size_t)z * 4 + h) * 4096;
    #pragma unroll
    for (int r = 0; r < 4; ++r) rp[m0 + wv * 16 + hk * 4 + r] = racc[r];
  }
  float* ob = oP + (size_t)z * 512 * 4096;
  #pragma unroll
  for (int ff = 0; ff < 4; ++ff) {
    const size_t fbase = (size_t)(h * 128 + ff * 16 + lr) * 4096;
    #pragma unroll
    for (int r = 0; r < 4; ++r) {
      const int q = m0 + wv * 16 + hk * 4 + r;
      ob[fbase + q] = oAcc[ff][r];
    }
  }
}

// =====================================================================
// Fused attention layer 2 v3: 2 q-blocks/wave + K=224 trim (cols 224-255
// of X/Xt/T are exactly zero -> skip 8th S-chunk and ff 14..15 in U).
// Grid (16 qtiles of 256, 4 heads, 4 z), 512 thr.
// =====================================================================
__global__ __launch_bounds__(512, 2) void fused_attn2(
    const ushort_t* __restrict__ Tm, const ushort_t* __restrict__ X,
    const ushort_t* __restrict__ Xt, ushort_t* __restrict__ Up, float scale)
{
  __shared__ ushort_t Xl[16384];        // [64 n][256 a] swizzled, 32 KB
  __shared__ ushort_t Xtl[2][16384];    // [256 a][64 n] swizzled, 32 KB ea
  __shared__ ushort_t Pl[256][66];      // [q][node], stride 132 B
  const int t = threadIdx.x;
  const int lane = t & 63;
  const int wv = t >> 6;
  const int h = blockIdx.y;
  const int m0 = blockIdx.x * 256;
  const int z = blockIdx.z;
  const int lr = lane & 15;
  const int hk = lane >> 4;

  // T fragments for 2 q-blocks (K=224 -> 7 chunks of 32)
  short8 tq[2][7];
  #pragma unroll
  for (int qb = 0; qb < 2; ++qb) {
    const ushort_t* trow = Tm + ((size_t)h * 4096 + m0 + wv * 32 + qb * 16 + lr) * 256;
    #pragma unroll
    for (int s = 0; s < 7; ++s) tq[qb][s] = *(const short8*)(trow + s * 32 + hk * 8);
  }

  f32x4 uAcc[14][2];
  #pragma unroll
  for (int i = 0; i < 14; ++i) {
    uAcc[i][0] = (f32x4){0.f, 0.f, 0.f, 0.f};
    uAcc[i][1] = (f32x4){0.f, 0.f, 0.f, 0.f};
  }

  auto stageX = [&](int n0) {
    #pragma unroll
    for (int i = 0; i < 4; ++i) {          // X tile: 64 rows x 32 chunks
      const int st = t + i * 512;
      const int row = st >> 5, ph = st & 31;
      const int lc = (ph & 24) | ((ph & 7) ^ (row & 7));
      __builtin_amdgcn_global_load_lds(
          (const __attribute__((address_space(1))) u32*)(X + (size_t)(n0 + row) * 256 + lc * 8),
          (__attribute__((address_space(3))) u32*)(&Xl[st * 8]), 16, 0, 0);
    }
  };
  auto stageXt = [&](int buf, int n0) {
    #pragma unroll
    for (int i = 0; i < 4; ++i) {          // Xt tile: 256 rows x 8 chunks
      const int st = t + i * 512;
      const int row = st >> 3, ph = st & 7;
      const int lc = ph ^ (row & 7);
      __builtin_amdgcn_global_load_lds(
          (const __attribute__((address_space(1))) u32*)(Xt + (size_t)row * 4096 + n0 + lc * 8),
          (__attribute__((address_space(3))) u32*)(&Xtl[buf][st * 8]), 16, 0, 0);
    }
  };

  const int base = z * 16;
  stageX(base * 64);
  stageXt(0, base * 64);
  __syncthreads();

  int cur = 0;
  for (int it = 0; it < 16; ++it) {
    if (it + 1 < 16) stageXt(cur ^ 1, (base + it + 1) * 64);
    // ---- S^T phase: C[node, q] x 2 q-blocks; K=224
    const char* xb = (const char*)&Xl[0];
    #pragma unroll
    for (int nf = 0; nf < 4; ++nf) {
      const int row = nf * 16 + lr;
      const char* rb = xb + row * 512;
      f32x4 sa0 = (f32x4){0.f, 0.f, 0.f, 0.f};
      f32x4 sa1 = (f32x4){0.f, 0.f, 0.f, 0.f};
      #pragma unroll
      for (int s = 0; s < 7; ++s) {
        const int c = s * 4 + hk;
        const int ph = (c & 24) | ((c & 7) ^ (row & 7));
        short8 xf = *(const short8*)(rb + ph * 16);
        sa0 = __builtin_amdgcn_mfma_f32_16x16x32_bf16(xf, tq[0][s], sa0, 0, 0, 0);
        sa1 = __builtin_amdgcn_mfma_f32_16x16x32_bf16(xf, tq[1][s], sa1, 0, 0, 0);
      }
      #pragma unroll
      for (int r = 0; r < 4; ++r) {
        Pl[wv * 32 + lr][nf * 16 + hk * 4 + r]      = f2bf(exp2f(sa0[r] * scale));
        Pl[wv * 32 + 16 + lr][nf * 16 + hk * 4 + r] = f2bf(exp2f(sa1[r] * scale));
      }
    }
    __syncthreads();                       // all waves done reading Xl
    if (it + 1 < 16) stageX((base + it + 1) * 64);
    // ---- U phase: C[a, q] += Xt . P, a < 224 (ff 0..13)
    short8 p00 = *(const short8*)((const char*)&Pl[wv * 32 + lr][0] + hk * 16);
    short8 p01 = *(const short8*)((const char*)&Pl[wv * 32 + lr][0] + (4 + hk) * 16);
    short8 p10 = *(const short8*)((const char*)&Pl[wv * 32 + 16 + lr][0] + hk * 16);
    short8 p11 = *(const short8*)((const char*)&Pl[wv * 32 + 16 + lr][0] + (4 + hk) * 16);
    const char* xtb = (const char*)&Xtl[cur][0];
    #pragma unroll
    for (int ff = 0; ff < 14; ++ff) {
      const int row = ff * 16 + lr;
      const char* rb2 = xtb + row * 128;
      short8 x0 = *(const short8*)(rb2 + ((hk ^ (row & 7)) * 16));
      short8 x1 = *(const short8*)(rb2 + (((4 + hk) ^ (row & 7)) * 16));
      uAcc[ff][0] = __builtin_amdgcn_mfma_f32_16x16x32_bf16(x0, p00, uAcc[ff][0], 0, 0, 0);
      uAcc[ff][0] = __builtin_amdgcn_mfma_f32_16x16x32_bf16(x1, p01, uAcc[ff][0], 0, 0, 0);
      uAcc[ff][1] = __builtin_amdgcn_mfma_f32_16x16x32_bf16(x0, p10, uAcc[ff][1], 0, 0, 0);
      uAcc[ff][1] = __builtin_amdgcn_mfma_f32_16x16x32_bf16(x1, p11, uAcc[ff][1], 0, 0, 0);
    }
    __syncthreads();                       // drains stages; guards flips
    cur ^= 1;
  }

  // ---- store U^T partials [z][h][a][4096] bf16 (a < 224)
  ushort_t* ub = Up + (size_t)(z * 4 + h) * 256 * 4096;
  #pragma unroll
  for (int ff = 0; ff < 14; ++ff) {
    #pragma unroll
    for (int qb = 0; qb < 2; ++qb) {
      #pragma unroll
      for (int r = 0; r < 4; ++r) {
        const int a = ff * 16 + hk * 4 + r;
        ub[(size_t)a * 4096 + m0 + wv * 32 + qb * 16 + lr] = f2bf(uAcc[ff][qb][r]);
      }
    }
  }
}

// ---------------- combine_u: Usum[h][q][256] = bf16(sum_z Uz) (transpose),
// r2[h][q] = sum_z Uz[a==200]. Grid (64 qtiles, 4 atiles, 4 heads).
// (a>=224 reads stale scratch; downstream Wcat cols are exactly 0.) --------
__global__ __launch_bounds__(256) void combine_u(
    const ushort_t* __restrict__ Up, ushort_t* __restrict__ Usum,
    float* __restrict__ r2)
{
  __shared__ float tl[64][65];
  const int t = threadIdx.x;
  const int qt = blockIdx.x;
  const int at = blockIdx.y;
  const int h  = blockIdx.z;
  const int c = t & 63;
  const int rb = t >> 6;
  const size_t PLN = (size_t)4 * 256 * 4096;
  #pragma unroll
  for (int i = 0; i < 16; ++i) {
    const int r = rb + i * 4;               // a-local
    const int a = at * 64 + r;
    const int q = qt * 64 + c;
    const size_t i0 = ((size_t)h * 256 + a) * 4096 + q;
    float val = bf2f(Up[i0]) + bf2f(Up[PLN + i0])
              + bf2f(Up[2 * PLN + i0]) + bf2f(Up[3 * PLN + i0]);
    tl[r][c] = val;
    if (a == 200) r2[(size_t)h * 4096 + q] = val;
  }
  __syncthreads();
  #pragma unroll
  for (int i = 0; i < 16; ++i) {
    const int r = rb + i * 4;               // q-local
    const int q = qt * 64 + r;
    const int a = at * 64 + c;
    Usum[((size_t)h * 4096 + q) * 256 + a] = f2bf(tl[c][r]);
  }
}

// =====================================================================
// 256x256-tile, 8-phase MFMA GEMM (LONG-K only). Used for the Gram.
// =====================================================================
#define RD_A(bb, mm, cc) (*(const short8*)(lsAc + (bb)*32768 + arow + (mm)*2048 + (cc)))
#define RD_B(bb, nn, cc) (*(const short8*)(lsBc + (bb)*32768 + brow + (nn)*2048 + (cc)))

#define MM8(nn, bv) { \
  acc[0][nn] = __builtin_amdgcn_mfma_f32_16x16x32_bf16(a0, bv, acc[0][nn], 0,0,0); \
  acc[1][nn] = __builtin_amdgcn_mfma_f32_16x16x32_bf16(a1, bv, acc[1][nn], 0,0,0); \
  acc[2][nn] = __builtin_amdgcn_mfma_f32_16x16x32_bf16(a2, bv, acc[2][nn], 0,0,0); \
  acc[3][nn] = __builtin_amdgcn_mfma_f32_16x16x32_bf16(a3, bv, acc[3][nn], 0,0,0); \
  acc[4][nn] = __builtin_amdgcn_mfma_f32_16x16x32_bf16(a4, bv, acc[4][nn], 0,0,0); \
  acc[5][nn] = __builtin_amdgcn_mfma_f32_16x16x32_bf16(a5, bv, acc[5][nn], 0,0,0); \
  acc[6][nn] = __builtin_amdgcn_mfma_f32_16x16x32_bf16(a6, bv, acc[6][nn], 0,0,0); \
  acc[7][nn] = __builtin_amdgcn_mfma_f32_16x16x32_bf16(a7, bv, acc[7][nn], 0,0,0); }

#define STG(BASE, LD, LS, bb, hf, tt) { \
  _Pragma("unroll") \
  for (int ii = 0; ii < 2; ++ii) { \
    const int s_ = t + ii * 512; \
    const int r_ = s_ >> 3; \
    const int lc_ = (s_ & 7) ^ (r_ & 7); \
    __builtin_amdgcn_global_load_lds( \
      (const __attribute__((address_space(1))) u32*)((BASE) + (size_t)((hf) * 128 + r_) * (LD) + (size_t)(tt) * 64 + lc_ * 8), \
      (__attribute__((address_space(3))) u32*)(&(LS)[bb][(hf) * 8192 + s_ * 8]), 16, 0, 0); \
  } }

#define BAR() __builtin_amdgcn_s_barrier()
#define PRIO(x) __builtin_amdgcn_s_setprio(x)

#define GRP(bf, tS1, tS2) { \
  a0=RD_A(bf,0,c0); a1=RD_A(bf,1,c0); a2=RD_A(bf,2,c0); a3=RD_A(bf,3,c0); \
  a4=RD_A(bf,4,c0); a5=RD_A(bf,5,c0); a6=RD_A(bf,6,c0); a7=RD_A(bf,7,c0); \
  b0=RD_B(bf,0,c0); b1=RD_B(bf,1,c0); \
  STG(Ab, lda, lsA, 1-(bf), 1, tS1); STG(Bb, ldb, lsB, 1-(bf), 0, tS1); \
  BAR(); PRIO(1); MM8(0, b0); MM8(1, b1); PRIO(0); BAR(); \
  b2=RD_B(bf,2,c0); b3=RD_B(bf,3,c0); \
  STG(Bb, ldb, lsB, 1-(bf), 1, tS1); \
  BAR(); PRIO(1); MM8(2, b2); MM8(3, b3); PRIO(0); BAR(); \
  a0=RD_A(bf,0,c1); a1=RD_A(bf,1,c1); a2=RD_A(bf,2,c1); a3=RD_A(bf,3,c1); \
  a4=RD_A(bf,4,c1); a5=RD_A(bf,5,c1); a6=RD_A(bf,6,c1); a7=RD_A(bf,7,c1); \
  b0=RD_B(bf,0,c1); b1=RD_B(bf,1,c1); \
  BAR(); PRIO(1); MM8(0, b0); MM8(1, b1); PRIO(0); BAR(); \
  b2=RD_B(bf,2,c1); b3=RD_B(bf,3,c1); \
  STG(Ab, lda, lsA, (bf), 0, tS2); \
  BAR(); PRIO(1); MM8(2, b2); MM8(3, b3); PRIO(0); \
  asm volatile("s_waitcnt vmcnt(2)" ::: "memory"); \
  BAR(); }

template<int CMODE, bool RELU>
__global__ __launch_bounds__(512, 2) void mfma256_8ph(
    const ushort_t* __restrict__ A, const ushort_t* __restrict__ B,
    void* __restrict__ Cv, int lda, int ldb, int ldc,
    int K, int zsplit, size_t zA, size_t zB, size_t zC,
    int bShift, size_t bHead, int Mvalid, float scale)
{
  __shared__ ushort_t lsA[2][16384];
  __shared__ ushort_t lsB[2][16384];
  const int t = threadIdx.x;
  const int gx = gridDim.x;
  const int nwg = gx * gridDim.y;
  const int bid = blockIdx.y * gx + blockIdx.x;
  const int qq = nwg >> 3, rr_ = nwg & 7;
  const int xcd = bid & 7, idx = bid >> 3;
  const int swz = (xcd < rr_ ? xcd * (qq + 1) : rr_ * (qq + 1) + (xcd - rr_) * qq) + idx;
  const int m0 = (swz / gx) * 256;
  const int n0 = (swz % gx) * 256;
  const int z = blockIdx.z;
  int Kc = K, kOff = 0;
  size_t aZ = 0, bZ = 0, cZ = 0;
  if (zsplit > 1) { Kc = K / zsplit; kOff = z * Kc; cZ = (size_t)z * zC; }
  else { aZ = (size_t)z * zA; bZ = (size_t)z * zB; cZ = (size_t)z * zC; }
  const ushort_t* Ab = A + aZ + (size_t)m0 * lda + kOff;
  const ushort_t* Bb = B + bZ + (size_t)n0 * ldb + kOff
                     + (bShift >= 0 ? (size_t)(m0 >> bShift) * bHead : 0);
  const int NT = Kc / 64;

  f32x4 acc[8][4];
  #pragma unroll
  for (int i = 0; i < 8; ++i)
    #pragma unroll
    for (int j = 0; j < 4; ++j) acc[i][j] = (f32x4){0.f, 0.f, 0.f, 0.f};

  const int lane = t & 63;
  const int wv = t >> 6;
  const int wr = (wv >> 2) * 128;
  const int wc = (wv & 3) * 64;
  const int lr = lane & 15;
  const int kc = lane >> 4;
  const int sw = lane & 7;
  const int c0 = (kc ^ sw) * 16;
  const int c1 = c0 ^ 64;
  const int arow = (wr + lr) * 128;
  const int brow = (wc + lr) * 128;
  const char* lsAc = (const char*)lsA;
  const char* lsBc = (const char*)lsB;

  short8 a0, a1, a2, a3, a4, a5, a6, a7, b0, b1, b2, b3;

  STG(Ab, lda, lsA, 0, 0, 0); STG(Ab, lda, lsA, 0, 1, 0);
  STG(Bb, ldb, lsB, 0, 0, 0); STG(Bb, ldb, lsB, 0, 1, 0);
  STG(Ab, lda, lsA, 1, 0, 1);
  asm volatile("s_waitcnt vmcnt(2)" ::: "memory");
  BAR();

  const int NITER = NT >> 1;
  for (int it = 0; it < NITER; ++it) {
    const int tb = 2 * it;
    const int s1 = tb + 1;
    const int s2 = (tb + 2 < NT) ? tb + 2 : 0;
    const int s3 = (tb + 3 < NT) ? tb + 3 : 0;
    GRP(0, s1, s2)
    GRP(1, s2, s3)
  }

  const int row4 = (lane >> 4) * 4;
  const int coln = lane & 15;
  float* Cf = (float*)Cv + cZ;
  ushort_t* Ch = (ushort_t*)Cv + cZ;
  #pragma unroll
  for (int m = 0; m < 8; ++m) {
    #pragma unroll
    for (int r = 0; r < 4; ++r) {
      const int gm = m0 + wr + m * 16 + row4 + r;
      const bool ok = gm < Mvalid;
      #pragma unroll
      for (int n = 0; n < 4; ++n) {
        const int gn = n0 + wc + n * 16 + coln;
        float v = acc[m][n][r] * scale;
        if (RELU) v = fmaxf(v, 0.f);
        if (ok) {
          if (CMODE == 0)      Cf[(size_t)gm * ldc + gn] = v;
          else if (CMODE == 1) Ch[(size_t)gm * ldc + gn] = f2bf(v);
          else                 atomicAdd(&Cf[(size_t)gm * ldc + gn], v);
        }
      }
    }
  }
}

#undef GRP
#undef STG
#undef MM8
#undef RD_A
#undef RD_B

// ================= 128x128-tile MFMA GEMM, 256 threads (SHORT-K) ===========
template<int CMODE, bool RELU>
__global__ __launch_bounds__(256) void mfma_bt(
    const ushort_t* __restrict__ A, const ushort_t* __restrict__ B,
    void* __restrict__ Cv, int lda, int ldb, int ldc,
    int K, int Ksplit, size_t zA, size_t zB, size_t zC,
    int bShift, size_t bHead, int mMask, int Mvalid, float scale)
{
  __shared__ ushort_t lsA[2][128 * 32];
  __shared__ ushort_t lsB[2][128 * 32];
  const int t  = threadIdx.x;
  const int m0 = blockIdx.y * 128;
  const int n0 = blockIdx.x * 128;
  const int z = blockIdx.z;
  int Kc = K, kOff = 0;
  size_t aZ = 0, bZ = 0, cZ = 0;
  if (Ksplit > 1) { Kc = K / Ksplit; kOff = z * Kc; cZ = (size_t)z * zC; }
  else { aZ = (size_t)z * zA; bZ = (size_t)z * zB; cZ = (size_t)z * zC; }
  const int NT = Kc / 32;
  const ushort_t* Ab = A + aZ + (size_t)m0 * lda + kOff;
  const ushort_t* Bb = B + bZ + (size_t)n0 * ldb + kOff
                     + (bShift >= 0 ? (size_t)(m0 >> bShift) * bHead : 0);
  const int cs = t & 3;

  f32x4 acc[4][4];
  #pragma unroll
  for (int i = 0; i < 4; ++i)
    #pragma unroll
    for (int j = 0; j < 4; ++j) acc[i][j] = (f32x4){0.f, 0.f, 0.f, 0.f};

  const int lane = t & 63;
  const int wv = t >> 6;
  const int wr = (wv >> 1) * 64;
  const int wc = (wv & 1) * 64;
  const int lr = lane & 15;
  const int kc = lane >> 4;

  int roffA[4], roffB[4];
  #pragma unroll
  for (int m = 0; m < 4; ++m) {
    int ra = wr + m * 16 + lr;
    roffA[m] = ra * 64 + ((kc ^ (ra & 3)) * 16);
    int rb = wc + m * 16 + lr;
    roffB[m] = rb * 64 + ((kc ^ (rb & 3)) * 16);
  }

  auto stage = [&](int buf, int kt) {
    const ushort_t* As = Ab + kt * 32;
    const ushort_t* Bs = Bb + kt * 32;
    #pragma unroll
    for (int i = 0; i < 2; ++i) {
      int s = t + i * 256;
      int r = s >> 2;
      int c = cs ^ (r & 3);
      __builtin_amdgcn_global_load_lds(
          (const __attribute__((address_space(1))) u32*)(As + (size_t)r * lda + c * 8),
          (__attribute__((address_space(3))) u32*)(&lsA[buf][s * 8]), 16, 0, 0);
    }
    #pragma unroll
    for (int i = 0; i < 2; ++i) {
      int s = t + i * 256;
      int r = s >> 2;
      int c = cs ^ (r & 3);
      __builtin_amdgcn_global_load_lds(
          (const __attribute__((address_space(1))) u32*)(Bs + (size_t)r * ldb + c * 8),
          (__attribute__((address_space(3))) u32*)(&lsB[buf][s * 8]), 16, 0, 0);
    }
  };

  stage(0, 0);
  __syncthreads();
  int cur = 0;
  for (int kt = 0; kt < NT; ++kt) {
    if (kt + 1 < NT) stage(cur ^ 1, kt + 1);
    short8 af[4], bfr[4];
    const char* baseA = (const char*)&lsA[cur][0];
    const char* baseB = (const char*)&lsB[cur][0];
    #pragma unroll
    for (int m = 0; m < 4; ++m) af[m]  = *(const short8*)(baseA + roffA[m]);
    #pragma unroll
    for (int n = 0; n < 4; ++n) bfr[n] = *(const short8*)(baseB + roffB[n]);
    #pragma unroll
    for (int m = 0; m < 4; ++m)
      #pragma unroll
      for (int n = 0; n < 4; ++n)
        acc[m][n] = __builtin_amdgcn_mfma_f32_16x16x32_bf16(af[m], bfr[n], acc[m][n], 0, 0, 0);
    __syncthreads();
    cur ^= 1;
  }

  const int row4 = (lane >> 4) * 4;
  const int coln = lane & 15;
  float* Cf = (float*)Cv + cZ;
  ushort_t* Ch = (ushort_t*)Cv + cZ;
  #pragma unroll
  for (int m = 0; m < 4; ++m) {
    #pragma unroll
    for (int r = 0; r < 4; ++r) {
      const int gm = m0 + wr + m * 16 + row4 + r;
      const bool ok = (mMask >= 0) ? ((gm & mMask) < Mvalid) : (gm < Mvalid);
      #pragma unroll
      for (int n = 0; n < 4; ++n) {
        const int gn = n0 + wc + n * 16 + coln;
        float v = acc[m][n][r] * scale;
        if (RELU) v = fmaxf(v, 0.f);
        if (ok) {
          if (CMODE == 0)      Cf[(size_t)gm * ldc + gn] = v;
          else if (CMODE == 1) Ch[(size_t)gm * ldc + gn] = f2bf(v);
          else                 atomicAdd(&Cf[(size_t)gm * ldc + gn], v);
        }
      }
    }
  }
}

// ---------------- weights: dst[Mp,Kp] bf16 = W^T (+ bias slot at k==Kv) ----
__global__ __launch_bounds__(256) void wt_conv(
    const float* __restrict__ W, const float* __restrict__ bias,
    ushort_t* __restrict__ dst, int Mtot, int ldw, int Kv, int Kp,
    int PADH, int VALH)
{
  const int m = blockIdx.x;
  const int h = m / PADH, c0 = m % PADH;
  const int fout = h * VALH + c0;
  const bool valid = (c0 < VALH) && (fout < Mtot);
  for (int k = threadIdx.x; k < Kp; k += blockDim.x) {
    float v = 0.f;
    if (valid) {
      if (k < Kv) v = W[(size_t)k * ldw + fout];
      else if (k == Kv) v = bias[fout];
    }
    dst[(size_t)m * Kp + k] = f2bf(v);
  }
}

// ---------------- wt_trans: dst[4][256][512] bf16 (padded W~^T per head) ---
__global__ __launch_bounds__(256) void wt_trans(
    const float* __restrict__ W, const float* __restrict__ bias,
    ushort_t* __restrict__ dst)
{
  const int rid = blockIdx.x;
  const int h = rid >> 8, a = rid & 255;
  for (int f = threadIdx.x; f < 512; f += 256) {
    float v = 0.f;
    if (a < 200)       v = W[(size_t)a * 2048 + h * 512 + f];
    else if (a == 200) v = bias[h * 512 + f];
    dst[(size_t)rid * 512 + f] = f2bf(v);
  }
}

// ---------------- xt_conv: Xt[256][4096] bf16 from h1nT (a-major) ----------
__global__ __launch_bounds__(256) void xt_conv(
    const float* __restrict__ h1nT, ushort_t* __restrict__ Xt)
{
  const int a = blockIdx.x;
  for (int q = threadIdx.x; q < 4096; q += 256) {
    float v = (a < 200) ? h1nT[(size_t)a * 4096 + q] : ((a == 200) ? 1.f : 0.f);
    Xt[(size_t)a * 4096 + q] = f2bf(v);
  }
}

// ---------------- transpose fp32 [Kv,4096] -> bf16 [4096,Kp], bias slot ----
__global__ __launch_bounds__(256) void trans_pad(
    const float* __restrict__ src, ushort_t* __restrict__ dst, int Kv, int Kp)
{
  __shared__ float tl[64][65];
  const int t = threadIdx.x;
  const int f0 = blockIdx.x * 64;
  const int i0 = blockIdx.y * 64;
  const int c = t & 63, rbase = t >> 6;
  #pragma unroll
  for (int it = 0; it < 16; ++it) {
    int r = rbase + it * 4;
    int f = f0 + r;
    tl[r][c] = (f < Kv) ? src[(size_t)f * 4096 + i0 + c] : 0.f;
  }
  __syncthreads();
  #pragma unroll
  for (int it = 0; it < 16; ++it) {
    int r = rbase + it * 4;
    int f = f0 + c;
    if (f < Kp) {
      float v = (f < Kv) ? tl[c][r] : ((f == Kv) ? 1.f : 0.f);
      dst[(size_t)(i0 + r) * Kp + f] = f2bf(v);
    }
  }
}

// ---------------- GraphNorm layer 1: x = skip(bf16) + (sum_z oP)/(sum_z r) -
__global__ __launch_bounds__(256) void graph_norm_attn1(
    const ushort_t* __restrict__ skip, const float* __restrict__ oP,
    const float* __restrict__ r1p, float* __restrict__ out,
    const float* __restrict__ w, const float* __restrict__ b,
    const float* __restrict__ ms)
{
  __shared__ float red[4];
  const int t = threadIdx.x;
  const int row = blockIdx.x;
  const int h = row / 50;
  const int pr = h * 128 + row % 50;
  const ushort_t* sk = skip + (size_t)pr * 4096;
  const size_t OSTR = (size_t)512 * 4096;
  float v[16];
  float s = 0.f;
  #pragma unroll
  for (int e = 0; e < 4; ++e) {
    const int idx = t * 4 + 1024 * e;
    float a[4];
    ld4bf(&sk[idx], a);
    float4 o0 = *(const float4*)&oP[(size_t)pr * 4096 + idx];
    float4 o1 = *(const float4*)&oP[OSTR + (size_t)pr * 4096 + idx];
    float4 o2 = *(const float4*)&oP[2 * OSTR + (size_t)pr * 4096 + idx];
    float4 o3 = *(const float4*)&oP[3 * OSTR + (size_t)pr * 4096 + idx];
    float4 r0 = *(const float4*)&r1p[(size_t)h * 4096 + idx];
    float4 r1 = *(const float4*)&r1p[(size_t)(4 + h) * 4096 + idx];
    float4 r2 = *(const float4*)&r1p[(size_t)(8 + h) * 4096 + idx];
    float4 r3 = *(const float4*)&r1p[(size_t)(12 + h) * 4096 + idx];
    v[e*4+0] = a[0] + (o0.x + o1.x + o2.x + o3.x) / (r0.x + r1.x + r2.x + r3.x);
    v[e*4+1] = a[1] + (o0.y + o1.y + o2.y + o3.y) / (r0.y + r1.y + r2.y + r3.y);
    v[e*4+2] = a[2] + (o0.z + o1.z + o2.z + o3.z) / (r0.z + r1.z + r2.z + r3.z);
    v[e*4+3] = a[3] + (o0.w + o1.w + o2.w + o3.w) / (r0.w + r1.w + r2.w + r3.w);
    s += v[e*4+0] + v[e*4+1] + v[e*4+2] + v[e*4+3];
  }
  const float mean = block_sum256(s, red) * (1.f / 4096.f);
  const float sub = mean * ms[row];
  float s2 = 0.f;
  #pragma unroll
  for (int e = 0; e < 16; ++e) { v[e] -= sub; s2 += v[e] * v[e]; }
  const float var = block_sum256(s2, red) * (1.f / 4096.f);
  const float scl = rsqrtf(var + 1e-5f) * w[row];
  const float bb = b[row];
  float* y = out + (size_t)row * 4096;
  #pragma unroll
  for (int e = 0; e < 4; ++e) {
    float o0[4];
    #pragma unroll
    for (int q = 0; q < 4; ++q) o0[q] = v[e * 4 + q] * scl + bb;
    *(float4*)&y[t * 4 + 1024 * e] = *(float4*)&o0[0];
  }
}

// ---------------- GraphNorm layer 2 (single O plane): x = skip + O/r -------
__global__ __launch_bounds__(256) void graph_norm_attn2(
    const ushort_t* __restrict__ skip, const ushort_t* __restrict__ O,
    const float* __restrict__ r2, ushort_t* __restrict__ out,
    const float* __restrict__ w, const float* __restrict__ b,
    const float* __restrict__ ms)
{
  __shared__ float red[4];
  const int t = threadIdx.x;
  const int row = blockIdx.x;
  const ushort_t* sk = skip + (size_t)row * 4096;
  const ushort_t* pa = O + (size_t)row * 4096;
  const float* rr = r2 + (size_t)(row >> 9) * 4096;
  float v[16];
  float s = 0.f;
  #pragma unroll
  for (int e = 0; e < 4; ++e) {
    const int idx = t * 4 + 1024 * e;
    float a[4], oa[4];
    ld4bf(&sk[idx], a); ld4bf(&pa[idx], oa);
    float4 rv = *(const float4*)&rr[idx];
    v[e*4+0] = a[0] + oa[0] / rv.x;
    v[e*4+1] = a[1] + oa[1] / rv.y;
    v[e*4+2] = a[2] + oa[2] / rv.z;
    v[e*4+3] = a[3] + oa[3] / rv.w;
    s += v[e*4+0] + v[e*4+1] + v[e*4+2] + v[e*4+3];
  }
  const float mean = block_sum256(s, red) * (1.f / 4096.f);
  const float sub = mean * ms[row];
  float s2 = 0.f;
  #pragma unroll
  for (int e = 0; e < 16; ++e) { v[e] -= sub; s2 += v[e] * v[e]; }
  const float var = block_sum256(s2, red) * (1.f / 4096.f);
  const float scl = rsqrtf(var + 1e-5f) * w[row];
  const float bb = b[row];
  #pragma unroll
  for (int e = 0; e < 16; ++e) v[e] = v[e] * scl + bb;
  float s3 = 0.f;
  #pragma unroll
  for (int e = 0; e < 16; ++e) s3 += v[e] * v[e];
  const float osc = rsqrtf(block_sum256(s3, red));
  ushort_t* y = out + (size_t)row * 4096;
  #pragma unroll
  for (int e = 0; e < 4; ++e) {
    ushort_t o0[4];
    #pragma unroll
    for (int q = 0; q < 4; ++q) o0[q] = f2bf(v[e * 4 + q] * osc);
    *(ushort2*)&y[t * 4 + 1024 * e] = *(ushort2*)&o0[0];
    *(ushort2*)&y[t * 4 + 1024 * e + 2] = *(ushort2*)&o0[2];
  }
}

// ---------------- out = relu(sum of 4 bf16 partial planes) -----------------
__global__ __launch_bounds__(256) void add4_relu_bf16(
    const ushort_t* __restrict__ g, float* __restrict__ out)
{
  const size_t i = (size_t)blockIdx.x * 256 + threadIdx.x;
  const size_t ss = (size_t)2048 * 2048;
  float a[4], b[4], c[4], d[4];
  ld4bf(&g[i * 4], a);
  ld4bf(&g[ss + i * 4], b);
  ld4bf(&g[2 * ss + i * 4], c);
  ld4bf(&g[3 * ss + i * 4], d);
  float4 o;
  o.x = fmaxf(a[0] + b[0] + c[0] + d[0], 0.f);
  o.y = fmaxf(a[1] + b[1] + c[1] + d[1], 0.f);
  o.z = fmaxf(a[2] + b[2] + c[2] + d[2], 0.f);
  o.w = fmaxf(a[3] + b[3] + c[3] + d[3], 0.f);
  ((float4*)out)[i] = o;
}

extern "C" void kernel_launch(void* const* d_in, const int* in_sizes, int n_in,
                              void* d_out, int out_size, void* d_ws, size_t ws_size,
                              hipStream_t stream)
{
  (void)in_sizes; (void)n_in; (void)out_size; (void)ws_size;
  const float* lr_x = (const float*)d_in[0];
  const float* Wq1 = (const float*)d_in[1];  const float* bq1 = (const float*)d_in[2];
  const float* Wk1 = (const float*)d_in[3];  const float* bk1 = (const float*)d_in[4];
  const float* Wv1 = (const float*)d_in[5];  const float* bv1 = (const float*)d_in[6];
  const float* Ws1 = (const float*)d_in[7];  const float* bs1 = (const float*)d_in[8];
  const float* gn1w = (const float*)d_in[9]; const float* gn1b = (const float*)d_in[10];
  const float* gn1ms = (const float*)d_in[11];
  const float* Wq2 = (const float*)d_in[12]; const float* bq2 = (const float*)d_in[13];
  const float* Wk2 = (const float*)d_in[14]; const float* bk2 = (const float*)d_in[15];
  const float* Wv2 = (const float*)d_in[16]; const float* bv2 = (const float*)d_in[17];
  const float* Ws2 = (const float*)d_in[18]; const float* bs2 = (const float*)d_in[19];
  const float* gn2w = (const float*)d_in[20]; const float* gn2b = (const float*)d_in[21];
  const float* gn2ms = (const float*)d_in[22];

  // ---- workspace ----
  char* p = (char*)d_ws;
  auto alloc = [&](size_t bytes) { char* r = p; p += (bytes + 255) & ~(size_t)255; return r; };
  char*     scrA = alloc((size_t)32 * 1024 * 1024);  // oP -> Up -> Gram partials
  ushort_t* xb   = (ushort_t*)alloc((size_t)4096 * 544 * 2);
  ushort_t* qk1b = (ushort_t*)alloc((size_t)4096 * 512 * 2);
  ushort_t* v1s  = (ushort_t*)alloc((size_t)1024 * 4096 * 2); // rows 0-511 v1, 512-1023 skip1
  char*     u0   = alloc((size_t)16 * 1024 * 1024);  // h2b
  float*    h1nT = (float*)   alloc((size_t)200 * 4096 * 4);
  ushort_t* h1nb = (ushort_t*)alloc((size_t)4096 * 256 * 2);
  ushort_t* Wqk1 = (ushort_t*)alloc((size_t)512 * 544 * 2);
  ushort_t* Wvs1 = (ushort_t*)alloc((size_t)1024 * 544 * 2); // [Wv1 | Ws1] head-padded
  ushort_t* Wcat = (ushort_t*)alloc((size_t)4096 * 256 * 2);
  ushort_t* Qt   = (ushort_t*)alloc((size_t)4 * 256 * 512 * 2);
  ushort_t* Kt   = (ushort_t*)alloc((size_t)4 * 256 * 512 * 2);
  ushort_t* Mtall= (ushort_t*)alloc((size_t)4 * 256 * 256 * 2);
  ushort_t* Tall = (ushort_t*)alloc((size_t)4 * 4096 * 256 * 2);
  ushort_t* Xtb  = (ushort_t*)alloc((size_t)256 * 4096 * 2);
  ushort_t* vs2b = (ushort_t*)alloc((size_t)4096 * 4096 * 2);
  ushort_t* Usum = (ushort_t*)alloc((size_t)4 * 4096 * 256 * 2);
  ushort_t* Opl  = (ushort_t*)alloc((size_t)2048 * 4096 * 2);
  float*    r1p  = (float*)   alloc((size_t)16 * 4096 * 4);
  float*    r2   = (float*)   alloc((size_t)4 * 4096 * 4);
  // phase aliases of scrA:
  float*    oP   = (float*)scrA;      // attn-1 partials (dead after gn1)
  ushort_t* UpH  = (ushort_t*)scrA;   // attn-2 U^T bf16 partials (dead after combine)
  ushort_t* g4   = (ushort_t*)scrA;   // Gram bf16 partials
  ushort_t* h2b  = (ushort_t*)u0;     // gn2 output

  const dim3 b256(256, 1, 1);
  const dim3 b512(512, 1, 1);
  const float LOG2E = 1.4426950408889634f;
  const float sc1e = 0.14142135623730951f * LOG2E;
  const float sc2e = 0.04419417382415922f * LOG2E;

  // ---- weight conversions
  wt_conv<<<dim3(256),  b256, 0, stream>>>(Wq1, bq1, Wqk1,             200, 200, 512, 544, 64, 50);
  wt_conv<<<dim3(256),  b256, 0, stream>>>(Wk1, bk1, Wqk1 + 256 * 544, 200, 200, 512, 544, 64, 50);
  wt_conv<<<dim3(512),  b256, 0, stream>>>(Wv1, bv1, Wvs1,             200, 200, 512, 544, 128, 50);
  wt_conv<<<dim3(512),  b256, 0, stream>>>(Ws1, bs1, Wvs1 + 512 * 544, 200, 200, 512, 544, 128, 50);
  wt_conv<<<dim3(2048), b256, 0, stream>>>(Wv2, bv2, Wcat,              2048, 2048, 200, 256, 2048, 2048);
  wt_conv<<<dim3(2048), b256, 0, stream>>>(Ws2, bs2, Wcat + 2048 * 256, 2048, 2048, 200, 256, 2048, 2048);
  wt_trans<<<dim3(1024), b256, 0, stream>>>(Wq2, bq2, Qt);
  wt_trans<<<dim3(1024), b256, 0, stream>>>(Wk2, bk2, Kt);
  trans_pad<<<dim3(9, 64), b256, 0, stream>>>(lr_x, xb, 512, 544);

  // ---- layer-1 projections (QK node-major; merged V+skip feature-major)
  mfma_bt<1, false><<<dim3(4, 32), b256, 0, stream>>>(
      xb, Wqk1, qk1b, 544, 544, 512, 544, 1, 0, 0, 0, -1, 0, -1, 4096, 1.f);
  mfma_bt<1, false><<<dim3(32, 8), b256, 0, stream>>>(
      Wvs1, xb, v1s, 544, 544, 4096, 544, 1, 0, 0, 0, -1, 0, -1, 1024, 1.f);

  // ---- attention 1 (fused) + gn1 (skip = v1s rows 512..1023, bf16)
  fused_attn1<<<dim3(32, 4, 4), b512, 0, stream>>>(qk1b, v1s, oP, r1p, sc1e);
  graph_norm_attn1<<<dim3(200), b256, 0, stream>>>(
      v1s + (size_t)512 * 4096, oP, r1p, h1nT, gn1w, gn1b, gn1ms);
  trans_pad<<<dim3(4, 64), b256, 0, stream>>>(h1nT, h1nb, 200, 256);
  xt_conv<<<dim3(256), b256, 0, stream>>>(h1nT, Xtb);

  // ---- layer-2 V+skip projection (K=224: cols 224..255 are zero)
  mfma_bt<1, false><<<dim3(32, 32), b256, 0, stream>>>(
      Wcat, h1nb, vs2b, 256, 256, 4096, 224, 1, 0, 0, 0, -1, 0, -1, 4096, 1.f);

  // ---- attention 2: low-rank T, then fused flash (no P, no V)
  mfma_bt<1, false><<<dim3(2, 2, 4), b256, 0, stream>>>(
      Kt, Qt, Mtall, 512, 512, 256, 512, 1,
      (size_t)256 * 512, (size_t)256 * 512, (size_t)256 * 256, -1, 0, -1, 256, 1.f);
  mfma_bt<1, false><<<dim3(2, 32, 4), b256, 0, stream>>>(
      h1nb, Mtall, Tall, 256, 256, 256, 224, 1,
      0, (size_t)256 * 256, (size_t)4096 * 256, -1, 0, -1, 4096, 1.f);
  fused_attn2<<<dim3(16, 4, 4), b512, 0, stream>>>(Tall, h1nb, Xtb, UpH, sc2e);
  combine_u<<<dim3(64, 4, 4), b256, 0, stream>>>(UpH, Usum, r2);
  // O = Wv . U  (bias rides via a==200 column; K=224)
  mfma_bt<1, false><<<dim3(32, 16), b256, 0, stream>>>(
      Wcat, Usum, Opl, 256, 256, 4096, 224, 1,
      0, 0, 0, 9, (size_t)4096 * 256, -1, 2048, 1.f);
  graph_norm_attn2<<<dim3(2048), b256, 0, stream>>>(
      vs2b + (size_t)2048 * 4096, Opl, r2, h2b, gn2w, gn2b, gn2ms);

  // ---- out = relu(h2n . h2n^T): K-split bf16 partials + reduce
  mfma256_8ph<1, false><<<dim3(8, 8, 4), b512, 0, stream>>>(
      h2b, h2b, g4, 4096, 4096, 2048, 4096, 4,
      0, 0, (size_t)2048 * 2048, -1, 0, 2048, 1.f);
  add4_relu_bf16<<<dim3(4096), b256, 0, stream>>>(g4, (float*)d_out);
}

// Round 17
// 327.146 us; speedup vs baseline: 1.6329x; 1.0031x over previous
//
#include <hip/hip_runtime.h>
#include <math.h>

typedef unsigned int u32;
typedef unsigned short ushort_t;
typedef __attribute__((ext_vector_type(8))) short short8;
typedef __attribute__((ext_vector_type(4))) float f32x4;

__device__ __forceinline__ ushort_t f2bf(float x) {
  u32 u = __float_as_uint(x);
  u32 r = (u + 0x7fffu + ((u >> 16) & 1u)) >> 16;
  return (ushort_t)r;
}
__device__ __forceinline__ float bf2f(u32 s) {
  return __uint_as_float(s << 16);
}
__device__ __forceinline__ void ld4bf(const ushort_t* p, float* o) {
  uint2 u = *(const uint2*)p;
  o[0] = bf2f(u.x & 0xffffu); o[1] = bf2f(u.x >> 16);
  o[2] = bf2f(u.y & 0xffffu); o[3] = bf2f(u.y >> 16);
}

// ---------------- block reduction helper (256 threads = 4 waves) -----------
__device__ __forceinline__ float block_sum256(float v, float* red) {
  #pragma unroll
  for (int o = 32; o > 0; o >>= 1) v += __shfl_down(v, o, 64);
  __syncthreads();
  if ((threadIdx.x & 63) == 0) red[threadIdx.x >> 6] = v;
  __syncthreads();
  return red[0] + red[1] + red[2] + red[3];
}

// =====================================================================
// Fused attention layer 1 v4: 2 q-blocks per wave (R16 lesson: halve
// K/V fragment reads per MFMA). 256 thr = 4 waves, each wave 32 q-rows.
// Grid (32 qtiles of 128, 4 heads, 4 kv-chunks). LDS 52 KB.
// =====================================================================
__global__ __launch_bounds__(256) void fused_attn1(
    const ushort_t* __restrict__ qk, const ushort_t* __restrict__ v,
    float* __restrict__ oP, float* __restrict__ r1p, float scale)
{
  __shared__ ushort_t Kl[2][4096];
  __shared__ ushort_t Vl[2][4096];
  __shared__ ushort_t Pl[128][80];     // row stride 160B (16B aligned)
  const int t = threadIdx.x;
  const int lane = t & 63;
  const int wv = t >> 6;               // 0..3, wave owns q rows wv*32..+31
  const int h = blockIdx.y;
  const int m0 = blockIdx.x * 128;
  const int z = blockIdx.z;
  const int lr = lane & 15;
  const int hk = lane >> 4;

  short8 aq[2][2];
  #pragma unroll
  for (int qb = 0; qb < 2; ++qb) {
    const ushort_t* qrow = qk + (size_t)(m0 + wv * 32 + qb * 16 + lr) * 512 + h * 64;
    aq[qb][0] = *(const short8*)(qrow + hk * 8);
    aq[qb][1] = *(const short8*)(qrow + 32 + hk * 8);
  }

  f32x4 oAcc[4][2];
  #pragma unroll
  for (int i = 0; i < 4; ++i) {
    oAcc[i][0] = (f32x4){0.f, 0.f, 0.f, 0.f};
    oAcc[i][1] = (f32x4){0.f, 0.f, 0.f, 0.f};
  }
  float racc[2][4] = {{0.f,0.f,0.f,0.f},{0.f,0.f,0.f,0.f}};

  const size_t kbase = (size_t)256 + h * 64;

  auto stage = [&](int buf, int n0) {
    #pragma unroll
    for (int i = 0; i < 2; ++i) {
      const int st = t + i * 256;
      const int row = st >> 3, cS = st & 7;
      const int lc = cS ^ (row & 7);
      __builtin_amdgcn_global_load_lds(
          (const __attribute__((address_space(1))) u32*)(qk + (size_t)(n0 + row) * 512 + kbase + lc * 8),
          (__attribute__((address_space(3))) u32*)(&Kl[buf][st * 8]), 16, 0, 0);
      __builtin_amdgcn_global_load_lds(
          (const __attribute__((address_space(1))) u32*)(v + (size_t)(h * 128 + row) * 4096 + n0 + lc * 8),
          (__attribute__((address_space(3))) u32*)(&Vl[buf][st * 8]), 16, 0, 0);
    }
  };

  stage(0, z * 1024);
  __syncthreads();

  int cur = 0;
  for (int it = 0; it < 16; ++it) {
    if (it + 1 < 16) stage(cur ^ 1, z * 1024 + (it + 1) * 64);
    // ---- S-tiles [16q x 64n] x 2 q-blocks (K frag feeds both)
    #pragma unroll
    for (int nf = 0; nf < 4; ++nf) {
      const int rl = nf * 16 + lr;
      const char* kb = (const char*)&Kl[cur][0] + rl * 128;
      short8 b0 = *(const short8*)(kb + ((hk ^ (rl & 7)) * 16));
      short8 b1 = *(const short8*)(kb + (((4 + hk) ^ (rl & 7)) * 16));
      #pragma unroll
      for (int qb = 0; qb < 2; ++qb) {
        f32x4 sa = (f32x4){0.f, 0.f, 0.f, 0.f};
        sa = __builtin_amdgcn_mfma_f32_16x16x32_bf16(aq[qb][0], b0, sa, 0, 0, 0);
        sa = __builtin_amdgcn_mfma_f32_16x16x32_bf16(aq[qb][1], b1, sa, 0, 0, 0);
        #pragma unroll
        for (int r = 0; r < 4; ++r) {
          float e = exp2f(sa[r] * scale);
          racc[qb][r] += e;
          Pl[wv * 32 + qb * 16 + hk * 4 + r][nf * 16 + lr] = f2bf(e);
        }
      }
    }
    // ---- PV: O[16q x 64f] x 2 q-blocks (V frag feeds both)
    short8 ap[2][2];
    #pragma unroll
    for (int qb = 0; qb < 2; ++qb) {
      ap[qb][0] = *(const short8*)&Pl[wv * 32 + qb * 16 + lr][hk * 8];
      ap[qb][1] = *(const short8*)&Pl[wv * 32 + qb * 16 + lr][32 + hk * 8];
    }
    #pragma unroll
    for (int ff = 0; ff < 4; ++ff) {
      const int rl = ff * 16 + lr;
      const char* vb = (const char*)&Vl[cur][0] + rl * 128;
      short8 b0 = *(const short8*)(vb + ((hk ^ (rl & 7)) * 16));
      short8 b1 = *(const short8*)(vb + (((4 + hk) ^ (rl & 7)) * 16));
      #pragma unroll
      for (int qb = 0; qb < 2; ++qb) {
        oAcc[ff][qb] = __builtin_amdgcn_mfma_f32_16x16x32_bf16(ap[qb][0], b0, oAcc[ff][qb], 0, 0, 0);
        oAcc[ff][qb] = __builtin_amdgcn_mfma_f32_16x16x32_bf16(ap[qb][1], b1, oAcc[ff][qb], 0, 0, 0);
      }
    }
    __syncthreads();
    cur ^= 1;
  }

  #pragma unroll
  for (int qb = 0; qb < 2; ++qb) {
    #pragma unroll
    for (int r = 0; r < 4; ++r) {
      racc[qb][r] += __shfl_xor(racc[qb][r], 1);
      racc[qb][r] += __shfl_xor(racc[qb][r], 2);
      racc[qb][r] += __shfl_xor(racc[qb][r], 4);
      racc[qb][r] += __shfl_xor(racc[qb][r], 8);
    }
  }
  if (lr == 0) {
    float* rp = r1p + ((size_t)z * 4 + h) * 4096;
    #pragma unroll
    for (int qb = 0; qb < 2; ++qb)
      #pragma unroll
      for (int r = 0; r < 4; ++r)
        rp[m0 + wv * 32 + qb * 16 + hk * 4 + r] = racc[qb][r];
  }
  float* ob = oP + (size_t)z * 512 * 4096;
  #pragma unroll
  for (int ff = 0; ff < 4; ++ff) {
    const size_t fbase = (size_t)(h * 128 + ff * 16 + lr) * 4096;
    #pragma unroll
    for (int qb = 0; qb < 2; ++qb)
      #pragma unroll
      for (int r = 0; r < 4; ++r)
        ob[fbase + m0 + wv * 32 + qb * 16 + hk * 4 + r] = oAcc[ff][qb][r];
  }
}

// =====================================================================
// Fused attention layer 2 v4: 2 q-blocks/wave, K=224, packed b64 P
// stores (stride 72 shorts = 144B, 16B aligned). Grid (16,4,4), 512 thr.
// =====================================================================
__global__ __launch_bounds__(512, 2) void fused_attn2(
    const ushort_t* __restrict__ Tm, const ushort_t* __restrict__ X,
    const ushort_t* __restrict__ Xt, ushort_t* __restrict__ Up, float scale)
{
  __shared__ ushort_t Xl[16384];        // [64 n][256 a] swizzled, 32 KB
  __shared__ ushort_t Xtl[2][16384];    // [256 a][64 n] swizzled, 32 KB ea
  __shared__ ushort_t Pl[256][72];      // [q][node], stride 144 B
  const int t = threadIdx.x;
  const int lane = t & 63;
  const int wv = t >> 6;
  const int h = blockIdx.y;
  const int m0 = blockIdx.x * 256;
  const int z = blockIdx.z;
  const int lr = lane & 15;
  const int hk = lane >> 4;

  // T fragments for 2 q-blocks (K=224 -> 7 chunks of 32)
  short8 tq[2][7];
  #pragma unroll
  for (int qb = 0; qb < 2; ++qb) {
    const ushort_t* trow = Tm + ((size_t)h * 4096 + m0 + wv * 32 + qb * 16 + lr) * 256;
    #pragma unroll
    for (int s = 0; s < 7; ++s) tq[qb][s] = *(const short8*)(trow + s * 32 + hk * 8);
  }

  f32x4 uAcc[14][2];
  #pragma unroll
  for (int i = 0; i < 14; ++i) {
    uAcc[i][0] = (f32x4){0.f, 0.f, 0.f, 0.f};
    uAcc[i][1] = (f32x4){0.f, 0.f, 0.f, 0.f};
  }

  auto stageX = [&](int n0) {
    #pragma unroll
    for (int i = 0; i < 4; ++i) {          // X tile: 64 rows x 32 chunks
      const int st = t + i * 512;
      const int row = st >> 5, ph = st & 31;
      const int lc = (ph & 24) | ((ph & 7) ^ (row & 7));
      __builtin_amdgcn_global_load_lds(
          (const __attribute__((address_space(1))) u32*)(X + (size_t)(n0 + row) * 256 + lc * 8),
          (__attribute__((address_space(3))) u32*)(&Xl[st * 8]), 16, 0, 0);
    }
  };
  auto stageXt = [&](int buf, int n0) {
    #pragma unroll
    for (int i = 0; i < 4; ++i) {          // Xt tile: 256 rows x 8 chunks
      const int st = t + i * 512;
      const int row = st >> 3, ph = st & 7;
      const int lc = ph ^ (row & 7);
      __builtin_amdgcn_global_load_lds(
          (const __attribute__((address_space(1))) u32*)(Xt + (size_t)row * 4096 + n0 + lc * 8),
          (__attribute__((address_space(3))) u32*)(&Xtl[buf][st * 8]), 16, 0, 0);
    }
  };

  const int base = z * 16;
  stageX(base * 64);
  stageXt(0, base * 64);
  __syncthreads();

  int cur = 0;
  for (int it = 0; it < 16; ++it) {
    if (it + 1 < 16) stageXt(cur ^ 1, (base + it + 1) * 64);
    // ---- S^T phase: C[node, q] x 2 q-blocks; K=224; packed b64 P stores
    const char* xb = (const char*)&Xl[0];
    #pragma unroll
    for (int nf = 0; nf < 4; ++nf) {
      const int row = nf * 16 + lr;
      const char* rb = xb + row * 512;
      f32x4 sa0 = (f32x4){0.f, 0.f, 0.f, 0.f};
      f32x4 sa1 = (f32x4){0.f, 0.f, 0.f, 0.f};
      #pragma unroll
      for (int s = 0; s < 7; ++s) {
        const int c = s * 4 + hk;
        const int ph = (c & 24) | ((c & 7) ^ (row & 7));
        short8 xf = *(const short8*)(rb + ph * 16);
        sa0 = __builtin_amdgcn_mfma_f32_16x16x32_bf16(xf, tq[0][s], sa0, 0, 0, 0);
        sa1 = __builtin_amdgcn_mfma_f32_16x16x32_bf16(xf, tq[1][s], sa1, 0, 0, 0);
      }
      uint2 w0, w1;
      w0.x = (u32)f2bf(exp2f(sa0[0] * scale)) | ((u32)f2bf(exp2f(sa0[1] * scale)) << 16);
      w0.y = (u32)f2bf(exp2f(sa0[2] * scale)) | ((u32)f2bf(exp2f(sa0[3] * scale)) << 16);
      w1.x = (u32)f2bf(exp2f(sa1[0] * scale)) | ((u32)f2bf(exp2f(sa1[1] * scale)) << 16);
      w1.y = (u32)f2bf(exp2f(sa1[2] * scale)) | ((u32)f2bf(exp2f(sa1[3] * scale)) << 16);
      *(uint2*)((char*)&Pl[wv * 32 + lr][0] + nf * 32 + hk * 8) = w0;
      *(uint2*)((char*)&Pl[wv * 32 + 16 + lr][0] + nf * 32 + hk * 8) = w1;
    }
    __syncthreads();                       // all waves done reading Xl
    if (it + 1 < 16) stageX((base + it + 1) * 64);
    // ---- U phase: C[a, q] += Xt . P, a < 224 (ff 0..13)
    short8 p00 = *(const short8*)((const char*)&Pl[wv * 32 + lr][0] + hk * 16);
    short8 p01 = *(const short8*)((const char*)&Pl[wv * 32 + lr][0] + (4 + hk) * 16);
    short8 p10 = *(const short8*)((const char*)&Pl[wv * 32 + 16 + lr][0] + hk * 16);
    short8 p11 = *(const short8*)((const char*)&Pl[wv * 32 + 16 + lr][0] + (4 + hk) * 16);
    const char* xtb = (const char*)&Xtl[cur][0];
    #pragma unroll
    for (int ff = 0; ff < 14; ++ff) {
      const int row = ff * 16 + lr;
      const char* rb2 = xtb + row * 128;
      short8 x0 = *(const short8*)(rb2 + ((hk ^ (row & 7)) * 16));
      short8 x1 = *(const short8*)(rb2 + (((4 + hk) ^ (row & 7)) * 16));
      uAcc[ff][0] = __builtin_amdgcn_mfma_f32_16x16x32_bf16(x0, p00, uAcc[ff][0], 0, 0, 0);
      uAcc[ff][0] = __builtin_amdgcn_mfma_f32_16x16x32_bf16(x1, p01, uAcc[ff][0], 0, 0, 0);
      uAcc[ff][1] = __builtin_amdgcn_mfma_f32_16x16x32_bf16(x0, p10, uAcc[ff][1], 0, 0, 0);
      uAcc[ff][1] = __builtin_amdgcn_mfma_f32_16x16x32_bf16(x1, p11, uAcc[ff][1], 0, 0, 0);
    }
    __syncthreads();                       // drains stages; guards flips
    cur ^= 1;
  }

  // ---- store U^T partials [z][h][a][4096] bf16 (a < 224)
  ushort_t* ub = Up + (size_t)(z * 4 + h) * 256 * 4096;
  #pragma unroll
  for (int ff = 0; ff < 14; ++ff) {
    #pragma unroll
    for (int qb = 0; qb < 2; ++qb) {
      #pragma unroll
      for (int r = 0; r < 4; ++r) {
        const int a = ff * 16 + hk * 4 + r;
        ub[(size_t)a * 4096 + m0 + wv * 32 + qb * 16 + lr] = f2bf(uAcc[ff][qb][r]);
      }
    }
  }
}

// ---------------- combine_u: Usum[h][q][256] = bf16(sum_z Uz) (transpose),
// r2[h][q] = sum_z Uz[a==200]. Grid (64 qtiles, 4 atiles, 4 heads). --------
__global__ __launch_bounds__(256) void combine_u(
    const ushort_t* __restrict__ Up, ushort_t* __restrict__ Usum,
    float* __restrict__ r2)
{
  __shared__ float tl[64][65];
  const int t = threadIdx.x;
  const int qt = blockIdx.x;
  const int at = blockIdx.y;
  const int h  = blockIdx.z;
  const int c = t & 63;
  const int rb = t >> 6;
  const size_t PLN = (size_t)4 * 256 * 4096;
  #pragma unroll
  for (int i = 0; i < 16; ++i) {
    const int r = rb + i * 4;               // a-local
    const int a = at * 64 + r;
    const int q = qt * 64 + c;
    const size_t i0 = ((size_t)h * 256 + a) * 4096 + q;
    float val = bf2f(Up[i0]) + bf2f(Up[PLN + i0])
              + bf2f(Up[2 * PLN + i0]) + bf2f(Up[3 * PLN + i0]);
    tl[r][c] = val;
    if (a == 200) r2[(size_t)h * 4096 + q] = val;
  }
  __syncthreads();
  #pragma unroll
  for (int i = 0; i < 16; ++i) {
    const int r = rb + i * 4;               // q-local
    const int q = qt * 64 + r;
    const int a = at * 64 + c;
    Usum[((size_t)h * 4096 + q) * 256 + a] = f2bf(tl[c][r]);
  }
}

// =====================================================================
// 256x256-tile, 8-phase MFMA GEMM (LONG-K only). Used for the Gram.
// =====================================================================
#define RD_A(bb, mm, cc) (*(const short8*)(lsAc + (bb)*32768 + arow + (mm)*2048 + (cc)))
#define RD_B(bb, nn, cc) (*(const short8*)(lsBc + (bb)*32768 + brow + (nn)*2048 + (cc)))

#define MM8(nn, bv) { \
  acc[0][nn] = __builtin_amdgcn_mfma_f32_16x16x32_bf16(a0, bv, acc[0][nn], 0,0,0); \
  acc[1][nn] = __builtin_amdgcn_mfma_f32_16x16x32_bf16(a1, bv, acc[1][nn], 0,0,0); \
  acc[2][nn] = __builtin_amdgcn_mfma_f32_16x16x32_bf16(a2, bv, acc[2][nn], 0,0,0); \
  acc[3][nn] = __builtin_amdgcn_mfma_f32_16x16x32_bf16(a3, bv, acc[3][nn], 0,0,0); \
  acc[4][nn] = __builtin_amdgcn_mfma_f32_16x16x32_bf16(a4, bv, acc[4][nn], 0,0,0); \
  acc[5][nn] = __builtin_amdgcn_mfma_f32_16x16x32_bf16(a5, bv, acc[5][nn], 0,0,0); \
  acc[6][nn] = __builtin_amdgcn_mfma_f32_16x16x32_bf16(a6, bv, acc[6][nn], 0,0,0); \
  acc[7][nn] = __builtin_amdgcn_mfma_f32_16x16x32_bf16(a7, bv, acc[7][nn], 0,0,0); }

#define STG(BASE, LD, LS, bb, hf, tt) { \
  _Pragma("unroll") \
  for (int ii = 0; ii < 2; ++ii) { \
    const int s_ = t + ii * 512; \
    const int r_ = s_ >> 3; \
    const int lc_ = (s_ & 7) ^ (r_ & 7); \
    __builtin_amdgcn_global_load_lds( \
      (const __attribute__((address_space(1))) u32*)((BASE) + (size_t)((hf) * 128 + r_) * (LD) + (size_t)(tt) * 64 + lc_ * 8), \
      (__attribute__((address_space(3))) u32*)(&(LS)[bb][(hf) * 8192 + s_ * 8]), 16, 0, 0); \
  } }

#define BAR() __builtin_amdgcn_s_barrier()
#define PRIO(x) __builtin_amdgcn_s_setprio(x)

#define GRP(bf, tS1, tS2) { \
  a0=RD_A(bf,0,c0); a1=RD_A(bf,1,c0); a2=RD_A(bf,2,c0); a3=RD_A(bf,3,c0); \
  a4=RD_A(bf,4,c0); a5=RD_A(bf,5,c0); a6=RD_A(bf,6,c0); a7=RD_A(bf,7,c0); \
  b0=RD_B(bf,0,c0); b1=RD_B(bf,1,c0); \
  STG(Ab, lda, lsA, 1-(bf), 1, tS1); STG(Bb, ldb, lsB, 1-(bf), 0, tS1); \
  BAR(); PRIO(1); MM8(0, b0); MM8(1, b1); PRIO(0); BAR(); \
  b2=RD_B(bf,2,c0); b3=RD_B(bf,3,c0); \
  STG(Bb, ldb, lsB, 1-(bf), 1, tS1); \
  BAR(); PRIO(1); MM8(2, b2); MM8(3, b3); PRIO(0); BAR(); \
  a0=RD_A(bf,0,c1); a1=RD_A(bf,1,c1); a2=RD_A(bf,2,c1); a3=RD_A(bf,3,c1); \
  a4=RD_A(bf,4,c1); a5=RD_A(bf,5,c1); a6=RD_A(bf,6,c1); a7=RD_A(bf,7,c1); \
  b0=RD_B(bf,0,c1); b1=RD_B(bf,1,c1); \
  BAR(); PRIO(1); MM8(0, b0); MM8(1, b1); PRIO(0); BAR(); \
  b2=RD_B(bf,2,c1); b3=RD_B(bf,3,c1); \
  STG(Ab, lda, lsA, (bf), 0, tS2); \
  BAR(); PRIO(1); MM8(2, b2); MM8(3, b3); PRIO(0); \
  asm volatile("s_waitcnt vmcnt(2)" ::: "memory"); \
  BAR(); }

template<int CMODE, bool RELU>
__global__ __launch_bounds__(512, 2) void mfma256_8ph(
    const ushort_t* __restrict__ A, const ushort_t* __restrict__ B,
    void* __restrict__ Cv, int lda, int ldb, int ldc,
    int K, int zsplit, size_t zA, size_t zB, size_t zC,
    int bShift, size_t bHead, int Mvalid, float scale)
{
  __shared__ ushort_t lsA[2][16384];
  __shared__ ushort_t lsB[2][16384];
  const int t = threadIdx.x;
  const int gx = gridDim.x;
  const int nwg = gx * gridDim.y;
  const int bid = blockIdx.y * gx + blockIdx.x;
  const int qq = nwg >> 3, rr_ = nwg & 7;
  const int xcd = bid & 7, idx = bid >> 3;
  const int swz = (xcd < rr_ ? xcd * (qq + 1) : rr_ * (qq + 1) + (xcd - rr_) * qq) + idx;
  const int m0 = (swz / gx) * 256;
  const int n0 = (swz % gx) * 256;
  const int z = blockIdx.z;
  int Kc = K, kOff = 0;
  size_t aZ = 0, bZ = 0, cZ = 0;
  if (zsplit > 1) { Kc = K / zsplit; kOff = z * Kc; cZ = (size_t)z * zC; }
  else { aZ = (size_t)z * zA; bZ = (size_t)z * zB; cZ = (size_t)z * zC; }
  const ushort_t* Ab = A + aZ + (size_t)m0 * lda + kOff;
  const ushort_t* Bb = B + bZ + (size_t)n0 * ldb + kOff
                     + (bShift >= 0 ? (size_t)(m0 >> bShift) * bHead : 0);
  const int NT = Kc / 64;

  f32x4 acc[8][4];
  #pragma unroll
  for (int i = 0; i < 8; ++i)
    #pragma unroll
    for (int j = 0; j < 4; ++j) acc[i][j] = (f32x4){0.f, 0.f, 0.f, 0.f};

  const int lane = t & 63;
  const int wv = t >> 6;
  const int wr = (wv >> 2) * 128;
  const int wc = (wv & 3) * 64;
  const int lr = lane & 15;
  const int kc = lane >> 4;
  const int sw = lane & 7;
  const int c0 = (kc ^ sw) * 16;
  const int c1 = c0 ^ 64;
  const int arow = (wr + lr) * 128;
  const int brow = (wc + lr) * 128;
  const char* lsAc = (const char*)lsA;
  const char* lsBc = (const char*)lsB;

  short8 a0, a1, a2, a3, a4, a5, a6, a7, b0, b1, b2, b3;

  STG(Ab, lda, lsA, 0, 0, 0); STG(Ab, lda, lsA, 0, 1, 0);
  STG(Bb, ldb, lsB, 0, 0, 0); STG(Bb, ldb, lsB, 0, 1, 0);
  STG(Ab, lda, lsA, 1, 0, 1);
  asm volatile("s_waitcnt vmcnt(2)" ::: "memory");
  BAR();

  const int NITER = NT >> 1;
  for (int it = 0; it < NITER; ++it) {
    const int tb = 2 * it;
    const int s1 = tb + 1;
    const int s2 = (tb + 2 < NT) ? tb + 2 : 0;
    const int s3 = (tb + 3 < NT) ? tb + 3 : 0;
    GRP(0, s1, s2)
    GRP(1, s2, s3)
  }

  const int row4 = (lane >> 4) * 4;
  const int coln = lane & 15;
  float* Cf = (float*)Cv + cZ;
  ushort_t* Ch = (ushort_t*)Cv + cZ;
  #pragma unroll
  for (int m = 0; m < 8; ++m) {
    #pragma unroll
    for (int r = 0; r < 4; ++r) {
      const int gm = m0 + wr + m * 16 + row4 + r;
      const bool ok = gm < Mvalid;
      #pragma unroll
      for (int n = 0; n < 4; ++n) {
        const int gn = n0 + wc + n * 16 + coln;
        float v = acc[m][n][r] * scale;
        if (RELU) v = fmaxf(v, 0.f);
        if (ok) {
          if (CMODE == 0)      Cf[(size_t)gm * ldc + gn] = v;
          else if (CMODE == 1) Ch[(size_t)gm * ldc + gn] = f2bf(v);
          else                 atomicAdd(&Cf[(size_t)gm * ldc + gn], v);
        }
      }
    }
  }
}

#undef GRP
#undef STG
#undef MM8
#undef RD_A
#undef RD_B

// ================= 128x128-tile MFMA GEMM, 256 threads (SHORT-K) ===========
template<int CMODE, bool RELU>
__global__ __launch_bounds__(256) void mfma_bt(
    const ushort_t* __restrict__ A, const ushort_t* __restrict__ B,
    void* __restrict__ Cv, int lda, int ldb, int ldc,
    int K, int Ksplit, size_t zA, size_t zB, size_t zC,
    int bShift, size_t bHead, int mMask, int Mvalid, float scale)
{
  __shared__ ushort_t lsA[2][128 * 32];
  __shared__ ushort_t lsB[2][128 * 32];
  const int t  = threadIdx.x;
  const int m0 = blockIdx.y * 128;
  const int n0 = blockIdx.x * 128;
  const int z = blockIdx.z;
  int Kc = K, kOff = 0;
  size_t aZ = 0, bZ = 0, cZ = 0;
  if (Ksplit > 1) { Kc = K / Ksplit; kOff = z * Kc; cZ = (size_t)z * zC; }
  else { aZ = (size_t)z * zA; bZ = (size_t)z * zB; cZ = (size_t)z * zC; }
  const int NT = (Kc + 31) / 32;
  const ushort_t* Ab = A + aZ + (size_t)m0 * lda + kOff;
  const ushort_t* Bb = B + bZ + (size_t)n0 * ldb + kOff
                     + (bShift >= 0 ? (size_t)(m0 >> bShift) * bHead : 0);
  const int cs = t & 3;

  f32x4 acc[4][4];
  #pragma unroll
  for (int i = 0; i < 4; ++i)
    #pragma unroll
    for (int j = 0; j < 4; ++j) acc[i][j] = (f32x4){0.f, 0.f, 0.f, 0.f};

  const int lane = t & 63;
  const int wv = t >> 6;
  const int wr = (wv >> 1) * 64;
  const int wc = (wv & 1) * 64;
  const int lr = lane & 15;
  const int kc = lane >> 4;

  int roffA[4], roffB[4];
  #pragma unroll
  for (int m = 0; m < 4; ++m) {
    int ra = wr + m * 16 + lr;
    roffA[m] = ra * 64 + ((kc ^ (ra & 3)) * 16);
    int rb = wc + m * 16 + lr;
    roffB[m] = rb * 64 + ((kc ^ (rb & 3)) * 16);
  }

  auto stage = [&](int buf, int kt) {
    const ushort_t* As = Ab + kt * 32;
    const ushort_t* Bs = Bb + kt * 32;
    #pragma unroll
    for (int i = 0; i < 2; ++i) {
      int s = t + i * 256;
      int r = s >> 2;
      int c = cs ^ (r & 3);
      __builtin_amdgcn_global_load_lds(
          (const __attribute__((address_space(1))) u32*)(As + (size_t)r * lda + c * 8),
          (__attribute__((address_space(3))) u32*)(&lsA[buf][s * 8]), 16, 0, 0);
    }
    #pragma unroll
    for (int i = 0; i < 2; ++i) {
      int s = t + i * 256;
      int r = s >> 2;
      int c = cs ^ (r & 3);
      __builtin_amdgcn_global_load_lds(
          (const __attribute__((address_space(1))) u32*)(Bs + (size_t)r * ldb + c * 8),
          (__attribute__((address_space(3))) u32*)(&lsB[buf][s * 8]), 16, 0, 0);
    }
  };

  stage(0, 0);
  __syncthreads();
  int cur = 0;
  for (int kt = 0; kt < NT; ++kt) {
    if (kt + 1 < NT) stage(cur ^ 1, kt + 1);
    short8 af[4], bfr[4];
    const char* baseA = (const char*)&lsA[cur][0];
    const char* baseB = (const char*)&lsB[cur][0];
    #pragma unroll
    for (int m = 0; m < 4; ++m) af[m]  = *(const short8*)(baseA + roffA[m]);
    #pragma unroll
    for (int n = 0; n < 4; ++n) bfr[n] = *(const short8*)(baseB + roffB[n]);
    #pragma unroll
    for (int m = 0; m < 4; ++m)
      #pragma unroll
      for (int n = 0; n < 4; ++n)
        acc[m][n] = __builtin_amdgcn_mfma_f32_16x16x32_bf16(af[m], bfr[n], acc[m][n], 0, 0, 0);
    __syncthreads();
    cur ^= 1;
  }

  const int row4 = (lane >> 4) * 4;
  const int coln = lane & 15;
  float* Cf = (float*)Cv + cZ;
  ushort_t* Ch = (ushort_t*)Cv + cZ;
  #pragma unroll
  for (int m = 0; m < 4; ++m) {
    #pragma unroll
    for (int r = 0; r < 4; ++r) {
      const int gm = m0 + wr + m * 16 + row4 + r;
      const bool ok = (mMask >= 0) ? ((gm & mMask) < Mvalid) : (gm < Mvalid);
      #pragma unroll
      for (int n = 0; n < 4; ++n) {
        const int gn = n0 + wc + n * 16 + coln;
        float v = acc[m][n][r] * scale;
        if (RELU) v = fmaxf(v, 0.f);
        if (ok) {
          if (CMODE == 0)      Cf[(size_t)gm * ldc + gn] = v;
          else if (CMODE == 1) Ch[(size_t)gm * ldc + gn] = f2bf(v);
          else                 atomicAdd(&Cf[(size_t)gm * ldc + gn], v);
        }
      }
    }
  }
}

// ---------------- weights: dst[Mp,Kp] bf16 = W^T (+ bias slot at k==Kv) ----
__global__ __launch_bounds__(256) void wt_conv(
    const float* __restrict__ W, const float* __restrict__ bias,
    ushort_t* __restrict__ dst, int Mtot, int ldw, int Kv, int Kp,
    int PADH, int VALH)
{
  const int m = blockIdx.x;
  const int h = m / PADH, c0 = m % PADH;
  const int fout = h * VALH + c0;
  const bool valid = (c0 < VALH) && (fout < Mtot);
  for (int k = threadIdx.x; k < Kp; k += blockDim.x) {
    float v = 0.f;
    if (valid) {
      if (k < Kv) v = W[(size_t)k * ldw + fout];
      else if (k == Kv) v = bias[fout];
    }
    dst[(size_t)m * Kp + k] = f2bf(v);
  }
}

// ---------------- wt_trans: dst[4][256][512] bf16 (padded W~^T per head) ---
__global__ __launch_bounds__(256) void wt_trans(
    const float* __restrict__ W, const float* __restrict__ bias,
    ushort_t* __restrict__ dst)
{
  const int rid = blockIdx.x;
  const int h = rid >> 8, a = rid & 255;
  for (int f = threadIdx.x; f < 512; f += 256) {
    float v = 0.f;
    if (a < 200)       v = W[(size_t)a * 2048 + h * 512 + f];
    else if (a == 200) v = bias[h * 512 + f];
    dst[(size_t)rid * 512 + f] = f2bf(v);
  }
}

// ---------------- xt_conv: Xt[256][4096] bf16 from h1nT (a-major) ----------
__global__ __launch_bounds__(256) void xt_conv(
    const float* __restrict__ h1nT, ushort_t* __restrict__ Xt)
{
  const int a = blockIdx.x;
  for (int q = threadIdx.x; q < 4096; q += 256) {
    float v = (a < 200) ? h1nT[(size_t)a * 4096 + q] : ((a == 200) ? 1.f : 0.f);
    Xt[(size_t)a * 4096 + q] = f2bf(v);
  }
}

// ---------------- transpose fp32 [Kv,4096] -> bf16 [4096,Kp], bias slot ----
__global__ __launch_bounds__(256) void trans_pad(
    const float* __restrict__ src, ushort_t* __restrict__ dst, int Kv, int Kp)
{
  __shared__ float tl[64][65];
  const int t = threadIdx.x;
  const int f0 = blockIdx.x * 64;
  const int i0 = blockIdx.y * 64;
  const int c = t & 63, rbase = t >> 6;
  #pragma unroll
  for (int it = 0; it < 16; ++it) {
    int r = rbase + it * 4;
    int f = f0 + r;
    tl[r][c] = (f < Kv) ? src[(size_t)f * 4096 + i0 + c] : 0.f;
  }
  __syncthreads();
  #pragma unroll
  for (int it = 0; it < 16; ++it) {
    int r = rbase + it * 4;
    int f = f0 + c;
    if (f < Kp) {
      float v = (f < Kv) ? tl[c][r] : ((f == Kv) ? 1.f : 0.f);
      dst[(size_t)(i0 + r) * Kp + f] = f2bf(v);
    }
  }
}

// ---------------- GraphNorm layer 1: x = skip(bf16) + (sum_z oP)/(sum_z r) -
__global__ __launch_bounds__(256) void graph_norm_attn1(
    const ushort_t* __restrict__ skip, const float* __restrict__ oP,
    const float* __restrict__ r1p, float* __restrict__ out,
    const float* __restrict__ w, const float* __restrict__ b,
    const float* __restrict__ ms)
{
  __shared__ float red[4];
  const int t = threadIdx.x;
  const int row = blockIdx.x;
  const int h = row / 50;
  const int pr = h * 128 + row % 50;
  const ushort_t* sk = skip + (size_t)pr * 4096;
  const size_t OSTR = (size_t)512 * 4096;
  float v[16];
  float s = 0.f;
  #pragma unroll
  for (int e = 0; e < 4; ++e) {
    const int idx = t * 4 + 1024 * e;
    float a[4];
    ld4bf(&sk[idx], a);
    float4 o0 = *(const float4*)&oP[(size_t)pr * 4096 + idx];
    float4 o1 = *(const float4*)&oP[OSTR + (size_t)pr * 4096 + idx];
    float4 o2 = *(const float4*)&oP[2 * OSTR + (size_t)pr * 4096 + idx];
    float4 o3 = *(const float4*)&oP[3 * OSTR + (size_t)pr * 4096 + idx];
    float4 r0 = *(const float4*)&r1p[(size_t)h * 4096 + idx];
    float4 r1 = *(const float4*)&r1p[(size_t)(4 + h) * 4096 + idx];
    float4 r2 = *(const float4*)&r1p[(size_t)(8 + h) * 4096 + idx];
    float4 r3 = *(const float4*)&r1p[(size_t)(12 + h) * 4096 + idx];
    v[e*4+0] = a[0] + (o0.x + o1.x + o2.x + o3.x) / (r0.x + r1.x + r2.x + r3.x);
    v[e*4+1] = a[1] + (o0.y + o1.y + o2.y + o3.y) / (r0.y + r1.y + r2.y + r3.y);
    v[e*4+2] = a[2] + (o0.z + o1.z + o2.z + o3.z) / (r0.z + r1.z + r2.z + r3.z);
    v[e*4+3] = a[3] + (o0.w + o1.w + o2.w + o3.w) / (r0.w + r1.w + r2.w + r3.w);
    s += v[e*4+0] + v[e*4+1] + v[e*4+2] + v[e*4+3];
  }
  const float mean = block_sum256(s, red) * (1.f / 4096.f);
  const float sub = mean * ms[row];
  float s2 = 0.f;
  #pragma unroll
  for (int e = 0; e < 16; ++e) { v[e] -= sub; s2 += v[e] * v[e]; }
  const float var = block_sum256(s2, red) * (1.f / 4096.f);
  const float scl = rsqrtf(var + 1e-5f) * w[row];
  const float bb = b[row];
  float* y = out + (size_t)row * 4096;
  #pragma unroll
  for (int e = 0; e < 4; ++e) {
    float o0[4];
    #pragma unroll
    for (int q = 0; q < 4; ++q) o0[q] = v[e * 4 + q] * scl + bb;
    *(float4*)&y[t * 4 + 1024 * e] = *(float4*)&o0[0];
  }
}

// ---------------- GraphNorm layer 2 (single O plane): x = skip + O/r -------
__global__ __launch_bounds__(256) void graph_norm_attn2(
    const ushort_t* __restrict__ skip, const ushort_t* __restrict__ O,
    const float* __restrict__ r2, ushort_t* __restrict__ out,
    const float* __restrict__ w, const float* __restrict__ b,
    const float* __restrict__ ms)
{
  __shared__ float red[4];
  const int t = threadIdx.x;
  const int row = blockIdx.x;
  const ushort_t* sk = skip + (size_t)row * 4096;
  const ushort_t* pa = O + (size_t)row * 4096;
  const float* rr = r2 + (size_t)(row >> 9) * 4096;
  float v[16];
  float s = 0.f;
  #pragma unroll
  for (int e = 0; e < 4; ++e) {
    const int idx = t * 4 + 1024 * e;
    float a[4], oa[4];
    ld4bf(&sk[idx], a); ld4bf(&pa[idx], oa);
    float4 rv = *(const float4*)&rr[idx];
    v[e*4+0] = a[0] + oa[0] / rv.x;
    v[e*4+1] = a[1] + oa[1] / rv.y;
    v[e*4+2] = a[2] + oa[2] / rv.z;
    v[e*4+3] = a[3] + oa[3] / rv.w;
    s += v[e*4+0] + v[e*4+1] + v[e*4+2] + v[e*4+3];
  }
  const float mean = block_sum256(s, red) * (1.f / 4096.f);
  const float sub = mean * ms[row];
  float s2 = 0.f;
  #pragma unroll
  for (int e = 0; e < 16; ++e) { v[e] -= sub; s2 += v[e] * v[e]; }
  const float var = block_sum256(s2, red) * (1.f / 4096.f);
  const float scl = rsqrtf(var + 1e-5f) * w[row];
  const float bb = b[row];
  #pragma unroll
  for (int e = 0; e < 16; ++e) v[e] = v[e] * scl + bb;
  float s3 = 0.f;
  #pragma unroll
  for (int e = 0; e < 16; ++e) s3 += v[e] * v[e];
  const float osc = rsqrtf(block_sum256(s3, red));
  ushort_t* y = out + (size_t)row * 4096;
  #pragma unroll
  for (int e = 0; e < 4; ++e) {
    ushort_t o0[4];
    #pragma unroll
    for (int q = 0; q < 4; ++q) o0[q] = f2bf(v[e * 4 + q] * osc);
    *(ushort2*)&y[t * 4 + 1024 * e] = *(ushort2*)&o0[0];
    *(ushort2*)&y[t * 4 + 1024 * e + 2] = *(ushort2*)&o0[2];
  }
}

// ---------------- out = relu(sum of 4 bf16 partial planes) -----------------
__global__ __launch_bounds__(256) void add4_relu_bf16(
    const ushort_t* __restrict__ g, float* __restrict__ out)
{
  const size_t i = (size_t)blockIdx.x * 256 + threadIdx.x;
  const size_t ss = (size_t)2048 * 2048;
  float a[4], b[4], c[4], d[4];
  ld4bf(&g[i * 4], a);
  ld4bf(&g[ss + i * 4], b);
  ld4bf(&g[2 * ss + i * 4], c);
  ld4bf(&g[3 * ss + i * 4], d);
  float4 o;
  o.x = fmaxf(a[0] + b[0] + c[0] + d[0], 0.f);
  o.y = fmaxf(a[1] + b[1] + c[1] + d[1], 0.f);
  o.z = fmaxf(a[2] + b[2] + c[2] + d[2], 0.f);
  o.w = fmaxf(a[3] + b[3] + c[3] + d[3], 0.f);
  ((float4*)out)[i] = o;
}

extern "C" void kernel_launch(void* const* d_in, const int* in_sizes, int n_in,
                              void* d_out, int out_size, void* d_ws, size_t ws_size,
                              hipStream_t stream)
{
  (void)in_sizes; (void)n_in; (void)out_size; (void)ws_size;
  const float* lr_x = (const float*)d_in[0];
  const float* Wq1 = (const float*)d_in[1];  const float* bq1 = (const float*)d_in[2];
  const float* Wk1 = (const float*)d_in[3];  const float* bk1 = (const float*)d_in[4];
  const float* Wv1 = (const float*)d_in[5];  const float* bv1 = (const float*)d_in[6];
  const float* Ws1 = (const float*)d_in[7];  const float* bs1 = (const float*)d_in[8];
  const float* gn1w = (const float*)d_in[9]; const float* gn1b = (const float*)d_in[10];
  const float* gn1ms = (const float*)d_in[11];
  const float* Wq2 = (const float*)d_in[12]; const float* bq2 = (const float*)d_in[13];
  const float* Wk2 = (const float*)d_in[14]; const float* bk2 = (const float*)d_in[15];
  const float* Wv2 = (const float*)d_in[16]; const float* bv2 = (const float*)d_in[17];
  const float* Ws2 = (const float*)d_in[18]; const float* bs2 = (const float*)d_in[19];
  const float* gn2w = (const float*)d_in[20]; const float* gn2b = (const float*)d_in[21];
  const float* gn2ms = (const float*)d_in[22];

  // ---- workspace ----
  char* p = (char*)d_ws;
  auto alloc = [&](size_t bytes) { char* r = p; p += (bytes + 255) & ~(size_t)255; return r; };
  char*     scrA = alloc((size_t)32 * 1024 * 1024);  // oP -> Up -> Gram partials
  ushort_t* xb   = (ushort_t*)alloc((size_t)4096 * 544 * 2);
  ushort_t* qk1b = (ushort_t*)alloc((size_t)4096 * 512 * 2);
  ushort_t* v1s  = (ushort_t*)alloc((size_t)1024 * 4096 * 2); // rows 0-511 v1, 512-1023 skip1
  char*     u0   = alloc((size_t)16 * 1024 * 1024);  // h2b
  float*    h1nT = (float*)   alloc((size_t)200 * 4096 * 4);
  ushort_t* h1nb = (ushort_t*)alloc((size_t)4096 * 256 * 2);
  ushort_t* Wqk1 = (ushort_t*)alloc((size_t)512 * 544 * 2);
  ushort_t* Wvs1 = (ushort_t*)alloc((size_t)1024 * 544 * 2); // [Wv1 | Ws1] head-padded
  ushort_t* Wcat = (ushort_t*)alloc((size_t)4096 * 256 * 2);
  ushort_t* Qt   = (ushort_t*)alloc((size_t)4 * 256 * 512 * 2);
  ushort_t* Kt   = (ushort_t*)alloc((size_t)4 * 256 * 512 * 2);
  ushort_t* Mtall= (ushort_t*)alloc((size_t)4 * 256 * 256 * 2);
  ushort_t* Tall = (ushort_t*)alloc((size_t)4 * 4096 * 256 * 2);
  ushort_t* Xtb  = (ushort_t*)alloc((size_t)256 * 4096 * 2);
  ushort_t* vs2b = (ushort_t*)alloc((size_t)4096 * 4096 * 2);
  ushort_t* Usum = (ushort_t*)alloc((size_t)4 * 4096 * 256 * 2);
  ushort_t* Opl  = (ushort_t*)alloc((size_t)2048 * 4096 * 2);
  float*    r1p  = (float*)   alloc((size_t)16 * 4096 * 4);
  float*    r2   = (float*)   alloc((size_t)4 * 4096 * 4);
  // phase aliases of scrA:
  float*    oP   = (float*)scrA;      // attn-1 partials (dead after gn1)
  ushort_t* UpH  = (ushort_t*)scrA;   // attn-2 U^T bf16 partials (dead after combine)
  ushort_t* g4   = (ushort_t*)scrA;   // Gram bf16 partials
  ushort_t* h2b  = (ushort_t*)u0;     // gn2 output

  const dim3 b256(256, 1, 1);
  const dim3 b512(512, 1, 1);
  const float LOG2E = 1.4426950408889634f;
  const float sc1e = 0.14142135623730951f * LOG2E;
  const float sc2e = 0.04419417382415922f * LOG2E;

  // ---- weight conversions
  wt_conv<<<dim3(256),  b256, 0, stream>>>(Wq1, bq1, Wqk1,             200, 200, 512, 544, 64, 50);
  wt_conv<<<dim3(256),  b256, 0, stream>>>(Wk1, bk1, Wqk1 + 256 * 544, 200, 200, 512, 544, 64, 50);
  wt_conv<<<dim3(512),  b256, 0, stream>>>(Wv1, bv1, Wvs1,             200, 200, 512, 544, 128, 50);
  wt_conv<<<dim3(512),  b256, 0, stream>>>(Ws1, bs1, Wvs1 + 512 * 544, 200, 200, 512, 544, 128, 50);
  wt_conv<<<dim3(2048), b256, 0, stream>>>(Wv2, bv2, Wcat,              2048, 2048, 200, 256, 2048, 2048);
  wt_conv<<<dim3(2048), b256, 0, stream>>>(Ws2, bs2, Wcat + 2048 * 256, 2048, 2048, 200, 256, 2048, 2048);
  wt_trans<<<dim3(1024), b256, 0, stream>>>(Wq2, bq2, Qt);
  wt_trans<<<dim3(1024), b256, 0, stream>>>(Wk2, bk2, Kt);
  trans_pad<<<dim3(9, 64), b256, 0, stream>>>(lr_x, xb, 512, 544);

  // ---- layer-1 projections (QK node-major; merged V+skip feature-major)
  mfma_bt<1, false><<<dim3(4, 32), b256, 0, stream>>>(
      xb, Wqk1, qk1b, 544, 544, 512, 544, 1, 0, 0, 0, -1, 0, -1, 4096, 1.f);
  mfma_bt<1, false><<<dim3(32, 8), b256, 0, stream>>>(
      Wvs1, xb, v1s, 544, 544, 4096, 544, 1, 0, 0, 0, -1, 0, -1, 1024, 1.f);

  // ---- attention 1 (fused, 2 qb/wave) + gn1
  fused_attn1<<<dim3(32, 4, 4), b256, 0, stream>>>(qk1b, v1s, oP, r1p, sc1e);
  graph_norm_attn1<<<dim3(200), b256, 0, stream>>>(
      v1s + (size_t)512 * 4096, oP, r1p, h1nT, gn1w, gn1b, gn1ms);
  trans_pad<<<dim3(4, 64), b256, 0, stream>>>(h1nT, h1nb, 200, 256);
  xt_conv<<<dim3(256), b256, 0, stream>>>(h1nT, Xtb);

  // ---- layer-2 V+skip projection (K=224)
  mfma_bt<1, false><<<dim3(32, 32), b256, 0, stream>>>(
      Wcat, h1nb, vs2b, 256, 256, 4096, 224, 1, 0, 0, 0, -1, 0, -1, 4096, 1.f);

  // ---- attention 2: low-rank T, then fused flash (no P, no V)
  mfma_bt<1, false><<<dim3(2, 2, 4), b256, 0, stream>>>(
      Kt, Qt, Mtall, 512, 512, 256, 512, 1,
      (size_t)256 * 512, (size_t)256 * 512, (size_t)256 * 256, -1, 0, -1, 256, 1.f);
  mfma_bt<1, false><<<dim3(2, 32, 4), b256, 0, stream>>>(
      h1nb, Mtall, Tall, 256, 256, 256, 224, 1,
      0, (size_t)256 * 256, (size_t)4096 * 256, -1, 0, -1, 4096, 1.f);
  fused_attn2<<<dim3(16, 4, 4), b512, 0, stream>>>(Tall, h1nb, Xtb, UpH, sc2e);
  combine_u<<<dim3(64, 4, 4), b256, 0, stream>>>(UpH, Usum, r2);
  // O = Wv . U  (bias rides via a==200 column; K=224)
  mfma_bt<1, false><<<dim3(32, 16), b256, 0, stream>>>(
      Wcat, Usum, Opl, 256, 256, 4096, 224, 1,
      0, 0, 0, 9, (size_t)4096 * 256, -1, 2048, 1.f);
  graph_norm_attn2<<<dim3(2048), b256, 0, stream>>>(
      vs2b + (size_t)2048 * 4096, Opl, r2, h2b, gn2w, gn2b, gn2ms);

  // ---- out = relu(h2n . h2n^T): K-split bf16 partials + reduce
  mfma256_8ph<1, false><<<dim3(8, 8, 4), b512, 0, stream>>>(
      h2b, h2b, g4, 4096, 4096, 2048, 4096, 4,
      0, 0, (size_t)2048 * 2048, -1, 0, 2048, 1.f);
  add4_relu_bf16<<<dim3(4096), b256, 0, stream>>>(g4, (float*)d_out);
}

// Round 18
// 325.406 us; speedup vs baseline: 1.6416x; 1.0053x over previous
//
#include <hip/hip_runtime.h>
#include <math.h>

typedef unsigned int u32;
typedef unsigned short ushort_t;
typedef __attribute__((ext_vector_type(8))) short short8;
typedef __attribute__((ext_vector_type(4))) float f32x4;

#define PRIO(x) __builtin_amdgcn_s_setprio(x)

__device__ __forceinline__ ushort_t f2bf(float x) {
  u32 u = __float_as_uint(x);
  u32 r = (u + 0x7fffu + ((u >> 16) & 1u)) >> 16;
  return (ushort_t)r;
}
__device__ __forceinline__ float bf2f(u32 s) {
  return __uint_as_float(s << 16);
}
__device__ __forceinline__ void ld4bf(const ushort_t* p, float* o) {
  uint2 u = *(const uint2*)p;
  o[0] = bf2f(u.x & 0xffffu); o[1] = bf2f(u.x >> 16);
  o[2] = bf2f(u.y & 0xffffu); o[3] = bf2f(u.y >> 16);
}

// ---------------- block reduction helper (256 threads = 4 waves) -----------
__device__ __forceinline__ float block_sum256(float v, float* red) {
  #pragma unroll
  for (int o = 32; o > 0; o >>= 1) v += __shfl_down(v, o, 64);
  __syncthreads();
  if ((threadIdx.x & 63) == 0) red[threadIdx.x >> 6] = v;
  __syncthreads();
  return red[0] + red[1] + red[2] + red[3];
}

// =====================================================================
// Fused attention layer 1 v4 + T5 setprio. 256 thr = 4 waves, 2 qb/wave.
// Grid (32 qtiles of 128, 4 heads, 4 kv-chunks). LDS 52 KB.
// =====================================================================
__global__ __launch_bounds__(256) void fused_attn1(
    const ushort_t* __restrict__ qk, const ushort_t* __restrict__ v,
    float* __restrict__ oP, float* __restrict__ r1p, float scale)
{
  __shared__ ushort_t Kl[2][4096];
  __shared__ ushort_t Vl[2][4096];
  __shared__ ushort_t Pl[128][80];     // row stride 160B (16B aligned)
  const int t = threadIdx.x;
  const int lane = t & 63;
  const int wv = t >> 6;               // 0..3, wave owns q rows wv*32..+31
  const int h = blockIdx.y;
  const int m0 = blockIdx.x * 128;
  const int z = blockIdx.z;
  const int lr = lane & 15;
  const int hk = lane >> 4;

  short8 aq[2][2];
  #pragma unroll
  for (int qb = 0; qb < 2; ++qb) {
    const ushort_t* qrow = qk + (size_t)(m0 + wv * 32 + qb * 16 + lr) * 512 + h * 64;
    aq[qb][0] = *(const short8*)(qrow + hk * 8);
    aq[qb][1] = *(const short8*)(qrow + 32 + hk * 8);
  }

  f32x4 oAcc[4][2];
  #pragma unroll
  for (int i = 0; i < 4; ++i) {
    oAcc[i][0] = (f32x4){0.f, 0.f, 0.f, 0.f};
    oAcc[i][1] = (f32x4){0.f, 0.f, 0.f, 0.f};
  }
  float racc[2][4] = {{0.f,0.f,0.f,0.f},{0.f,0.f,0.f,0.f}};

  const size_t kbase = (size_t)256 + h * 64;

  auto stage = [&](int buf, int n0) {
    #pragma unroll
    for (int i = 0; i < 2; ++i) {
      const int st = t + i * 256;
      const int row = st >> 3, cS = st & 7;
      const int lc = cS ^ (row & 7);
      __builtin_amdgcn_global_load_lds(
          (const __attribute__((address_space(1))) u32*)(qk + (size_t)(n0 + row) * 512 + kbase + lc * 8),
          (__attribute__((address_space(3))) u32*)(&Kl[buf][st * 8]), 16, 0, 0);
      __builtin_amdgcn_global_load_lds(
          (const __attribute__((address_space(1))) u32*)(v + (size_t)(h * 128 + row) * 4096 + n0 + lc * 8),
          (__attribute__((address_space(3))) u32*)(&Vl[buf][st * 8]), 16, 0, 0);
    }
  };

  stage(0, z * 1024);
  __syncthreads();

  int cur = 0;
  for (int it = 0; it < 16; ++it) {
    if (it + 1 < 16) stage(cur ^ 1, z * 1024 + (it + 1) * 64);
    // ---- S-tiles [16q x 64n] x 2 q-blocks (K frag feeds both)
    #pragma unroll
    for (int nf = 0; nf < 4; ++nf) {
      const int rl = nf * 16 + lr;
      const char* kb = (const char*)&Kl[cur][0] + rl * 128;
      short8 b0 = *(const short8*)(kb + ((hk ^ (rl & 7)) * 16));
      short8 b1 = *(const short8*)(kb + (((4 + hk) ^ (rl & 7)) * 16));
      #pragma unroll
      for (int qb = 0; qb < 2; ++qb) {
        f32x4 sa = (f32x4){0.f, 0.f, 0.f, 0.f};
        PRIO(1);
        sa = __builtin_amdgcn_mfma_f32_16x16x32_bf16(aq[qb][0], b0, sa, 0, 0, 0);
        sa = __builtin_amdgcn_mfma_f32_16x16x32_bf16(aq[qb][1], b1, sa, 0, 0, 0);
        PRIO(0);
        #pragma unroll
        for (int r = 0; r < 4; ++r) {
          float e = exp2f(sa[r] * scale);
          racc[qb][r] += e;
          Pl[wv * 32 + qb * 16 + hk * 4 + r][nf * 16 + lr] = f2bf(e);
        }
      }
    }
    // ---- PV: O[16q x 64f] x 2 q-blocks (V frag feeds both)
    short8 ap[2][2];
    #pragma unroll
    for (int qb = 0; qb < 2; ++qb) {
      ap[qb][0] = *(const short8*)&Pl[wv * 32 + qb * 16 + lr][hk * 8];
      ap[qb][1] = *(const short8*)&Pl[wv * 32 + qb * 16 + lr][32 + hk * 8];
    }
    #pragma unroll
    for (int ff = 0; ff < 4; ++ff) {
      const int rl = ff * 16 + lr;
      const char* vb = (const char*)&Vl[cur][0] + rl * 128;
      short8 b0 = *(const short8*)(vb + ((hk ^ (rl & 7)) * 16));
      short8 b1 = *(const short8*)(vb + (((4 + hk) ^ (rl & 7)) * 16));
      PRIO(1);
      #pragma unroll
      for (int qb = 0; qb < 2; ++qb) {
        oAcc[ff][qb] = __builtin_amdgcn_mfma_f32_16x16x32_bf16(ap[qb][0], b0, oAcc[ff][qb], 0, 0, 0);
        oAcc[ff][qb] = __builtin_amdgcn_mfma_f32_16x16x32_bf16(ap[qb][1], b1, oAcc[ff][qb], 0, 0, 0);
      }
      PRIO(0);
    }
    __syncthreads();
    cur ^= 1;
  }

  #pragma unroll
  for (int qb = 0; qb < 2; ++qb) {
    #pragma unroll
    for (int r = 0; r < 4; ++r) {
      racc[qb][r] += __shfl_xor(racc[qb][r], 1);
      racc[qb][r] += __shfl_xor(racc[qb][r], 2);
      racc[qb][r] += __shfl_xor(racc[qb][r], 4);
      racc[qb][r] += __shfl_xor(racc[qb][r], 8);
    }
  }
  if (lr == 0) {
    float* rp = r1p + ((size_t)z * 4 + h) * 4096;
    #pragma unroll
    for (int qb = 0; qb < 2; ++qb)
      #pragma unroll
      for (int r = 0; r < 4; ++r)
        rp[m0 + wv * 32 + qb * 16 + hk * 4 + r] = racc[qb][r];
  }
  float* ob = oP + (size_t)z * 512 * 4096;
  #pragma unroll
  for (int ff = 0; ff < 4; ++ff) {
    const size_t fbase = (size_t)(h * 128 + ff * 16 + lr) * 4096;
    #pragma unroll
    for (int qb = 0; qb < 2; ++qb)
      #pragma unroll
      for (int r = 0; r < 4; ++r)
        ob[fbase + m0 + wv * 32 + qb * 16 + hk * 4 + r] = oAcc[ff][qb][r];
  }
}

// =====================================================================
// Fused attention layer 2 v5: v4 + T5 setprio around MFMA clusters.
// Grid (16,4,4), 512 thr.
// =====================================================================
__global__ __launch_bounds__(512, 2) void fused_attn2(
    const ushort_t* __restrict__ Tm, const ushort_t* __restrict__ X,
    const ushort_t* __restrict__ Xt, ushort_t* __restrict__ Up, float scale)
{
  __shared__ ushort_t Xl[16384];        // [64 n][256 a] swizzled, 32 KB
  __shared__ ushort_t Xtl[2][16384];    // [256 a][64 n] swizzled, 32 KB ea
  __shared__ ushort_t Pl[256][72];      // [q][node], stride 144 B
  const int t = threadIdx.x;
  const int lane = t & 63;
  const int wv = t >> 6;
  const int h = blockIdx.y;
  const int m0 = blockIdx.x * 256;
  const int z = blockIdx.z;
  const int lr = lane & 15;
  const int hk = lane >> 4;

  // T fragments for 2 q-blocks (K=224 -> 7 chunks of 32)
  short8 tq[2][7];
  #pragma unroll
  for (int qb = 0; qb < 2; ++qb) {
    const ushort_t* trow = Tm + ((size_t)h * 4096 + m0 + wv * 32 + qb * 16 + lr) * 256;
    #pragma unroll
    for (int s = 0; s < 7; ++s) tq[qb][s] = *(const short8*)(trow + s * 32 + hk * 8);
  }

  f32x4 uAcc[14][2];
  #pragma unroll
  for (int i = 0; i < 14; ++i) {
    uAcc[i][0] = (f32x4){0.f, 0.f, 0.f, 0.f};
    uAcc[i][1] = (f32x4){0.f, 0.f, 0.f, 0.f};
  }

  auto stageX = [&](int n0) {
    #pragma unroll
    for (int i = 0; i < 4; ++i) {          // X tile: 64 rows x 32 chunks
      const int st = t + i * 512;
      const int row = st >> 5, ph = st & 31;
      const int lc = (ph & 24) | ((ph & 7) ^ (row & 7));
      __builtin_amdgcn_global_load_lds(
          (const __attribute__((address_space(1))) u32*)(X + (size_t)(n0 + row) * 256 + lc * 8),
          (__attribute__((address_space(3))) u32*)(&Xl[st * 8]), 16, 0, 0);
    }
  };
  auto stageXt = [&](int buf, int n0) {
    #pragma unroll
    for (int i = 0; i < 4; ++i) {          // Xt tile: 256 rows x 8 chunks
      const int st = t + i * 512;
      const int row = st >> 3, ph = st & 7;
      const int lc = ph ^ (row & 7);
      __builtin_amdgcn_global_load_lds(
          (const __attribute__((address_space(1))) u32*)(Xt + (size_t)row * 4096 + n0 + lc * 8),
          (__attribute__((address_space(3))) u32*)(&Xtl[buf][st * 8]), 16, 0, 0);
    }
  };

  const int base = z * 16;
  stageX(base * 64);
  stageXt(0, base * 64);
  __syncthreads();

  int cur = 0;
  for (int it = 0; it < 16; ++it) {
    if (it + 1 < 16) stageXt(cur ^ 1, (base + it + 1) * 64);
    // ---- S^T phase: C[node, q] x 2 q-blocks; K=224; packed b64 P stores
    const char* xb = (const char*)&Xl[0];
    #pragma unroll
    for (int nf = 0; nf < 4; ++nf) {
      const int row = nf * 16 + lr;
      const char* rb = xb + row * 512;
      f32x4 sa0 = (f32x4){0.f, 0.f, 0.f, 0.f};
      f32x4 sa1 = (f32x4){0.f, 0.f, 0.f, 0.f};
      PRIO(1);
      #pragma unroll
      for (int s = 0; s < 7; ++s) {
        const int c = s * 4 + hk;
        const int ph = (c & 24) | ((c & 7) ^ (row & 7));
        short8 xf = *(const short8*)(rb + ph * 16);
        sa0 = __builtin_amdgcn_mfma_f32_16x16x32_bf16(xf, tq[0][s], sa0, 0, 0, 0);
        sa1 = __builtin_amdgcn_mfma_f32_16x16x32_bf16(xf, tq[1][s], sa1, 0, 0, 0);
      }
      PRIO(0);
      uint2 w0, w1;
      w0.x = (u32)f2bf(exp2f(sa0[0] * scale)) | ((u32)f2bf(exp2f(sa0[1] * scale)) << 16);
      w0.y = (u32)f2bf(exp2f(sa0[2] * scale)) | ((u32)f2bf(exp2f(sa0[3] * scale)) << 16);
      w1.x = (u32)f2bf(exp2f(sa1[0] * scale)) | ((u32)f2bf(exp2f(sa1[1] * scale)) << 16);
      w1.y = (u32)f2bf(exp2f(sa1[2] * scale)) | ((u32)f2bf(exp2f(sa1[3] * scale)) << 16);
      *(uint2*)((char*)&Pl[wv * 32 + lr][0] + nf * 32 + hk * 8) = w0;
      *(uint2*)((char*)&Pl[wv * 32 + 16 + lr][0] + nf * 32 + hk * 8) = w1;
    }
    __syncthreads();                       // all waves done reading Xl
    if (it + 1 < 16) stageX((base + it + 1) * 64);
    // ---- U phase: C[a, q] += Xt . P, a < 224 (ff 0..13)
    short8 p00 = *(const short8*)((const char*)&Pl[wv * 32 + lr][0] + hk * 16);
    short8 p01 = *(const short8*)((const char*)&Pl[wv * 32 + lr][0] + (4 + hk) * 16);
    short8 p10 = *(const short8*)((const char*)&Pl[wv * 32 + 16 + lr][0] + hk * 16);
    short8 p11 = *(const short8*)((const char*)&Pl[wv * 32 + 16 + lr][0] + (4 + hk) * 16);
    const char* xtb = (const char*)&Xtl[cur][0];
    #pragma unroll
    for (int ff = 0; ff < 14; ++ff) {
      const int row = ff * 16 + lr;
      const char* rb2 = xtb + row * 128;
      short8 x0 = *(const short8*)(rb2 + ((hk ^ (row & 7)) * 16));
      short8 x1 = *(const short8*)(rb2 + (((4 + hk) ^ (row & 7)) * 16));
      PRIO(1);
      uAcc[ff][0] = __builtin_amdgcn_mfma_f32_16x16x32_bf16(x0, p00, uAcc[ff][0], 0, 0, 0);
      uAcc[ff][0] = __builtin_amdgcn_mfma_f32_16x16x32_bf16(x1, p01, uAcc[ff][0], 0, 0, 0);
      uAcc[ff][1] = __builtin_amdgcn_mfma_f32_16x16x32_bf16(x0, p10, uAcc[ff][1], 0, 0, 0);
      uAcc[ff][1] = __builtin_amdgcn_mfma_f32_16x16x32_bf16(x1, p11, uAcc[ff][1], 0, 0, 0);
      PRIO(0);
    }
    __syncthreads();                       // drains stages; guards flips
    cur ^= 1;
  }

  // ---- store U^T partials [z][h][a][4096] bf16 (a < 224)
  ushort_t* ub = Up + (size_t)(z * 4 + h) * 256 * 4096;
  #pragma unroll
  for (int ff = 0; ff < 14; ++ff) {
    #pragma unroll
    for (int qb = 0; qb < 2; ++qb) {
      #pragma unroll
      for (int r = 0; r < 4; ++r) {
        const int a = ff * 16 + hk * 4 + r;
        ub[(size_t)a * 4096 + m0 + wv * 32 + qb * 16 + lr] = f2bf(uAcc[ff][qb][r]);
      }
    }
  }
}

// ---------------- combine_u: Usum[h][q][256] = bf16(sum_z Uz) (transpose),
// r2[h][q] = sum_z Uz[a==200]. Grid (64 qtiles, 4 atiles, 4 heads). --------
__global__ __launch_bounds__(256) void combine_u(
    const ushort_t* __restrict__ Up, ushort_t* __restrict__ Usum,
    float* __restrict__ r2)
{
  __shared__ float tl[64][65];
  const int t = threadIdx.x;
  const int qt = blockIdx.x;
  const int at = blockIdx.y;
  const int h  = blockIdx.z;
  const int c = t & 63;
  const int rb = t >> 6;
  const size_t PLN = (size_t)4 * 256 * 4096;
  #pragma unroll
  for (int i = 0; i < 16; ++i) {
    const int r = rb + i * 4;               // a-local
    const int a = at * 64 + r;
    const int q = qt * 64 + c;
    const size_t i0 = ((size_t)h * 256 + a) * 4096 + q;
    float val = bf2f(Up[i0]) + bf2f(Up[PLN + i0])
              + bf2f(Up[2 * PLN + i0]) + bf2f(Up[3 * PLN + i0]);
    tl[r][c] = val;
    if (a == 200) r2[(size_t)h * 4096 + q] = val;
  }
  __syncthreads();
  #pragma unroll
  for (int i = 0; i < 16; ++i) {
    const int r = rb + i * 4;               // q-local
    const int q = qt * 64 + r;
    const int a = at * 64 + c;
    Usum[((size_t)h * 4096 + q) * 256 + a] = f2bf(tl[c][r]);
  }
}

// =====================================================================
// 256x256-tile, 8-phase MFMA GEMM (LONG-K only). Used for the Gram.
// =====================================================================
#define RD_A(bb, mm, cc) (*(const short8*)(lsAc + (bb)*32768 + arow + (mm)*2048 + (cc)))
#define RD_B(bb, nn, cc) (*(const short8*)(lsBc + (bb)*32768 + brow + (nn)*2048 + (cc)))

#define MM8(nn, bv) { \
  acc[0][nn] = __builtin_amdgcn_mfma_f32_16x16x32_bf16(a0, bv, acc[0][nn], 0,0,0); \
  acc[1][nn] = __builtin_amdgcn_mfma_f32_16x16x32_bf16(a1, bv, acc[1][nn], 0,0,0); \
  acc[2][nn] = __builtin_amdgcn_mfma_f32_16x16x32_bf16(a2, bv, acc[2][nn], 0,0,0); \
  acc[3][nn] = __builtin_amdgcn_mfma_f32_16x16x32_bf16(a3, bv, acc[3][nn], 0,0,0); \
  acc[4][nn] = __builtin_amdgcn_mfma_f32_16x16x32_bf16(a4, bv, acc[4][nn], 0,0,0); \
  acc[5][nn] = __builtin_amdgcn_mfma_f32_16x16x32_bf16(a5, bv, acc[5][nn], 0,0,0); \
  acc[6][nn] = __builtin_amdgcn_mfma_f32_16x16x32_bf16(a6, bv, acc[6][nn], 0,0,0); \
  acc[7][nn] = __builtin_amdgcn_mfma_f32_16x16x32_bf16(a7, bv, acc[7][nn], 0,0,0); }

#define STG(BASE, LD, LS, bb, hf, tt) { \
  _Pragma("unroll") \
  for (int ii = 0; ii < 2; ++ii) { \
    const int s_ = t + ii * 512; \
    const int r_ = s_ >> 3; \
    const int lc_ = (s_ & 7) ^ (r_ & 7); \
    __builtin_amdgcn_global_load_lds( \
      (const __attribute__((address_space(1))) u32*)((BASE) + (size_t)((hf) * 128 + r_) * (LD) + (size_t)(tt) * 64 + lc_ * 8), \
      (__attribute__((address_space(3))) u32*)(&(LS)[bb][(hf) * 8192 + s_ * 8]), 16, 0, 0); \
  } }

#define BAR() __builtin_amdgcn_s_barrier()

#define GRP(bf, tS1, tS2) { \
  a0=RD_A(bf,0,c0); a1=RD_A(bf,1,c0); a2=RD_A(bf,2,c0); a3=RD_A(bf,3,c0); \
  a4=RD_A(bf,4,c0); a5=RD_A(bf,5,c0); a6=RD_A(bf,6,c0); a7=RD_A(bf,7,c0); \
  b0=RD_B(bf,0,c0); b1=RD_B(bf,1,c0); \
  STG(Ab, lda, lsA, 1-(bf), 1, tS1); STG(Bb, ldb, lsB, 1-(bf), 0, tS1); \
  BAR(); PRIO(1); MM8(0, b0); MM8(1, b1); PRIO(0); BAR(); \
  b2=RD_B(bf,2,c0); b3=RD_B(bf,3,c0); \
  STG(Bb, ldb, lsB, 1-(bf), 1, tS1); \
  BAR(); PRIO(1); MM8(2, b2); MM8(3, b3); PRIO(0); BAR(); \
  a0=RD_A(bf,0,c1); a1=RD_A(bf,1,c1); a2=RD_A(bf,2,c1); a3=RD_A(bf,3,c1); \
  a4=RD_A(bf,4,c1); a5=RD_A(bf,5,c1); a6=RD_A(bf,6,c1); a7=RD_A(bf,7,c1); \
  b0=RD_B(bf,0,c1); b1=RD_B(bf,1,c1); \
  BAR(); PRIO(1); MM8(0, b0); MM8(1, b1); PRIO(0); BAR(); \
  b2=RD_B(bf,2,c1); b3=RD_B(bf,3,c1); \
  STG(Ab, lda, lsA, (bf), 0, tS2); \
  BAR(); PRIO(1); MM8(2, b2); MM8(3, b3); PRIO(0); \
  asm volatile("s_waitcnt vmcnt(2)" ::: "memory"); \
  BAR(); }

template<int CMODE, bool RELU>
__global__ __launch_bounds__(512, 2) void mfma256_8ph(
    const ushort_t* __restrict__ A, const ushort_t* __restrict__ B,
    void* __restrict__ Cv, int lda, int ldb, int ldc,
    int K, int zsplit, size_t zA, size_t zB, size_t zC,
    int bShift, size_t bHead, int Mvalid, float scale)
{
  __shared__ ushort_t lsA[2][16384];
  __shared__ ushort_t lsB[2][16384];
  const int t = threadIdx.x;
  const int gx = gridDim.x;
  const int nwg = gx * gridDim.y;
  const int bid = blockIdx.y * gx + blockIdx.x;
  const int qq = nwg >> 3, rr_ = nwg & 7;
  const int xcd = bid & 7, idx = bid >> 3;
  const int swz = (xcd < rr_ ? xcd * (qq + 1) : rr_ * (qq + 1) + (xcd - rr_) * qq) + idx;
  const int m0 = (swz / gx) * 256;
  const int n0 = (swz % gx) * 256;
  const int z = blockIdx.z;
  int Kc = K, kOff = 0;
  size_t aZ = 0, bZ = 0, cZ = 0;
  if (zsplit > 1) { Kc = K / zsplit; kOff = z * Kc; cZ = (size_t)z * zC; }
  else { aZ = (size_t)z * zA; bZ = (size_t)z * zB; cZ = (size_t)z * zC; }
  const ushort_t* Ab = A + aZ + (size_t)m0 * lda + kOff;
  const ushort_t* Bb = B + bZ + (size_t)n0 * ldb + kOff
                     + (bShift >= 0 ? (size_t)(m0 >> bShift) * bHead : 0);
  const int NT = Kc / 64;

  f32x4 acc[8][4];
  #pragma unroll
  for (int i = 0; i < 8; ++i)
    #pragma unroll
    for (int j = 0; j < 4; ++j) acc[i][j] = (f32x4){0.f, 0.f, 0.f, 0.f};

  const int lane = t & 63;
  const int wv = t >> 6;
  const int wr = (wv >> 2) * 128;
  const int wc = (wv & 3) * 64;
  const int lr = lane & 15;
  const int kc = lane >> 4;
  const int sw = lane & 7;
  const int c0 = (kc ^ sw) * 16;
  const int c1 = c0 ^ 64;
  const int arow = (wr + lr) * 128;
  const int brow = (wc + lr) * 128;
  const char* lsAc = (const char*)lsA;
  const char* lsBc = (const char*)lsB;

  short8 a0, a1, a2, a3, a4, a5, a6, a7, b0, b1, b2, b3;

  STG(Ab, lda, lsA, 0, 0, 0); STG(Ab, lda, lsA, 0, 1, 0);
  STG(Bb, ldb, lsB, 0, 0, 0); STG(Bb, ldb, lsB, 0, 1, 0);
  STG(Ab, lda, lsA, 1, 0, 1);
  asm volatile("s_waitcnt vmcnt(2)" ::: "memory");
  BAR();

  const int NITER = NT >> 1;
  for (int it = 0; it < NITER; ++it) {
    const int tb = 2 * it;
    const int s1 = tb + 1;
    const int s2 = (tb + 2 < NT) ? tb + 2 : 0;
    const int s3 = (tb + 3 < NT) ? tb + 3 : 0;
    GRP(0, s1, s2)
    GRP(1, s2, s3)
  }

  const int row4 = (lane >> 4) * 4;
  const int coln = lane & 15;
  float* Cf = (float*)Cv + cZ;
  ushort_t* Ch = (ushort_t*)Cv + cZ;
  #pragma unroll
  for (int m = 0; m < 8; ++m) {
    #pragma unroll
    for (int r = 0; r < 4; ++r) {
      const int gm = m0 + wr + m * 16 + row4 + r;
      const bool ok = gm < Mvalid;
      #pragma unroll
      for (int n = 0; n < 4; ++n) {
        const int gn = n0 + wc + n * 16 + coln;
        float v = acc[m][n][r] * scale;
        if (RELU) v = fmaxf(v, 0.f);
        if (ok) {
          if (CMODE == 0)      Cf[(size_t)gm * ldc + gn] = v;
          else if (CMODE == 1) Ch[(size_t)gm * ldc + gn] = f2bf(v);
          else                 atomicAdd(&Cf[(size_t)gm * ldc + gn], v);
        }
      }
    }
  }
}

#undef GRP
#undef STG
#undef MM8
#undef RD_A
#undef RD_B

// ================= 128x128-tile MFMA GEMM, 256 threads (SHORT-K) ===========
template<int CMODE, bool RELU>
__global__ __launch_bounds__(256) void mfma_bt(
    const ushort_t* __restrict__ A, const ushort_t* __restrict__ B,
    void* __restrict__ Cv, int lda, int ldb, int ldc,
    int K, int Ksplit, size_t zA, size_t zB, size_t zC,
    int bShift, size_t bHead, int mMask, int Mvalid, float scale)
{
  __shared__ ushort_t lsA[2][128 * 32];
  __shared__ ushort_t lsB[2][128 * 32];
  const int t  = threadIdx.x;
  const int m0 = blockIdx.y * 128;
  const int n0 = blockIdx.x * 128;
  const int z = blockIdx.z;
  int Kc = K, kOff = 0;
  size_t aZ = 0, bZ = 0, cZ = 0;
  if (Ksplit > 1) { Kc = K / Ksplit; kOff = z * Kc; cZ = (size_t)z * zC; }
  else { aZ = (size_t)z * zA; bZ = (size_t)z * zB; cZ = (size_t)z * zC; }
  const int NT = (Kc + 31) / 32;
  const ushort_t* Ab = A + aZ + (size_t)m0 * lda + kOff;
  const ushort_t* Bb = B + bZ + (size_t)n0 * ldb + kOff
                     + (bShift >= 0 ? (size_t)(m0 >> bShift) * bHead : 0);
  const int cs = t & 3;

  f32x4 acc[4][4];
  #pragma unroll
  for (int i = 0; i < 4; ++i)
    #pragma unroll
    for (int j = 0; j < 4; ++j) acc[i][j] = (f32x4){0.f, 0.f, 0.f, 0.f};

  const int lane = t & 63;
  const int wv = t >> 6;
  const int wr = (wv >> 1) * 64;
  const int wc = (wv & 1) * 64;
  const int lr = lane & 15;
  const int kc = lane >> 4;

  int roffA[4], roffB[4];
  #pragma unroll
  for (int m = 0; m < 4; ++m) {
    int ra = wr + m * 16 + lr;
    roffA[m] = ra * 64 + ((kc ^ (ra & 3)) * 16);
    int rb = wc + m * 16 + lr;
    roffB[m] = rb * 64 + ((kc ^ (rb & 3)) * 16);
  }

  auto stage = [&](int buf, int kt) {
    const ushort_t* As = Ab + kt * 32;
    const ushort_t* Bs = Bb + kt * 32;
    #pragma unroll
    for (int i = 0; i < 2; ++i) {
      int s = t + i * 256;
      int r = s >> 2;
      int c = cs ^ (r & 3);
      __builtin_amdgcn_global_load_lds(
          (const __attribute__((address_space(1))) u32*)(As + (size_t)r * lda + c * 8),
          (__attribute__((address_space(3))) u32*)(&lsA[buf][s * 8]), 16, 0, 0);
    }
    #pragma unroll
    for (int i = 0; i < 2; ++i) {
      int s = t + i * 256;
      int r = s >> 2;
      int c = cs ^ (r & 3);
      __builtin_amdgcn_global_load_lds(
          (const __attribute__((address_space(1))) u32*)(Bs + (size_t)r * ldb + c * 8),
          (__attribute__((address_space(3))) u32*)(&lsB[buf][s * 8]), 16, 0, 0);
    }
  };

  stage(0, 0);
  __syncthreads();
  int cur = 0;
  for (int kt = 0; kt < NT; ++kt) {
    if (kt + 1 < NT) stage(cur ^ 1, kt + 1);
    short8 af[4], bfr[4];
    const char* baseA = (const char*)&lsA[cur][0];
    const char* baseB = (const char*)&lsB[cur][0];
    #pragma unroll
    for (int m = 0; m < 4; ++m) af[m]  = *(const short8*)(baseA + roffA[m]);
    #pragma unroll
    for (int n = 0; n < 4; ++n) bfr[n] = *(const short8*)(baseB + roffB[n]);
    PRIO(1);
    #pragma unroll
    for (int m = 0; m < 4; ++m)
      #pragma unroll
      for (int n = 0; n < 4; ++n)
        acc[m][n] = __builtin_amdgcn_mfma_f32_16x16x32_bf16(af[m], bfr[n], acc[m][n], 0, 0, 0);
    PRIO(0);
    __syncthreads();
    cur ^= 1;
  }

  const int row4 = (lane >> 4) * 4;
  const int coln = lane & 15;
  float* Cf = (float*)Cv + cZ;
  ushort_t* Ch = (ushort_t*)Cv + cZ;
  #pragma unroll
  for (int m = 0; m < 4; ++m) {
    #pragma unroll
    for (int r = 0; r < 4; ++r) {
      const int gm = m0 + wr + m * 16 + row4 + r;
      const bool ok = (mMask >= 0) ? ((gm & mMask) < Mvalid) : (gm < Mvalid);
      #pragma unroll
      for (int n = 0; n < 4; ++n) {
        const int gn = n0 + wc + n * 16 + coln;
        float v = acc[m][n][r] * scale;
        if (RELU) v = fmaxf(v, 0.f);
        if (ok) {
          if (CMODE == 0)      Cf[(size_t)gm * ldc + gn] = v;
          else if (CMODE == 1) Ch[(size_t)gm * ldc + gn] = f2bf(v);
          else                 atomicAdd(&Cf[(size_t)gm * ldc + gn], v);
        }
      }
    }
  }
}

// ---------------- weights: dst[Mp,Kp] bf16 = W^T (+ bias slot at k==Kv) ----
__global__ __launch_bounds__(256) void wt_conv(
    const float* __restrict__ W, const float* __restrict__ bias,
    ushort_t* __restrict__ dst, int Mtot, int ldw, int Kv, int Kp,
    int PADH, int VALH)
{
  const int m = blockIdx.x;
  const int h = m / PADH, c0 = m % PADH;
  const int fout = h * VALH + c0;
  const bool valid = (c0 < VALH) && (fout < Mtot);
  for (int k = threadIdx.x; k < Kp; k += blockDim.x) {
    float v = 0.f;
    if (valid) {
      if (k < Kv) v = W[(size_t)k * ldw + fout];
      else if (k == Kv) v = bias[fout];
    }
    dst[(size_t)m * Kp + k] = f2bf(v);
  }
}

// ---------------- wt_trans: dst[4][256][512] bf16 (padded W~^T per head) ---
__global__ __launch_bounds__(256) void wt_trans(
    const float* __restrict__ W, const float* __restrict__ bias,
    ushort_t* __restrict__ dst)
{
  const int rid = blockIdx.x;
  const int h = rid >> 8, a = rid & 255;
  for (int f = threadIdx.x; f < 512; f += 256) {
    float v = 0.f;
    if (a < 200)       v = W[(size_t)a * 2048 + h * 512 + f];
    else if (a == 200) v = bias[h * 512 + f];
    dst[(size_t)rid * 512 + f] = f2bf(v);
  }
}

// ---------------- xt_conv: Xt[256][4096] bf16 from h1nT (a-major) ----------
__global__ __launch_bounds__(256) void xt_conv(
    const float* __restrict__ h1nT, ushort_t* __restrict__ Xt)
{
  const int a = blockIdx.x;
  for (int q = threadIdx.x; q < 4096; q += 256) {
    float v = (a < 200) ? h1nT[(size_t)a * 4096 + q] : ((a == 200) ? 1.f : 0.f);
    Xt[(size_t)a * 4096 + q] = f2bf(v);
  }
}

// ---------------- transpose fp32 [Kv,4096] -> bf16 [4096,Kp], bias slot ----
__global__ __launch_bounds__(256) void trans_pad(
    const float* __restrict__ src, ushort_t* __restrict__ dst, int Kv, int Kp)
{
  __shared__ float tl[64][65];
  const int t = threadIdx.x;
  const int f0 = blockIdx.x * 64;
  const int i0 = blockIdx.y * 64;
  const int c = t & 63, rbase = t >> 6;
  #pragma unroll
  for (int it = 0; it < 16; ++it) {
    int r = rbase + it * 4;
    int f = f0 + r;
    tl[r][c] = (f < Kv) ? src[(size_t)f * 4096 + i0 + c] : 0.f;
  }
  __syncthreads();
  #pragma unroll
  for (int it = 0; it < 16; ++it) {
    int r = rbase + it * 4;
    int f = f0 + c;
    if (f < Kp) {
      float v = (f < Kv) ? tl[c][r] : ((f == Kv) ? 1.f : 0.f);
      dst[(size_t)(i0 + r) * Kp + f] = f2bf(v);
    }
  }
}

// ---------------- GraphNorm layer 1: x = skip(bf16) + (sum_z oP)/(sum_z r) -
__global__ __launch_bounds__(256) void graph_norm_attn1(
    const ushort_t* __restrict__ skip, const float* __restrict__ oP,
    const float* __restrict__ r1p, float* __restrict__ out,
    const float* __restrict__ w, const float* __restrict__ b,
    const float* __restrict__ ms)
{
  __shared__ float red[4];
  const int t = threadIdx.x;
  const int row = blockIdx.x;
  const int h = row / 50;
  const int pr = h * 128 + row % 50;
  const ushort_t* sk = skip + (size_t)pr * 4096;
  const size_t OSTR = (size_t)512 * 4096;
  float v[16];
  float s = 0.f;
  #pragma unroll
  for (int e = 0; e < 4; ++e) {
    const int idx = t * 4 + 1024 * e;
    float a[4];
    ld4bf(&sk[idx], a);
    float4 o0 = *(const float4*)&oP[(size_t)pr * 4096 + idx];
    float4 o1 = *(const float4*)&oP[OSTR + (size_t)pr * 4096 + idx];
    float4 o2 = *(const float4*)&oP[2 * OSTR + (size_t)pr * 4096 + idx];
    float4 o3 = *(const float4*)&oP[3 * OSTR + (size_t)pr * 4096 + idx];
    float4 r0 = *(const float4*)&r1p[(size_t)h * 4096 + idx];
    float4 r1 = *(const float4*)&r1p[(size_t)(4 + h) * 4096 + idx];
    float4 r2 = *(const float4*)&r1p[(size_t)(8 + h) * 4096 + idx];
    float4 r3 = *(const float4*)&r1p[(size_t)(12 + h) * 4096 + idx];
    v[e*4+0] = a[0] + (o0.x + o1.x + o2.x + o3.x) / (r0.x + r1.x + r2.x + r3.x);
    v[e*4+1] = a[1] + (o0.y + o1.y + o2.y + o3.y) / (r0.y + r1.y + r2.y + r3.y);
    v[e*4+2] = a[2] + (o0.z + o1.z + o2.z + o3.z) / (r0.z + r1.z + r2.z + r3.z);
    v[e*4+3] = a[3] + (o0.w + o1.w + o2.w + o3.w) / (r0.w + r1.w + r2.w + r3.w);
    s += v[e*4+0] + v[e*4+1] + v[e*4+2] + v[e*4+3];
  }
  const float mean = block_sum256(s, red) * (1.f / 4096.f);
  const float sub = mean * ms[row];
  float s2 = 0.f;
  #pragma unroll
  for (int e = 0; e < 16; ++e) { v[e] -= sub; s2 += v[e] * v[e]; }
  const float var = block_sum256(s2, red) * (1.f / 4096.f);
  const float scl = rsqrtf(var + 1e-5f) * w[row];
  const float bb = b[row];
  float* y = out + (size_t)row * 4096;
  #pragma unroll
  for (int e = 0; e < 4; ++e) {
    float o0[4];
    #pragma unroll
    for (int q = 0; q < 4; ++q) o0[q] = v[e * 4 + q] * scl + bb;
    *(float4*)&y[t * 4 + 1024 * e] = *(float4*)&o0[0];
  }
}

// ---------------- GraphNorm layer 2 (single O plane): x = skip + O/r -------
__global__ __launch_bounds__(256) void graph_norm_attn2(
    const ushort_t* __restrict__ skip, const ushort_t* __restrict__ O,
    const float* __restrict__ r2, ushort_t* __restrict__ out,
    const float* __restrict__ w, const float* __restrict__ b,
    const float* __restrict__ ms)
{
  __shared__ float red[4];
  const int t = threadIdx.x;
  const int row = blockIdx.x;
  const ushort_t* sk = skip + (size_t)row * 4096;
  const ushort_t* pa = O + (size_t)row * 4096;
  const float* rr = r2 + (size_t)(row >> 9) * 4096;
  float v[16];
  float s = 0.f;
  #pragma unroll
  for (int e = 0; e < 4; ++e) {
    const int idx = t * 4 + 1024 * e;
    float a[4], oa[4];
    ld4bf(&sk[idx], a); ld4bf(&pa[idx], oa);
    float4 rv = *(const float4*)&rr[idx];
    v[e*4+0] = a[0] + oa[0] / rv.x;
    v[e*4+1] = a[1] + oa[1] / rv.y;
    v[e*4+2] = a[2] + oa[2] / rv.z;
    v[e*4+3] = a[3] + oa[3] / rv.w;
    s += v[e*4+0] + v[e*4+1] + v[e*4+2] + v[e*4+3];
  }
  const float mean = block_sum256(s, red) * (1.f / 4096.f);
  const float sub = mean * ms[row];
  float s2 = 0.f;
  #pragma unroll
  for (int e = 0; e < 16; ++e) { v[e] -= sub; s2 += v[e] * v[e]; }
  const float var = block_sum256(s2, red) * (1.f / 4096.f);
  const float scl = rsqrtf(var + 1e-5f) * w[row];
  const float bb = b[row];
  #pragma unroll
  for (int e = 0; e < 16; ++e) v[e] = v[e] * scl + bb;
  float s3 = 0.f;
  #pragma unroll
  for (int e = 0; e < 16; ++e) s3 += v[e] * v[e];
  const float osc = rsqrtf(block_sum256(s3, red));
  ushort_t* y = out + (size_t)row * 4096;
  #pragma unroll
  for (int e = 0; e < 4; ++e) {
    ushort_t o0[4];
    #pragma unroll
    for (int q = 0; q < 4; ++q) o0[q] = f2bf(v[e * 4 + q] * osc);
    *(ushort2*)&y[t * 4 + 1024 * e] = *(ushort2*)&o0[0];
    *(ushort2*)&y[t * 4 + 1024 * e + 2] = *(ushort2*)&o0[2];
  }
}

// ---------------- out = relu(sum of 4 bf16 partial planes) -----------------
__global__ __launch_bounds__(256) void add4_relu_bf16(
    const ushort_t* __restrict__ g, float* __restrict__ out)
{
  const size_t i = (size_t)blockIdx.x * 256 + threadIdx.x;
  const size_t ss = (size_t)2048 * 2048;
  float a[4], b[4], c[4], d[4];
  ld4bf(&g[i * 4], a);
  ld4bf(&g[ss + i * 4], b);
  ld4bf(&g[2 * ss + i * 4], c);
  ld4bf(&g[3 * ss + i * 4], d);
  float4 o;
  o.x = fmaxf(a[0] + b[0] + c[0] + d[0], 0.f);
  o.y = fmaxf(a[1] + b[1] + c[1] + d[1], 0.f);
  o.z = fmaxf(a[2] + b[2] + c[2] + d[2], 0.f);
  o.w = fmaxf(a[3] + b[3] + c[3] + d[3], 0.f);
  ((float4*)out)[i] = o;
}

extern "C" void kernel_launch(void* const* d_in, const int* in_sizes, int n_in,
                              void* d_out, int out_size, void* d_ws, size_t ws_size,
                              hipStream_t stream)
{
  (void)in_sizes; (void)n_in; (void)out_size; (void)ws_size;
  const float* lr_x = (const float*)d_in[0];
  const float* Wq1 = (const float*)d_in[1];  const float* bq1 = (const float*)d_in[2];
  const float* Wk1 = (const float*)d_in[3];  const float* bk1 = (const float*)d_in[4];
  const float* Wv1 = (const float*)d_in[5];  const float* bv1 = (const float*)d_in[6];
  const float* Ws1 = (const float*)d_in[7];  const float* bs1 = (const float*)d_in[8];
  const float* gn1w = (const float*)d_in[9]; const float* gn1b = (const float*)d_in[10];
  const float* gn1ms = (const float*)d_in[11];
  const float* Wq2 = (const float*)d_in[12]; const float* bq2 = (const float*)d_in[13];
  const float* Wk2 = (const float*)d_in[14]; const float* bk2 = (const float*)d_in[15];
  const float* Wv2 = (const float*)d_in[16]; const float* bv2 = (const float*)d_in[17];
  const float* Ws2 = (const float*)d_in[18]; const float* bs2 = (const float*)d_in[19];
  const float* gn2w = (const float*)d_in[20]; const float* gn2b = (const float*)d_in[21];
  const float* gn2ms = (const float*)d_in[22];

  // ---- workspace ----
  char* p = (char*)d_ws;
  auto alloc = [&](size_t bytes) { char* r = p; p += (bytes + 255) & ~(size_t)255; return r; };
  char*     scrA = alloc((size_t)32 * 1024 * 1024);  // oP -> Up -> Gram partials
  ushort_t* xb   = (ushort_t*)alloc((size_t)4096 * 544 * 2);
  ushort_t* qk1b = (ushort_t*)alloc((size_t)4096 * 512 * 2);
  ushort_t* v1s  = (ushort_t*)alloc((size_t)1024 * 4096 * 2); // rows 0-511 v1, 512-1023 skip1
  char*     u0   = alloc((size_t)16 * 1024 * 1024);  // h2b
  float*    h1nT = (float*)   alloc((size_t)200 * 4096 * 4);
  ushort_t* h1nb = (ushort_t*)alloc((size_t)4096 * 256 * 2);
  ushort_t* Wqk1 = (ushort_t*)alloc((size_t)512 * 544 * 2);
  ushort_t* Wvs1 = (ushort_t*)alloc((size_t)1024 * 544 * 2); // [Wv1 | Ws1] head-padded
  ushort_t* Wcat = (ushort_t*)alloc((size_t)4096 * 256 * 2);
  ushort_t* Qt   = (ushort_t*)alloc((size_t)4 * 256 * 512 * 2);
  ushort_t* Kt   = (ushort_t*)alloc((size_t)4 * 256 * 512 * 2);
  ushort_t* Mtall= (ushort_t*)alloc((size_t)4 * 256 * 256 * 2);
  ushort_t* Tall = (ushort_t*)alloc((size_t)4 * 4096 * 256 * 2);
  ushort_t* Xtb  = (ushort_t*)alloc((size_t)256 * 4096 * 2);
  ushort_t* vs2b = (ushort_t*)alloc((size_t)4096 * 4096 * 2);
  ushort_t* Usum = (ushort_t*)alloc((size_t)4 * 4096 * 256 * 2);
  ushort_t* Opl  = (ushort_t*)alloc((size_t)2048 * 4096 * 2);
  float*    r1p  = (float*)   alloc((size_t)16 * 4096 * 4);
  float*    r2   = (float*)   alloc((size_t)4 * 4096 * 4);
  // phase aliases of scrA:
  float*    oP   = (float*)scrA;      // attn-1 partials (dead after gn1)
  ushort_t* UpH  = (ushort_t*)scrA;   // attn-2 U^T bf16 partials (dead after combine)
  ushort_t* g4   = (ushort_t*)scrA;   // Gram bf16 partials
  ushort_t* h2b  = (ushort_t*)u0;     // gn2 output

  const dim3 b256(256, 1, 1);
  const dim3 b512(512, 1, 1);
  const float LOG2E = 1.4426950408889634f;
  const float sc1e = 0.14142135623730951f * LOG2E;
  const float sc2e = 0.04419417382415922f * LOG2E;

  // ---- weight conversions
  wt_conv<<<dim3(256),  b256, 0, stream>>>(Wq1, bq1, Wqk1,             200, 200, 512, 544, 64, 50);
  wt_conv<<<dim3(256),  b256, 0, stream>>>(Wk1, bk1, Wqk1 + 256 * 544, 200, 200, 512, 544, 64, 50);
  wt_conv<<<dim3(512),  b256, 0, stream>>>(Wv1, bv1, Wvs1,             200, 200, 512, 544, 128, 50);
  wt_conv<<<dim3(512),  b256, 0, stream>>>(Ws1, bs1, Wvs1 + 512 * 544, 200, 200, 512, 544, 128, 50);
  wt_conv<<<dim3(2048), b256, 0, stream>>>(Wv2, bv2, Wcat,              2048, 2048, 200, 256, 2048, 2048);
  wt_conv<<<dim3(2048), b256, 0, stream>>>(Ws2, bs2, Wcat + 2048 * 256, 2048, 2048, 200, 256, 2048, 2048);
  wt_trans<<<dim3(1024), b256, 0, stream>>>(Wq2, bq2, Qt);
  wt_trans<<<dim3(1024), b256, 0, stream>>>(Wk2, bk2, Kt);
  trans_pad<<<dim3(9, 64), b256, 0, stream>>>(lr_x, xb, 512, 544);

  // ---- layer-1 projections (QK node-major; merged V+skip feature-major)
  mfma_bt<1, false><<<dim3(4, 32), b256, 0, stream>>>(
      xb, Wqk1, qk1b, 544, 544, 512, 544, 1, 0, 0, 0, -1, 0, -1, 4096, 1.f);
  mfma_bt<1, false><<<dim3(32, 8), b256, 0, stream>>>(
      Wvs1, xb, v1s, 544, 544, 4096, 544, 1, 0, 0, 0, -1, 0, -1, 1024, 1.f);

  // ---- attention 1 (fused, 2 qb/wave) + gn1
  fused_attn1<<<dim3(32, 4, 4), b256, 0, stream>>>(qk1b, v1s, oP, r1p, sc1e);
  graph_norm_attn1<<<dim3(200), b256, 0, stream>>>(
      v1s + (size_t)512 * 4096, oP, r1p, h1nT, gn1w, gn1b, gn1ms);
  trans_pad<<<dim3(4, 64), b256, 0, stream>>>(h1nT, h1nb, 200, 256);
  xt_conv<<<dim3(256), b256, 0, stream>>>(h1nT, Xtb);

  // ---- layer-2 V+skip projection (K=224)
  mfma_bt<1, false><<<dim3(32, 32), b256, 0, stream>>>(
      Wcat, h1nb, vs2b, 256, 256, 4096, 224, 1, 0, 0, 0, -1, 0, -1, 4096, 1.f);

  // ---- attention 2: low-rank T, then fused flash (no P, no V)
  mfma_bt<1, false><<<dim3(2, 2, 4), b256, 0, stream>>>(
      Kt, Qt, Mtall, 512, 512, 256, 512, 1,
      (size_t)256 * 512, (size_t)256 * 512, (size_t)256 * 256, -1, 0, -1, 256, 1.f);
  mfma_bt<1, false><<<dim3(2, 32, 4), b256, 0, stream>>>(
      h1nb, Mtall, Tall, 256, 256, 256, 224, 1,
      0, (size_t)256 * 256, (size_t)4096 * 256, -1, 0, -1, 4096, 1.f);
  fused_attn2<<<dim3(16, 4, 4), b512, 0, stream>>>(Tall, h1nb, Xtb, UpH, sc2e);
  combine_u<<<dim3(64, 4, 4), b256, 0, stream>>>(UpH, Usum, r2);
  // O = Wv . U  (bias rides via a==200 column; K=224)
  mfma_bt<1, false><<<dim3(32, 16), b256, 0, stream>>>(
      Wcat, Usum, Opl, 256, 256, 4096, 224, 1,
      0, 0, 0, 9, (size_t)4096 * 256, -1, 2048, 1.f);
  graph_norm_attn2<<<dim3(2048), b256, 0, stream>>>(
      vs2b + (size_t)2048 * 4096, Opl, r2, h2b, gn2w, gn2b, gn2ms);

  // ---- out = relu(h2n . h2n^T): K-split bf16 partials + reduce
  mfma256_8ph<1, false><<<dim3(8, 8, 4), b512, 0, stream>>>(
      h2b, h2b, g4, 4096, 4096, 2048, 4096, 4,
      0, 0, (size_t)2048 * 2048, -1, 0, 2048, 1.f);
  add4_relu_bf16<<<dim3(4096), b256, 0, stream>>>(g4, (float*)d_out);
}

// Round 19
// 304.326 us; speedup vs baseline: 1.7553x; 1.0693x over previous
//
#include <hip/hip_runtime.h>
#include <math.h>

typedef unsigned int u32;
typedef unsigned short ushort_t;
typedef __attribute__((ext_vector_type(8))) short short8;
typedef __attribute__((ext_vector_type(4))) float f32x4;

#define PRIO(x) __builtin_amdgcn_s_setprio(x)

__device__ __forceinline__ ushort_t f2bf(float x) {
  u32 u = __float_as_uint(x);
  u32 r = (u + 0x7fffu + ((u >> 16) & 1u)) >> 16;
  return (ushort_t)r;
}
__device__ __forceinline__ float bf2f(u32 s) {
  return __uint_as_float(s << 16);
}
__device__ __forceinline__ void ld4bf(const ushort_t* p, float* o) {
  uint2 u = *(const uint2*)p;
  o[0] = bf2f(u.x & 0xffffu); o[1] = bf2f(u.x >> 16);
  o[2] = bf2f(u.y & 0xffffu); o[3] = bf2f(u.y >> 16);
}

// ---------------- block reduction helper (256 threads = 4 waves) -----------
__device__ __forceinline__ float block_sum256(float v, float* red) {
  #pragma unroll
  for (int o = 32; o > 0; o >>= 1) v += __shfl_down(v, o, 64);
  __syncthreads();
  if ((threadIdx.x & 63) == 0) red[threadIdx.x >> 6] = v;
  __syncthreads();
  return red[0] + red[1] + red[2] + red[3];
}

// =====================================================================
// Fused attention layer 1 v5: v4 + bf16 O partials. 256 thr = 4 waves,
// 2 qb/wave. Grid (32 qtiles of 128, 4 heads, 4 kv-chunks). LDS 52 KB.
// =====================================================================
__global__ __launch_bounds__(256) void fused_attn1(
    const ushort_t* __restrict__ qk, const ushort_t* __restrict__ v,
    ushort_t* __restrict__ oP, float* __restrict__ r1p, float scale)
{
  __shared__ ushort_t Kl[2][4096];
  __shared__ ushort_t Vl[2][4096];
  __shared__ ushort_t Pl[128][80];     // row stride 160B (16B aligned)
  const int t = threadIdx.x;
  const int lane = t & 63;
  const int wv = t >> 6;               // 0..3, wave owns q rows wv*32..+31
  const int h = blockIdx.y;
  const int m0 = blockIdx.x * 128;
  const int z = blockIdx.z;
  const int lr = lane & 15;
  const int hk = lane >> 4;

  short8 aq[2][2];
  #pragma unroll
  for (int qb = 0; qb < 2; ++qb) {
    const ushort_t* qrow = qk + (size_t)(m0 + wv * 32 + qb * 16 + lr) * 512 + h * 64;
    aq[qb][0] = *(const short8*)(qrow + hk * 8);
    aq[qb][1] = *(const short8*)(qrow + 32 + hk * 8);
  }

  f32x4 oAcc[4][2];
  #pragma unroll
  for (int i = 0; i < 4; ++i) {
    oAcc[i][0] = (f32x4){0.f, 0.f, 0.f, 0.f};
    oAcc[i][1] = (f32x4){0.f, 0.f, 0.f, 0.f};
  }
  float racc[2][4] = {{0.f,0.f,0.f,0.f},{0.f,0.f,0.f,0.f}};

  const size_t kbase = (size_t)256 + h * 64;

  auto stage = [&](int buf, int n0) {
    #pragma unroll
    for (int i = 0; i < 2; ++i) {
      const int st = t + i * 256;
      const int row = st >> 3, cS = st & 7;
      const int lc = cS ^ (row & 7);
      __builtin_amdgcn_global_load_lds(
          (const __attribute__((address_space(1))) u32*)(qk + (size_t)(n0 + row) * 512 + kbase + lc * 8),
          (__attribute__((address_space(3))) u32*)(&Kl[buf][st * 8]), 16, 0, 0);
      __builtin_amdgcn_global_load_lds(
          (const __attribute__((address_space(1))) u32*)(v + (size_t)(h * 128 + row) * 4096 + n0 + lc * 8),
          (__attribute__((address_space(3))) u32*)(&Vl[buf][st * 8]), 16, 0, 0);
    }
  };

  stage(0, z * 1024);
  __syncthreads();

  int cur = 0;
  for (int it = 0; it < 16; ++it) {
    if (it + 1 < 16) stage(cur ^ 1, z * 1024 + (it + 1) * 64);
    // ---- S-tiles [16q x 64n] x 2 q-blocks (K frag feeds both)
    #pragma unroll
    for (int nf = 0; nf < 4; ++nf) {
      const int rl = nf * 16 + lr;
      const char* kb = (const char*)&Kl[cur][0] + rl * 128;
      short8 b0 = *(const short8*)(kb + ((hk ^ (rl & 7)) * 16));
      short8 b1 = *(const short8*)(kb + (((4 + hk) ^ (rl & 7)) * 16));
      #pragma unroll
      for (int qb = 0; qb < 2; ++qb) {
        f32x4 sa = (f32x4){0.f, 0.f, 0.f, 0.f};
        PRIO(1);
        sa = __builtin_amdgcn_mfma_f32_16x16x32_bf16(aq[qb][0], b0, sa, 0, 0, 0);
        sa = __builtin_amdgcn_mfma_f32_16x16x32_bf16(aq[qb][1], b1, sa, 0, 0, 0);
        PRIO(0);
        #pragma unroll
        for (int r = 0; r < 4; ++r) {
          float e = exp2f(sa[r] * scale);
          racc[qb][r] += e;
          Pl[wv * 32 + qb * 16 + hk * 4 + r][nf * 16 + lr] = f2bf(e);
        }
      }
    }
    // ---- PV: O[16q x 64f] x 2 q-blocks (V frag feeds both)
    short8 ap[2][2];
    #pragma unroll
    for (int qb = 0; qb < 2; ++qb) {
      ap[qb][0] = *(const short8*)&Pl[wv * 32 + qb * 16 + lr][hk * 8];
      ap[qb][1] = *(const short8*)&Pl[wv * 32 + qb * 16 + lr][32 + hk * 8];
    }
    #pragma unroll
    for (int ff = 0; ff < 4; ++ff) {
      const int rl = ff * 16 + lr;
      const char* vb = (const char*)&Vl[cur][0] + rl * 128;
      short8 b0 = *(const short8*)(vb + ((hk ^ (rl & 7)) * 16));
      short8 b1 = *(const short8*)(vb + (((4 + hk) ^ (rl & 7)) * 16));
      PRIO(1);
      #pragma unroll
      for (int qb = 0; qb < 2; ++qb) {
        oAcc[ff][qb] = __builtin_amdgcn_mfma_f32_16x16x32_bf16(ap[qb][0], b0, oAcc[ff][qb], 0, 0, 0);
        oAcc[ff][qb] = __builtin_amdgcn_mfma_f32_16x16x32_bf16(ap[qb][1], b1, oAcc[ff][qb], 0, 0, 0);
      }
      PRIO(0);
    }
    __syncthreads();
    cur ^= 1;
  }

  #pragma unroll
  for (int qb = 0; qb < 2; ++qb) {
    #pragma unroll
    for (int r = 0; r < 4; ++r) {
      racc[qb][r] += __shfl_xor(racc[qb][r], 1);
      racc[qb][r] += __shfl_xor(racc[qb][r], 2);
      racc[qb][r] += __shfl_xor(racc[qb][r], 4);
      racc[qb][r] += __shfl_xor(racc[qb][r], 8);
    }
  }
  if (lr == 0) {
    float* rp = r1p + ((size_t)z * 4 + h) * 4096;
    #pragma unroll
    for (int qb = 0; qb < 2; ++qb)
      #pragma unroll
      for (int r = 0; r < 4; ++r)
        rp[m0 + wv * 32 + qb * 16 + hk * 4 + r] = racc[qb][r];
  }
  // bf16 O partials, packed 4-wide (8B) stores
  ushort_t* ob = oP + (size_t)z * 512 * 4096;
  #pragma unroll
  for (int ff = 0; ff < 4; ++ff) {
    const size_t fbase = (size_t)(h * 128 + ff * 16 + lr) * 4096;
    #pragma unroll
    for (int qb = 0; qb < 2; ++qb) {
      const int q0 = m0 + wv * 32 + qb * 16 + hk * 4;
      uint2 w;
      w.x = (u32)f2bf(oAcc[ff][qb][0]) | ((u32)f2bf(oAcc[ff][qb][1]) << 16);
      w.y = (u32)f2bf(oAcc[ff][qb][2]) | ((u32)f2bf(oAcc[ff][qb][3]) << 16);
      *(uint2*)&ob[fbase + q0] = w;
    }
  }
}

// =====================================================================
// Fused attention layer 2 v5 (R18-proven): 2 qb/wave, K=224, packed P,
// setprio. Grid (16,4,4), 512 thr.
// =====================================================================
__global__ __launch_bounds__(512, 2) void fused_attn2(
    const ushort_t* __restrict__ Tm, const ushort_t* __restrict__ X,
    const ushort_t* __restrict__ Xt, ushort_t* __restrict__ Up, float scale)
{
  __shared__ ushort_t Xl[16384];        // [64 n][256 a] swizzled, 32 KB
  __shared__ ushort_t Xtl[2][16384];    // [256 a][64 n] swizzled, 32 KB ea
  __shared__ ushort_t Pl[256][72];      // [q][node], stride 144 B
  const int t = threadIdx.x;
  const int lane = t & 63;
  const int wv = t >> 6;
  const int h = blockIdx.y;
  const int m0 = blockIdx.x * 256;
  const int z = blockIdx.z;
  const int lr = lane & 15;
  const int hk = lane >> 4;

  short8 tq[2][7];
  #pragma unroll
  for (int qb = 0; qb < 2; ++qb) {
    const ushort_t* trow = Tm + ((size_t)h * 4096 + m0 + wv * 32 + qb * 16 + lr) * 256;
    #pragma unroll
    for (int s = 0; s < 7; ++s) tq[qb][s] = *(const short8*)(trow + s * 32 + hk * 8);
  }

  f32x4 uAcc[14][2];
  #pragma unroll
  for (int i = 0; i < 14; ++i) {
    uAcc[i][0] = (f32x4){0.f, 0.f, 0.f, 0.f};
    uAcc[i][1] = (f32x4){0.f, 0.f, 0.f, 0.f};
  }

  auto stageX = [&](int n0) {
    #pragma unroll
    for (int i = 0; i < 4; ++i) {          // X tile: 64 rows x 32 chunks
      const int st = t + i * 512;
      const int row = st >> 5, ph = st & 31;
      const int lc = (ph & 24) | ((ph & 7) ^ (row & 7));
      __builtin_amdgcn_global_load_lds(
          (const __attribute__((address_space(1))) u32*)(X + (size_t)(n0 + row) * 256 + lc * 8),
          (__attribute__((address_space(3))) u32*)(&Xl[st * 8]), 16, 0, 0);
    }
  };
  auto stageXt = [&](int buf, int n0) {
    #pragma unroll
    for (int i = 0; i < 4; ++i) {          // Xt tile: 256 rows x 8 chunks
      const int st = t + i * 512;
      const int row = st >> 3, ph = st & 7;
      const int lc = ph ^ (row & 7);
      __builtin_amdgcn_global_load_lds(
          (const __attribute__((address_space(1))) u32*)(Xt + (size_t)row * 4096 + n0 + lc * 8),
          (__attribute__((address_space(3))) u32*)(&Xtl[buf][st * 8]), 16, 0, 0);
    }
  };

  const int base = z * 16;
  stageX(base * 64);
  stageXt(0, base * 64);
  __syncthreads();

  int cur = 0;
  for (int it = 0; it < 16; ++it) {
    if (it + 1 < 16) stageXt(cur ^ 1, (base + it + 1) * 64);
    // ---- S^T phase
    const char* xb = (const char*)&Xl[0];
    #pragma unroll
    for (int nf = 0; nf < 4; ++nf) {
      const int row = nf * 16 + lr;
      const char* rb = xb + row * 512;
      f32x4 sa0 = (f32x4){0.f, 0.f, 0.f, 0.f};
      f32x4 sa1 = (f32x4){0.f, 0.f, 0.f, 0.f};
      PRIO(1);
      #pragma unroll
      for (int s = 0; s < 7; ++s) {
        const int c = s * 4 + hk;
        const int ph = (c & 24) | ((c & 7) ^ (row & 7));
        short8 xf = *(const short8*)(rb + ph * 16);
        sa0 = __builtin_amdgcn_mfma_f32_16x16x32_bf16(xf, tq[0][s], sa0, 0, 0, 0);
        sa1 = __builtin_amdgcn_mfma_f32_16x16x32_bf16(xf, tq[1][s], sa1, 0, 0, 0);
      }
      PRIO(0);
      uint2 w0, w1;
      w0.x = (u32)f2bf(exp2f(sa0[0] * scale)) | ((u32)f2bf(exp2f(sa0[1] * scale)) << 16);
      w0.y = (u32)f2bf(exp2f(sa0[2] * scale)) | ((u32)f2bf(exp2f(sa0[3] * scale)) << 16);
      w1.x = (u32)f2bf(exp2f(sa1[0] * scale)) | ((u32)f2bf(exp2f(sa1[1] * scale)) << 16);
      w1.y = (u32)f2bf(exp2f(sa1[2] * scale)) | ((u32)f2bf(exp2f(sa1[3] * scale)) << 16);
      *(uint2*)((char*)&Pl[wv * 32 + lr][0] + nf * 32 + hk * 8) = w0;
      *(uint2*)((char*)&Pl[wv * 32 + 16 + lr][0] + nf * 32 + hk * 8) = w1;
    }
    __syncthreads();
    if (it + 1 < 16) stageX((base + it + 1) * 64);
    // ---- U phase: C[a, q] += Xt . P, a < 224
    short8 p00 = *(const short8*)((const char*)&Pl[wv * 32 + lr][0] + hk * 16);
    short8 p01 = *(const short8*)((const char*)&Pl[wv * 32 + lr][0] + (4 + hk) * 16);
    short8 p10 = *(const short8*)((const char*)&Pl[wv * 32 + 16 + lr][0] + hk * 16);
    short8 p11 = *(const short8*)((const char*)&Pl[wv * 32 + 16 + lr][0] + (4 + hk) * 16);
    const char* xtb = (const char*)&Xtl[cur][0];
    #pragma unroll
    for (int ff = 0; ff < 14; ++ff) {
      const int row = ff * 16 + lr;
      const char* rb2 = xtb + row * 128;
      short8 x0 = *(const short8*)(rb2 + ((hk ^ (row & 7)) * 16));
      short8 x1 = *(const short8*)(rb2 + (((4 + hk) ^ (row & 7)) * 16));
      PRIO(1);
      uAcc[ff][0] = __builtin_amdgcn_mfma_f32_16x16x32_bf16(x0, p00, uAcc[ff][0], 0, 0, 0);
      uAcc[ff][0] = __builtin_amdgcn_mfma_f32_16x16x32_bf16(x1, p01, uAcc[ff][0], 0, 0, 0);
      uAcc[ff][1] = __builtin_amdgcn_mfma_f32_16x16x32_bf16(x0, p10, uAcc[ff][1], 0, 0, 0);
      uAcc[ff][1] = __builtin_amdgcn_mfma_f32_16x16x32_bf16(x1, p11, uAcc[ff][1], 0, 0, 0);
      PRIO(0);
    }
    __syncthreads();
    cur ^= 1;
  }

  ushort_t* ub = Up + (size_t)(z * 4 + h) * 256 * 4096;
  #pragma unroll
  for (int ff = 0; ff < 14; ++ff) {
    #pragma unroll
    for (int qb = 0; qb < 2; ++qb) {
      #pragma unroll
      for (int r = 0; r < 4; ++r) {
        const int a = ff * 16 + hk * 4 + r;
        ub[(size_t)a * 4096 + m0 + wv * 32 + qb * 16 + lr] = f2bf(uAcc[ff][qb][r]);
      }
    }
  }
}

// ---------------- combine_u (R18-proven) -----------------------------------
__global__ __launch_bounds__(256) void combine_u(
    const ushort_t* __restrict__ Up, ushort_t* __restrict__ Usum,
    float* __restrict__ r2)
{
  __shared__ float tl[64][65];
  const int t = threadIdx.x;
  const int qt = blockIdx.x;
  const int at = blockIdx.y;
  const int h  = blockIdx.z;
  const int c = t & 63;
  const int rb = t >> 6;
  const size_t PLN = (size_t)4 * 256 * 4096;
  #pragma unroll
  for (int i = 0; i < 16; ++i) {
    const int r = rb + i * 4;               // a-local
    const int a = at * 64 + r;
    const int q = qt * 64 + c;
    const size_t i0 = ((size_t)h * 256 + a) * 4096 + q;
    float val = bf2f(Up[i0]) + bf2f(Up[PLN + i0])
              + bf2f(Up[2 * PLN + i0]) + bf2f(Up[3 * PLN + i0]);
    tl[r][c] = val;
    if (a == 200) r2[(size_t)h * 4096 + q] = val;
  }
  __syncthreads();
  #pragma unroll
  for (int i = 0; i < 16; ++i) {
    const int r = rb + i * 4;               // q-local
    const int q = qt * 64 + r;
    const int a = at * 64 + c;
    Usum[((size_t)h * 4096 + q) * 256 + a] = f2bf(tl[c][r]);
  }
}

// =====================================================================
// 256x256-tile, 8-phase MFMA GEMM (LONG-K only). Used for the Gram.
// =====================================================================
#define RD_A(bb, mm, cc) (*(const short8*)(lsAc + (bb)*32768 + arow + (mm)*2048 + (cc)))
#define RD_B(bb, nn, cc) (*(const short8*)(lsBc + (bb)*32768 + brow + (nn)*2048 + (cc)))

#define MM8(nn, bv) { \
  acc[0][nn] = __builtin_amdgcn_mfma_f32_16x16x32_bf16(a0, bv, acc[0][nn], 0,0,0); \
  acc[1][nn] = __builtin_amdgcn_mfma_f32_16x16x32_bf16(a1, bv, acc[1][nn], 0,0,0); \
  acc[2][nn] = __builtin_amdgcn_mfma_f32_16x16x32_bf16(a2, bv, acc[2][nn], 0,0,0); \
  acc[3][nn] = __builtin_amdgcn_mfma_f32_16x16x32_bf16(a3, bv, acc[3][nn], 0,0,0); \
  acc[4][nn] = __builtin_amdgcn_mfma_f32_16x16x32_bf16(a4, bv, acc[4][nn], 0,0,0); \
  acc[5][nn] = __builtin_amdgcn_mfma_f32_16x16x32_bf16(a5, bv, acc[5][nn], 0,0,0); \
  acc[6][nn] = __builtin_amdgcn_mfma_f32_16x16x32_bf16(a6, bv, acc[6][nn], 0,0,0); \
  acc[7][nn] = __builtin_amdgcn_mfma_f32_16x16x32_bf16(a7, bv, acc[7][nn], 0,0,0); }

#define STG(BASE, LD, LS, bb, hf, tt) { \
  _Pragma("unroll") \
  for (int ii = 0; ii < 2; ++ii) { \
    const int s_ = t + ii * 512; \
    const int r_ = s_ >> 3; \
    const int lc_ = (s_ & 7) ^ (r_ & 7); \
    __builtin_amdgcn_global_load_lds( \
      (const __attribute__((address_space(1))) u32*)((BASE) + (size_t)((hf) * 128 + r_) * (LD) + (size_t)(tt) * 64 + lc_ * 8), \
      (__attribute__((address_space(3))) u32*)(&(LS)[bb][(hf) * 8192 + s_ * 8]), 16, 0, 0); \
  } }

#define BAR() __builtin_amdgcn_s_barrier()

#define GRP(bf, tS1, tS2) { \
  a0=RD_A(bf,0,c0); a1=RD_A(bf,1,c0); a2=RD_A(bf,2,c0); a3=RD_A(bf,3,c0); \
  a4=RD_A(bf,4,c0); a5=RD_A(bf,5,c0); a6=RD_A(bf,6,c0); a7=RD_A(bf,7,c0); \
  b0=RD_B(bf,0,c0); b1=RD_B(bf,1,c0); \
  STG(Ab, lda, lsA, 1-(bf), 1, tS1); STG(Bb, ldb, lsB, 1-(bf), 0, tS1); \
  BAR(); PRIO(1); MM8(0, b0); MM8(1, b1); PRIO(0); BAR(); \
  b2=RD_B(bf,2,c0); b3=RD_B(bf,3,c0); \
  STG(Bb, ldb, lsB, 1-(bf), 1, tS1); \
  BAR(); PRIO(1); MM8(2, b2); MM8(3, b3); PRIO(0); BAR(); \
  a0=RD_A(bf,0,c1); a1=RD_A(bf,1,c1); a2=RD_A(bf,2,c1); a3=RD_A(bf,3,c1); \
  a4=RD_A(bf,4,c1); a5=RD_A(bf,5,c1); a6=RD_A(bf,6,c1); a7=RD_A(bf,7,c1); \
  b0=RD_B(bf,0,c1); b1=RD_B(bf,1,c1); \
  BAR(); PRIO(1); MM8(0, b0); MM8(1, b1); PRIO(0); BAR(); \
  b2=RD_B(bf,2,c1); b3=RD_B(bf,3,c1); \
  STG(Ab, lda, lsA, (bf), 0, tS2); \
  BAR(); PRIO(1); MM8(2, b2); MM8(3, b3); PRIO(0); \
  asm volatile("s_waitcnt vmcnt(2)" ::: "memory"); \
  BAR(); }

template<int CMODE, bool RELU>
__global__ __launch_bounds__(512, 2) void mfma256_8ph(
    const ushort_t* __restrict__ A, const ushort_t* __restrict__ B,
    void* __restrict__ Cv, int lda, int ldb, int ldc,
    int K, int zsplit, size_t zA, size_t zB, size_t zC,
    int bShift, size_t bHead, int Mvalid, float scale)
{
  __shared__ ushort_t lsA[2][16384];
  __shared__ ushort_t lsB[2][16384];
  const int t = threadIdx.x;
  const int gx = gridDim.x;
  const int nwg = gx * gridDim.y;
  const int bid = blockIdx.y * gx + blockIdx.x;
  const int qq = nwg >> 3, rr_ = nwg & 7;
  const int xcd = bid & 7, idx = bid >> 3;
  const int swz = (xcd < rr_ ? xcd * (qq + 1) : rr_ * (qq + 1) + (xcd - rr_) * qq) + idx;
  const int m0 = (swz / gx) * 256;
  const int n0 = (swz % gx) * 256;
  const int z = blockIdx.z;
  int Kc = K, kOff = 0;
  size_t aZ = 0, bZ = 0, cZ = 0;
  if (zsplit > 1) { Kc = K / zsplit; kOff = z * Kc; cZ = (size_t)z * zC; }
  else { aZ = (size_t)z * zA; bZ = (size_t)z * zB; cZ = (size_t)z * zC; }
  const ushort_t* Ab = A + aZ + (size_t)m0 * lda + kOff;
  const ushort_t* Bb = B + bZ + (size_t)n0 * ldb + kOff
                     + (bShift >= 0 ? (size_t)(m0 >> bShift) * bHead : 0);
  const int NT = Kc / 64;

  f32x4 acc[8][4];
  #pragma unroll
  for (int i = 0; i < 8; ++i)
    #pragma unroll
    for (int j = 0; j < 4; ++j) acc[i][j] = (f32x4){0.f, 0.f, 0.f, 0.f};

  const int lane = t & 63;
  const int wv = t >> 6;
  const int wr = (wv >> 2) * 128;
  const int wc = (wv & 3) * 64;
  const int lr = lane & 15;
  const int kc = lane >> 4;
  const int sw = lane & 7;
  const int c0 = (kc ^ sw) * 16;
  const int c1 = c0 ^ 64;
  const int arow = (wr + lr) * 128;
  const int brow = (wc + lr) * 128;
  const char* lsAc = (const char*)lsA;
  const char* lsBc = (const char*)lsB;

  short8 a0, a1, a2, a3, a4, a5, a6, a7, b0, b1, b2, b3;

  STG(Ab, lda, lsA, 0, 0, 0); STG(Ab, lda, lsA, 0, 1, 0);
  STG(Bb, ldb, lsB, 0, 0, 0); STG(Bb, ldb, lsB, 0, 1, 0);
  STG(Ab, lda, lsA, 1, 0, 1);
  asm volatile("s_waitcnt vmcnt(2)" ::: "memory");
  BAR();

  const int NITER = NT >> 1;
  for (int it = 0; it < NITER; ++it) {
    const int tb = 2 * it;
    const int s1 = tb + 1;
    const int s2 = (tb + 2 < NT) ? tb + 2 : 0;
    const int s3 = (tb + 3 < NT) ? tb + 3 : 0;
    GRP(0, s1, s2)
    GRP(1, s2, s3)
  }

  const int row4 = (lane >> 4) * 4;
  const int coln = lane & 15;
  float* Cf = (float*)Cv + cZ;
  ushort_t* Ch = (ushort_t*)Cv + cZ;
  #pragma unroll
  for (int m = 0; m < 8; ++m) {
    #pragma unroll
    for (int r = 0; r < 4; ++r) {
      const int gm = m0 + wr + m * 16 + row4 + r;
      const bool ok = gm < Mvalid;
      #pragma unroll
      for (int n = 0; n < 4; ++n) {
        const int gn = n0 + wc + n * 16 + coln;
        float v = acc[m][n][r] * scale;
        if (RELU) v = fmaxf(v, 0.f);
        if (ok) {
          if (CMODE == 0)      Cf[(size_t)gm * ldc + gn] = v;
          else if (CMODE == 1) Ch[(size_t)gm * ldc + gn] = f2bf(v);
          else                 atomicAdd(&Cf[(size_t)gm * ldc + gn], v);
        }
      }
    }
  }
}

#undef GRP
#undef STG
#undef MM8
#undef RD_A
#undef RD_B

// ================= 128x128-tile MFMA GEMM, 256 threads (SHORT-K) ===========
template<int CMODE, bool RELU>
__global__ __launch_bounds__(256) void mfma_bt(
    const ushort_t* __restrict__ A, const ushort_t* __restrict__ B,
    void* __restrict__ Cv, int lda, int ldb, int ldc,
    int K, int Ksplit, size_t zA, size_t zB, size_t zC,
    int bShift, size_t bHead, int mMask, int Mvalid, float scale)
{
  __shared__ ushort_t lsA[2][128 * 32];
  __shared__ ushort_t lsB[2][128 * 32];
  const int t  = threadIdx.x;
  const int m0 = blockIdx.y * 128;
  const int n0 = blockIdx.x * 128;
  const int z = blockIdx.z;
  int Kc = K, kOff = 0;
  size_t aZ = 0, bZ = 0, cZ = 0;
  if (Ksplit > 1) { Kc = K / Ksplit; kOff = z * Kc; cZ = (size_t)z * zC; }
  else { aZ = (size_t)z * zA; bZ = (size_t)z * zB; cZ = (size_t)z * zC; }
  const int NT = (Kc + 31) / 32;
  const ushort_t* Ab = A + aZ + (size_t)m0 * lda + kOff;
  const ushort_t* Bb = B + bZ + (size_t)n0 * ldb + kOff
                     + (bShift >= 0 ? (size_t)(m0 >> bShift) * bHead : 0);
  const int cs = t & 3;

  f32x4 acc[4][4];
  #pragma unroll
  for (int i = 0; i < 4; ++i)
    #pragma unroll
    for (int j = 0; j < 4; ++j) acc[i][j] = (f32x4){0.f, 0.f, 0.f, 0.f};

  const int lane = t & 63;
  const int wv = t >> 6;
  const int wr = (wv >> 1) * 64;
  const int wc = (wv & 1) * 64;
  const int lr = lane & 15;
  const int kc = lane >> 4;

  int roffA[4], roffB[4];
  #pragma unroll
  for (int m = 0; m < 4; ++m) {
    int ra = wr + m * 16 + lr;
    roffA[m] = ra * 64 + ((kc ^ (ra & 3)) * 16);
    int rb = wc + m * 16 + lr;
    roffB[m] = rb * 64 + ((kc ^ (rb & 3)) * 16);
  }

  auto stage = [&](int buf, int kt) {
    const ushort_t* As = Ab + kt * 32;
    const ushort_t* Bs = Bb + kt * 32;
    #pragma unroll
    for (int i = 0; i < 2; ++i) {
      int s = t + i * 256;
      int r = s >> 2;
      int c = cs ^ (r & 3);
      __builtin_amdgcn_global_load_lds(
          (const __attribute__((address_space(1))) u32*)(As + (size_t)r * lda + c * 8),
          (__attribute__((address_space(3))) u32*)(&lsA[buf][s * 8]), 16, 0, 0);
    }
    #pragma unroll
    for (int i = 0; i < 2; ++i) {
      int s = t + i * 256;
      int r = s >> 2;
      int c = cs ^ (r & 3);
      __builtin_amdgcn_global_load_lds(
          (const __attribute__((address_space(1))) u32*)(Bs + (size_t)r * ldb + c * 8),
          (__attribute__((address_space(3))) u32*)(&lsB[buf][s * 8]), 16, 0, 0);
    }
  };

  stage(0, 0);
  __syncthreads();
  int cur = 0;
  for (int kt = 0; kt < NT; ++kt) {
    if (kt + 1 < NT) stage(cur ^ 1, kt + 1);
    short8 af[4], bfr[4];
    const char* baseA = (const char*)&lsA[cur][0];
    const char* baseB = (const char*)&lsB[cur][0];
    #pragma unroll
    for (int m = 0; m < 4; ++m) af[m]  = *(const short8*)(baseA + roffA[m]);
    #pragma unroll
    for (int n = 0; n < 4; ++n) bfr[n] = *(const short8*)(baseB + roffB[n]);
    PRIO(1);
    #pragma unroll
    for (int m = 0; m < 4; ++m)
      #pragma unroll
      for (int n = 0; n < 4; ++n)
        acc[m][n] = __builtin_amdgcn_mfma_f32_16x16x32_bf16(af[m], bfr[n], acc[m][n], 0, 0, 0);
    PRIO(0);
    __syncthreads();
    cur ^= 1;
  }

  const int row4 = (lane >> 4) * 4;
  const int coln = lane & 15;
  float* Cf = (float*)Cv + cZ;
  ushort_t* Ch = (ushort_t*)Cv + cZ;
  #pragma unroll
  for (int m = 0; m < 4; ++m) {
    #pragma unroll
    for (int r = 0; r < 4; ++r) {
      const int gm = m0 + wr + m * 16 + row4 + r;
      const bool ok = (mMask >= 0) ? ((gm & mMask) < Mvalid) : (gm < Mvalid);
      #pragma unroll
      for (int n = 0; n < 4; ++n) {
        const int gn = n0 + wc + n * 16 + coln;
        float v = acc[m][n][r] * scale;
        if (RELU) v = fmaxf(v, 0.f);
        if (ok) {
          if (CMODE == 0)      Cf[(size_t)gm * ldc + gn] = v;
          else if (CMODE == 1) Ch[(size_t)gm * ldc + gn] = f2bf(v);
          else                 atomicAdd(&Cf[(size_t)gm * ldc + gn], v);
        }
      }
    }
  }
}

// ---------------- wt_conv2: two (W,bias,dst) sets, blockIdx.y selects ------
__global__ __launch_bounds__(256) void wt_conv2(
    const float* __restrict__ W0, const float* __restrict__ b0v, ushort_t* __restrict__ d0,
    const float* __restrict__ W1, const float* __restrict__ b1v, ushort_t* __restrict__ d1,
    int Mtot, int ldw, int Kv, int Kp, int PADH, int VALH)
{
  const float* W = blockIdx.y ? W1 : W0;
  const float* bias = blockIdx.y ? b1v : b0v;
  ushort_t* dst = blockIdx.y ? d1 : d0;
  const int m = blockIdx.x;
  const int h = m / PADH, c0 = m % PADH;
  const int fout = h * VALH + c0;
  const bool valid = (c0 < VALH) && (fout < Mtot);
  for (int k = threadIdx.x; k < Kp; k += blockDim.x) {
    float v = 0.f;
    if (valid) {
      if (k < Kv) v = W[(size_t)k * ldw + fout];
      else if (k == Kv) v = bias[fout];
    }
    dst[(size_t)m * Kp + k] = f2bf(v);
  }
}

// ---------------- wt_trans2: two sets of padded W~^T [4][256][512] ---------
__global__ __launch_bounds__(256) void wt_trans2(
    const float* __restrict__ W0, const float* __restrict__ b0v, ushort_t* __restrict__ d0,
    const float* __restrict__ W1, const float* __restrict__ b1v, ushort_t* __restrict__ d1)
{
  const float* W = blockIdx.y ? W1 : W0;
  const float* bias = blockIdx.y ? b1v : b0v;
  ushort_t* dst = blockIdx.y ? d1 : d0;
  const int rid = blockIdx.x;
  const int h = rid >> 8, a = rid & 255;
  for (int f = threadIdx.x; f < 512; f += 256) {
    float v = 0.f;
    if (a < 200)       v = W[(size_t)a * 2048 + h * 512 + f];
    else if (a == 200) v = bias[h * 512 + f];
    dst[(size_t)rid * 512 + f] = f2bf(v);
  }
}

// ---------------- transpose fp32 [Kv,4096] -> bf16 [4096,Kp], bias slot ----
__global__ __launch_bounds__(256) void trans_pad(
    const float* __restrict__ src, ushort_t* __restrict__ dst, int Kv, int Kp)
{
  __shared__ float tl[64][65];
  const int t = threadIdx.x;
  const int f0 = blockIdx.x * 64;
  const int i0 = blockIdx.y * 64;
  const int c = t & 63, rbase = t >> 6;
  #pragma unroll
  for (int it = 0; it < 16; ++it) {
    int r = rbase + it * 4;
    int f = f0 + r;
    tl[r][c] = (f < Kv) ? src[(size_t)f * 4096 + i0 + c] : 0.f;
  }
  __syncthreads();
  #pragma unroll
  for (int it = 0; it < 16; ++it) {
    int r = rbase + it * 4;
    int f = f0 + c;
    if (f < Kp) {
      float v = (f < Kv) ? tl[c][r] : ((f == Kv) ? 1.f : 0.f);
      dst[(size_t)(i0 + r) * Kp + f] = f2bf(v);
    }
  }
}

// ---------------- transb: bf16 transpose Xtb[256][4096] -> h1nb[4096][256] -
__global__ __launch_bounds__(256) void transb(
    const ushort_t* __restrict__ Xt, ushort_t* __restrict__ dst)
{
  __shared__ ushort_t tl[64][68];
  const int t = threadIdx.x;
  const int a0 = blockIdx.x * 64;
  const int q0 = blockIdx.y * 64;
  const int c = t & 63, rb = t >> 6;
  #pragma unroll
  for (int i = 0; i < 16; ++i) {
    const int r = rb + i * 4;
    tl[r][c] = Xt[(size_t)(a0 + r) * 4096 + q0 + c];
  }
  __syncthreads();
  #pragma unroll
  for (int i = 0; i < 16; ++i) {
    const int r = rb + i * 4;
    dst[(size_t)(q0 + r) * 256 + a0 + c] = tl[c][r];
  }
}

// ---------------- GraphNorm layer 1 -> bf16 Xtb rows (incl. const rows) ----
// Grid 256: blocks 0..199 normalize feature rows; 200..255 seed bias/zero.
__global__ __launch_bounds__(256) void graph_norm_attn1(
    const ushort_t* __restrict__ skip, const ushort_t* __restrict__ oP,
    const float* __restrict__ r1p, ushort_t* __restrict__ outXt,
    const float* __restrict__ w, const float* __restrict__ b,
    const float* __restrict__ ms)
{
  const int t = threadIdx.x;
  const int row = blockIdx.x;
  if (row >= 200) {
    const ushort_t val = (row == 200) ? f2bf(1.f) : (ushort_t)0;
    for (int q = t; q < 4096; q += 256) outXt[(size_t)row * 4096 + q] = val;
    return;
  }
  __shared__ float red[4];
  const int h = row / 50;
  const int pr = h * 128 + row % 50;
  const ushort_t* sk = skip + (size_t)pr * 4096;
  const size_t OSTR = (size_t)512 * 4096;
  float v[16];
  float s = 0.f;
  #pragma unroll
  for (int e = 0; e < 4; ++e) {
    const int idx = t * 4 + 1024 * e;
    float a[4], o0[4], o1[4], o2[4], o3[4];
    ld4bf(&sk[idx], a);
    ld4bf(&oP[(size_t)pr * 4096 + idx], o0);
    ld4bf(&oP[OSTR + (size_t)pr * 4096 + idx], o1);
    ld4bf(&oP[2 * OSTR + (size_t)pr * 4096 + idx], o2);
    ld4bf(&oP[3 * OSTR + (size_t)pr * 4096 + idx], o3);
    float4 r0 = *(const float4*)&r1p[(size_t)h * 4096 + idx];
    float4 r1 = *(const float4*)&r1p[(size_t)(4 + h) * 4096 + idx];
    float4 r2 = *(const float4*)&r1p[(size_t)(8 + h) * 4096 + idx];
    float4 r3 = *(const float4*)&r1p[(size_t)(12 + h) * 4096 + idx];
    v[e*4+0] = a[0] + (o0[0] + o1[0] + o2[0] + o3[0]) / (r0.x + r1.x + r2.x + r3.x);
    v[e*4+1] = a[1] + (o0[1] + o1[1] + o2[1] + o3[1]) / (r0.y + r1.y + r2.y + r3.y);
    v[e*4+2] = a[2] + (o0[2] + o1[2] + o2[2] + o3[2]) / (r0.z + r1.z + r2.z + r3.z);
    v[e*4+3] = a[3] + (o0[3] + o1[3] + o2[3] + o3[3]) / (r0.w + r1.w + r2.w + r3.w);
    s += v[e*4+0] + v[e*4+1] + v[e*4+2] + v[e*4+3];
  }
  const float mean = block_sum256(s, red) * (1.f / 4096.f);
  const float sub = mean * ms[row];
  float s2 = 0.f;
  #pragma unroll
  for (int e = 0; e < 16; ++e) { v[e] -= sub; s2 += v[e] * v[e]; }
  const float var = block_sum256(s2, red) * (1.f / 4096.f);
  const float scl = rsqrtf(var + 1e-5f) * w[row];
  const float bb = b[row];
  ushort_t* y = outXt + (size_t)row * 4096;
  #pragma unroll
  for (int e = 0; e < 4; ++e) {
    const int idx = t * 4 + 1024 * e;
    uint2 wd;
    wd.x = (u32)f2bf(v[e*4+0] * scl + bb) | ((u32)f2bf(v[e*4+1] * scl + bb) << 16);
    wd.y = (u32)f2bf(v[e*4+2] * scl + bb) | ((u32)f2bf(v[e*4+3] * scl + bb) << 16);
    *(uint2*)&y[idx] = wd;
  }
}

// ---------------- GraphNorm layer 2 (single O plane): x = skip + O/r -------
__global__ __launch_bounds__(256) void graph_norm_attn2(
    const ushort_t* __restrict__ skip, const ushort_t* __restrict__ O,
    const float* __restrict__ r2, ushort_t* __restrict__ out,
    const float* __restrict__ w, const float* __restrict__ b,
    const float* __restrict__ ms)
{
  __shared__ float red[4];
  const int t = threadIdx.x;
  const int row = blockIdx.x;
  const ushort_t* sk = skip + (size_t)row * 4096;
  const ushort_t* pa = O + (size_t)row * 4096;
  const float* rr = r2 + (size_t)(row >> 9) * 4096;
  float v[16];
  float s = 0.f;
  #pragma unroll
  for (int e = 0; e < 4; ++e) {
    const int idx = t * 4 + 1024 * e;
    float a[4], oa[4];
    ld4bf(&sk[idx], a); ld4bf(&pa[idx], oa);
    float4 rv = *(const float4*)&rr[idx];
    v[e*4+0] = a[0] + oa[0] / rv.x;
    v[e*4+1] = a[1] + oa[1] / rv.y;
    v[e*4+2] = a[2] + oa[2] / rv.z;
    v[e*4+3] = a[3] + oa[3] / rv.w;
    s += v[e*4+0] + v[e*4+1] + v[e*4+2] + v[e*4+3];
  }
  const float mean = block_sum256(s, red) * (1.f / 4096.f);
  const float sub = mean * ms[row];
  float s2 = 0.f;
  #pragma unroll
  for (int e = 0; e < 16; ++e) { v[e] -= sub; s2 += v[e] * v[e]; }
  const float var = block_sum256(s2, red) * (1.f / 4096.f);
  const float scl = rsqrtf(var + 1e-5f) * w[row];
  const float bb = b[row];
  #pragma unroll
  for (int e = 0; e < 16; ++e) v[e] = v[e] * scl + bb;
  float s3 = 0.f;
  #pragma unroll
  for (int e = 0; e < 16; ++e) s3 += v[e] * v[e];
  const float osc = rsqrtf(block_sum256(s3, red));
  ushort_t* y = out + (size_t)row * 4096;
  #pragma unroll
  for (int e = 0; e < 4; ++e) {
    ushort_t o0[4];
    #pragma unroll
    for (int q = 0; q < 4; ++q) o0[q] = f2bf(v[e * 4 + q] * osc);
    *(ushort2*)&y[t * 4 + 1024 * e] = *(ushort2*)&o0[0];
    *(ushort2*)&y[t * 4 + 1024 * e + 2] = *(ushort2*)&o0[2];
  }
}

// ---------------- out = relu(sum of 4 bf16 partial planes) -----------------
__global__ __launch_bounds__(256) void add4_relu_bf16(
    const ushort_t* __restrict__ g, float* __restrict__ out)
{
  const size_t i = (size_t)blockIdx.x * 256 + threadIdx.x;
  const size_t ss = (size_t)2048 * 2048;
  float a[4], b[4], c[4], d[4];
  ld4bf(&g[i * 4], a);
  ld4bf(&g[ss + i * 4], b);
  ld4bf(&g[2 * ss + i * 4], c);
  ld4bf(&g[3 * ss + i * 4], d);
  float4 o;
  o.x = fmaxf(a[0] + b[0] + c[0] + d[0], 0.f);
  o.y = fmaxf(a[1] + b[1] + c[1] + d[1], 0.f);
  o.z = fmaxf(a[2] + b[2] + c[2] + d[2], 0.f);
  o.w = fmaxf(a[3] + b[3] + c[3] + d[3], 0.f);
  ((float4*)out)[i] = o;
}

extern "C" void kernel_launch(void* const* d_in, const int* in_sizes, int n_in,
                              void* d_out, int out_size, void* d_ws, size_t ws_size,
                              hipStream_t stream)
{
  (void)in_sizes; (void)n_in; (void)out_size; (void)ws_size;
  const float* lr_x = (const float*)d_in[0];
  const float* Wq1 = (const float*)d_in[1];  const float* bq1 = (const float*)d_in[2];
  const float* Wk1 = (const float*)d_in[3];  const float* bk1 = (const float*)d_in[4];
  const float* Wv1 = (const float*)d_in[5];  const float* bv1 = (const float*)d_in[6];
  const float* Ws1 = (const float*)d_in[7];  const float* bs1 = (const float*)d_in[8];
  const float* gn1w = (const float*)d_in[9]; const float* gn1b = (const float*)d_in[10];
  const float* gn1ms = (const float*)d_in[11];
  const float* Wq2 = (const float*)d_in[12]; const float* bq2 = (const float*)d_in[13];
  const float* Wk2 = (const float*)d_in[14]; const float* bk2 = (const float*)d_in[15];
  const float* Wv2 = (const float*)d_in[16]; const float* bv2 = (const float*)d_in[17];
  const float* Ws2 = (const float*)d_in[18]; const float* bs2 = (const float*)d_in[19];
  const float* gn2w = (const float*)d_in[20]; const float* gn2b = (const float*)d_in[21];
  const float* gn2ms = (const float*)d_in[22];

  // ---- workspace ----
  char* p = (char*)d_ws;
  auto alloc = [&](size_t bytes) { char* r = p; p += (bytes + 255) & ~(size_t)255; return r; };
  char*     scrA = alloc((size_t)32 * 1024 * 1024);  // oP(bf16) -> Up -> Gram partials
  ushort_t* xb   = (ushort_t*)alloc((size_t)4096 * 544 * 2);
  ushort_t* qk1b = (ushort_t*)alloc((size_t)4096 * 512 * 2);
  ushort_t* v1s  = (ushort_t*)alloc((size_t)1024 * 4096 * 2); // rows 0-511 v1, 512-1023 skip1
  char*     u0   = alloc((size_t)16 * 1024 * 1024);  // h2b
  ushort_t* h1nb = (ushort_t*)alloc((size_t)4096 * 256 * 2);
  ushort_t* Wqk1 = (ushort_t*)alloc((size_t)512 * 544 * 2);
  ushort_t* Wvs1 = (ushort_t*)alloc((size_t)1024 * 544 * 2); // [Wv1 | Ws1] head-padded
  ushort_t* Wcat = (ushort_t*)alloc((size_t)4096 * 256 * 2);
  ushort_t* Qt   = (ushort_t*)alloc((size_t)4 * 256 * 512 * 2);
  ushort_t* Kt   = (ushort_t*)alloc((size_t)4 * 256 * 512 * 2);
  ushort_t* Mtall= (ushort_t*)alloc((size_t)4 * 256 * 256 * 2);
  ushort_t* Tall = (ushort_t*)alloc((size_t)4 * 4096 * 256 * 2);
  ushort_t* Xtb  = (ushort_t*)alloc((size_t)256 * 4096 * 2);
  ushort_t* vs2b = (ushort_t*)alloc((size_t)4096 * 4096 * 2);
  ushort_t* Usum = (ushort_t*)alloc((size_t)4 * 4096 * 256 * 2);
  ushort_t* Opl  = (ushort_t*)alloc((size_t)2048 * 4096 * 2);
  float*    r1p  = (float*)   alloc((size_t)16 * 4096 * 4);
  float*    r2   = (float*)   alloc((size_t)4 * 4096 * 4);
  // phase aliases of scrA:
  ushort_t* oP   = (ushort_t*)scrA;   // attn-1 bf16 partials (dead after gn1)
  ushort_t* UpH  = (ushort_t*)scrA;   // attn-2 U^T bf16 partials (dead after combine)
  ushort_t* g4   = (ushort_t*)scrA;   // Gram bf16 partials
  ushort_t* h2b  = (ushort_t*)u0;     // gn2 output

  const dim3 b256(256, 1, 1);
  const dim3 b512(512, 1, 1);
  const float LOG2E = 1.4426950408889634f;
  const float sc1e = 0.14142135623730951f * LOG2E;
  const float sc2e = 0.04419417382415922f * LOG2E;

  // ---- weight conversions (batched)
  wt_conv2<<<dim3(256, 2), b256, 0, stream>>>(
      Wq1, bq1, Wqk1, Wk1, bk1, Wqk1 + 256 * 544, 200, 200, 512, 544, 64, 50);
  wt_conv2<<<dim3(512, 2), b256, 0, stream>>>(
      Wv1, bv1, Wvs1, Ws1, bs1, Wvs1 + 512 * 544, 200, 200, 512, 544, 128, 50);
  wt_conv2<<<dim3(2048, 2), b256, 0, stream>>>(
      Wv2, bv2, Wcat, Ws2, bs2, Wcat + 2048 * 256, 2048, 2048, 200, 256, 2048, 2048);
  wt_trans2<<<dim3(1024, 2), b256, 0, stream>>>(Wq2, bq2, Qt, Wk2, bk2, Kt);
  trans_pad<<<dim3(9, 64), b256, 0, stream>>>(lr_x, xb, 512, 544);

  // ---- layer-1 projections (QK node-major; merged V+skip feature-major)
  mfma_bt<1, false><<<dim3(4, 32), b256, 0, stream>>>(
      xb, Wqk1, qk1b, 544, 544, 512, 544, 1, 0, 0, 0, -1, 0, -1, 4096, 1.f);
  mfma_bt<1, false><<<dim3(32, 8), b256, 0, stream>>>(
      Wvs1, xb, v1s, 544, 544, 4096, 544, 1, 0, 0, 0, -1, 0, -1, 1024, 1.f);

  // ---- attention 1 (fused, bf16 partials) + gn1 -> Xtb (bf16, + const rows)
  fused_attn1<<<dim3(32, 4, 4), b256, 0, stream>>>(qk1b, v1s, oP, r1p, sc1e);
  graph_norm_attn1<<<dim3(256), b256, 0, stream>>>(
      v1s + (size_t)512 * 4096, oP, r1p, Xtb, gn1w, gn1b, gn1ms);
  transb<<<dim3(4, 64), b256, 0, stream>>>(Xtb, h1nb);

  // ---- layer-2 V+skip projection (K=224)
  mfma_bt<1, false><<<dim3(32, 32), b256, 0, stream>>>(
      Wcat, h1nb, vs2b, 256, 256, 4096, 224, 1, 0, 0, 0, -1, 0, -1, 4096, 1.f);

  // ---- attention 2: low-rank T, then fused flash (no P, no V)
  mfma_bt<1, false><<<dim3(2, 2, 4), b256, 0, stream>>>(
      Kt, Qt, Mtall, 512, 512, 256, 512, 1,
      (size_t)256 * 512, (size_t)256 * 512, (size_t)256 * 256, -1, 0, -1, 256, 1.f);
  mfma_bt<1, false><<<dim3(2, 32, 4), b256, 0, stream>>>(
      h1nb, Mtall, Tall, 256, 256, 256, 224, 1,
      0, (size_t)256 * 256, (size_t)4096 * 256, -1, 0, -1, 4096, 1.f);
  fused_attn2<<<dim3(16, 4, 4), b512, 0, stream>>>(Tall, h1nb, Xtb, UpH, sc2e);
  combine_u<<<dim3(64, 4, 4), b256, 0, stream>>>(UpH, Usum, r2);
  // O = Wv . U  (bias rides via a==200 column; K=224)
  mfma_bt<1, false><<<dim3(32, 16), b256, 0, stream>>>(
      Wcat, Usum, Opl, 256, 256, 4096, 224, 1,
      0, 0, 0, 9, (size_t)4096 * 256, -1, 2048, 1.f);
  graph_norm_attn2<<<dim3(2048), b256, 0, stream>>>(
      vs2b + (size_t)2048 * 4096, Opl, r2, h2b, gn2w, gn2b, gn2ms);

  // ---- out = relu(h2n . h2n^T): K-split bf16 partials + reduce
  mfma256_8ph<1, false><<<dim3(8, 8, 4), b512, 0, stream>>>(
      h2b, h2b, g4, 4096, 4096, 2048, 4096, 4,
      0, 0, (size_t)2048 * 2048, -1, 0, 2048, 1.f);
  add4_relu_bf16<<<dim3(4096), b256, 0, stream>>>(g4, (float*)d_out);
}